// Round 8
// baseline (689.699 us; speedup 1.0000x reference)
//
#include <hip/hip_runtime.h>

#define N_USERS 40000
#define N_POIS  20000
#define DIM     128
#define N_EDGES 500000
#define BATCH   256
#define NPOS    100
#define TOPK    20
#define NCHUNK  128
#define CPT     313   // ceil(40000/128)
#define SCHUNK  1024  // scan chunk (256 thr x 4)
#define RCH     40    // ceil(40000/1024)
#define CCH     20    // ceil(20000/1024)
#define LOSS_BLOCKS 25  // 25600/1024

typedef _Float16 f16x8 __attribute__((ext_vector_type(8)));
typedef float f32x4 __attribute__((ext_vector_type(4)));

__device__ __forceinline__ int iclamp(int x, int lo, int hi) {
    return x < lo ? lo : (x > hi ? hi : x);
}
__device__ __forceinline__ float2 h2f2(unsigned int u) {
    union { unsigned int u32; _Float16 h[2]; } v; v.u32 = u;
    return make_float2((float)v.h[0], (float)v.h[1]);
}
__device__ __forceinline__ unsigned int f2h2(float x, float y) {
    union { unsigned int u32; _Float16 h[2]; } v;
    v.h[0] = (_Float16)x; v.h[1] = (_Float16)y; return v.u32;
}
__device__ __forceinline__ float softmax3(const float* p, int sel) {
    float a0 = p[0], a1 = p[1], a2 = p[2];
    float m = fmaxf(a0, fmaxf(a1, a2));
    float e0 = expf(a0 - m), e1 = expf(a1 - m), e2 = expf(a2 - m);
    float den = e0 + e1 + e2;
    float e = (sel == 0) ? e0 : ((sel == 1) ? e1 : e2);
    return e / den;
}
// compile-time channel pick from packed edge {idx, v0, v1, v2}
template<int CH>
__device__ __forceinline__ float pickvT(int4 q) {
    return __int_as_float(CH == 0 ? q.y : (CH == 1 ? q.z : q.w));
}
// build fp16x8 fragment from 8 contiguous fp32
__device__ __forceinline__ f16x8 frag8(const float* p) {
    float4 x = *(const float4*)(p);
    float4 y = *(const float4*)(p + 4);
    f16x8 f;
    f[0] = (_Float16)x.x; f[1] = (_Float16)x.y; f[2] = (_Float16)x.z; f[3] = (_Float16)x.w;
    f[4] = (_Float16)y.x; f[5] = (_Float16)y.y; f[6] = (_Float16)y.z; f[7] = (_Float16)y.w;
    return f;
}

// ---------------- zero init ----------------
__global__ void zero_kernel(unsigned int* __restrict__ p, int nwords) {
    int i = blockIdx.x * blockDim.x + threadIdx.x;
    if (i < nwords) p[i] = 0u;
}

// ---------------- fp32 -> fp16 cast ----------------
__global__ void cast_f16_kernel(const float* __restrict__ src, unsigned short* __restrict__ dst,
                                int n2) {
    int i = blockIdx.x * blockDim.x + threadIdx.x;
    if (i < n2) {
        float2 v = *(const float2*)(src + 2 * (size_t)i);
        *(unsigned int*)(dst + 2 * (size_t)i) = f2h2(v.x, v.y);
    }
}

// ---------------- CSR build ----------------
__global__ void hist_kernel(const int* __restrict__ er, const int* __restrict__ ec,
                            int* __restrict__ rcnt, int* __restrict__ ccnt) {
    int e = blockIdx.x * blockDim.x + threadIdx.x;
    if (e < N_EDGES) {
        atomicAdd(&rcnt[iclamp(er[e], 0, N_USERS - 1)], 1);
        atomicAdd(&ccnt[iclamp(ec[e], 0, N_POIS - 1)], 1);
    }
}

// ---------------- parallel prefix sum, stage 1: per-1024-chunk sums ----------------
__global__ void chunksum_kernel(const int* __restrict__ rcnt, const int* __restrict__ ccnt,
                                int* __restrict__ rsum, int* __restrict__ csum) {
    int side = blockIdx.y;
    const int* cnt = side ? ccnt : rcnt;
    int n = side ? N_POIS : N_USERS;
    int nch = side ? CCH : RCH;
    int b = blockIdx.x;
    if (b >= nch) return;
    int t = threadIdx.x;
    int i = b * SCHUNK + t * 4;
    int s = 0;
    if (i + 4 <= n) {
        int4 v = *(const int4*)(cnt + i);
        s = v.x + v.y + v.z + v.w;
    } else {
        for (int j = i; j < n; j++) s += cnt[j];
    }
    __shared__ int red[256];
    red[t] = s;
    __syncthreads();
    for (int o = 128; o > 0; o >>= 1) {
        if (t < o) red[t] += red[t + o];
        __syncthreads();
    }
    if (t == 0) (side ? csum : rsum)[b] = red[0];
}

// ---------------- stage 2: scan chunk sums (wave shfl), write totals ----------------
__global__ void chunkscan_kernel(const int* __restrict__ rsum, const int* __restrict__ csum,
                                 int* __restrict__ rbase, int* __restrict__ cbase,
                                 int* __restrict__ rptr, int* __restrict__ cptr) {
    int w = threadIdx.x >> 6, l = threadIdx.x & 63;  // block 128: wave0=users, wave1=pois
    const int* src = w ? csum : rsum;
    int* dst = w ? cbase : rbase;
    int nch = w ? CCH : RCH;
    int orig = (l < nch) ? src[l] : 0;
    int v = orig;
    #pragma unroll
    for (int o = 1; o < 64; o <<= 1) {
        int u = __shfl_up(v, o, 64);
        if (l >= o) v += u;
    }
    if (l < nch) dst[l] = v - orig;                 // exclusive base
    if (l == nch - 1) {
        if (w) cptr[N_POIS] = v; else rptr[N_USERS] = v;
    }
}

// ---------------- stage 3: block scan within chunk + chunk base ----------------
__global__ void scatterscan_kernel(const int* __restrict__ rcnt, const int* __restrict__ ccnt,
                                   const int* __restrict__ rbase, const int* __restrict__ cbase,
                                   int* __restrict__ rptr, int* __restrict__ cptr) {
    int side = blockIdx.y;
    const int* cnt = side ? ccnt : rcnt;
    const int* basea = side ? cbase : rbase;
    int* ptr = side ? cptr : rptr;
    int n = side ? N_POIS : N_USERS;
    int nch = side ? CCH : RCH;
    int b = blockIdx.x;
    if (b >= nch) return;
    int t = threadIdx.x;
    int i = b * SCHUNK + t * 4;
    int c0 = 0, c1 = 0, c2 = 0, c3 = 0;
    if (i + 4 <= n) {
        int4 v = *(const int4*)(cnt + i);
        c0 = v.x; c1 = v.y; c2 = v.z; c3 = v.w;
    } else {
        if (i + 0 < n) c0 = cnt[i + 0];
        if (i + 1 < n) c1 = cnt[i + 1];
        if (i + 2 < n) c2 = cnt[i + 2];
    }
    int tsum = c0 + c1 + c2 + c3;
    int l = t & 63, w = t >> 6;
    int v = tsum;
    #pragma unroll
    for (int o = 1; o < 64; o <<= 1) {
        int u = __shfl_up(v, o, 64);
        if (l >= o) v += u;
    }
    __shared__ int wsum[4];
    if (l == 63) wsum[w] = v;
    __syncthreads();
    int wbase = 0;
    for (int k = 0; k < w; k++) wbase += wsum[k];
    int ex = v - tsum + wbase + basea[b];
    if (i + 4 <= n) {
        *(int4*)(ptr + i) = make_int4(ex, ex + c0, ex + c0 + c1, ex + c0 + c1 + c2);
    } else {
        if (i + 0 < n) ptr[i + 0] = ex;
        if (i + 1 < n) ptr[i + 1] = ex + c0;
        if (i + 2 < n) ptr[i + 2] = ex + c0 + c1;
    }
}

// ---------------- AoS CSR fill: 4 edges/thread for MLP; 2 x 16B stores per edge ----------------
__global__ void fill_kernel(const int* __restrict__ er, const int* __restrict__ ec,
                            const int* __restrict__ rptr, const int* __restrict__ cptr,
                            int* __restrict__ rcur, int* __restrict__ ccur,
                            int4* __restrict__ rpack, int4* __restrict__ cpack,
                            const float* __restrict__ ck, const float* __restrict__ fv,
                            const float* __restrict__ cs) {
    int e0 = 4 * (blockIdx.x * blockDim.x + threadIdx.x);
    if (e0 + 4 <= N_EDGES) {
        int4 r4 = *(const int4*)(er + e0);
        int4 c4 = *(const int4*)(ec + e0);
        float4 k4 = *(const float4*)(ck + e0);
        float4 f4 = *(const float4*)(fv + e0);
        float4 s4 = *(const float4*)(cs + e0);
        int rr[4] = { r4.x, r4.y, r4.z, r4.w };
        int cc[4] = { c4.x, c4.y, c4.z, c4.w };
        float kk[4] = { k4.x, k4.y, k4.z, k4.w };
        float ff[4] = { f4.x, f4.y, f4.z, f4.w };
        float ss[4] = { s4.x, s4.y, s4.z, s4.w };
        #pragma unroll
        for (int j = 0; j < 4; j++) {
            int r = iclamp(rr[j], 0, N_USERS - 1), c = iclamp(cc[j], 0, N_POIS - 1);
            int v0 = __float_as_int(kk[j]);
            int v1 = __float_as_int(ff[j]);
            int v2 = __float_as_int(ss[j]);
            int pr = iclamp(rptr[r] + atomicAdd(&rcur[r], 1), 0, N_EDGES - 1);
            rpack[pr] = make_int4(c, v0, v1, v2);
            int pc = iclamp(cptr[c] + atomicAdd(&ccur[c], 1), 0, N_EDGES - 1);
            cpack[pc] = make_int4(r, v0, v1, v2);
        }
    } else {
        for (int e = e0; e < N_EDGES; e++) {
            int r = iclamp(er[e], 0, N_USERS - 1), c = iclamp(ec[e], 0, N_POIS - 1);
            int v0 = __float_as_int(ck[e]);
            int v1 = __float_as_int(fv[e]);
            int v2 = __float_as_int(cs[e]);
            int pr = iclamp(rptr[r] + atomicAdd(&rcur[r], 1), 0, N_EDGES - 1);
            rpack[pr] = make_int4(c, v0, v1, v2);
            int pc = iclamp(cptr[c] + atomicAdd(&ccur[c], 1), 0, N_EDGES - 1);
            cpack[pc] = make_int4(r, v0, v1, v2);
        }
    }
}

// ---------------- SpMM: one wave per row; packed edges; fp16 src gather ----------------
// raw_h (fp16) = A*src ; acc (fp32) = base + raw/||raw||
template<int CH>
__global__ __launch_bounds__(256) void spmm_kernel(
        const int* __restrict__ ptr, const int4* __restrict__ pack,
        const unsigned short* __restrict__ src,         // fp16 [*,128]
        unsigned short* __restrict__ raw_h,             // fp16 out
        const float* __restrict__ base,                 // fp32 (may alias acc)
        float* __restrict__ acc, int nrows) {
    int wid = (blockIdx.x * blockDim.x + threadIdx.x) >> 6;
    int lane = threadIdx.x & 63;
    if (wid >= nrows) return;
    int beg = __builtin_amdgcn_readfirstlane(iclamp(ptr[wid], 0, N_EDGES));
    int end = __builtin_amdgcn_readfirstlane(iclamp(ptr[wid + 1], 0, N_EDGES));
    if (end < beg) end = beg;
    float ax = 0.f, ay = 0.f;
    int e = beg;
    int lo2 = lane * 2;
    for (; e + 8 <= end; e += 8) {
        int4 q0 = pack[e + 0], q1 = pack[e + 1], q2 = pack[e + 2], q3 = pack[e + 3];
        int4 q4 = pack[e + 4], q5 = pack[e + 5], q6 = pack[e + 6], q7 = pack[e + 7];
        float v0 = pickvT<CH>(q0), v1 = pickvT<CH>(q1), v2 = pickvT<CH>(q2), v3 = pickvT<CH>(q3);
        float v4 = pickvT<CH>(q4), v5 = pickvT<CH>(q5), v6 = pickvT<CH>(q6), v7 = pickvT<CH>(q7);
        float2 p0 = h2f2(*(const unsigned int*)(src + (size_t)q0.x * DIM + lo2));
        float2 p1 = h2f2(*(const unsigned int*)(src + (size_t)q1.x * DIM + lo2));
        float2 p2 = h2f2(*(const unsigned int*)(src + (size_t)q2.x * DIM + lo2));
        float2 p3 = h2f2(*(const unsigned int*)(src + (size_t)q3.x * DIM + lo2));
        float2 p4 = h2f2(*(const unsigned int*)(src + (size_t)q4.x * DIM + lo2));
        float2 p5 = h2f2(*(const unsigned int*)(src + (size_t)q5.x * DIM + lo2));
        float2 p6 = h2f2(*(const unsigned int*)(src + (size_t)q6.x * DIM + lo2));
        float2 p7 = h2f2(*(const unsigned int*)(src + (size_t)q7.x * DIM + lo2));
        ax = fmaf(v0, p0.x, fmaf(v1, p1.x, fmaf(v2, p2.x, fmaf(v3, p3.x, ax))));
        ax = fmaf(v4, p4.x, fmaf(v5, p5.x, fmaf(v6, p6.x, fmaf(v7, p7.x, ax))));
        ay = fmaf(v0, p0.y, fmaf(v1, p1.y, fmaf(v2, p2.y, fmaf(v3, p3.y, ay))));
        ay = fmaf(v4, p4.y, fmaf(v5, p5.y, fmaf(v6, p6.y, fmaf(v7, p7.y, ay))));
    }
    if (e < end) {
        int last = end - 1;
        int e1 = e + 1 <= last ? e + 1 : last;
        int e2 = e + 2 <= last ? e + 2 : last;
        int e3 = e + 3 <= last ? e + 3 : last;
        int e4 = e + 4 <= last ? e + 4 : last;
        int e5 = e + 5 <= last ? e + 5 : last;
        int e6 = e + 6 <= last ? e + 6 : last;
        int e7 = e + 7 <= last ? e + 7 : last;
        int4 q0 = pack[e], q1 = pack[e1], q2 = pack[e2], q3 = pack[e3];
        int4 q4 = pack[e4], q5 = pack[e5], q6 = pack[e6], q7 = pack[e7];
        float v0 = pickvT<CH>(q0);
        float v1 = (e + 1 < end) ? pickvT<CH>(q1) : 0.f;
        float v2 = (e + 2 < end) ? pickvT<CH>(q2) : 0.f;
        float v3 = (e + 3 < end) ? pickvT<CH>(q3) : 0.f;
        float v4 = (e + 4 < end) ? pickvT<CH>(q4) : 0.f;
        float v5 = (e + 5 < end) ? pickvT<CH>(q5) : 0.f;
        float v6 = (e + 6 < end) ? pickvT<CH>(q6) : 0.f;
        float v7 = (e + 7 < end) ? pickvT<CH>(q7) : 0.f;
        float2 p0 = h2f2(*(const unsigned int*)(src + (size_t)q0.x * DIM + lo2));
        float2 p1 = h2f2(*(const unsigned int*)(src + (size_t)q1.x * DIM + lo2));
        float2 p2 = h2f2(*(const unsigned int*)(src + (size_t)q2.x * DIM + lo2));
        float2 p3 = h2f2(*(const unsigned int*)(src + (size_t)q3.x * DIM + lo2));
        float2 p4 = h2f2(*(const unsigned int*)(src + (size_t)q4.x * DIM + lo2));
        float2 p5 = h2f2(*(const unsigned int*)(src + (size_t)q5.x * DIM + lo2));
        float2 p6 = h2f2(*(const unsigned int*)(src + (size_t)q6.x * DIM + lo2));
        float2 p7 = h2f2(*(const unsigned int*)(src + (size_t)q7.x * DIM + lo2));
        ax = fmaf(v0, p0.x, fmaf(v1, p1.x, fmaf(v2, p2.x, fmaf(v3, p3.x, ax))));
        ax = fmaf(v4, p4.x, fmaf(v5, p5.x, fmaf(v6, p6.x, fmaf(v7, p7.x, ax))));
        ay = fmaf(v0, p0.y, fmaf(v1, p1.y, fmaf(v2, p2.y, fmaf(v3, p3.y, ay))));
        ay = fmaf(v4, p4.y, fmaf(v5, p5.y, fmaf(v6, p6.y, fmaf(v7, p7.y, ay))));
    }
    float n2 = ax * ax + ay * ay;
    #pragma unroll
    for (int o = 32; o > 0; o >>= 1) n2 += __shfl_xor(n2, o, 64);
    float inv = rsqrtf(fmaxf(n2, 1e-30f));
    *(unsigned int*)(raw_h + (size_t)wid * DIM + lo2) = f2h2(ax, ay);
    float2 bv = *(const float2*)(base + (size_t)wid * DIM + lo2);
    *(float2*)(acc + (size_t)wid * DIM + lo2) =
        make_float2(bv.x + ax * inv, bv.y + ay * inv);
}

// ---------------- fused 3-channel L1-user SpMM: shared gather, 3 raw outputs ----------------
__global__ __launch_bounds__(256) void spmm3_kernel(
        const int* __restrict__ ptr, const int4* __restrict__ pack,
        const unsigned short* __restrict__ src,     // pid_h (shared across channels)
        unsigned short* __restrict__ r0, unsigned short* __restrict__ r1,
        unsigned short* __restrict__ r2, int nrows) {
    int wid = (blockIdx.x * blockDim.x + threadIdx.x) >> 6;
    int lane = threadIdx.x & 63;
    if (wid >= nrows) return;
    int beg = __builtin_amdgcn_readfirstlane(iclamp(ptr[wid], 0, N_EDGES));
    int end = __builtin_amdgcn_readfirstlane(iclamp(ptr[wid + 1], 0, N_EDGES));
    if (end < beg) end = beg;
    float a0x = 0.f, a0y = 0.f, a1x = 0.f, a1y = 0.f, a2x = 0.f, a2y = 0.f;
    int e = beg;
    int lo2 = lane * 2;
    for (; e + 4 <= end; e += 4) {
        int4 q0 = pack[e + 0], q1 = pack[e + 1], q2 = pack[e + 2], q3 = pack[e + 3];
        float2 p0 = h2f2(*(const unsigned int*)(src + (size_t)q0.x * DIM + lo2));
        float2 p1 = h2f2(*(const unsigned int*)(src + (size_t)q1.x * DIM + lo2));
        float2 p2 = h2f2(*(const unsigned int*)(src + (size_t)q2.x * DIM + lo2));
        float2 p3 = h2f2(*(const unsigned int*)(src + (size_t)q3.x * DIM + lo2));
        a0x = fmaf(__int_as_float(q0.y), p0.x, fmaf(__int_as_float(q1.y), p1.x,
              fmaf(__int_as_float(q2.y), p2.x, fmaf(__int_as_float(q3.y), p3.x, a0x))));
        a0y = fmaf(__int_as_float(q0.y), p0.y, fmaf(__int_as_float(q1.y), p1.y,
              fmaf(__int_as_float(q2.y), p2.y, fmaf(__int_as_float(q3.y), p3.y, a0y))));
        a1x = fmaf(__int_as_float(q0.z), p0.x, fmaf(__int_as_float(q1.z), p1.x,
              fmaf(__int_as_float(q2.z), p2.x, fmaf(__int_as_float(q3.z), p3.x, a1x))));
        a1y = fmaf(__int_as_float(q0.z), p0.y, fmaf(__int_as_float(q1.z), p1.y,
              fmaf(__int_as_float(q2.z), p2.y, fmaf(__int_as_float(q3.z), p3.y, a1y))));
        a2x = fmaf(__int_as_float(q0.w), p0.x, fmaf(__int_as_float(q1.w), p1.x,
              fmaf(__int_as_float(q2.w), p2.x, fmaf(__int_as_float(q3.w), p3.x, a2x))));
        a2y = fmaf(__int_as_float(q0.w), p0.y, fmaf(__int_as_float(q1.w), p1.y,
              fmaf(__int_as_float(q2.w), p2.y, fmaf(__int_as_float(q3.w), p3.y, a2y))));
    }
    for (; e < end; e++) {
        int4 q = pack[e];
        float2 p = h2f2(*(const unsigned int*)(src + (size_t)q.x * DIM + lo2));
        a0x = fmaf(__int_as_float(q.y), p.x, a0x);
        a0y = fmaf(__int_as_float(q.y), p.y, a0y);
        a1x = fmaf(__int_as_float(q.z), p.x, a1x);
        a1y = fmaf(__int_as_float(q.z), p.y, a1y);
        a2x = fmaf(__int_as_float(q.w), p.x, a2x);
        a2y = fmaf(__int_as_float(q.w), p.y, a2y);
    }
    size_t o = (size_t)wid * DIM + lo2;
    *(unsigned int*)(r0 + o) = f2h2(a0x, a0y);
    *(unsigned int*)(r1 + o) = f2h2(a1x, a1y);
    *(unsigned int*)(r2 + o) = f2h2(a2x, a2y);
}

// ---------------- L2-user SpMM: su = uid + n(u1) + n(u2); u1raw overwritten with u2 ----------------
template<int CH>
__global__ __launch_bounds__(256) void spmm_l2u_kernel(
        const int* __restrict__ ptr, const int4* __restrict__ pack,
        const unsigned short* __restrict__ src,     // ptr_h (p1 raw fp16)
        unsigned short* __restrict__ u1raw,         // in: u1 raw; out: u2 raw
        const float* __restrict__ uid,
        float* __restrict__ su, int nrows) {
    int wid = (blockIdx.x * blockDim.x + threadIdx.x) >> 6;
    int lane = threadIdx.x & 63;
    if (wid >= nrows) return;
    int beg = __builtin_amdgcn_readfirstlane(iclamp(ptr[wid], 0, N_EDGES));
    int end = __builtin_amdgcn_readfirstlane(iclamp(ptr[wid + 1], 0, N_EDGES));
    if (end < beg) end = beg;
    float ax = 0.f, ay = 0.f;
    int e = beg;
    int lo2 = lane * 2;
    for (; e + 8 <= end; e += 8) {
        int4 q0 = pack[e + 0], q1 = pack[e + 1], q2 = pack[e + 2], q3 = pack[e + 3];
        int4 q4 = pack[e + 4], q5 = pack[e + 5], q6 = pack[e + 6], q7 = pack[e + 7];
        float v0 = pickvT<CH>(q0), v1 = pickvT<CH>(q1), v2 = pickvT<CH>(q2), v3 = pickvT<CH>(q3);
        float v4 = pickvT<CH>(q4), v5 = pickvT<CH>(q5), v6 = pickvT<CH>(q6), v7 = pickvT<CH>(q7);
        float2 p0 = h2f2(*(const unsigned int*)(src + (size_t)q0.x * DIM + lo2));
        float2 p1 = h2f2(*(const unsigned int*)(src + (size_t)q1.x * DIM + lo2));
        float2 p2 = h2f2(*(const unsigned int*)(src + (size_t)q2.x * DIM + lo2));
        float2 p3 = h2f2(*(const unsigned int*)(src + (size_t)q3.x * DIM + lo2));
        float2 p4 = h2f2(*(const unsigned int*)(src + (size_t)q4.x * DIM + lo2));
        float2 p5 = h2f2(*(const unsigned int*)(src + (size_t)q5.x * DIM + lo2));
        float2 p6 = h2f2(*(const unsigned int*)(src + (size_t)q6.x * DIM + lo2));
        float2 p7 = h2f2(*(const unsigned int*)(src + (size_t)q7.x * DIM + lo2));
        ax = fmaf(v0, p0.x, fmaf(v1, p1.x, fmaf(v2, p2.x, fmaf(v3, p3.x, ax))));
        ax = fmaf(v4, p4.x, fmaf(v5, p5.x, fmaf(v6, p6.x, fmaf(v7, p7.x, ax))));
        ay = fmaf(v0, p0.y, fmaf(v1, p1.y, fmaf(v2, p2.y, fmaf(v3, p3.y, ay))));
        ay = fmaf(v4, p4.y, fmaf(v5, p5.y, fmaf(v6, p6.y, fmaf(v7, p7.y, ay))));
    }
    if (e < end) {
        int last = end - 1;
        int e1 = e + 1 <= last ? e + 1 : last;
        int e2 = e + 2 <= last ? e + 2 : last;
        int e3 = e + 3 <= last ? e + 3 : last;
        int e4 = e + 4 <= last ? e + 4 : last;
        int e5 = e + 5 <= last ? e + 5 : last;
        int e6 = e + 6 <= last ? e + 6 : last;
        int e7 = e + 7 <= last ? e + 7 : last;
        int4 q0 = pack[e], q1 = pack[e1], q2 = pack[e2], q3 = pack[e3];
        int4 q4 = pack[e4], q5 = pack[e5], q6 = pack[e6], q7 = pack[e7];
        float v0 = pickvT<CH>(q0);
        float v1 = (e + 1 < end) ? pickvT<CH>(q1) : 0.f;
        float v2 = (e + 2 < end) ? pickvT<CH>(q2) : 0.f;
        float v3 = (e + 3 < end) ? pickvT<CH>(q3) : 0.f;
        float v4 = (e + 4 < end) ? pickvT<CH>(q4) : 0.f;
        float v5 = (e + 5 < end) ? pickvT<CH>(q5) : 0.f;
        float v6 = (e + 6 < end) ? pickvT<CH>(q6) : 0.f;
        float v7 = (e + 7 < end) ? pickvT<CH>(q7) : 0.f;
        float2 p0 = h2f2(*(const unsigned int*)(src + (size_t)q0.x * DIM + lo2));
        float2 p1 = h2f2(*(const unsigned int*)(src + (size_t)q1.x * DIM + lo2));
        float2 p2 = h2f2(*(const unsigned int*)(src + (size_t)q2.x * DIM + lo2));
        float2 p3 = h2f2(*(const unsigned int*)(src + (size_t)q3.x * DIM + lo2));
        float2 p4 = h2f2(*(const unsigned int*)(src + (size_t)q4.x * DIM + lo2));
        float2 p5 = h2f2(*(const unsigned int*)(src + (size_t)q5.x * DIM + lo2));
        float2 p6 = h2f2(*(const unsigned int*)(src + (size_t)q6.x * DIM + lo2));
        float2 p7 = h2f2(*(const unsigned int*)(src + (size_t)q7.x * DIM + lo2));
        ax = fmaf(v0, p0.x, fmaf(v1, p1.x, fmaf(v2, p2.x, fmaf(v3, p3.x, ax))));
        ax = fmaf(v4, p4.x, fmaf(v5, p5.x, fmaf(v6, p6.x, fmaf(v7, p7.x, ax))));
        ay = fmaf(v0, p0.y, fmaf(v1, p1.y, fmaf(v2, p2.y, fmaf(v3, p3.y, ay))));
        ay = fmaf(v4, p4.y, fmaf(v5, p5.y, fmaf(v6, p6.y, fmaf(v7, p7.y, ay))));
    }
    size_t o = (size_t)wid * DIM + lo2;
    float2 u1 = h2f2(*(const unsigned int*)(u1raw + o));
    float n2a = ax * ax + ay * ay;        // u2
    float n2b = u1.x * u1.x + u1.y * u1.y; // u1
    #pragma unroll
    for (int oo = 32; oo > 0; oo >>= 1) {
        n2a += __shfl_xor(n2a, oo, 64);
        n2b += __shfl_xor(n2b, oo, 64);
    }
    float i2 = rsqrtf(fmaxf(n2a, 1e-30f));
    float i1 = rsqrtf(fmaxf(n2b, 1e-30f));
    *(unsigned int*)(u1raw + o) = f2h2(ax, ay);   // u2 raw (src for L2-poi)
    float2 bv = *(const float2*)(uid + o);
    *(float2*)(su + o) = make_float2(bv.x + u1.x * i1 + ax * i2,
                                     bv.y + u1.y * i1 + ay * i2);
}

// ---------------- MFMA: out[Mx128] = A[Mx128] @ W^T ; fp32 in, fp16 frags, fp32 accum ----------------
__global__ __launch_bounds__(256) void gemm_mfma_kernel(
        const float* __restrict__ A, const float* __restrict__ W,
        float* __restrict__ store, float* __restrict__ accum,
        _Float16* __restrict__ accum_h,
        const float* __restrict__ fw3, int fsel, int first, int M) {
    int w = threadIdx.x >> 6, l = threadIdx.x & 63;
    int lg = l >> 4, lc = l & 15;
    int j0 = w * 32;
    float coef = accum ? softmax3(fw3, fsel) : 0.f;
    f16x8 Bf[2][4];
    #pragma unroll
    for (int t = 0; t < 2; t++) {
        const float* wr = W + (size_t)(j0 + t * 16 + lc) * DIM + lg * 8;
        #pragma unroll
        for (int s = 0; s < 4; s++) Bf[t][s] = frag8(wr + s * 32);
    }
    int base = blockIdx.x * 64;
    #pragma unroll
    for (int rt = 0; rt < 4; rt++) {
        int u0 = base + rt * 16;
        int ar = u0 + lc; if (ar > M - 1) ar = M - 1;
        const float* arow = A + (size_t)ar * DIM + lg * 8;
        f16x8 Af[4];
        #pragma unroll
        for (int s = 0; s < 4; s++) Af[s] = frag8(arow + s * 32);
        f32x4 acc0 = {0.f, 0.f, 0.f, 0.f};
        f32x4 acc1 = {0.f, 0.f, 0.f, 0.f};
        #pragma unroll
        for (int s = 0; s < 4; s++) {
            acc0 = __builtin_amdgcn_mfma_f32_16x16x32_f16(Af[s], Bf[0][s], acc0, 0, 0, 0);
            acc1 = __builtin_amdgcn_mfma_f32_16x16x32_f16(Af[s], Bf[1][s], acc1, 0, 0, 0);
        }
        int rbase = u0 + lg * 4;
        #pragma unroll
        for (int r = 0; r < 4; r++) {
            int row = rbase + r;
            if (row >= M) continue;
            size_t o0 = (size_t)row * DIM + j0 + lc;
            size_t o1 = o0 + 16;
            if (store) { store[o0] = acc0[r]; store[o1] = acc1[r]; }
            if (accum) {
                float p0 = first ? 0.f : accum[o0];
                float p1 = first ? 0.f : accum[o1];
                float n0 = p0 + coef * acc0[r];
                float n1 = p1 + coef * acc1[r];
                accum[o0] = n0;
                accum[o1] = n1;
                if (accum_h) {
                    accum_h[o0] = (_Float16)n0;
                    accum_h[o1] = (_Float16)n1;
                }
            }
        }
    }
}

// ---------------- 256 selected rows of uf = su @ Wu^T ----------------
__global__ void ufsel_kernel(const float* __restrict__ su, const float* __restrict__ W,
                             const int* __restrict__ uidx, float* __restrict__ outsel) {
    int b = blockIdx.x, j = threadIdx.x;  // block 128
    __shared__ float ar[128];
    int u = iclamp(uidx[b], 0, N_USERS - 1);
    ar[j] = su[(size_t)u * DIM + j];
    __syncthreads();
    const float4* Wr = (const float4*)(W + (size_t)j * DIM);
    float acc = 0.f;
    #pragma unroll 8
    for (int q = 0; q < 32; q++) {
        float4 wq = Wr[q];
        acc = fmaf(ar[4 * q + 0], wq.x, acc);
        acc = fmaf(ar[4 * q + 1], wq.y, acc);
        acc = fmaf(ar[4 * q + 2], wq.z, acc);
        acc = fmaf(ar[4 * q + 3], wq.w, acc);
    }
    outsel[(size_t)b * DIM + j] = acc;
}

// ---------------- alt[b,j] (+)= wn_c * dot(uf_c[b], pf_c[poi]) ----------------
__global__ __launch_bounds__(256) void predict_kernel(
        const float* __restrict__ ufs, const float* __restrict__ pf,
        const int* __restrict__ pidx, const float* __restrict__ w3,
        int wsel, int first, float* __restrict__ alt) {
    int wid = (blockIdx.x * blockDim.x + threadIdx.x) >> 6;
    int lane = threadIdx.x & 63;
    if (wid >= BATCH * NPOS) return;
    int b = wid / NPOS;
    int poi = iclamp(pidx[wid], 0, N_POIS - 1);
    const float2 uv = *(const float2*)(ufs + (size_t)b * DIM + lane * 2);
    const float2 pv = *(const float2*)(pf + (size_t)poi * DIM + lane * 2);
    float s = uv.x * pv.x + uv.y * pv.y;
    #pragma unroll
    for (int o = 32; o > 0; o >>= 1) s += __shfl_xor(s, o, 64);
    if (lane == 0) {
        float coef = softmax3(w3, wsel);
        float prev = first ? 0.f : alt[wid];
        alt[wid] = prev + coef * s;
    }
}

// ---------------- BCE loss: stage 1 partials (25 blocks) ----------------
__global__ void loss_part_kernel(const float* __restrict__ alt, const float* __restrict__ labels,
                                 float* __restrict__ part) {
    int b = blockIdx.x, t = threadIdx.x;
    int i = b * 1024 + t * 4;
    float4 x4 = *(const float4*)(alt + i);
    float4 y4 = *(const float4*)(labels + i);
    float s = 0.f;
    s += fmaxf(x4.x, 0.f) - x4.x * y4.x + log1pf(expf(-fabsf(x4.x)));
    s += fmaxf(x4.y, 0.f) - x4.y * y4.y + log1pf(expf(-fabsf(x4.y)));
    s += fmaxf(x4.z, 0.f) - x4.z * y4.z + log1pf(expf(-fabsf(x4.z)));
    s += fmaxf(x4.w, 0.f) - x4.w * y4.w + log1pf(expf(-fabsf(x4.w)));
    __shared__ float red[256];
    red[t] = s;
    __syncthreads();
    for (int o = 128; o > 0; o >>= 1) {
        if (t < o) red[t] += red[t + o];
        __syncthreads();
    }
    if (t == 0) part[b] = red[0];
}

// ---------------- BCE loss: stage 2 final (deterministic) ----------------
__global__ void loss_final_kernel(const float* __restrict__ part, float* __restrict__ out) {
    if (threadIdx.x == 0) {
        float s = 0.f;
        #pragma unroll
        for (int b = 0; b < LOSS_BLOCKS; b++) s += part[b];
        out[0] = s / (float)(BATCH * NPOS);
    }
}

// ---------------- bst_h[b][j] = id_feat[cur[b]] @ Ws^T + bias (fp16, row-major) ----------------
__global__ void bs_kernel(const float* __restrict__ idf, const float* __restrict__ Ws,
                          const float* __restrict__ bias, const int* __restrict__ uidx,
                          _Float16* __restrict__ bst_h) {
    int b = blockIdx.x, j = threadIdx.x;  // block 128
    __shared__ float ar[128];
    int u = iclamp(uidx[b], 0, N_USERS - 1);
    ar[j] = idf[(size_t)u * DIM + j];
    __syncthreads();
    const float4* Wr = (const float4*)(Ws + (size_t)j * DIM);
    float acc = 0.f;
    #pragma unroll 8
    for (int q = 0; q < 32; q++) {
        float4 wq = Wr[q];
        acc = fmaf(ar[4 * q + 0], wq.x, acc);
        acc = fmaf(ar[4 * q + 1], wq.y, acc);
        acc = fmaf(ar[4 * q + 2], wq.z, acc);
        acc = fmaf(ar[4 * q + 3], wq.w, acc);
    }
    bst_h[(size_t)b * DIM + j] = (_Float16)(acc + bias[j]);
}

__device__ __forceinline__ void topk_insert(float s, int u, float* ts, int* ti) {
    if (s > ts[TOPK - 1]) {
        #pragma unroll
        for (int j = TOPK - 1; j > 0; --j) {
            bool above = s > ts[j - 1];
            bool here = (!above) && (s > ts[j]);
            float nv = above ? ts[j - 1] : (here ? s : ts[j]);
            int ni = above ? ti[j - 1] : (here ? u : ti[j]);
            ts[j] = nv; ti[j] = ni;
        }
        if (s > ts[0]) { ts[0] = s; ti[0] = u; }
    }
}

// ---------------- MFMA uu scores + per-block top-20: 512 thr, 8 waves ----------------
// waves 0-3: lower user half of chunk; waves 4-7: upper half. Same 64 batch cols.
// Per batch col: 8 disjoint lists (2 halves x 4 lane groups) -> 8-way merge.
__global__ __launch_bounds__(512) void score_topk_kernel(
        const _Float16* __restrict__ idf_h, const _Float16* __restrict__ bst_h,
        float* __restrict__ cand_s, int* __restrict__ cand_i) {
    __shared__ __align__(16) unsigned char smraw[61440];
    float* ms = (float*)smraw;                              // [20][512] 40 KB
    unsigned short* mi = (unsigned short*)(smraw + 40960);  // [20][512] 20 KB
    int cid = blockIdx.x, bg = blockIdx.y;
    int tid = threadIdx.x;
    int w = tid >> 6, l = tid & 63;
    int half = w >> 2, wq = w & 3;
    int lg = l >> 4, lc = l & 15;
    const _Float16* bbase = bst_h + ((size_t)(bg * 64 + wq * 16 + lc)) * DIM + lg * 8;
    f16x8 B0 = *(const f16x8*)(bbase + 0);
    f16x8 B1 = *(const f16x8*)(bbase + 32);
    f16x8 B2 = *(const f16x8*)(bbase + 64);
    f16x8 B3 = *(const f16x8*)(bbase + 96);
    float ts[TOPK]; int ti[TOPK];
    #pragma unroll
    for (int k = 0; k < TOPK; k++) { ts[k] = -3.0e38f; ti[k] = 0; }
    int lo = cid * CPT;
    int hi = lo + CPT; if (hi > N_USERS) hi = N_USERS;
    int ntiles = (hi - lo + 15) >> 4;
    int t0 = half ? (ntiles >> 1) : 0;
    int t1 = half ? ntiles : (ntiles >> 1);
    #pragma unroll 2
    for (int t = t0; t < t1; t++) {
        int u0 = lo + t * 16;
        int ar = u0 + lc; if (ar > N_USERS - 1) ar = N_USERS - 1;
        const _Float16* abase = idf_h + (size_t)ar * DIM + lg * 8;
        f16x8 A0 = *(const f16x8*)(abase + 0);
        f16x8 A1 = *(const f16x8*)(abase + 32);
        f16x8 A2 = *(const f16x8*)(abase + 64);
        f16x8 A3 = *(const f16x8*)(abase + 96);
        f32x4 accA = {0.f, 0.f, 0.f, 0.f};
        f32x4 accB = {0.f, 0.f, 0.f, 0.f};
        accA = __builtin_amdgcn_mfma_f32_16x16x32_f16(A0, B0, accA, 0, 0, 0);
        accB = __builtin_amdgcn_mfma_f32_16x16x32_f16(A1, B1, accB, 0, 0, 0);
        accA = __builtin_amdgcn_mfma_f32_16x16x32_f16(A2, B2, accA, 0, 0, 0);
        accB = __builtin_amdgcn_mfma_f32_16x16x32_f16(A3, B3, accB, 0, 0, 0);
        int ub = u0 + lg * 4;
        #pragma unroll
        for (int r = 0; r < 4; r++) {
            float s = accA[r] + accB[r];
            int u = ub + r;
            if (u < hi) topk_insert(s, u, ts, ti);
        }
    }
    #pragma unroll
    for (int k = 0; k < TOPK; k++) {
        ms[k * 512 + tid] = ts[k];
        mi[k * 512 + tid] = (unsigned short)ti[k];
    }
    __syncthreads();
    if (tid < 64) {
        int wm = tid >> 4, cm = tid & 15;
        // 8 source threads for this (wave-quad, col): h in {0,1} x lg in {0..3}
        int s0 = 0 * 256 + wm * 64 + 0 * 16 + cm;
        int s1 = s0 + 16, s2 = s0 + 32, s3 = s0 + 48;
        int s4 = s0 + 256, s5 = s1 + 256, s6 = s2 + 256, s7 = s3 + 256;
        int p0 = 0, p1 = 0, p2 = 0, p3 = 0, p4 = 0, p5 = 0, p6 = 0, p7 = 0;
        size_t ob = ((size_t)cid * 256 + bg * 64 + wm * 16 + cm) * TOPK;
        for (int k = 0; k < TOPK; k++) {
            float h0 = ms[p0 * 512 + s0];
            float h1 = ms[p1 * 512 + s1];
            float h2 = ms[p2 * 512 + s2];
            float h3 = ms[p3 * 512 + s3];
            float h4 = ms[p4 * 512 + s4];
            float h5 = ms[p5 * 512 + s5];
            float h6 = ms[p6 * 512 + s6];
            float h7 = ms[p7 * 512 + s7];
            float best = h0; int which = 0;
            if (h1 > best) { best = h1; which = 1; }
            if (h2 > best) { best = h2; which = 2; }
            if (h3 > best) { best = h3; which = 3; }
            if (h4 > best) { best = h4; which = 4; }
            if (h5 > best) { best = h5; which = 5; }
            if (h6 > best) { best = h6; which = 6; }
            if (h7 > best) { best = h7; which = 7; }
            int idx;
            if (which == 0)      { idx = mi[p0 * 512 + s0]; p0++; }
            else if (which == 1) { idx = mi[p1 * 512 + s1]; p1++; }
            else if (which == 2) { idx = mi[p2 * 512 + s2]; p2++; }
            else if (which == 3) { idx = mi[p3 * 512 + s3]; p3++; }
            else if (which == 4) { idx = mi[p4 * 512 + s4]; p4++; }
            else if (which == 5) { idx = mi[p5 * 512 + s5]; p5++; }
            else if (which == 6) { idx = mi[p6 * 512 + s6]; p6++; }
            else                 { idx = mi[p7 * 512 + s7]; p7++; }
            cand_s[ob + k] = best;
            cand_i[ob + k] = idx;
        }
    }
}

// ---------------- global merge + softmax + weighted gather ----------------
__global__ void topk_merge_kernel(const float* __restrict__ cand_s, const int* __restrict__ cand_i,
                                  const float* __restrict__ guf,
                                  float* __restrict__ outp) {
    int b = blockIdx.x, t = threadIdx.x;  // block 128 (= NCHUNK)
    __shared__ float rs[NCHUNK]; __shared__ int ru[NCHUNK]; __shared__ int rt[NCHUNK];
    __shared__ float win_s[TOPK]; __shared__ int win_u[TOPK]; __shared__ float wk[TOPK];
    __shared__ int winner;
    int ptr = 0;
    size_t base = ((size_t)t * 256 + b) * TOPK;
    for (int k = 0; k < TOPK; k++) {
        rs[t] = (ptr < TOPK) ? cand_s[base + ptr] : -3.0e38f;
        ru[t] = (ptr < TOPK) ? cand_i[base + ptr] : 0;
        rt[t] = t;
        __syncthreads();
        for (int off = NCHUNK / 2; off > 0; off >>= 1) {
            if (t < off && rs[t + off] > rs[t]) {
                rs[t] = rs[t + off]; ru[t] = ru[t + off]; rt[t] = rt[t + off];
            }
            __syncthreads();
        }
        if (t == 0) { win_s[k] = rs[0]; win_u[k] = iclamp(ru[0], 0, N_USERS - 1); winner = rt[0]; }
        __syncthreads();
        if (t == winner) ptr++;
        __syncthreads();
    }
    if (t == 0) {
        float m = win_s[0], den = 0.f;
        for (int k = 0; k < TOPK; k++) { wk[k] = expf(win_s[k] - m); den += wk[k]; }
        float inv = 1.f / den;
        for (int k = 0; k < TOPK; k++) wk[k] *= inv;
    }
    __syncthreads();
    float acc = 0.f;
    #pragma unroll
    for (int k = 0; k < TOPK; k++)
        acc = fmaf(wk[k], guf[(size_t)win_u[k] * DIM + t], acc);
    outp[1 + (size_t)b * DIM + t] = acc;
}

extern "C" void kernel_launch(void* const* d_in, const int* in_sizes, int n_in,
                              void* d_out, int out_size, void* d_ws, size_t ws_size,
                              hipStream_t stream) {
    (void)in_sizes; (void)n_in; (void)out_size;
    const int*   er      = (const int*)d_in[0];
    const int*   ec      = (const int*)d_in[1];
    const float* click   = (const float*)d_in[2];
    const float* favor   = (const float*)d_in[3];
    const float* consume = (const float*)d_in[4];
    const float* uid     = (const float*)d_in[5];
    const float* pid     = (const float*)d_in[6];
    const int*   uidx    = (const int*)d_in[7];
    const int*   pidx    = (const int*)d_in[8];
    const float* labels  = (const float*)d_in[9];
    const float* guf     = (const float*)d_in[10];
    const float* w3      = (const float*)d_in[11];
    const float* fw3     = (const float*)d_in[12];
    const float* Wuc     = (const float*)d_in[13];
    const float* Wpc     = (const float*)d_in[14];
    const float* Wufv    = (const float*)d_in[15];
    const float* Wpfv    = (const float*)d_in[16];
    const float* Wuco    = (const float*)d_in[17];
    const float* Wpco    = (const float*)d_in[18];
    const float* Wss     = (const float*)d_in[19];
    const float* bias    = (const float*)d_in[20];
    float* outp = (float*)d_out;

    char* ws = (char*)d_ws;
    size_t off = 0;
    auto carve = [&](size_t bytes) -> void* {
        off = (off + 255) & ~(size_t)255;
        void* p = ws + off;
        off += bytes;
        return p;
    };
    // base layout (~89 MB, proven safe)
    float* ufs = (float*)carve(4ll * 3 * BATCH * DIM);
    float* alt = (float*)carve(4ll * BATCH * NPOS);
    float* bst = (float*)carve(4ll * DIM * BATCH);       // reused as fp16 bst_h
    int* rptr = (int*)carve(4 * (N_USERS + 1));
    int* cptr = (int*)carve(4 * (N_POIS + 1));
    int* cnts = (int*)carve(4 * (2 * (N_USERS + N_POIS)));
    int* rcnt = cnts;
    int* ccnt = cnts + N_USERS;
    int* rcur = ccnt + N_POIS;
    int* ccur = rcur + N_USERS;
    int* scanws = (int*)carve(4 * 2 * (RCH + CCH) + 4 * 64);  // rsum/csum/rbase/cbase
    int* rsum = scanws;
    int* csum = rsum + RCH;
    int* rbase = csum + CCH;
    int* cbase = rbase + RCH;
    float* losspart = (float*)carve(4 * (LOSS_BLOCKS + 7));
    int4* rpack = (int4*)carve(16ll * N_EDGES);   // {col, v0, v1, v2}
    int4* cpack = (int4*)carve(16ll * N_EDGES);   // {row, v0, v1, v2}
    unsigned short* pid_h = (unsigned short*)carve(2ll * N_POIS * DIM);
    unsigned short* utr0 = (unsigned short*)carve(2ll * N_USERS * DIM);  // 10.24 MB; pf alias
    unsigned short* ptr_h = (unsigned short*)carve(2ll * N_POIS * DIM);
    float* su  = (float*)carve(4ll * N_USERS * DIM);   // cand alias
    float* sp  = (float*)carve(4ll * N_POIS * DIM);
    float* idf = (float*)carve(4ll * N_USERS * DIM);
    float* pf = (float*)utr0;             // utr0 dead before pf written
    float* cand_s = su;                   // su dead before score_topk
    int*   cand_i = (int*)(su + (size_t)NCHUNK * BATCH * TOPK);
    _Float16* idf_h = (_Float16*)rpack;   // rpack dead after last L2-user spmm
    _Float16* bst_h = (_Float16*)bst;
    // extra carves for the channel-fused path (+20.5 MB) — only used if they fit
    unsigned short* utr1 = (unsigned short*)carve(2ll * N_USERS * DIM);
    unsigned short* utr2 = (unsigned short*)carve(2ll * N_USERS * DIM);
    bool fused = (off <= ws_size);

    zero_kernel<<<(2 * (N_USERS + N_POIS) + 255) / 256, 256, 0, stream>>>(
        (unsigned int*)cnts, 2 * (N_USERS + N_POIS));
    cast_f16_kernel<<<(N_POIS * DIM / 2 + 255) / 256, 256, 0, stream>>>(pid, pid_h, N_POIS * DIM / 2);
    hist_kernel<<<(N_EDGES + 255) / 256, 256, 0, stream>>>(er, ec, rcnt, ccnt);
    // parallel exclusive prefix sum
    dim3 sg2(RCH, 2);
    chunksum_kernel<<<sg2, 256, 0, stream>>>(rcnt, ccnt, rsum, csum);
    chunkscan_kernel<<<1, 128, 0, stream>>>(rsum, csum, rbase, cbase, rptr, cptr);
    scatterscan_kernel<<<sg2, 256, 0, stream>>>(rcnt, ccnt, rbase, cbase, rptr, cptr);
    fill_kernel<<<(N_EDGES / 4 + 255) / 256, 256, 0, stream>>>(
        er, ec, rptr, cptr, rcur, ccur, rpack, cpack, click, favor, consume);

    struct Ch { const float* Wu; const float* Wp; int wsel; int fsel; };
    // wn (softmax over w[1,3]):  favor=0, click=1, consume=2
    // fwn (softmax over fw[3,1]): favor=0, consume=1, click=2
    Ch chs[3] = { { Wuc,  Wpc,  1, 2 },     // ch0 = click
                  { Wufv, Wpfv, 0, 0 },     // ch1 = favor
                  { Wuco, Wpco, 2, 1 } };   // ch2 = consume

    const int UGB = N_USERS / 64;                 // 625
    const int PGB = (N_POIS + 63) / 64;           // 313
    const int PW = N_POIS * 64 / 256;
    const int UW = N_USERS * 64 / 256;

    auto launch_spmm_poi = [&](int c, const unsigned short* src, unsigned short* raw,
                               const float* base, float* acc) {
        if (c == 0)      spmm_kernel<0><<<PW, 256, 0, stream>>>(cptr, cpack, src, raw, base, acc, N_POIS);
        else if (c == 1) spmm_kernel<1><<<PW, 256, 0, stream>>>(cptr, cpack, src, raw, base, acc, N_POIS);
        else             spmm_kernel<2><<<PW, 256, 0, stream>>>(cptr, cpack, src, raw, base, acc, N_POIS);
    };
    auto launch_spmm_usr = [&](int c, const unsigned short* src, unsigned short* raw,
                               const float* base, float* acc) {
        if (c == 0)      spmm_kernel<0><<<UW, 256, 0, stream>>>(rptr, rpack, src, raw, base, acc, N_USERS);
        else if (c == 1) spmm_kernel<1><<<UW, 256, 0, stream>>>(rptr, rpack, src, raw, base, acc, N_USERS);
        else             spmm_kernel<2><<<UW, 256, 0, stream>>>(rptr, rpack, src, raw, base, acc, N_USERS);
    };
    auto launch_l2u = [&](int c, const unsigned short* src, unsigned short* u1raw) {
        if (c == 0)      spmm_l2u_kernel<0><<<UW, 256, 0, stream>>>(rptr, rpack, src, u1raw, uid, su, N_USERS);
        else if (c == 1) spmm_l2u_kernel<1><<<UW, 256, 0, stream>>>(rptr, rpack, src, u1raw, uid, su, N_USERS);
        else             spmm_l2u_kernel<2><<<UW, 256, 0, stream>>>(rptr, rpack, src, u1raw, uid, su, N_USERS);
    };

    if (fused) {
        // fused 3-channel L1-user hop: one shared pid_h gather, 3 raw outputs
        spmm3_kernel<<<UW, 256, 0, stream>>>(rptr, rpack, pid_h, utr0, utr1, utr2, N_USERS);
        for (int c = 0; c < 3; c++) {
            unsigned short* uc = (c == 0) ? utr0 : ((c == 1) ? utr1 : utr2);
            launch_spmm_poi(c, uc, ptr_h, pid, sp);
            launch_l2u(c, ptr_h, uc);
            launch_spmm_poi(c, uc, ptr_h, sp, sp);
            gemm_mfma_kernel<<<UGB, 256, 0, stream>>>(
                su, chs[c].Wu, nullptr, idf, (c == 2) ? idf_h : nullptr,
                fw3, chs[c].fsel, (c == 0) ? 1 : 0, N_USERS);
            ufsel_kernel<<<BATCH, 128, 0, stream>>>(su, chs[c].Wu, uidx, ufs + (size_t)c * BATCH * DIM);
            gemm_mfma_kernel<<<PGB, 256, 0, stream>>>(
                sp, chs[c].Wp, pf, nullptr, nullptr, fw3, 0, 0, N_POIS);
            predict_kernel<<<BATCH * NPOS * 64 / 256, 256, 0, stream>>>(
                ufs + (size_t)c * BATCH * DIM, pf, pidx, w3, chs[c].wsel, (c == 0) ? 1 : 0, alt);
        }
    } else {
        // proven fallback: per-channel schedule, single utr0 buffer
        for (int c = 0; c < 3; c++) {
            launch_spmm_usr(c, pid_h, utr0, uid, su);
            launch_spmm_poi(c, utr0, ptr_h, pid, sp);
            launch_spmm_usr(c, ptr_h, utr0, su, su);
            launch_spmm_poi(c, utr0, ptr_h, sp, sp);
            gemm_mfma_kernel<<<UGB, 256, 0, stream>>>(
                su, chs[c].Wu, nullptr, idf, (c == 2) ? idf_h : nullptr,
                fw3, chs[c].fsel, (c == 0) ? 1 : 0, N_USERS);
            ufsel_kernel<<<BATCH, 128, 0, stream>>>(su, chs[c].Wu, uidx, ufs + (size_t)c * BATCH * DIM);
            gemm_mfma_kernel<<<PGB, 256, 0, stream>>>(
                sp, chs[c].Wp, pf, nullptr, nullptr, fw3, 0, 0, N_POIS);
            predict_kernel<<<BATCH * NPOS * 64 / 256, 256, 0, stream>>>(
                ufs + (size_t)c * BATCH * DIM, pf, pidx, w3, chs[c].wsel, (c == 0) ? 1 : 0, alt);
        }
    }

    loss_part_kernel<<<LOSS_BLOCKS, 256, 0, stream>>>(alt, labels, losspart);
    loss_final_kernel<<<1, 64, 0, stream>>>(losspart, outp);
    bs_kernel<<<BATCH, 128, 0, stream>>>(idf, Wss, bias, uidx, bst_h);
    dim3 sg(NCHUNK, 4);
    score_topk_kernel<<<sg, 512, 0, stream>>>(idf_h, bst_h, cand_s, cand_i);
    topk_merge_kernel<<<BATCH, NCHUNK, 0, stream>>>(cand_s, cand_i, guf, outp);
}

// Round 9
// 660.982 us; speedup vs baseline: 1.0434x; 1.0434x over previous
//
#include <hip/hip_runtime.h>

#define N_USERS 40000
#define N_POIS  20000
#define DIM     128
#define N_EDGES 500000
#define BATCH   256
#define NPOS    100
#define TOPK    20
#define NCHUNK  128
#define CPT     313   // ceil(40000/128)
#define SCHUNK  1024  // scan chunk (256 thr x 4)
#define RCH     40    // ceil(40000/1024)
#define CCH     20    // ceil(20000/1024)
#define LOSS_BLOCKS 25  // 25600/1024

typedef _Float16 f16x8 __attribute__((ext_vector_type(8)));
typedef float f32x4 __attribute__((ext_vector_type(4)));

__device__ __forceinline__ int iclamp(int x, int lo, int hi) {
    return x < lo ? lo : (x > hi ? hi : x);
}
__device__ __forceinline__ float2 h2f2(unsigned int u) {
    union { unsigned int u32; _Float16 h[2]; } v; v.u32 = u;
    return make_float2((float)v.h[0], (float)v.h[1]);
}
__device__ __forceinline__ unsigned int f2h2(float x, float y) {
    union { unsigned int u32; _Float16 h[2]; } v;
    v.h[0] = (_Float16)x; v.h[1] = (_Float16)y; return v.u32;
}
__device__ __forceinline__ float softmax3(const float* p, int sel) {
    float a0 = p[0], a1 = p[1], a2 = p[2];
    float m = fmaxf(a0, fmaxf(a1, a2));
    float e0 = expf(a0 - m), e1 = expf(a1 - m), e2 = expf(a2 - m);
    float den = e0 + e1 + e2;
    float e = (sel == 0) ? e0 : ((sel == 1) ? e1 : e2);
    return e / den;
}
// compile-time channel pick from packed edge {idx, v0, v1, v2}
template<int CH>
__device__ __forceinline__ float pickvT(int4 q) {
    return __int_as_float(CH == 0 ? q.y : (CH == 1 ? q.z : q.w));
}
// build fp16x8 fragment from 8 contiguous fp32
__device__ __forceinline__ f16x8 frag8(const float* p) {
    float4 x = *(const float4*)(p);
    float4 y = *(const float4*)(p + 4);
    f16x8 f;
    f[0] = (_Float16)x.x; f[1] = (_Float16)x.y; f[2] = (_Float16)x.z; f[3] = (_Float16)x.w;
    f[4] = (_Float16)y.x; f[5] = (_Float16)y.y; f[6] = (_Float16)y.z; f[7] = (_Float16)y.w;
    return f;
}

// ---------------- zero init ----------------
__global__ void zero_kernel(unsigned int* __restrict__ p, int nwords) {
    int i = blockIdx.x * blockDim.x + threadIdx.x;
    if (i < nwords) p[i] = 0u;
}

// ---------------- fp32 -> fp16 cast ----------------
__global__ void cast_f16_kernel(const float* __restrict__ src, unsigned short* __restrict__ dst,
                                int n2) {
    int i = blockIdx.x * blockDim.x + threadIdx.x;
    if (i < n2) {
        float2 v = *(const float2*)(src + 2 * (size_t)i);
        *(unsigned int*)(dst + 2 * (size_t)i) = f2h2(v.x, v.y);
    }
}

// ---------------- CSR hist: counts + per-edge within-row/col ordinals ----------------
// 4 edges/thread; ordinal stores are coalesced (indexed by e).
__global__ void hist_kernel(const int* __restrict__ er, const int* __restrict__ ec,
                            int* __restrict__ rcnt, int* __restrict__ ccnt,
                            int* __restrict__ rord, int* __restrict__ cord) {
    int e0 = 4 * (blockIdx.x * blockDim.x + threadIdx.x);
    if (e0 + 4 <= N_EDGES) {
        int4 r4 = *(const int4*)(er + e0);
        int4 c4 = *(const int4*)(ec + e0);
        int rr[4] = { r4.x, r4.y, r4.z, r4.w };
        int cc[4] = { c4.x, c4.y, c4.z, c4.w };
        int ro[4], co[4];
        #pragma unroll
        for (int j = 0; j < 4; j++) {
            ro[j] = atomicAdd(&rcnt[iclamp(rr[j], 0, N_USERS - 1)], 1);
            co[j] = atomicAdd(&ccnt[iclamp(cc[j], 0, N_POIS - 1)], 1);
        }
        *(int4*)(rord + e0) = make_int4(ro[0], ro[1], ro[2], ro[3]);
        *(int4*)(cord + e0) = make_int4(co[0], co[1], co[2], co[3]);
    } else {
        for (int e = e0; e < N_EDGES; e++) {
            rord[e] = atomicAdd(&rcnt[iclamp(er[e], 0, N_USERS - 1)], 1);
            cord[e] = atomicAdd(&ccnt[iclamp(ec[e], 0, N_POIS - 1)], 1);
        }
    }
}

// ---------------- parallel prefix sum, stage 1: per-1024-chunk sums ----------------
__global__ void chunksum_kernel(const int* __restrict__ rcnt, const int* __restrict__ ccnt,
                                int* __restrict__ rsum, int* __restrict__ csum) {
    int side = blockIdx.y;
    const int* cnt = side ? ccnt : rcnt;
    int n = side ? N_POIS : N_USERS;
    int nch = side ? CCH : RCH;
    int b = blockIdx.x;
    if (b >= nch) return;
    int t = threadIdx.x;
    int i = b * SCHUNK + t * 4;
    int s = 0;
    if (i + 4 <= n) {
        int4 v = *(const int4*)(cnt + i);
        s = v.x + v.y + v.z + v.w;
    } else {
        for (int j = i; j < n; j++) s += cnt[j];
    }
    __shared__ int red[256];
    red[t] = s;
    __syncthreads();
    for (int o = 128; o > 0; o >>= 1) {
        if (t < o) red[t] += red[t + o];
        __syncthreads();
    }
    if (t == 0) (side ? csum : rsum)[b] = red[0];
}

// ---------------- stage 2: scan chunk sums (wave shfl), write totals ----------------
__global__ void chunkscan_kernel(const int* __restrict__ rsum, const int* __restrict__ csum,
                                 int* __restrict__ rbase, int* __restrict__ cbase,
                                 int* __restrict__ rptr, int* __restrict__ cptr) {
    int w = threadIdx.x >> 6, l = threadIdx.x & 63;  // block 128: wave0=users, wave1=pois
    const int* src = w ? csum : rsum;
    int* dst = w ? cbase : rbase;
    int nch = w ? CCH : RCH;
    int orig = (l < nch) ? src[l] : 0;
    int v = orig;
    #pragma unroll
    for (int o = 1; o < 64; o <<= 1) {
        int u = __shfl_up(v, o, 64);
        if (l >= o) v += u;
    }
    if (l < nch) dst[l] = v - orig;                 // exclusive base
    if (l == nch - 1) {
        if (w) cptr[N_POIS] = v; else rptr[N_USERS] = v;
    }
}

// ---------------- stage 3: block scan within chunk + chunk base ----------------
__global__ void scatterscan_kernel(const int* __restrict__ rcnt, const int* __restrict__ ccnt,
                                   const int* __restrict__ rbase, const int* __restrict__ cbase,
                                   int* __restrict__ rptr, int* __restrict__ cptr) {
    int side = blockIdx.y;
    const int* cnt = side ? ccnt : rcnt;
    const int* basea = side ? cbase : rbase;
    int* ptr = side ? cptr : rptr;
    int n = side ? N_POIS : N_USERS;
    int nch = side ? CCH : RCH;
    int b = blockIdx.x;
    if (b >= nch) return;
    int t = threadIdx.x;
    int i = b * SCHUNK + t * 4;
    int c0 = 0, c1 = 0, c2 = 0, c3 = 0;
    if (i + 4 <= n) {
        int4 v = *(const int4*)(cnt + i);
        c0 = v.x; c1 = v.y; c2 = v.z; c3 = v.w;
    } else {
        if (i + 0 < n) c0 = cnt[i + 0];
        if (i + 1 < n) c1 = cnt[i + 1];
        if (i + 2 < n) c2 = cnt[i + 2];
    }
    int tsum = c0 + c1 + c2 + c3;
    int l = t & 63, w = t >> 6;
    int v = tsum;
    #pragma unroll
    for (int o = 1; o < 64; o <<= 1) {
        int u = __shfl_up(v, o, 64);
        if (l >= o) v += u;
    }
    __shared__ int wsum[4];
    if (l == 63) wsum[w] = v;
    __syncthreads();
    int wbase = 0;
    for (int k = 0; k < w; k++) wbase += wsum[k];
    int ex = v - tsum + wbase + basea[b];
    if (i + 4 <= n) {
        *(int4*)(ptr + i) = make_int4(ex, ex + c0, ex + c0 + c1, ex + c0 + c1 + c2);
    } else {
        if (i + 0 < n) ptr[i + 0] = ex;
        if (i + 1 < n) ptr[i + 1] = ex + c0;
        if (i + 2 < n) ptr[i + 2] = ex + c0 + c1;
    }
}

// ---------------- AoS CSR fill: NO atomics (slots precomputed in hist) ----------------
__global__ void fill_kernel(const int* __restrict__ er, const int* __restrict__ ec,
                            const int* __restrict__ rptr, const int* __restrict__ cptr,
                            const int* __restrict__ rord, const int* __restrict__ cord,
                            int4* __restrict__ rpack, int4* __restrict__ cpack,
                            const float* __restrict__ ck, const float* __restrict__ fv,
                            const float* __restrict__ cs) {
    int e0 = 4 * (blockIdx.x * blockDim.x + threadIdx.x);
    if (e0 + 4 <= N_EDGES) {
        int4 r4 = *(const int4*)(er + e0);
        int4 c4 = *(const int4*)(ec + e0);
        int4 ro4 = *(const int4*)(rord + e0);
        int4 co4 = *(const int4*)(cord + e0);
        float4 k4 = *(const float4*)(ck + e0);
        float4 f4 = *(const float4*)(fv + e0);
        float4 s4 = *(const float4*)(cs + e0);
        int rr[4] = { r4.x, r4.y, r4.z, r4.w };
        int cc[4] = { c4.x, c4.y, c4.z, c4.w };
        int ro[4] = { ro4.x, ro4.y, ro4.z, ro4.w };
        int co[4] = { co4.x, co4.y, co4.z, co4.w };
        float kk[4] = { k4.x, k4.y, k4.z, k4.w };
        float ff[4] = { f4.x, f4.y, f4.z, f4.w };
        float ss[4] = { s4.x, s4.y, s4.z, s4.w };
        #pragma unroll
        for (int j = 0; j < 4; j++) {
            int r = iclamp(rr[j], 0, N_USERS - 1), c = iclamp(cc[j], 0, N_POIS - 1);
            int v0 = __float_as_int(kk[j]);
            int v1 = __float_as_int(ff[j]);
            int v2 = __float_as_int(ss[j]);
            int pr = iclamp(rptr[r] + ro[j], 0, N_EDGES - 1);
            rpack[pr] = make_int4(c, v0, v1, v2);
            int pc = iclamp(cptr[c] + co[j], 0, N_EDGES - 1);
            cpack[pc] = make_int4(r, v0, v1, v2);
        }
    } else {
        for (int e = e0; e < N_EDGES; e++) {
            int r = iclamp(er[e], 0, N_USERS - 1), c = iclamp(ec[e], 0, N_POIS - 1);
            int v0 = __float_as_int(ck[e]);
            int v1 = __float_as_int(fv[e]);
            int v2 = __float_as_int(cs[e]);
            int pr = iclamp(rptr[r] + rord[e], 0, N_EDGES - 1);
            rpack[pr] = make_int4(c, v0, v1, v2);
            int pc = iclamp(cptr[c] + cord[e], 0, N_EDGES - 1);
            cpack[pc] = make_int4(r, v0, v1, v2);
        }
    }
}

// ---------------- SpMM: one wave per row; packed edges; fp16 src gather ----------------
// raw_h (fp16) = A*src ; acc (fp32) = base + raw/||raw||
template<int CH>
__global__ __launch_bounds__(256) void spmm_kernel(
        const int* __restrict__ ptr, const int4* __restrict__ pack,
        const unsigned short* __restrict__ src,         // fp16 [*,128]
        unsigned short* __restrict__ raw_h,             // fp16 out
        const float* __restrict__ base,                 // fp32 (may alias acc)
        float* __restrict__ acc, int nrows) {
    int wid = (blockIdx.x * blockDim.x + threadIdx.x) >> 6;
    int lane = threadIdx.x & 63;
    if (wid >= nrows) return;
    int beg = __builtin_amdgcn_readfirstlane(iclamp(ptr[wid], 0, N_EDGES));
    int end = __builtin_amdgcn_readfirstlane(iclamp(ptr[wid + 1], 0, N_EDGES));
    if (end < beg) end = beg;
    float ax = 0.f, ay = 0.f;
    int e = beg;
    int lo2 = lane * 2;
    for (; e + 8 <= end; e += 8) {
        int4 q0 = pack[e + 0], q1 = pack[e + 1], q2 = pack[e + 2], q3 = pack[e + 3];
        int4 q4 = pack[e + 4], q5 = pack[e + 5], q6 = pack[e + 6], q7 = pack[e + 7];
        float v0 = pickvT<CH>(q0), v1 = pickvT<CH>(q1), v2 = pickvT<CH>(q2), v3 = pickvT<CH>(q3);
        float v4 = pickvT<CH>(q4), v5 = pickvT<CH>(q5), v6 = pickvT<CH>(q6), v7 = pickvT<CH>(q7);
        float2 p0 = h2f2(*(const unsigned int*)(src + (size_t)q0.x * DIM + lo2));
        float2 p1 = h2f2(*(const unsigned int*)(src + (size_t)q1.x * DIM + lo2));
        float2 p2 = h2f2(*(const unsigned int*)(src + (size_t)q2.x * DIM + lo2));
        float2 p3 = h2f2(*(const unsigned int*)(src + (size_t)q3.x * DIM + lo2));
        float2 p4 = h2f2(*(const unsigned int*)(src + (size_t)q4.x * DIM + lo2));
        float2 p5 = h2f2(*(const unsigned int*)(src + (size_t)q5.x * DIM + lo2));
        float2 p6 = h2f2(*(const unsigned int*)(src + (size_t)q6.x * DIM + lo2));
        float2 p7 = h2f2(*(const unsigned int*)(src + (size_t)q7.x * DIM + lo2));
        ax = fmaf(v0, p0.x, fmaf(v1, p1.x, fmaf(v2, p2.x, fmaf(v3, p3.x, ax))));
        ax = fmaf(v4, p4.x, fmaf(v5, p5.x, fmaf(v6, p6.x, fmaf(v7, p7.x, ax))));
        ay = fmaf(v0, p0.y, fmaf(v1, p1.y, fmaf(v2, p2.y, fmaf(v3, p3.y, ay))));
        ay = fmaf(v4, p4.y, fmaf(v5, p5.y, fmaf(v6, p6.y, fmaf(v7, p7.y, ay))));
    }
    if (e < end) {
        int last = end - 1;
        int e1 = e + 1 <= last ? e + 1 : last;
        int e2 = e + 2 <= last ? e + 2 : last;
        int e3 = e + 3 <= last ? e + 3 : last;
        int e4 = e + 4 <= last ? e + 4 : last;
        int e5 = e + 5 <= last ? e + 5 : last;
        int e6 = e + 6 <= last ? e + 6 : last;
        int e7 = e + 7 <= last ? e + 7 : last;
        int4 q0 = pack[e], q1 = pack[e1], q2 = pack[e2], q3 = pack[e3];
        int4 q4 = pack[e4], q5 = pack[e5], q6 = pack[e6], q7 = pack[e7];
        float v0 = pickvT<CH>(q0);
        float v1 = (e + 1 < end) ? pickvT<CH>(q1) : 0.f;
        float v2 = (e + 2 < end) ? pickvT<CH>(q2) : 0.f;
        float v3 = (e + 3 < end) ? pickvT<CH>(q3) : 0.f;
        float v4 = (e + 4 < end) ? pickvT<CH>(q4) : 0.f;
        float v5 = (e + 5 < end) ? pickvT<CH>(q5) : 0.f;
        float v6 = (e + 6 < end) ? pickvT<CH>(q6) : 0.f;
        float v7 = (e + 7 < end) ? pickvT<CH>(q7) : 0.f;
        float2 p0 = h2f2(*(const unsigned int*)(src + (size_t)q0.x * DIM + lo2));
        float2 p1 = h2f2(*(const unsigned int*)(src + (size_t)q1.x * DIM + lo2));
        float2 p2 = h2f2(*(const unsigned int*)(src + (size_t)q2.x * DIM + lo2));
        float2 p3 = h2f2(*(const unsigned int*)(src + (size_t)q3.x * DIM + lo2));
        float2 p4 = h2f2(*(const unsigned int*)(src + (size_t)q4.x * DIM + lo2));
        float2 p5 = h2f2(*(const unsigned int*)(src + (size_t)q5.x * DIM + lo2));
        float2 p6 = h2f2(*(const unsigned int*)(src + (size_t)q6.x * DIM + lo2));
        float2 p7 = h2f2(*(const unsigned int*)(src + (size_t)q7.x * DIM + lo2));
        ax = fmaf(v0, p0.x, fmaf(v1, p1.x, fmaf(v2, p2.x, fmaf(v3, p3.x, ax))));
        ax = fmaf(v4, p4.x, fmaf(v5, p5.x, fmaf(v6, p6.x, fmaf(v7, p7.x, ax))));
        ay = fmaf(v0, p0.y, fmaf(v1, p1.y, fmaf(v2, p2.y, fmaf(v3, p3.y, ay))));
        ay = fmaf(v4, p4.y, fmaf(v5, p5.y, fmaf(v6, p6.y, fmaf(v7, p7.y, ay))));
    }
    float n2 = ax * ax + ay * ay;
    #pragma unroll
    for (int o = 32; o > 0; o >>= 1) n2 += __shfl_xor(n2, o, 64);
    float inv = rsqrtf(fmaxf(n2, 1e-30f));
    *(unsigned int*)(raw_h + (size_t)wid * DIM + lo2) = f2h2(ax, ay);
    float2 bv = *(const float2*)(base + (size_t)wid * DIM + lo2);
    *(float2*)(acc + (size_t)wid * DIM + lo2) =
        make_float2(bv.x + ax * inv, bv.y + ay * inv);
}

// ---------------- fused 3-channel L1-user SpMM: shared gather, 3 raw outputs ----------------
__global__ __launch_bounds__(256) void spmm3_kernel(
        const int* __restrict__ ptr, const int4* __restrict__ pack,
        const unsigned short* __restrict__ src,     // pid_h (shared across channels)
        unsigned short* __restrict__ r0, unsigned short* __restrict__ r1,
        unsigned short* __restrict__ r2, int nrows) {
    int wid = (blockIdx.x * blockDim.x + threadIdx.x) >> 6;
    int lane = threadIdx.x & 63;
    if (wid >= nrows) return;
    int beg = __builtin_amdgcn_readfirstlane(iclamp(ptr[wid], 0, N_EDGES));
    int end = __builtin_amdgcn_readfirstlane(iclamp(ptr[wid + 1], 0, N_EDGES));
    if (end < beg) end = beg;
    float a0x = 0.f, a0y = 0.f, a1x = 0.f, a1y = 0.f, a2x = 0.f, a2y = 0.f;
    int e = beg;
    int lo2 = lane * 2;
    for (; e + 4 <= end; e += 4) {
        int4 q0 = pack[e + 0], q1 = pack[e + 1], q2 = pack[e + 2], q3 = pack[e + 3];
        float2 p0 = h2f2(*(const unsigned int*)(src + (size_t)q0.x * DIM + lo2));
        float2 p1 = h2f2(*(const unsigned int*)(src + (size_t)q1.x * DIM + lo2));
        float2 p2 = h2f2(*(const unsigned int*)(src + (size_t)q2.x * DIM + lo2));
        float2 p3 = h2f2(*(const unsigned int*)(src + (size_t)q3.x * DIM + lo2));
        a0x = fmaf(__int_as_float(q0.y), p0.x, fmaf(__int_as_float(q1.y), p1.x,
              fmaf(__int_as_float(q2.y), p2.x, fmaf(__int_as_float(q3.y), p3.x, a0x))));
        a0y = fmaf(__int_as_float(q0.y), p0.y, fmaf(__int_as_float(q1.y), p1.y,
              fmaf(__int_as_float(q2.y), p2.y, fmaf(__int_as_float(q3.y), p3.y, a0y))));
        a1x = fmaf(__int_as_float(q0.z), p0.x, fmaf(__int_as_float(q1.z), p1.x,
              fmaf(__int_as_float(q2.z), p2.x, fmaf(__int_as_float(q3.z), p3.x, a1x))));
        a1y = fmaf(__int_as_float(q0.z), p0.y, fmaf(__int_as_float(q1.z), p1.y,
              fmaf(__int_as_float(q2.z), p2.y, fmaf(__int_as_float(q3.z), p3.y, a1y))));
        a2x = fmaf(__int_as_float(q0.w), p0.x, fmaf(__int_as_float(q1.w), p1.x,
              fmaf(__int_as_float(q2.w), p2.x, fmaf(__int_as_float(q3.w), p3.x, a2x))));
        a2y = fmaf(__int_as_float(q0.w), p0.y, fmaf(__int_as_float(q1.w), p1.y,
              fmaf(__int_as_float(q2.w), p2.y, fmaf(__int_as_float(q3.w), p3.y, a2y))));
    }
    for (; e < end; e++) {
        int4 q = pack[e];
        float2 p = h2f2(*(const unsigned int*)(src + (size_t)q.x * DIM + lo2));
        a0x = fmaf(__int_as_float(q.y), p.x, a0x);
        a0y = fmaf(__int_as_float(q.y), p.y, a0y);
        a1x = fmaf(__int_as_float(q.z), p.x, a1x);
        a1y = fmaf(__int_as_float(q.z), p.y, a1y);
        a2x = fmaf(__int_as_float(q.w), p.x, a2x);
        a2y = fmaf(__int_as_float(q.w), p.y, a2y);
    }
    size_t o = (size_t)wid * DIM + lo2;
    *(unsigned int*)(r0 + o) = f2h2(a0x, a0y);
    *(unsigned int*)(r1 + o) = f2h2(a1x, a1y);
    *(unsigned int*)(r2 + o) = f2h2(a2x, a2y);
}

// ---------------- L2-user SpMM: su = uid + n(u1) + n(u2); u1raw overwritten with u2 ----------------
template<int CH>
__global__ __launch_bounds__(256) void spmm_l2u_kernel(
        const int* __restrict__ ptr, const int4* __restrict__ pack,
        const unsigned short* __restrict__ src,     // ptr_h (p1 raw fp16)
        unsigned short* __restrict__ u1raw,         // in: u1 raw; out: u2 raw
        const float* __restrict__ uid,
        float* __restrict__ su, int nrows) {
    int wid = (blockIdx.x * blockDim.x + threadIdx.x) >> 6;
    int lane = threadIdx.x & 63;
    if (wid >= nrows) return;
    int beg = __builtin_amdgcn_readfirstlane(iclamp(ptr[wid], 0, N_EDGES));
    int end = __builtin_amdgcn_readfirstlane(iclamp(ptr[wid + 1], 0, N_EDGES));
    if (end < beg) end = beg;
    float ax = 0.f, ay = 0.f;
    int e = beg;
    int lo2 = lane * 2;
    for (; e + 8 <= end; e += 8) {
        int4 q0 = pack[e + 0], q1 = pack[e + 1], q2 = pack[e + 2], q3 = pack[e + 3];
        int4 q4 = pack[e + 4], q5 = pack[e + 5], q6 = pack[e + 6], q7 = pack[e + 7];
        float v0 = pickvT<CH>(q0), v1 = pickvT<CH>(q1), v2 = pickvT<CH>(q2), v3 = pickvT<CH>(q3);
        float v4 = pickvT<CH>(q4), v5 = pickvT<CH>(q5), v6 = pickvT<CH>(q6), v7 = pickvT<CH>(q7);
        float2 p0 = h2f2(*(const unsigned int*)(src + (size_t)q0.x * DIM + lo2));
        float2 p1 = h2f2(*(const unsigned int*)(src + (size_t)q1.x * DIM + lo2));
        float2 p2 = h2f2(*(const unsigned int*)(src + (size_t)q2.x * DIM + lo2));
        float2 p3 = h2f2(*(const unsigned int*)(src + (size_t)q3.x * DIM + lo2));
        float2 p4 = h2f2(*(const unsigned int*)(src + (size_t)q4.x * DIM + lo2));
        float2 p5 = h2f2(*(const unsigned int*)(src + (size_t)q5.x * DIM + lo2));
        float2 p6 = h2f2(*(const unsigned int*)(src + (size_t)q6.x * DIM + lo2));
        float2 p7 = h2f2(*(const unsigned int*)(src + (size_t)q7.x * DIM + lo2));
        ax = fmaf(v0, p0.x, fmaf(v1, p1.x, fmaf(v2, p2.x, fmaf(v3, p3.x, ax))));
        ax = fmaf(v4, p4.x, fmaf(v5, p5.x, fmaf(v6, p6.x, fmaf(v7, p7.x, ax))));
        ay = fmaf(v0, p0.y, fmaf(v1, p1.y, fmaf(v2, p2.y, fmaf(v3, p3.y, ay))));
        ay = fmaf(v4, p4.y, fmaf(v5, p5.y, fmaf(v6, p6.y, fmaf(v7, p7.y, ay))));
    }
    if (e < end) {
        int last = end - 1;
        int e1 = e + 1 <= last ? e + 1 : last;
        int e2 = e + 2 <= last ? e + 2 : last;
        int e3 = e + 3 <= last ? e + 3 : last;
        int e4 = e + 4 <= last ? e + 4 : last;
        int e5 = e + 5 <= last ? e + 5 : last;
        int e6 = e + 6 <= last ? e + 6 : last;
        int e7 = e + 7 <= last ? e + 7 : last;
        int4 q0 = pack[e], q1 = pack[e1], q2 = pack[e2], q3 = pack[e3];
        int4 q4 = pack[e4], q5 = pack[e5], q6 = pack[e6], q7 = pack[e7];
        float v0 = pickvT<CH>(q0);
        float v1 = (e + 1 < end) ? pickvT<CH>(q1) : 0.f;
        float v2 = (e + 2 < end) ? pickvT<CH>(q2) : 0.f;
        float v3 = (e + 3 < end) ? pickvT<CH>(q3) : 0.f;
        float v4 = (e + 4 < end) ? pickvT<CH>(q4) : 0.f;
        float v5 = (e + 5 < end) ? pickvT<CH>(q5) : 0.f;
        float v6 = (e + 6 < end) ? pickvT<CH>(q6) : 0.f;
        float v7 = (e + 7 < end) ? pickvT<CH>(q7) : 0.f;
        float2 p0 = h2f2(*(const unsigned int*)(src + (size_t)q0.x * DIM + lo2));
        float2 p1 = h2f2(*(const unsigned int*)(src + (size_t)q1.x * DIM + lo2));
        float2 p2 = h2f2(*(const unsigned int*)(src + (size_t)q2.x * DIM + lo2));
        float2 p3 = h2f2(*(const unsigned int*)(src + (size_t)q3.x * DIM + lo2));
        float2 p4 = h2f2(*(const unsigned int*)(src + (size_t)q4.x * DIM + lo2));
        float2 p5 = h2f2(*(const unsigned int*)(src + (size_t)q5.x * DIM + lo2));
        float2 p6 = h2f2(*(const unsigned int*)(src + (size_t)q6.x * DIM + lo2));
        float2 p7 = h2f2(*(const unsigned int*)(src + (size_t)q7.x * DIM + lo2));
        ax = fmaf(v0, p0.x, fmaf(v1, p1.x, fmaf(v2, p2.x, fmaf(v3, p3.x, ax))));
        ax = fmaf(v4, p4.x, fmaf(v5, p5.x, fmaf(v6, p6.x, fmaf(v7, p7.x, ax))));
        ay = fmaf(v0, p0.y, fmaf(v1, p1.y, fmaf(v2, p2.y, fmaf(v3, p3.y, ay))));
        ay = fmaf(v4, p4.y, fmaf(v5, p5.y, fmaf(v6, p6.y, fmaf(v7, p7.y, ay))));
    }
    size_t o = (size_t)wid * DIM + lo2;
    float2 u1 = h2f2(*(const unsigned int*)(u1raw + o));
    float n2a = ax * ax + ay * ay;        // u2
    float n2b = u1.x * u1.x + u1.y * u1.y; // u1
    #pragma unroll
    for (int oo = 32; oo > 0; oo >>= 1) {
        n2a += __shfl_xor(n2a, oo, 64);
        n2b += __shfl_xor(n2b, oo, 64);
    }
    float i2 = rsqrtf(fmaxf(n2a, 1e-30f));
    float i1 = rsqrtf(fmaxf(n2b, 1e-30f));
    *(unsigned int*)(u1raw + o) = f2h2(ax, ay);   // u2 raw (src for L2-poi)
    float2 bv = *(const float2*)(uid + o);
    *(float2*)(su + o) = make_float2(bv.x + u1.x * i1 + ax * i2,
                                     bv.y + u1.y * i1 + ay * i2);
}

// ---------------- MFMA: out[Mx128] = A[Mx128] @ W^T ; fp32 in, fp16 frags, fp32 accum ----------------
__global__ __launch_bounds__(256) void gemm_mfma_kernel(
        const float* __restrict__ A, const float* __restrict__ W,
        float* __restrict__ store, float* __restrict__ accum,
        _Float16* __restrict__ accum_h,
        const float* __restrict__ fw3, int fsel, int first, int M) {
    int w = threadIdx.x >> 6, l = threadIdx.x & 63;
    int lg = l >> 4, lc = l & 15;
    int j0 = w * 32;
    float coef = accum ? softmax3(fw3, fsel) : 0.f;
    f16x8 Bf[2][4];
    #pragma unroll
    for (int t = 0; t < 2; t++) {
        const float* wr = W + (size_t)(j0 + t * 16 + lc) * DIM + lg * 8;
        #pragma unroll
        for (int s = 0; s < 4; s++) Bf[t][s] = frag8(wr + s * 32);
    }
    int base = blockIdx.x * 64;
    #pragma unroll
    for (int rt = 0; rt < 4; rt++) {
        int u0 = base + rt * 16;
        int ar = u0 + lc; if (ar > M - 1) ar = M - 1;
        const float* arow = A + (size_t)ar * DIM + lg * 8;
        f16x8 Af[4];
        #pragma unroll
        for (int s = 0; s < 4; s++) Af[s] = frag8(arow + s * 32);
        f32x4 acc0 = {0.f, 0.f, 0.f, 0.f};
        f32x4 acc1 = {0.f, 0.f, 0.f, 0.f};
        #pragma unroll
        for (int s = 0; s < 4; s++) {
            acc0 = __builtin_amdgcn_mfma_f32_16x16x32_f16(Af[s], Bf[0][s], acc0, 0, 0, 0);
            acc1 = __builtin_amdgcn_mfma_f32_16x16x32_f16(Af[s], Bf[1][s], acc1, 0, 0, 0);
        }
        int rbase = u0 + lg * 4;
        #pragma unroll
        for (int r = 0; r < 4; r++) {
            int row = rbase + r;
            if (row >= M) continue;
            size_t o0 = (size_t)row * DIM + j0 + lc;
            size_t o1 = o0 + 16;
            if (store) { store[o0] = acc0[r]; store[o1] = acc1[r]; }
            if (accum) {
                float p0 = first ? 0.f : accum[o0];
                float p1 = first ? 0.f : accum[o1];
                float n0 = p0 + coef * acc0[r];
                float n1 = p1 + coef * acc1[r];
                accum[o0] = n0;
                accum[o1] = n1;
                if (accum_h) {
                    accum_h[o0] = (_Float16)n0;
                    accum_h[o1] = (_Float16)n1;
                }
            }
        }
    }
}

// ---------------- 256 selected rows of uf = su @ Wu^T ----------------
__global__ void ufsel_kernel(const float* __restrict__ su, const float* __restrict__ W,
                             const int* __restrict__ uidx, float* __restrict__ outsel) {
    int b = blockIdx.x, j = threadIdx.x;  // block 128
    __shared__ float ar[128];
    int u = iclamp(uidx[b], 0, N_USERS - 1);
    ar[j] = su[(size_t)u * DIM + j];
    __syncthreads();
    const float4* Wr = (const float4*)(W + (size_t)j * DIM);
    float acc = 0.f;
    #pragma unroll 8
    for (int q = 0; q < 32; q++) {
        float4 wq = Wr[q];
        acc = fmaf(ar[4 * q + 0], wq.x, acc);
        acc = fmaf(ar[4 * q + 1], wq.y, acc);
        acc = fmaf(ar[4 * q + 2], wq.z, acc);
        acc = fmaf(ar[4 * q + 3], wq.w, acc);
    }
    outsel[(size_t)b * DIM + j] = acc;
}

// ---------------- alt[b,j] (+)= wn_c * dot(uf_c[b], pf_c[poi]) ----------------
__global__ __launch_bounds__(256) void predict_kernel(
        const float* __restrict__ ufs, const float* __restrict__ pf,
        const int* __restrict__ pidx, const float* __restrict__ w3,
        int wsel, int first, float* __restrict__ alt) {
    int wid = (blockIdx.x * blockDim.x + threadIdx.x) >> 6;
    int lane = threadIdx.x & 63;
    if (wid >= BATCH * NPOS) return;
    int b = wid / NPOS;
    int poi = iclamp(pidx[wid], 0, N_POIS - 1);
    const float2 uv = *(const float2*)(ufs + (size_t)b * DIM + lane * 2);
    const float2 pv = *(const float2*)(pf + (size_t)poi * DIM + lane * 2);
    float s = uv.x * pv.x + uv.y * pv.y;
    #pragma unroll
    for (int o = 32; o > 0; o >>= 1) s += __shfl_xor(s, o, 64);
    if (lane == 0) {
        float coef = softmax3(w3, wsel);
        float prev = first ? 0.f : alt[wid];
        alt[wid] = prev + coef * s;
    }
}

// ---------------- BCE loss: stage 1 partials (25 blocks) ----------------
__global__ void loss_part_kernel(const float* __restrict__ alt, const float* __restrict__ labels,
                                 float* __restrict__ part) {
    int b = blockIdx.x, t = threadIdx.x;
    int i = b * 1024 + t * 4;
    float4 x4 = *(const float4*)(alt + i);
    float4 y4 = *(const float4*)(labels + i);
    float s = 0.f;
    s += fmaxf(x4.x, 0.f) - x4.x * y4.x + log1pf(expf(-fabsf(x4.x)));
    s += fmaxf(x4.y, 0.f) - x4.y * y4.y + log1pf(expf(-fabsf(x4.y)));
    s += fmaxf(x4.z, 0.f) - x4.z * y4.z + log1pf(expf(-fabsf(x4.z)));
    s += fmaxf(x4.w, 0.f) - x4.w * y4.w + log1pf(expf(-fabsf(x4.w)));
    __shared__ float red[256];
    red[t] = s;
    __syncthreads();
    for (int o = 128; o > 0; o >>= 1) {
        if (t < o) red[t] += red[t + o];
        __syncthreads();
    }
    if (t == 0) part[b] = red[0];
}

// ---------------- BCE loss: stage 2 final (deterministic) ----------------
__global__ void loss_final_kernel(const float* __restrict__ part, float* __restrict__ out) {
    if (threadIdx.x == 0) {
        float s = 0.f;
        #pragma unroll
        for (int b = 0; b < LOSS_BLOCKS; b++) s += part[b];
        out[0] = s / (float)(BATCH * NPOS);
    }
}

// ---------------- bst_h[b][j] = id_feat[cur[b]] @ Ws^T + bias (fp16, row-major) ----------------
__global__ void bs_kernel(const float* __restrict__ idf, const float* __restrict__ Ws,
                          const float* __restrict__ bias, const int* __restrict__ uidx,
                          _Float16* __restrict__ bst_h) {
    int b = blockIdx.x, j = threadIdx.x;  // block 128
    __shared__ float ar[128];
    int u = iclamp(uidx[b], 0, N_USERS - 1);
    ar[j] = idf[(size_t)u * DIM + j];
    __syncthreads();
    const float4* Wr = (const float4*)(Ws + (size_t)j * DIM);
    float acc = 0.f;
    #pragma unroll 8
    for (int q = 0; q < 32; q++) {
        float4 wq = Wr[q];
        acc = fmaf(ar[4 * q + 0], wq.x, acc);
        acc = fmaf(ar[4 * q + 1], wq.y, acc);
        acc = fmaf(ar[4 * q + 2], wq.z, acc);
        acc = fmaf(ar[4 * q + 3], wq.w, acc);
    }
    bst_h[(size_t)b * DIM + j] = (_Float16)(acc + bias[j]);
}

__device__ __forceinline__ void topk_insert(float s, int u, float* ts, int* ti) {
    if (s > ts[TOPK - 1]) {
        #pragma unroll
        for (int j = TOPK - 1; j > 0; --j) {
            bool above = s > ts[j - 1];
            bool here = (!above) && (s > ts[j]);
            float nv = above ? ts[j - 1] : (here ? s : ts[j]);
            int ni = above ? ti[j - 1] : (here ? u : ti[j]);
            ts[j] = nv; ti[j] = ni;
        }
        if (s > ts[0]) { ts[0] = s; ti[0] = u; }
    }
}

// ---------------- MFMA uu scores + per-block top-20: 512 thr, 8 waves ----------------
__global__ __launch_bounds__(512) void score_topk_kernel(
        const _Float16* __restrict__ idf_h, const _Float16* __restrict__ bst_h,
        float* __restrict__ cand_s, int* __restrict__ cand_i) {
    __shared__ __align__(16) unsigned char smraw[61440];
    float* ms = (float*)smraw;                              // [20][512] 40 KB
    unsigned short* mi = (unsigned short*)(smraw + 40960);  // [20][512] 20 KB
    int cid = blockIdx.x, bg = blockIdx.y;
    int tid = threadIdx.x;
    int w = tid >> 6, l = tid & 63;
    int half = w >> 2, wq = w & 3;
    int lg = l >> 4, lc = l & 15;
    const _Float16* bbase = bst_h + ((size_t)(bg * 64 + wq * 16 + lc)) * DIM + lg * 8;
    f16x8 B0 = *(const f16x8*)(bbase + 0);
    f16x8 B1 = *(const f16x8*)(bbase + 32);
    f16x8 B2 = *(const f16x8*)(bbase + 64);
    f16x8 B3 = *(const f16x8*)(bbase + 96);
    float ts[TOPK]; int ti[TOPK];
    #pragma unroll
    for (int k = 0; k < TOPK; k++) { ts[k] = -3.0e38f; ti[k] = 0; }
    int lo = cid * CPT;
    int hi = lo + CPT; if (hi > N_USERS) hi = N_USERS;
    int ntiles = (hi - lo + 15) >> 4;
    int t0 = half ? (ntiles >> 1) : 0;
    int t1 = half ? ntiles : (ntiles >> 1);
    #pragma unroll 2
    for (int t = t0; t < t1; t++) {
        int u0 = lo + t * 16;
        int ar = u0 + lc; if (ar > N_USERS - 1) ar = N_USERS - 1;
        const _Float16* abase = idf_h + (size_t)ar * DIM + lg * 8;
        f16x8 A0 = *(const f16x8*)(abase + 0);
        f16x8 A1 = *(const f16x8*)(abase + 32);
        f16x8 A2 = *(const f16x8*)(abase + 64);
        f16x8 A3 = *(const f16x8*)(abase + 96);
        f32x4 accA = {0.f, 0.f, 0.f, 0.f};
        f32x4 accB = {0.f, 0.f, 0.f, 0.f};
        accA = __builtin_amdgcn_mfma_f32_16x16x32_f16(A0, B0, accA, 0, 0, 0);
        accB = __builtin_amdgcn_mfma_f32_16x16x32_f16(A1, B1, accB, 0, 0, 0);
        accA = __builtin_amdgcn_mfma_f32_16x16x32_f16(A2, B2, accA, 0, 0, 0);
        accB = __builtin_amdgcn_mfma_f32_16x16x32_f16(A3, B3, accB, 0, 0, 0);
        int ub = u0 + lg * 4;
        #pragma unroll
        for (int r = 0; r < 4; r++) {
            float s = accA[r] + accB[r];
            int u = ub + r;
            if (u < hi) topk_insert(s, u, ts, ti);
        }
    }
    #pragma unroll
    for (int k = 0; k < TOPK; k++) {
        ms[k * 512 + tid] = ts[k];
        mi[k * 512 + tid] = (unsigned short)ti[k];
    }
    __syncthreads();
    if (tid < 64) {
        int wm = tid >> 4, cm = tid & 15;
        int s0 = 0 * 256 + wm * 64 + 0 * 16 + cm;
        int s1 = s0 + 16, s2 = s0 + 32, s3 = s0 + 48;
        int s4 = s0 + 256, s5 = s1 + 256, s6 = s2 + 256, s7 = s3 + 256;
        int p0 = 0, p1 = 0, p2 = 0, p3 = 0, p4 = 0, p5 = 0, p6 = 0, p7 = 0;
        size_t ob = ((size_t)cid * 256 + bg * 64 + wm * 16 + cm) * TOPK;
        for (int k = 0; k < TOPK; k++) {
            float h0 = ms[p0 * 512 + s0];
            float h1 = ms[p1 * 512 + s1];
            float h2 = ms[p2 * 512 + s2];
            float h3 = ms[p3 * 512 + s3];
            float h4 = ms[p4 * 512 + s4];
            float h5 = ms[p5 * 512 + s5];
            float h6 = ms[p6 * 512 + s6];
            float h7 = ms[p7 * 512 + s7];
            float best = h0; int which = 0;
            if (h1 > best) { best = h1; which = 1; }
            if (h2 > best) { best = h2; which = 2; }
            if (h3 > best) { best = h3; which = 3; }
            if (h4 > best) { best = h4; which = 4; }
            if (h5 > best) { best = h5; which = 5; }
            if (h6 > best) { best = h6; which = 6; }
            if (h7 > best) { best = h7; which = 7; }
            int idx;
            if (which == 0)      { idx = mi[p0 * 512 + s0]; p0++; }
            else if (which == 1) { idx = mi[p1 * 512 + s1]; p1++; }
            else if (which == 2) { idx = mi[p2 * 512 + s2]; p2++; }
            else if (which == 3) { idx = mi[p3 * 512 + s3]; p3++; }
            else if (which == 4) { idx = mi[p4 * 512 + s4]; p4++; }
            else if (which == 5) { idx = mi[p5 * 512 + s5]; p5++; }
            else if (which == 6) { idx = mi[p6 * 512 + s6]; p6++; }
            else                 { idx = mi[p7 * 512 + s7]; p7++; }
            cand_s[ob + k] = best;
            cand_i[ob + k] = idx;
        }
    }
}

// ---------------- global merge + softmax + weighted gather ----------------
__global__ void topk_merge_kernel(const float* __restrict__ cand_s, const int* __restrict__ cand_i,
                                  const float* __restrict__ guf,
                                  float* __restrict__ outp) {
    int b = blockIdx.x, t = threadIdx.x;  // block 128 (= NCHUNK)
    __shared__ float rs[NCHUNK]; __shared__ int ru[NCHUNK]; __shared__ int rt[NCHUNK];
    __shared__ float win_s[TOPK]; __shared__ int win_u[TOPK]; __shared__ float wk[TOPK];
    __shared__ int winner;
    int ptr = 0;
    size_t base = ((size_t)t * 256 + b) * TOPK;
    for (int k = 0; k < TOPK; k++) {
        rs[t] = (ptr < TOPK) ? cand_s[base + ptr] : -3.0e38f;
        ru[t] = (ptr < TOPK) ? cand_i[base + ptr] : 0;
        rt[t] = t;
        __syncthreads();
        for (int off = NCHUNK / 2; off > 0; off >>= 1) {
            if (t < off && rs[t + off] > rs[t]) {
                rs[t] = rs[t + off]; ru[t] = ru[t + off]; rt[t] = rt[t + off];
            }
            __syncthreads();
        }
        if (t == 0) { win_s[k] = rs[0]; win_u[k] = iclamp(ru[0], 0, N_USERS - 1); winner = rt[0]; }
        __syncthreads();
        if (t == winner) ptr++;
        __syncthreads();
    }
    if (t == 0) {
        float m = win_s[0], den = 0.f;
        for (int k = 0; k < TOPK; k++) { wk[k] = expf(win_s[k] - m); den += wk[k]; }
        float inv = 1.f / den;
        for (int k = 0; k < TOPK; k++) wk[k] *= inv;
    }
    __syncthreads();
    float acc = 0.f;
    #pragma unroll
    for (int k = 0; k < TOPK; k++)
        acc = fmaf(wk[k], guf[(size_t)win_u[k] * DIM + t], acc);
    outp[1 + (size_t)b * DIM + t] = acc;
}

extern "C" void kernel_launch(void* const* d_in, const int* in_sizes, int n_in,
                              void* d_out, int out_size, void* d_ws, size_t ws_size,
                              hipStream_t stream) {
    (void)in_sizes; (void)n_in; (void)out_size;
    const int*   er      = (const int*)d_in[0];
    const int*   ec      = (const int*)d_in[1];
    const float* click   = (const float*)d_in[2];
    const float* favor   = (const float*)d_in[3];
    const float* consume = (const float*)d_in[4];
    const float* uid     = (const float*)d_in[5];
    const float* pid     = (const float*)d_in[6];
    const int*   uidx    = (const int*)d_in[7];
    const int*   pidx    = (const int*)d_in[8];
    const float* labels  = (const float*)d_in[9];
    const float* guf     = (const float*)d_in[10];
    const float* w3      = (const float*)d_in[11];
    const float* fw3     = (const float*)d_in[12];
    const float* Wuc     = (const float*)d_in[13];
    const float* Wpc     = (const float*)d_in[14];
    const float* Wufv    = (const float*)d_in[15];
    const float* Wpfv    = (const float*)d_in[16];
    const float* Wuco    = (const float*)d_in[17];
    const float* Wpco    = (const float*)d_in[18];
    const float* Wss     = (const float*)d_in[19];
    const float* bias    = (const float*)d_in[20];
    float* outp = (float*)d_out;

    char* ws = (char*)d_ws;
    size_t off = 0;
    auto carve = [&](size_t bytes) -> void* {
        off = (off + 255) & ~(size_t)255;
        void* p = ws + off;
        off += bytes;
        return p;
    };
    // base layout (~89 MB, proven safe)
    float* ufs = (float*)carve(4ll * 3 * BATCH * DIM);
    float* alt = (float*)carve(4ll * BATCH * NPOS);
    float* bst = (float*)carve(4ll * DIM * BATCH);       // reused as fp16 bst_h
    int* rptr = (int*)carve(4 * (N_USERS + 1));
    int* cptr = (int*)carve(4 * (N_POIS + 1));
    int* cnts = (int*)carve(4 * (N_USERS + N_POIS));
    int* rcnt = cnts;
    int* ccnt = cnts + N_USERS;
    int* scanws = (int*)carve(4 * 2 * (RCH + CCH) + 4 * 64);  // rsum/csum/rbase/cbase
    int* rsum = scanws;
    int* csum = rsum + RCH;
    int* rbase = csum + CCH;
    int* cbase = rbase + RCH;
    float* losspart = (float*)carve(4 * (LOSS_BLOCKS + 7));
    int4* rpack = (int4*)carve(16ll * N_EDGES);   // {col, v0, v1, v2}
    int4* cpack = (int4*)carve(16ll * N_EDGES);   // {row, v0, v1, v2}
    unsigned short* pid_h = (unsigned short*)carve(2ll * N_POIS * DIM);
    unsigned short* utr0 = (unsigned short*)carve(2ll * N_USERS * DIM);  // 10.24 MB; pf alias
    unsigned short* ptr_h = (unsigned short*)carve(2ll * N_POIS * DIM);
    float* su  = (float*)carve(4ll * N_USERS * DIM);   // cand alias; rord/cord alias
    float* sp  = (float*)carve(4ll * N_POIS * DIM);
    float* idf = (float*)carve(4ll * N_USERS * DIM);
    float* pf = (float*)utr0;             // utr0 dead before pf written
    float* cand_s = su;                   // su dead before score_topk
    int*   cand_i = (int*)(su + (size_t)NCHUNK * BATCH * TOPK);
    _Float16* idf_h = (_Float16*)rpack;   // rpack dead after last L2-user spmm
    _Float16* bst_h = (_Float16*)bst;
    // rord/cord (4 MB) alias su: written by hist, read by fill; su first written
    // by spmm_l2u (channel 0), which runs strictly after fill completes.
    int* rord = (int*)su;
    int* cord = rord + N_EDGES;
    // extra carves for the channel-fused path (+20.5 MB) — only used if they fit
    unsigned short* utr1 = (unsigned short*)carve(2ll * N_USERS * DIM);
    unsigned short* utr2 = (unsigned short*)carve(2ll * N_USERS * DIM);
    bool fused = (off <= ws_size);

    zero_kernel<<<(N_USERS + N_POIS + 255) / 256, 256, 0, stream>>>(
        (unsigned int*)cnts, N_USERS + N_POIS);
    cast_f16_kernel<<<(N_POIS * DIM / 2 + 255) / 256, 256, 0, stream>>>(pid, pid_h, N_POIS * DIM / 2);
    hist_kernel<<<(N_EDGES / 4 + 255) / 256, 256, 0, stream>>>(er, ec, rcnt, ccnt, rord, cord);
    // parallel exclusive prefix sum
    dim3 sg2(RCH, 2);
    chunksum_kernel<<<sg2, 256, 0, stream>>>(rcnt, ccnt, rsum, csum);
    chunkscan_kernel<<<1, 128, 0, stream>>>(rsum, csum, rbase, cbase, rptr, cptr);
    scatterscan_kernel<<<sg2, 256, 0, stream>>>(rcnt, ccnt, rbase, cbase, rptr, cptr);
    fill_kernel<<<(N_EDGES / 4 + 255) / 256, 256, 0, stream>>>(
        er, ec, rptr, cptr, rord, cord, rpack, cpack, click, favor, consume);

    struct Ch { const float* Wu; const float* Wp; int wsel; int fsel; };
    // wn (softmax over w[1,3]):  favor=0, click=1, consume=2
    // fwn (softmax over fw[3,1]): favor=0, consume=1, click=2
    Ch chs[3] = { { Wuc,  Wpc,  1, 2 },     // ch0 = click
                  { Wufv, Wpfv, 0, 0 },     // ch1 = favor
                  { Wuco, Wpco, 2, 1 } };   // ch2 = consume

    const int UGB = N_USERS / 64;                 // 625
    const int PGB = (N_POIS + 63) / 64;           // 313
    const int PW = N_POIS * 64 / 256;
    const int UW = N_USERS * 64 / 256;

    auto launch_spmm_poi = [&](int c, const unsigned short* src, unsigned short* raw,
                               const float* base, float* acc) {
        if (c == 0)      spmm_kernel<0><<<PW, 256, 0, stream>>>(cptr, cpack, src, raw, base, acc, N_POIS);
        else if (c == 1) spmm_kernel<1><<<PW, 256, 0, stream>>>(cptr, cpack, src, raw, base, acc, N_POIS);
        else             spmm_kernel<2><<<PW, 256, 0, stream>>>(cptr, cpack, src, raw, base, acc, N_POIS);
    };
    auto launch_spmm_usr = [&](int c, const unsigned short* src, unsigned short* raw,
                               const float* base, float* acc) {
        if (c == 0)      spmm_kernel<0><<<UW, 256, 0, stream>>>(rptr, rpack, src, raw, base, acc, N_USERS);
        else if (c == 1) spmm_kernel<1><<<UW, 256, 0, stream>>>(rptr, rpack, src, raw, base, acc, N_USERS);
        else             spmm_kernel<2><<<UW, 256, 0, stream>>>(rptr, rpack, src, raw, base, acc, N_USERS);
    };
    auto launch_l2u = [&](int c, const unsigned short* src, unsigned short* u1raw) {
        if (c == 0)      spmm_l2u_kernel<0><<<UW, 256, 0, stream>>>(rptr, rpack, src, u1raw, uid, su, N_USERS);
        else if (c == 1) spmm_l2u_kernel<1><<<UW, 256, 0, stream>>>(rptr, rpack, src, u1raw, uid, su, N_USERS);
        else             spmm_l2u_kernel<2><<<UW, 256, 0, stream>>>(rptr, rpack, src, u1raw, uid, su, N_USERS);
    };

    if (fused) {
        // fused 3-channel L1-user hop: one shared pid_h gather, 3 raw outputs
        spmm3_kernel<<<UW, 256, 0, stream>>>(rptr, rpack, pid_h, utr0, utr1, utr2, N_USERS);
        for (int c = 0; c < 3; c++) {
            unsigned short* uc = (c == 0) ? utr0 : ((c == 1) ? utr1 : utr2);
            launch_spmm_poi(c, uc, ptr_h, pid, sp);
            launch_l2u(c, ptr_h, uc);
            launch_spmm_poi(c, uc, ptr_h, sp, sp);
            gemm_mfma_kernel<<<UGB, 256, 0, stream>>>(
                su, chs[c].Wu, nullptr, idf, (c == 2) ? idf_h : nullptr,
                fw3, chs[c].fsel, (c == 0) ? 1 : 0, N_USERS);
            ufsel_kernel<<<BATCH, 128, 0, stream>>>(su, chs[c].Wu, uidx, ufs + (size_t)c * BATCH * DIM);
            gemm_mfma_kernel<<<PGB, 256, 0, stream>>>(
                sp, chs[c].Wp, pf, nullptr, nullptr, fw3, 0, 0, N_POIS);
            predict_kernel<<<BATCH * NPOS * 64 / 256, 256, 0, stream>>>(
                ufs + (size_t)c * BATCH * DIM, pf, pidx, w3, chs[c].wsel, (c == 0) ? 1 : 0, alt);
        }
    } else {
        // proven fallback: per-channel schedule, single utr0 buffer
        for (int c = 0; c < 3; c++) {
            launch_spmm_usr(c, pid_h, utr0, uid, su);
            launch_spmm_poi(c, utr0, ptr_h, pid, sp);
            launch_spmm_usr(c, ptr_h, utr0, su, su);
            launch_spmm_poi(c, utr0, ptr_h, sp, sp);
            gemm_mfma_kernel<<<UGB, 256, 0, stream>>>(
                su, chs[c].Wu, nullptr, idf, (c == 2) ? idf_h : nullptr,
                fw3, chs[c].fsel, (c == 0) ? 1 : 0, N_USERS);
            ufsel_kernel<<<BATCH, 128, 0, stream>>>(su, chs[c].Wu, uidx, ufs + (size_t)c * BATCH * DIM);
            gemm_mfma_kernel<<<PGB, 256, 0, stream>>>(
                sp, chs[c].Wp, pf, nullptr, nullptr, fw3, 0, 0, N_POIS);
            predict_kernel<<<BATCH * NPOS * 64 / 256, 256, 0, stream>>>(
                ufs + (size_t)c * BATCH * DIM, pf, pidx, w3, chs[c].wsel, (c == 0) ? 1 : 0, alt);
        }
    }

    loss_part_kernel<<<LOSS_BLOCKS, 256, 0, stream>>>(alt, labels, losspart);
    loss_final_kernel<<<1, 64, 0, stream>>>(losspart, outp);
    bs_kernel<<<BATCH, 128, 0, stream>>>(idf, Wss, bias, uidx, bst_h);
    dim3 sg(NCHUNK, 4);
    score_topk_kernel<<<sg, 512, 0, stream>>>(idf_h, bst_h, cand_s, cand_i);
    topk_merge_kernel<<<BATCH, NCHUNK, 0, stream>>>(cand_s, cand_i, guf, outp);
}

// Round 11
// 647.390 us; speedup vs baseline: 1.0654x; 1.0210x over previous
//
#include <hip/hip_runtime.h>

#define N_USERS 40000
#define N_POIS  20000
#define DIM     128
#define N_EDGES 500000
#define BATCH   256
#define NPOS    100
#define TOPK    20
#define NCHUNK  128
#define CPT     313   // ceil(40000/128)
#define SCHUNK  1024  // scan chunk (256 thr x 4)
#define RCH     40    // ceil(40000/1024)
#define CCH     20    // ceil(20000/1024)
#define LOSS_BLOCKS 25  // 25600/1024

typedef _Float16 f16x8 __attribute__((ext_vector_type(8)));
typedef float f32x4 __attribute__((ext_vector_type(4)));

__device__ __forceinline__ int iclamp(int x, int lo, int hi) {
    return x < lo ? lo : (x > hi ? hi : x);
}
__device__ __forceinline__ float2 h2f2(unsigned int u) {
    union { unsigned int u32; _Float16 h[2]; } v; v.u32 = u;
    return make_float2((float)v.h[0], (float)v.h[1]);
}
__device__ __forceinline__ unsigned int f2h2(float x, float y) {
    union { unsigned int u32; _Float16 h[2]; } v;
    v.h[0] = (_Float16)x; v.h[1] = (_Float16)y; return v.u32;
}
__device__ __forceinline__ float softmax3(const float* p, int sel) {
    float a0 = p[0], a1 = p[1], a2 = p[2];
    float m = fmaxf(a0, fmaxf(a1, a2));
    float e0 = expf(a0 - m), e1 = expf(a1 - m), e2 = expf(a2 - m);
    float den = e0 + e1 + e2;
    float e = (sel == 0) ? e0 : ((sel == 1) ? e1 : e2);
    return e / den;
}
// compile-time channel pick from packed edge {idx, v0, v1, v2}
template<int CH>
__device__ __forceinline__ float pickvT(int4 q) {
    return __int_as_float(CH == 0 ? q.y : (CH == 1 ? q.z : q.w));
}
// build fp16x8 fragment from 8 contiguous fp32
__device__ __forceinline__ f16x8 frag8(const float* p) {
    float4 x = *(const float4*)(p);
    float4 y = *(const float4*)(p + 4);
    f16x8 f;
    f[0] = (_Float16)x.x; f[1] = (_Float16)x.y; f[2] = (_Float16)x.z; f[3] = (_Float16)x.w;
    f[4] = (_Float16)y.x; f[5] = (_Float16)y.y; f[6] = (_Float16)y.z; f[7] = (_Float16)y.w;
    return f;
}

// ---------------- zero init ----------------
__global__ void zero_kernel(unsigned int* __restrict__ p, int nwords) {
    int i = blockIdx.x * blockDim.x + threadIdx.x;
    if (i < nwords) p[i] = 0u;
}

// ---------------- fp32 -> fp16 cast ----------------
__global__ void cast_f16_kernel(const float* __restrict__ src, unsigned short* __restrict__ dst,
                                int n2) {
    int i = blockIdx.x * blockDim.x + threadIdx.x;
    if (i < n2) {
        float2 v = *(const float2*)(src + 2 * (size_t)i);
        *(unsigned int*)(dst + 2 * (size_t)i) = f2h2(v.x, v.y);
    }
}

// ---------------- CSR hist: counts + per-edge within-row/col ordinals ----------------
__global__ void hist_kernel(const int* __restrict__ er, const int* __restrict__ ec,
                            int* __restrict__ rcnt, int* __restrict__ ccnt,
                            int* __restrict__ rord, int* __restrict__ cord) {
    int e0 = 4 * (blockIdx.x * blockDim.x + threadIdx.x);
    if (e0 + 4 <= N_EDGES) {
        int4 r4 = *(const int4*)(er + e0);
        int4 c4 = *(const int4*)(ec + e0);
        int rr[4] = { r4.x, r4.y, r4.z, r4.w };
        int cc[4] = { c4.x, c4.y, c4.z, c4.w };
        int ro[4], co[4];
        #pragma unroll
        for (int j = 0; j < 4; j++) {
            ro[j] = atomicAdd(&rcnt[iclamp(rr[j], 0, N_USERS - 1)], 1);
            co[j] = atomicAdd(&ccnt[iclamp(cc[j], 0, N_POIS - 1)], 1);
        }
        *(int4*)(rord + e0) = make_int4(ro[0], ro[1], ro[2], ro[3]);
        *(int4*)(cord + e0) = make_int4(co[0], co[1], co[2], co[3]);
    } else {
        for (int e = e0; e < N_EDGES; e++) {
            rord[e] = atomicAdd(&rcnt[iclamp(er[e], 0, N_USERS - 1)], 1);
            cord[e] = atomicAdd(&ccnt[iclamp(ec[e], 0, N_POIS - 1)], 1);
        }
    }
}

// ---------------- parallel prefix sum, stage 1: per-1024-chunk sums ----------------
__global__ void chunksum_kernel(const int* __restrict__ rcnt, const int* __restrict__ ccnt,
                                int* __restrict__ rsum, int* __restrict__ csum) {
    int side = blockIdx.y;
    const int* cnt = side ? ccnt : rcnt;
    int n = side ? N_POIS : N_USERS;
    int nch = side ? CCH : RCH;
    int b = blockIdx.x;
    if (b >= nch) return;
    int t = threadIdx.x;
    int i = b * SCHUNK + t * 4;
    int s = 0;
    if (i + 4 <= n) {
        int4 v = *(const int4*)(cnt + i);
        s = v.x + v.y + v.z + v.w;
    } else {
        for (int j = i; j < n; j++) s += cnt[j];
    }
    __shared__ int red[256];
    red[t] = s;
    __syncthreads();
    for (int o = 128; o > 0; o >>= 1) {
        if (t < o) red[t] += red[t + o];
        __syncthreads();
    }
    if (t == 0) (side ? csum : rsum)[b] = red[0];
}

// ---------------- stage 2: scan chunk sums (wave shfl), write totals ----------------
__global__ void chunkscan_kernel(const int* __restrict__ rsum, const int* __restrict__ csum,
                                 int* __restrict__ rbase, int* __restrict__ cbase,
                                 int* __restrict__ rptr, int* __restrict__ cptr) {
    int w = threadIdx.x >> 6, l = threadIdx.x & 63;  // block 128: wave0=users, wave1=pois
    const int* src = w ? csum : rsum;
    int* dst = w ? cbase : rbase;
    int nch = w ? CCH : RCH;
    int orig = (l < nch) ? src[l] : 0;
    int v = orig;
    #pragma unroll
    for (int o = 1; o < 64; o <<= 1) {
        int u = __shfl_up(v, o, 64);
        if (l >= o) v += u;
    }
    if (l < nch) dst[l] = v - orig;                 // exclusive base
    if (l == nch - 1) {
        if (w) cptr[N_POIS] = v; else rptr[N_USERS] = v;
    }
}

// ---------------- stage 3: block scan within chunk + chunk base ----------------
__global__ void scatterscan_kernel(const int* __restrict__ rcnt, const int* __restrict__ ccnt,
                                   const int* __restrict__ rbase, const int* __restrict__ cbase,
                                   int* __restrict__ rptr, int* __restrict__ cptr) {
    int side = blockIdx.y;
    const int* cnt = side ? ccnt : rcnt;
    const int* basea = side ? cbase : rbase;
    int* ptr = side ? cptr : rptr;
    int n = side ? N_POIS : N_USERS;
    int nch = side ? CCH : RCH;
    int b = blockIdx.x;
    if (b >= nch) return;
    int t = threadIdx.x;
    int i = b * SCHUNK + t * 4;
    int c0 = 0, c1 = 0, c2 = 0, c3 = 0;
    if (i + 4 <= n) {
        int4 v = *(const int4*)(cnt + i);
        c0 = v.x; c1 = v.y; c2 = v.z; c3 = v.w;
    } else {
        if (i + 0 < n) c0 = cnt[i + 0];
        if (i + 1 < n) c1 = cnt[i + 1];
        if (i + 2 < n) c2 = cnt[i + 2];
    }
    int tsum = c0 + c1 + c2 + c3;
    int l = t & 63, w = t >> 6;
    int v = tsum;
    #pragma unroll
    for (int o = 1; o < 64; o <<= 1) {
        int u = __shfl_up(v, o, 64);
        if (l >= o) v += u;
    }
    __shared__ int wsum[4];
    if (l == 63) wsum[w] = v;
    __syncthreads();
    int wbase = 0;
    for (int k = 0; k < w; k++) wbase += wsum[k];
    int ex = v - tsum + wbase + basea[b];
    if (i + 4 <= n) {
        *(int4*)(ptr + i) = make_int4(ex, ex + c0, ex + c0 + c1, ex + c0 + c1 + c2);
    } else {
        if (i + 0 < n) ptr[i + 0] = ex;
        if (i + 1 < n) ptr[i + 1] = ex + c0;
        if (i + 2 < n) ptr[i + 2] = ex + c0 + c1;
    }
}

// ---------------- AoS CSR fill: NO atomics (slots precomputed in hist) ----------------
__global__ void fill_kernel(const int* __restrict__ er, const int* __restrict__ ec,
                            const int* __restrict__ rptr, const int* __restrict__ cptr,
                            const int* __restrict__ rord, const int* __restrict__ cord,
                            int4* __restrict__ rpack, int4* __restrict__ cpack,
                            const float* __restrict__ ck, const float* __restrict__ fv,
                            const float* __restrict__ cs) {
    int e0 = 4 * (blockIdx.x * blockDim.x + threadIdx.x);
    if (e0 + 4 <= N_EDGES) {
        int4 r4 = *(const int4*)(er + e0);
        int4 c4 = *(const int4*)(ec + e0);
        int4 ro4 = *(const int4*)(rord + e0);
        int4 co4 = *(const int4*)(cord + e0);
        float4 k4 = *(const float4*)(ck + e0);
        float4 f4 = *(const float4*)(fv + e0);
        float4 s4 = *(const float4*)(cs + e0);
        int rr[4] = { r4.x, r4.y, r4.z, r4.w };
        int cc[4] = { c4.x, c4.y, c4.z, c4.w };
        int ro[4] = { ro4.x, ro4.y, ro4.z, ro4.w };
        int co[4] = { co4.x, co4.y, co4.z, co4.w };
        float kk[4] = { k4.x, k4.y, k4.z, k4.w };
        float ff[4] = { f4.x, f4.y, f4.z, f4.w };
        float ss[4] = { s4.x, s4.y, s4.z, s4.w };
        #pragma unroll
        for (int j = 0; j < 4; j++) {
            int r = iclamp(rr[j], 0, N_USERS - 1), c = iclamp(cc[j], 0, N_POIS - 1);
            int v0 = __float_as_int(kk[j]);
            int v1 = __float_as_int(ff[j]);
            int v2 = __float_as_int(ss[j]);
            int pr = iclamp(rptr[r] + ro[j], 0, N_EDGES - 1);
            rpack[pr] = make_int4(c, v0, v1, v2);
            int pc = iclamp(cptr[c] + co[j], 0, N_EDGES - 1);
            cpack[pc] = make_int4(r, v0, v1, v2);
        }
    } else {
        for (int e = e0; e < N_EDGES; e++) {
            int r = iclamp(er[e], 0, N_USERS - 1), c = iclamp(ec[e], 0, N_POIS - 1);
            int v0 = __float_as_int(ck[e]);
            int v1 = __float_as_int(fv[e]);
            int v2 = __float_as_int(cs[e]);
            int pr = iclamp(rptr[r] + rord[e], 0, N_EDGES - 1);
            rpack[pr] = make_int4(c, v0, v1, v2);
            int pc = iclamp(cptr[c] + cord[e], 0, N_EDGES - 1);
            cpack[pc] = make_int4(r, v0, v1, v2);
        }
    }
}

// ---------------- SpMM: one wave per row; packed edges; fp16 src gather ----------------
// raw_h (fp16) = A*src ; acc (fp32) = base + raw/||raw||
template<int CH>
__global__ __launch_bounds__(256) void spmm_kernel(
        const int* __restrict__ ptr, const int4* __restrict__ pack,
        const unsigned short* __restrict__ src,         // fp16 [*,128]
        unsigned short* __restrict__ raw_h,             // fp16 out
        const float* __restrict__ base,                 // fp32 (may alias acc)
        float* __restrict__ acc, int nrows) {
    int wid = (blockIdx.x * blockDim.x + threadIdx.x) >> 6;
    int lane = threadIdx.x & 63;
    if (wid >= nrows) return;
    int beg = __builtin_amdgcn_readfirstlane(iclamp(ptr[wid], 0, N_EDGES));
    int end = __builtin_amdgcn_readfirstlane(iclamp(ptr[wid + 1], 0, N_EDGES));
    if (end < beg) end = beg;
    float ax = 0.f, ay = 0.f;
    int e = beg;
    int lo2 = lane * 2;
    for (; e + 8 <= end; e += 8) {
        int4 q0 = pack[e + 0], q1 = pack[e + 1], q2 = pack[e + 2], q3 = pack[e + 3];
        int4 q4 = pack[e + 4], q5 = pack[e + 5], q6 = pack[e + 6], q7 = pack[e + 7];
        float v0 = pickvT<CH>(q0), v1 = pickvT<CH>(q1), v2 = pickvT<CH>(q2), v3 = pickvT<CH>(q3);
        float v4 = pickvT<CH>(q4), v5 = pickvT<CH>(q5), v6 = pickvT<CH>(q6), v7 = pickvT<CH>(q7);
        float2 p0 = h2f2(*(const unsigned int*)(src + (size_t)q0.x * DIM + lo2));
        float2 p1 = h2f2(*(const unsigned int*)(src + (size_t)q1.x * DIM + lo2));
        float2 p2 = h2f2(*(const unsigned int*)(src + (size_t)q2.x * DIM + lo2));
        float2 p3 = h2f2(*(const unsigned int*)(src + (size_t)q3.x * DIM + lo2));
        float2 p4 = h2f2(*(const unsigned int*)(src + (size_t)q4.x * DIM + lo2));
        float2 p5 = h2f2(*(const unsigned int*)(src + (size_t)q5.x * DIM + lo2));
        float2 p6 = h2f2(*(const unsigned int*)(src + (size_t)q6.x * DIM + lo2));
        float2 p7 = h2f2(*(const unsigned int*)(src + (size_t)q7.x * DIM + lo2));
        ax = fmaf(v0, p0.x, fmaf(v1, p1.x, fmaf(v2, p2.x, fmaf(v3, p3.x, ax))));
        ax = fmaf(v4, p4.x, fmaf(v5, p5.x, fmaf(v6, p6.x, fmaf(v7, p7.x, ax))));
        ay = fmaf(v0, p0.y, fmaf(v1, p1.y, fmaf(v2, p2.y, fmaf(v3, p3.y, ay))));
        ay = fmaf(v4, p4.y, fmaf(v5, p5.y, fmaf(v6, p6.y, fmaf(v7, p7.y, ay))));
    }
    if (e < end) {
        int last = end - 1;
        int e1 = e + 1 <= last ? e + 1 : last;
        int e2 = e + 2 <= last ? e + 2 : last;
        int e3 = e + 3 <= last ? e + 3 : last;
        int e4 = e + 4 <= last ? e + 4 : last;
        int e5 = e + 5 <= last ? e + 5 : last;
        int e6 = e + 6 <= last ? e + 6 : last;
        int e7 = e + 7 <= last ? e + 7 : last;
        int4 q0 = pack[e], q1 = pack[e1], q2 = pack[e2], q3 = pack[e3];
        int4 q4 = pack[e4], q5 = pack[e5], q6 = pack[e6], q7 = pack[e7];
        float v0 = pickvT<CH>(q0);
        float v1 = (e + 1 < end) ? pickvT<CH>(q1) : 0.f;
        float v2 = (e + 2 < end) ? pickvT<CH>(q2) : 0.f;
        float v3 = (e + 3 < end) ? pickvT<CH>(q3) : 0.f;
        float v4 = (e + 4 < end) ? pickvT<CH>(q4) : 0.f;
        float v5 = (e + 5 < end) ? pickvT<CH>(q5) : 0.f;
        float v6 = (e + 6 < end) ? pickvT<CH>(q6) : 0.f;
        float v7 = (e + 7 < end) ? pickvT<CH>(q7) : 0.f;
        float2 p0 = h2f2(*(const unsigned int*)(src + (size_t)q0.x * DIM + lo2));
        float2 p1 = h2f2(*(const unsigned int*)(src + (size_t)q1.x * DIM + lo2));
        float2 p2 = h2f2(*(const unsigned int*)(src + (size_t)q2.x * DIM + lo2));
        float2 p3 = h2f2(*(const unsigned int*)(src + (size_t)q3.x * DIM + lo2));
        float2 p4 = h2f2(*(const unsigned int*)(src + (size_t)q4.x * DIM + lo2));
        float2 p5 = h2f2(*(const unsigned int*)(src + (size_t)q5.x * DIM + lo2));
        float2 p6 = h2f2(*(const unsigned int*)(src + (size_t)q6.x * DIM + lo2));
        float2 p7 = h2f2(*(const unsigned int*)(src + (size_t)q7.x * DIM + lo2));
        ax = fmaf(v0, p0.x, fmaf(v1, p1.x, fmaf(v2, p2.x, fmaf(v3, p3.x, ax))));
        ax = fmaf(v4, p4.x, fmaf(v5, p5.x, fmaf(v6, p6.x, fmaf(v7, p7.x, ax))));
        ay = fmaf(v0, p0.y, fmaf(v1, p1.y, fmaf(v2, p2.y, fmaf(v3, p3.y, ay))));
        ay = fmaf(v4, p4.y, fmaf(v5, p5.y, fmaf(v6, p6.y, fmaf(v7, p7.y, ay))));
    }
    float n2 = ax * ax + ay * ay;
    #pragma unroll
    for (int o = 32; o > 0; o >>= 1) n2 += __shfl_xor(n2, o, 64);
    float inv = rsqrtf(fmaxf(n2, 1e-30f));
    *(unsigned int*)(raw_h + (size_t)wid * DIM + lo2) = f2h2(ax, ay);
    float2 bv = *(const float2*)(base + (size_t)wid * DIM + lo2);
    *(float2*)(acc + (size_t)wid * DIM + lo2) =
        make_float2(bv.x + ax * inv, bv.y + ay * inv);
}

// ---------------- fused 3-channel L1-user SpMM: shared src gather, 3 raw outputs ----------------
__global__ __launch_bounds__(256) void spmm3_kernel(
        const int* __restrict__ ptr, const int4* __restrict__ pack,
        const unsigned short* __restrict__ src,     // pid_h (shared across channels)
        unsigned short* __restrict__ r0, unsigned short* __restrict__ r1,
        unsigned short* __restrict__ r2, int nrows) {
    int wid = (blockIdx.x * blockDim.x + threadIdx.x) >> 6;
    int lane = threadIdx.x & 63;
    if (wid >= nrows) return;
    int beg = __builtin_amdgcn_readfirstlane(iclamp(ptr[wid], 0, N_EDGES));
    int end = __builtin_amdgcn_readfirstlane(iclamp(ptr[wid + 1], 0, N_EDGES));
    if (end < beg) end = beg;
    float a0x = 0.f, a0y = 0.f, a1x = 0.f, a1y = 0.f, a2x = 0.f, a2y = 0.f;
    int e = beg;
    int lo2 = lane * 2;
    for (; e + 4 <= end; e += 4) {
        int4 q0 = pack[e + 0], q1 = pack[e + 1], q2 = pack[e + 2], q3 = pack[e + 3];
        float2 p0 = h2f2(*(const unsigned int*)(src + (size_t)q0.x * DIM + lo2));
        float2 p1 = h2f2(*(const unsigned int*)(src + (size_t)q1.x * DIM + lo2));
        float2 p2 = h2f2(*(const unsigned int*)(src + (size_t)q2.x * DIM + lo2));
        float2 p3 = h2f2(*(const unsigned int*)(src + (size_t)q3.x * DIM + lo2));
        a0x = fmaf(__int_as_float(q0.y), p0.x, fmaf(__int_as_float(q1.y), p1.x,
              fmaf(__int_as_float(q2.y), p2.x, fmaf(__int_as_float(q3.y), p3.x, a0x))));
        a0y = fmaf(__int_as_float(q0.y), p0.y, fmaf(__int_as_float(q1.y), p1.y,
              fmaf(__int_as_float(q2.y), p2.y, fmaf(__int_as_float(q3.y), p3.y, a0y))));
        a1x = fmaf(__int_as_float(q0.z), p0.x, fmaf(__int_as_float(q1.z), p1.x,
              fmaf(__int_as_float(q2.z), p2.x, fmaf(__int_as_float(q3.z), p3.x, a1x))));
        a1y = fmaf(__int_as_float(q0.z), p0.y, fmaf(__int_as_float(q1.z), p1.y,
              fmaf(__int_as_float(q2.z), p2.y, fmaf(__int_as_float(q3.z), p3.y, a1y))));
        a2x = fmaf(__int_as_float(q0.w), p0.x, fmaf(__int_as_float(q1.w), p1.x,
              fmaf(__int_as_float(q2.w), p2.x, fmaf(__int_as_float(q3.w), p3.x, a2x))));
        a2y = fmaf(__int_as_float(q0.w), p0.y, fmaf(__int_as_float(q1.w), p1.y,
              fmaf(__int_as_float(q2.w), p2.y, fmaf(__int_as_float(q3.w), p3.y, a2y))));
    }
    for (; e < end; e++) {
        int4 q = pack[e];
        float2 p = h2f2(*(const unsigned int*)(src + (size_t)q.x * DIM + lo2));
        a0x = fmaf(__int_as_float(q.y), p.x, a0x);
        a0y = fmaf(__int_as_float(q.y), p.y, a0y);
        a1x = fmaf(__int_as_float(q.z), p.x, a1x);
        a1y = fmaf(__int_as_float(q.z), p.y, a1y);
        a2x = fmaf(__int_as_float(q.w), p.x, a2x);
        a2y = fmaf(__int_as_float(q.w), p.y, a2y);
    }
    size_t o = (size_t)wid * DIM + lo2;
    *(unsigned int*)(r0 + o) = f2h2(a0x, a0y);
    *(unsigned int*)(r1 + o) = f2h2(a1x, a1y);
    *(unsigned int*)(r2 + o) = f2h2(a2x, a2y);
}

// ---------------- fused 3-channel L1-poi SpMM: 3 distinct srcs (u1 per channel) ----------------
// p1_c = A^T u1_c ; outputs raw fp16 only (sp deferred to spmm_l2p)
__global__ __launch_bounds__(256) void spmm3p_kernel(
        const int* __restrict__ ptr, const int4* __restrict__ pack,
        const unsigned short* __restrict__ s0, const unsigned short* __restrict__ s1,
        const unsigned short* __restrict__ s2,
        unsigned short* __restrict__ r0, unsigned short* __restrict__ r1,
        unsigned short* __restrict__ r2, int nrows) {
    int wid = (blockIdx.x * blockDim.x + threadIdx.x) >> 6;
    int lane = threadIdx.x & 63;
    if (wid >= nrows) return;
    int beg = __builtin_amdgcn_readfirstlane(iclamp(ptr[wid], 0, N_EDGES));
    int end = __builtin_amdgcn_readfirstlane(iclamp(ptr[wid + 1], 0, N_EDGES));
    if (end < beg) end = beg;
    float a0x = 0.f, a0y = 0.f, a1x = 0.f, a1y = 0.f, a2x = 0.f, a2y = 0.f;
    int e = beg;
    int lo2 = lane * 2;
    for (; e + 4 <= end; e += 4) {
        int4 q0 = pack[e + 0], q1 = pack[e + 1], q2 = pack[e + 2], q3 = pack[e + 3];
        size_t o0 = (size_t)q0.x * DIM + lo2, o1 = (size_t)q1.x * DIM + lo2;
        size_t o2 = (size_t)q2.x * DIM + lo2, o3 = (size_t)q3.x * DIM + lo2;
        float2 u00 = h2f2(*(const unsigned int*)(s0 + o0));
        float2 u01 = h2f2(*(const unsigned int*)(s0 + o1));
        float2 u02 = h2f2(*(const unsigned int*)(s0 + o2));
        float2 u03 = h2f2(*(const unsigned int*)(s0 + o3));
        float2 u10 = h2f2(*(const unsigned int*)(s1 + o0));
        float2 u11 = h2f2(*(const unsigned int*)(s1 + o1));
        float2 u12 = h2f2(*(const unsigned int*)(s1 + o2));
        float2 u13 = h2f2(*(const unsigned int*)(s1 + o3));
        float2 u20 = h2f2(*(const unsigned int*)(s2 + o0));
        float2 u21 = h2f2(*(const unsigned int*)(s2 + o1));
        float2 u22 = h2f2(*(const unsigned int*)(s2 + o2));
        float2 u23 = h2f2(*(const unsigned int*)(s2 + o3));
        a0x = fmaf(__int_as_float(q0.y), u00.x, fmaf(__int_as_float(q1.y), u01.x,
              fmaf(__int_as_float(q2.y), u02.x, fmaf(__int_as_float(q3.y), u03.x, a0x))));
        a0y = fmaf(__int_as_float(q0.y), u00.y, fmaf(__int_as_float(q1.y), u01.y,
              fmaf(__int_as_float(q2.y), u02.y, fmaf(__int_as_float(q3.y), u03.y, a0y))));
        a1x = fmaf(__int_as_float(q0.z), u10.x, fmaf(__int_as_float(q1.z), u11.x,
              fmaf(__int_as_float(q2.z), u12.x, fmaf(__int_as_float(q3.z), u13.x, a1x))));
        a1y = fmaf(__int_as_float(q0.z), u10.y, fmaf(__int_as_float(q1.z), u11.y,
              fmaf(__int_as_float(q2.z), u12.y, fmaf(__int_as_float(q3.z), u13.y, a1y))));
        a2x = fmaf(__int_as_float(q0.w), u20.x, fmaf(__int_as_float(q1.w), u21.x,
              fmaf(__int_as_float(q2.w), u22.x, fmaf(__int_as_float(q3.w), u23.x, a2x))));
        a2y = fmaf(__int_as_float(q0.w), u20.y, fmaf(__int_as_float(q1.w), u21.y,
              fmaf(__int_as_float(q2.w), u22.y, fmaf(__int_as_float(q3.w), u23.y, a2y))));
    }
    for (; e < end; e++) {
        int4 q = pack[e];
        size_t o = (size_t)q.x * DIM + lo2;
        float2 p0 = h2f2(*(const unsigned int*)(s0 + o));
        float2 p1 = h2f2(*(const unsigned int*)(s1 + o));
        float2 p2 = h2f2(*(const unsigned int*)(s2 + o));
        a0x = fmaf(__int_as_float(q.y), p0.x, a0x);
        a0y = fmaf(__int_as_float(q.y), p0.y, a0y);
        a1x = fmaf(__int_as_float(q.z), p1.x, a1x);
        a1y = fmaf(__int_as_float(q.z), p1.y, a1y);
        a2x = fmaf(__int_as_float(q.w), p2.x, a2x);
        a2y = fmaf(__int_as_float(q.w), p2.y, a2y);
    }
    size_t o = (size_t)wid * DIM + lo2;
    *(unsigned int*)(r0 + o) = f2h2(a0x, a0y);
    *(unsigned int*)(r1 + o) = f2h2(a1x, a1y);
    *(unsigned int*)(r2 + o) = f2h2(a2x, a2y);
}

// ---------------- L2-user SpMM: su = uid + n(u1) + n(u2); u1raw overwritten with u2 ----------------
template<int CH>
__global__ __launch_bounds__(256) void spmm_l2u_kernel(
        const int* __restrict__ ptr, const int4* __restrict__ pack,
        const unsigned short* __restrict__ src,     // p1raw_c fp16
        unsigned short* __restrict__ u1raw,         // in: u1 raw; out: u2 raw
        const float* __restrict__ uid,
        float* __restrict__ su, int nrows) {
    int wid = (blockIdx.x * blockDim.x + threadIdx.x) >> 6;
    int lane = threadIdx.x & 63;
    if (wid >= nrows) return;
    int beg = __builtin_amdgcn_readfirstlane(iclamp(ptr[wid], 0, N_EDGES));
    int end = __builtin_amdgcn_readfirstlane(iclamp(ptr[wid + 1], 0, N_EDGES));
    if (end < beg) end = beg;
    float ax = 0.f, ay = 0.f;
    int e = beg;
    int lo2 = lane * 2;
    for (; e + 8 <= end; e += 8) {
        int4 q0 = pack[e + 0], q1 = pack[e + 1], q2 = pack[e + 2], q3 = pack[e + 3];
        int4 q4 = pack[e + 4], q5 = pack[e + 5], q6 = pack[e + 6], q7 = pack[e + 7];
        float v0 = pickvT<CH>(q0), v1 = pickvT<CH>(q1), v2 = pickvT<CH>(q2), v3 = pickvT<CH>(q3);
        float v4 = pickvT<CH>(q4), v5 = pickvT<CH>(q5), v6 = pickvT<CH>(q6), v7 = pickvT<CH>(q7);
        float2 p0 = h2f2(*(const unsigned int*)(src + (size_t)q0.x * DIM + lo2));
        float2 p1 = h2f2(*(const unsigned int*)(src + (size_t)q1.x * DIM + lo2));
        float2 p2 = h2f2(*(const unsigned int*)(src + (size_t)q2.x * DIM + lo2));
        float2 p3 = h2f2(*(const unsigned int*)(src + (size_t)q3.x * DIM + lo2));
        float2 p4 = h2f2(*(const unsigned int*)(src + (size_t)q4.x * DIM + lo2));
        float2 p5 = h2f2(*(const unsigned int*)(src + (size_t)q5.x * DIM + lo2));
        float2 p6 = h2f2(*(const unsigned int*)(src + (size_t)q6.x * DIM + lo2));
        float2 p7 = h2f2(*(const unsigned int*)(src + (size_t)q7.x * DIM + lo2));
        ax = fmaf(v0, p0.x, fmaf(v1, p1.x, fmaf(v2, p2.x, fmaf(v3, p3.x, ax))));
        ax = fmaf(v4, p4.x, fmaf(v5, p5.x, fmaf(v6, p6.x, fmaf(v7, p7.x, ax))));
        ay = fmaf(v0, p0.y, fmaf(v1, p1.y, fmaf(v2, p2.y, fmaf(v3, p3.y, ay))));
        ay = fmaf(v4, p4.y, fmaf(v5, p5.y, fmaf(v6, p6.y, fmaf(v7, p7.y, ay))));
    }
    if (e < end) {
        int last = end - 1;
        int e1 = e + 1 <= last ? e + 1 : last;
        int e2 = e + 2 <= last ? e + 2 : last;
        int e3 = e + 3 <= last ? e + 3 : last;
        int e4 = e + 4 <= last ? e + 4 : last;
        int e5 = e + 5 <= last ? e + 5 : last;
        int e6 = e + 6 <= last ? e + 6 : last;
        int e7 = e + 7 <= last ? e + 7 : last;
        int4 q0 = pack[e], q1 = pack[e1], q2 = pack[e2], q3 = pack[e3];
        int4 q4 = pack[e4], q5 = pack[e5], q6 = pack[e6], q7 = pack[e7];
        float v0 = pickvT<CH>(q0);
        float v1 = (e + 1 < end) ? pickvT<CH>(q1) : 0.f;
        float v2 = (e + 2 < end) ? pickvT<CH>(q2) : 0.f;
        float v3 = (e + 3 < end) ? pickvT<CH>(q3) : 0.f;
        float v4 = (e + 4 < end) ? pickvT<CH>(q4) : 0.f;
        float v5 = (e + 5 < end) ? pickvT<CH>(q5) : 0.f;
        float v6 = (e + 6 < end) ? pickvT<CH>(q6) : 0.f;
        float v7 = (e + 7 < end) ? pickvT<CH>(q7) : 0.f;
        float2 p0 = h2f2(*(const unsigned int*)(src + (size_t)q0.x * DIM + lo2));
        float2 p1 = h2f2(*(const unsigned int*)(src + (size_t)q1.x * DIM + lo2));
        float2 p2 = h2f2(*(const unsigned int*)(src + (size_t)q2.x * DIM + lo2));
        float2 p3 = h2f2(*(const unsigned int*)(src + (size_t)q3.x * DIM + lo2));
        float2 p4 = h2f2(*(const unsigned int*)(src + (size_t)q4.x * DIM + lo2));
        float2 p5 = h2f2(*(const unsigned int*)(src + (size_t)q5.x * DIM + lo2));
        float2 p6 = h2f2(*(const unsigned int*)(src + (size_t)q6.x * DIM + lo2));
        float2 p7 = h2f2(*(const unsigned int*)(src + (size_t)q7.x * DIM + lo2));
        ax = fmaf(v0, p0.x, fmaf(v1, p1.x, fmaf(v2, p2.x, fmaf(v3, p3.x, ax))));
        ax = fmaf(v4, p4.x, fmaf(v5, p5.x, fmaf(v6, p6.x, fmaf(v7, p7.x, ax))));
        ay = fmaf(v0, p0.y, fmaf(v1, p1.y, fmaf(v2, p2.y, fmaf(v3, p3.y, ay))));
        ay = fmaf(v4, p4.y, fmaf(v5, p5.y, fmaf(v6, p6.y, fmaf(v7, p7.y, ay))));
    }
    size_t o = (size_t)wid * DIM + lo2;
    float2 u1 = h2f2(*(const unsigned int*)(u1raw + o));
    float n2a = ax * ax + ay * ay;        // u2
    float n2b = u1.x * u1.x + u1.y * u1.y; // u1
    #pragma unroll
    for (int oo = 32; oo > 0; oo >>= 1) {
        n2a += __shfl_xor(n2a, oo, 64);
        n2b += __shfl_xor(n2b, oo, 64);
    }
    float i2 = rsqrtf(fmaxf(n2a, 1e-30f));
    float i1 = rsqrtf(fmaxf(n2b, 1e-30f));
    *(unsigned int*)(u1raw + o) = f2h2(ax, ay);   // u2 raw (src for L2-poi)
    float2 bv = *(const float2*)(uid + o);
    *(float2*)(su + o) = make_float2(bv.x + u1.x * i1 + ax * i2,
                                     bv.y + u1.y * i1 + ay * i2);
}

// ---------------- L2-poi SpMM: sp = pid + n(p1) + n(p2); p1 from p1raw ----------------
template<int CH>
__global__ __launch_bounds__(256) void spmm_l2p_kernel(
        const int* __restrict__ ptr, const int4* __restrict__ pack,
        const unsigned short* __restrict__ src,     // u2raw_c fp16
        const unsigned short* __restrict__ p1raw,   // p1raw_c fp16
        const float* __restrict__ pid,
        float* __restrict__ sp, int nrows) {
    int wid = (blockIdx.x * blockDim.x + threadIdx.x) >> 6;
    int lane = threadIdx.x & 63;
    if (wid >= nrows) return;
    int beg = __builtin_amdgcn_readfirstlane(iclamp(ptr[wid], 0, N_EDGES));
    int end = __builtin_amdgcn_readfirstlane(iclamp(ptr[wid + 1], 0, N_EDGES));
    if (end < beg) end = beg;
    float ax = 0.f, ay = 0.f;
    int e = beg;
    int lo2 = lane * 2;
    for (; e + 8 <= end; e += 8) {
        int4 q0 = pack[e + 0], q1 = pack[e + 1], q2 = pack[e + 2], q3 = pack[e + 3];
        int4 q4 = pack[e + 4], q5 = pack[e + 5], q6 = pack[e + 6], q7 = pack[e + 7];
        float v0 = pickvT<CH>(q0), v1 = pickvT<CH>(q1), v2 = pickvT<CH>(q2), v3 = pickvT<CH>(q3);
        float v4 = pickvT<CH>(q4), v5 = pickvT<CH>(q5), v6 = pickvT<CH>(q6), v7 = pickvT<CH>(q7);
        float2 p0 = h2f2(*(const unsigned int*)(src + (size_t)q0.x * DIM + lo2));
        float2 p1 = h2f2(*(const unsigned int*)(src + (size_t)q1.x * DIM + lo2));
        float2 p2 = h2f2(*(const unsigned int*)(src + (size_t)q2.x * DIM + lo2));
        float2 p3 = h2f2(*(const unsigned int*)(src + (size_t)q3.x * DIM + lo2));
        float2 p4 = h2f2(*(const unsigned int*)(src + (size_t)q4.x * DIM + lo2));
        float2 p5 = h2f2(*(const unsigned int*)(src + (size_t)q5.x * DIM + lo2));
        float2 p6 = h2f2(*(const unsigned int*)(src + (size_t)q6.x * DIM + lo2));
        float2 p7 = h2f2(*(const unsigned int*)(src + (size_t)q7.x * DIM + lo2));
        ax = fmaf(v0, p0.x, fmaf(v1, p1.x, fmaf(v2, p2.x, fmaf(v3, p3.x, ax))));
        ax = fmaf(v4, p4.x, fmaf(v5, p5.x, fmaf(v6, p6.x, fmaf(v7, p7.x, ax))));
        ay = fmaf(v0, p0.y, fmaf(v1, p1.y, fmaf(v2, p2.y, fmaf(v3, p3.y, ay))));
        ay = fmaf(v4, p4.y, fmaf(v5, p5.y, fmaf(v6, p6.y, fmaf(v7, p7.y, ay))));
    }
    if (e < end) {
        int last = end - 1;
        int e1 = e + 1 <= last ? e + 1 : last;
        int e2 = e + 2 <= last ? e + 2 : last;
        int e3 = e + 3 <= last ? e + 3 : last;
        int e4 = e + 4 <= last ? e + 4 : last;
        int e5 = e + 5 <= last ? e + 5 : last;
        int e6 = e + 6 <= last ? e + 6 : last;
        int e7 = e + 7 <= last ? e + 7 : last;
        int4 q0 = pack[e], q1 = pack[e1], q2 = pack[e2], q3 = pack[e3];
        int4 q4 = pack[e4], q5 = pack[e5], q6 = pack[e6], q7 = pack[e7];
        float v0 = pickvT<CH>(q0);
        float v1 = (e + 1 < end) ? pickvT<CH>(q1) : 0.f;
        float v2 = (e + 2 < end) ? pickvT<CH>(q2) : 0.f;
        float v3 = (e + 3 < end) ? pickvT<CH>(q3) : 0.f;
        float v4 = (e + 4 < end) ? pickvT<CH>(q4) : 0.f;
        float v5 = (e + 5 < end) ? pickvT<CH>(q5) : 0.f;
        float v6 = (e + 6 < end) ? pickvT<CH>(q6) : 0.f;
        float v7 = (e + 7 < end) ? pickvT<CH>(q7) : 0.f;
        float2 p0 = h2f2(*(const unsigned int*)(src + (size_t)q0.x * DIM + lo2));
        float2 p1 = h2f2(*(const unsigned int*)(src + (size_t)q1.x * DIM + lo2));
        float2 p2 = h2f2(*(const unsigned int*)(src + (size_t)q2.x * DIM + lo2));
        float2 p3 = h2f2(*(const unsigned int*)(src + (size_t)q3.x * DIM + lo2));
        float2 p4 = h2f2(*(const unsigned int*)(src + (size_t)q4.x * DIM + lo2));
        float2 p5 = h2f2(*(const unsigned int*)(src + (size_t)q5.x * DIM + lo2));
        float2 p6 = h2f2(*(const unsigned int*)(src + (size_t)q6.x * DIM + lo2));
        float2 p7 = h2f2(*(const unsigned int*)(src + (size_t)q7.x * DIM + lo2));
        ax = fmaf(v0, p0.x, fmaf(v1, p1.x, fmaf(v2, p2.x, fmaf(v3, p3.x, ax))));
        ax = fmaf(v4, p4.x, fmaf(v5, p5.x, fmaf(v6, p6.x, fmaf(v7, p7.x, ax))));
        ay = fmaf(v0, p0.y, fmaf(v1, p1.y, fmaf(v2, p2.y, fmaf(v3, p3.y, ay))));
        ay = fmaf(v4, p4.y, fmaf(v5, p5.y, fmaf(v6, p6.y, fmaf(v7, p7.y, ay))));
    }
    size_t o = (size_t)wid * DIM + lo2;
    float2 p1v = h2f2(*(const unsigned int*)(p1raw + o));
    float n2a = ax * ax + ay * ay;            // p2
    float n2b = p1v.x * p1v.x + p1v.y * p1v.y; // p1
    #pragma unroll
    for (int oo = 32; oo > 0; oo >>= 1) {
        n2a += __shfl_xor(n2a, oo, 64);
        n2b += __shfl_xor(n2b, oo, 64);
    }
    float i2 = rsqrtf(fmaxf(n2a, 1e-30f));
    float i1 = rsqrtf(fmaxf(n2b, 1e-30f));
    float2 bv = *(const float2*)(pid + o);
    *(float2*)(sp + o) = make_float2(bv.x + p1v.x * i1 + ax * i2,
                                     bv.y + p1v.y * i1 + ay * i2);
}

// ---------------- MFMA: out[Mx128] = A[Mx128] @ W^T ; fp32 in, fp16 frags, fp32 accum ----------------
__global__ __launch_bounds__(256) void gemm_mfma_kernel(
        const float* __restrict__ A, const float* __restrict__ W,
        float* __restrict__ store, float* __restrict__ accum,
        _Float16* __restrict__ accum_h,
        const float* __restrict__ fw3, int fsel, int first, int M) {
    int w = threadIdx.x >> 6, l = threadIdx.x & 63;
    int lg = l >> 4, lc = l & 15;
    int j0 = w * 32;
    float coef = accum ? softmax3(fw3, fsel) : 0.f;
    f16x8 Bf[2][4];
    #pragma unroll
    for (int t = 0; t < 2; t++) {
        const float* wr = W + (size_t)(j0 + t * 16 + lc) * DIM + lg * 8;
        #pragma unroll
        for (int s = 0; s < 4; s++) Bf[t][s] = frag8(wr + s * 32);
    }
    int base = blockIdx.x * 64;
    #pragma unroll
    for (int rt = 0; rt < 4; rt++) {
        int u0 = base + rt * 16;
        int ar = u0 + lc; if (ar > M - 1) ar = M - 1;
        const float* arow = A + (size_t)ar * DIM + lg * 8;
        f16x8 Af[4];
        #pragma unroll
        for (int s = 0; s < 4; s++) Af[s] = frag8(arow + s * 32);
        f32x4 acc0 = {0.f, 0.f, 0.f, 0.f};
        f32x4 acc1 = {0.f, 0.f, 0.f, 0.f};
        #pragma unroll
        for (int s = 0; s < 4; s++) {
            acc0 = __builtin_amdgcn_mfma_f32_16x16x32_f16(Af[s], Bf[0][s], acc0, 0, 0, 0);
            acc1 = __builtin_amdgcn_mfma_f32_16x16x32_f16(Af[s], Bf[1][s], acc1, 0, 0, 0);
        }
        int rbase = u0 + lg * 4;
        #pragma unroll
        for (int r = 0; r < 4; r++) {
            int row = rbase + r;
            if (row >= M) continue;
            size_t o0 = (size_t)row * DIM + j0 + lc;
            size_t o1 = o0 + 16;
            if (store) { store[o0] = acc0[r]; store[o1] = acc1[r]; }
            if (accum) {
                float p0 = first ? 0.f : accum[o0];
                float p1 = first ? 0.f : accum[o1];
                float n0 = p0 + coef * acc0[r];
                float n1 = p1 + coef * acc1[r];
                accum[o0] = n0;
                accum[o1] = n1;
                if (accum_h) {
                    accum_h[o0] = (_Float16)n0;
                    accum_h[o1] = (_Float16)n1;
                }
            }
        }
    }
}

// ---------------- 256 selected rows of uf = su @ Wu^T ----------------
__global__ void ufsel_kernel(const float* __restrict__ su, const float* __restrict__ W,
                             const int* __restrict__ uidx, float* __restrict__ outsel) {
    int b = blockIdx.x, j = threadIdx.x;  // block 128
    __shared__ float ar[128];
    int u = iclamp(uidx[b], 0, N_USERS - 1);
    ar[j] = su[(size_t)u * DIM + j];
    __syncthreads();
    const float4* Wr = (const float4*)(W + (size_t)j * DIM);
    float acc = 0.f;
    #pragma unroll 8
    for (int q = 0; q < 32; q++) {
        float4 wq = Wr[q];
        acc = fmaf(ar[4 * q + 0], wq.x, acc);
        acc = fmaf(ar[4 * q + 1], wq.y, acc);
        acc = fmaf(ar[4 * q + 2], wq.z, acc);
        acc = fmaf(ar[4 * q + 3], wq.w, acc);
    }
    outsel[(size_t)b * DIM + j] = acc;
}

// ---------------- alt[b,j] (+)= wn_c * dot(uf_c[b], pf_c[poi]) ----------------
__global__ __launch_bounds__(256) void predict_kernel(
        const float* __restrict__ ufs, const float* __restrict__ pf,
        const int* __restrict__ pidx, const float* __restrict__ w3,
        int wsel, int first, float* __restrict__ alt) {
    int wid = (blockIdx.x * blockDim.x + threadIdx.x) >> 6;
    int lane = threadIdx.x & 63;
    if (wid >= BATCH * NPOS) return;
    int b = wid / NPOS;
    int poi = iclamp(pidx[wid], 0, N_POIS - 1);
    const float2 uv = *(const float2*)(ufs + (size_t)b * DIM + lane * 2);
    const float2 pv = *(const float2*)(pf + (size_t)poi * DIM + lane * 2);
    float s = uv.x * pv.x + uv.y * pv.y;
    #pragma unroll
    for (int o = 32; o > 0; o >>= 1) s += __shfl_xor(s, o, 64);
    if (lane == 0) {
        float coef = softmax3(w3, wsel);
        float prev = first ? 0.f : alt[wid];
        alt[wid] = prev + coef * s;
    }
}

// ---------------- BCE loss: stage 1 partials (25 blocks) ----------------
__global__ void loss_part_kernel(const float* __restrict__ alt, const float* __restrict__ labels,
                                 float* __restrict__ part) {
    int b = blockIdx.x, t = threadIdx.x;
    int i = b * 1024 + t * 4;
    float4 x4 = *(const float4*)(alt + i);
    float4 y4 = *(const float4*)(labels + i);
    float s = 0.f;
    s += fmaxf(x4.x, 0.f) - x4.x * y4.x + log1pf(expf(-fabsf(x4.x)));
    s += fmaxf(x4.y, 0.f) - x4.y * y4.y + log1pf(expf(-fabsf(x4.y)));
    s += fmaxf(x4.z, 0.f) - x4.z * y4.z + log1pf(expf(-fabsf(x4.z)));
    s += fmaxf(x4.w, 0.f) - x4.w * y4.w + log1pf(expf(-fabsf(x4.w)));
    __shared__ float red[256];
    red[t] = s;
    __syncthreads();
    for (int o = 128; o > 0; o >>= 1) {
        if (t < o) red[t] += red[t + o];
        __syncthreads();
    }
    if (t == 0) part[b] = red[0];
}

// ---------------- BCE loss: stage 2 final (deterministic) ----------------
__global__ void loss_final_kernel(const float* __restrict__ part, float* __restrict__ out) {
    if (threadIdx.x == 0) {
        float s = 0.f;
        #pragma unroll
        for (int b = 0; b < LOSS_BLOCKS; b++) s += part[b];
        out[0] = s / (float)(BATCH * NPOS);
    }
}

// ---------------- bst_h[b][j] = id_feat[cur[b]] @ Ws^T + bias (fp16, row-major) ----------------
__global__ void bs_kernel(const float* __restrict__ idf, const float* __restrict__ Ws,
                          const float* __restrict__ bias, const int* __restrict__ uidx,
                          _Float16* __restrict__ bst_h) {
    int b = blockIdx.x, j = threadIdx.x;  // block 128
    __shared__ float ar[128];
    int u = iclamp(uidx[b], 0, N_USERS - 1);
    ar[j] = idf[(size_t)u * DIM + j];
    __syncthreads();
    const float4* Wr = (const float4*)(Ws + (size_t)j * DIM);
    float acc = 0.f;
    #pragma unroll 8
    for (int q = 0; q < 32; q++) {
        float4 wq = Wr[q];
        acc = fmaf(ar[4 * q + 0], wq.x, acc);
        acc = fmaf(ar[4 * q + 1], wq.y, acc);
        acc = fmaf(ar[4 * q + 2], wq.z, acc);
        acc = fmaf(ar[4 * q + 3], wq.w, acc);
    }
    bst_h[(size_t)b * DIM + j] = (_Float16)(acc + bias[j]);
}

__device__ __forceinline__ void topk_insert(float s, int u, float* ts, int* ti) {
    if (s > ts[TOPK - 1]) {
        #pragma unroll
        for (int j = TOPK - 1; j > 0; --j) {
            bool above = s > ts[j - 1];
            bool here = (!above) && (s > ts[j]);
            float nv = above ? ts[j - 1] : (here ? s : ts[j]);
            int ni = above ? ti[j - 1] : (here ? u : ti[j]);
            ts[j] = nv; ti[j] = ni;
        }
        if (s > ts[0]) { ts[0] = s; ti[0] = u; }
    }
}

// ---------------- MFMA uu scores + per-block top-20: 512 thr, 8 waves ----------------
__global__ __launch_bounds__(512) void score_topk_kernel(
        const _Float16* __restrict__ idf_h, const _Float16* __restrict__ bst_h,
        float* __restrict__ cand_s, int* __restrict__ cand_i) {
    __shared__ __align__(16) unsigned char smraw[61440];
    float* ms = (float*)smraw;                              // [20][512] 40 KB
    unsigned short* mi = (unsigned short*)(smraw + 40960);  // [20][512] 20 KB
    int cid = blockIdx.x, bg = blockIdx.y;
    int tid = threadIdx.x;
    int w = tid >> 6, l = tid & 63;
    int half = w >> 2, wq = w & 3;
    int lg = l >> 4, lc = l & 15;
    const _Float16* bbase = bst_h + ((size_t)(bg * 64 + wq * 16 + lc)) * DIM + lg * 8;
    f16x8 B0 = *(const f16x8*)(bbase + 0);
    f16x8 B1 = *(const f16x8*)(bbase + 32);
    f16x8 B2 = *(const f16x8*)(bbase + 64);
    f16x8 B3 = *(const f16x8*)(bbase + 96);
    float ts[TOPK]; int ti[TOPK];
    #pragma unroll
    for (int k = 0; k < TOPK; k++) { ts[k] = -3.0e38f; ti[k] = 0; }
    int lo = cid * CPT;
    int hi = lo + CPT; if (hi > N_USERS) hi = N_USERS;
    int ntiles = (hi - lo + 15) >> 4;
    int t0 = half ? (ntiles >> 1) : 0;
    int t1 = half ? ntiles : (ntiles >> 1);
    #pragma unroll 2
    for (int t = t0; t < t1; t++) {
        int u0 = lo + t * 16;
        int ar = u0 + lc; if (ar > N_USERS - 1) ar = N_USERS - 1;
        const _Float16* abase = idf_h + (size_t)ar * DIM + lg * 8;
        f16x8 A0 = *(const f16x8*)(abase + 0);
        f16x8 A1 = *(const f16x8*)(abase + 32);
        f16x8 A2 = *(const f16x8*)(abase + 64);
        f16x8 A3 = *(const f16x8*)(abase + 96);
        f32x4 accA = {0.f, 0.f, 0.f, 0.f};
        f32x4 accB = {0.f, 0.f, 0.f, 0.f};
        accA = __builtin_amdgcn_mfma_f32_16x16x32_f16(A0, B0, accA, 0, 0, 0);
        accB = __builtin_amdgcn_mfma_f32_16x16x32_f16(A1, B1, accB, 0, 0, 0);
        accA = __builtin_amdgcn_mfma_f32_16x16x32_f16(A2, B2, accA, 0, 0, 0);
        accB = __builtin_amdgcn_mfma_f32_16x16x32_f16(A3, B3, accB, 0, 0, 0);
        int ub = u0 + lg * 4;
        #pragma unroll
        for (int r = 0; r < 4; r++) {
            float s = accA[r] + accB[r];
            int u = ub + r;
            if (u < hi) topk_insert(s, u, ts, ti);
        }
    }
    #pragma unroll
    for (int k = 0; k < TOPK; k++) {
        ms[k * 512 + tid] = ts[k];
        mi[k * 512 + tid] = (unsigned short)ti[k];
    }
    __syncthreads();
    if (tid < 64) {
        int wm = tid >> 4, cm = tid & 15;
        int s0 = 0 * 256 + wm * 64 + 0 * 16 + cm;
        int s1 = s0 + 16, s2 = s0 + 32, s3 = s0 + 48;
        int s4 = s0 + 256, s5 = s1 + 256, s6 = s2 + 256, s7 = s3 + 256;
        int p0 = 0, p1 = 0, p2 = 0, p3 = 0, p4 = 0, p5 = 0, p6 = 0, p7 = 0;
        size_t ob = ((size_t)cid * 256 + bg * 64 + wm * 16 + cm) * TOPK;
        for (int k = 0; k < TOPK; k++) {
            float h0 = ms[p0 * 512 + s0];
            float h1 = ms[p1 * 512 + s1];
            float h2 = ms[p2 * 512 + s2];
            float h3 = ms[p3 * 512 + s3];
            float h4 = ms[p4 * 512 + s4];
            float h5 = ms[p5 * 512 + s5];
            float h6 = ms[p6 * 512 + s6];
            float h7 = ms[p7 * 512 + s7];
            float best = h0; int which = 0;
            if (h1 > best) { best = h1; which = 1; }
            if (h2 > best) { best = h2; which = 2; }
            if (h3 > best) { best = h3; which = 3; }
            if (h4 > best) { best = h4; which = 4; }
            if (h5 > best) { best = h5; which = 5; }
            if (h6 > best) { best = h6; which = 6; }
            if (h7 > best) { best = h7; which = 7; }
            int idx;
            if (which == 0)      { idx = mi[p0 * 512 + s0]; p0++; }
            else if (which == 1) { idx = mi[p1 * 512 + s1]; p1++; }
            else if (which == 2) { idx = mi[p2 * 512 + s2]; p2++; }
            else if (which == 3) { idx = mi[p3 * 512 + s3]; p3++; }
            else if (which == 4) { idx = mi[p4 * 512 + s4]; p4++; }
            else if (which == 5) { idx = mi[p5 * 512 + s5]; p5++; }
            else if (which == 6) { idx = mi[p6 * 512 + s6]; p6++; }
            else                 { idx = mi[p7 * 512 + s7]; p7++; }
            cand_s[ob + k] = best;
            cand_i[ob + k] = idx;
        }
    }
}

// ---------------- global merge + softmax + weighted gather ----------------
__global__ void topk_merge_kernel(const float* __restrict__ cand_s, const int* __restrict__ cand_i,
                                  const float* __restrict__ guf,
                                  float* __restrict__ outp) {
    int b = blockIdx.x, t = threadIdx.x;  // block 128 (= NCHUNK)
    __shared__ float rs[NCHUNK]; __shared__ int ru[NCHUNK]; __shared__ int rt[NCHUNK];
    __shared__ float win_s[TOPK]; __shared__ int win_u[TOPK]; __shared__ float wk[TOPK];
    __shared__ int winner;
    int ptr = 0;
    size_t base = ((size_t)t * 256 + b) * TOPK;
    for (int k = 0; k < TOPK; k++) {
        rs[t] = (ptr < TOPK) ? cand_s[base + ptr] : -3.0e38f;
        ru[t] = (ptr < TOPK) ? cand_i[base + ptr] : 0;
        rt[t] = t;
        __syncthreads();
        for (int off = NCHUNK / 2; off > 0; off >>= 1) {
            if (t < off && rs[t + off] > rs[t]) {
                rs[t] = rs[t + off]; ru[t] = ru[t + off]; rt[t] = rt[t + off];
            }
            __syncthreads();
        }
        if (t == 0) { win_s[k] = rs[0]; win_u[k] = iclamp(ru[0], 0, N_USERS - 1); winner = rt[0]; }
        __syncthreads();
        if (t == winner) ptr++;
        __syncthreads();
    }
    if (t == 0) {
        float m = win_s[0], den = 0.f;
        for (int k = 0; k < TOPK; k++) { wk[k] = expf(win_s[k] - m); den += wk[k]; }
        float inv = 1.f / den;
        for (int k = 0; k < TOPK; k++) wk[k] *= inv;
    }
    __syncthreads();
    float acc = 0.f;
    #pragma unroll
    for (int k = 0; k < TOPK; k++)
        acc = fmaf(wk[k], guf[(size_t)win_u[k] * DIM + t], acc);
    outp[1 + (size_t)b * DIM + t] = acc;
}

extern "C" void kernel_launch(void* const* d_in, const int* in_sizes, int n_in,
                              void* d_out, int out_size, void* d_ws, size_t ws_size,
                              hipStream_t stream) {
    (void)in_sizes; (void)n_in; (void)out_size;
    const int*   er      = (const int*)d_in[0];
    const int*   ec      = (const int*)d_in[1];
    const float* click   = (const float*)d_in[2];
    const float* favor   = (const float*)d_in[3];
    const float* consume = (const float*)d_in[4];
    const float* uid     = (const float*)d_in[5];
    const float* pid     = (const float*)d_in[6];
    const int*   uidx    = (const int*)d_in[7];
    const int*   pidx    = (const int*)d_in[8];
    const float* labels  = (const float*)d_in[9];
    const float* guf     = (const float*)d_in[10];
    const float* w3      = (const float*)d_in[11];
    const float* fw3     = (const float*)d_in[12];
    const float* Wuc     = (const float*)d_in[13];
    const float* Wpc     = (const float*)d_in[14];
    const float* Wufv    = (const float*)d_in[15];
    const float* Wpfv    = (const float*)d_in[16];
    const float* Wuco    = (const float*)d_in[17];
    const float* Wpco    = (const float*)d_in[18];
    const float* Wss     = (const float*)d_in[19];
    const float* bias    = (const float*)d_in[20];
    float* outp = (float*)d_out;

    char* ws = (char*)d_ws;
    size_t off = 0;
    auto carve = [&](size_t bytes) -> void* {
        off = (off + 255) & ~(size_t)255;
        void* p = ws + off;
        off += bytes;
        return p;
    };
    // base layout (~89 MB, proven safe)
    float* ufs = (float*)carve(4ll * 3 * BATCH * DIM);
    float* alt = (float*)carve(4ll * BATCH * NPOS);
    float* bst = (float*)carve(4ll * DIM * BATCH);       // reused as fp16 bst_h
    int* rptr = (int*)carve(4 * (N_USERS + 1));
    int* cptr = (int*)carve(4 * (N_POIS + 1));
    int* cnts = (int*)carve(4 * (N_USERS + N_POIS));
    int* rcnt = cnts;
    int* ccnt = cnts + N_USERS;
    int* scanws = (int*)carve(4 * 2 * (RCH + CCH) + 4 * 64);  // rsum/csum/rbase/cbase
    int* rsum = scanws;
    int* csum = rsum + RCH;
    int* rbase = csum + CCH;
    int* cbase = rbase + RCH;
    float* losspart = (float*)carve(4 * (LOSS_BLOCKS + 7));
    int4* rpack = (int4*)carve(16ll * N_EDGES);   // {col, v0, v1, v2}
    int4* cpack = (int4*)carve(16ll * N_EDGES);   // {row, v0, v1, v2}
    unsigned short* pid_h = (unsigned short*)carve(2ll * N_POIS * DIM);
    unsigned short* utr0 = (unsigned short*)carve(2ll * N_USERS * DIM);  // 10.24 MB; pf alias
    unsigned short* ptr_h = (unsigned short*)carve(2ll * N_POIS * DIM);  // p1raw ch0
    float* su  = (float*)carve(4ll * N_USERS * DIM);   // cand alias; rord/cord alias
    float* sp  = (float*)carve(4ll * N_POIS * DIM);
    float* idf = (float*)carve(4ll * N_USERS * DIM);
    float* pf = (float*)utr0;             // utr0 dead before pf written
    float* cand_s = su;                   // su dead before score_topk
    int*   cand_i = (int*)(su + (size_t)NCHUNK * BATCH * TOPK);
    // idf_h = rpack base, 10.24 MB: covers ALL of rpack (8 MB) + first 2.24 MB
    // of cpack. INVARIANT: the last read of rpack (l2u c==2) AND the last read
    // of cpack (l2p c==2) must both precede the c==2 user gemm that writes idf_h.
    _Float16* idf_h = (_Float16*)rpack;
    _Float16* bst_h = (_Float16*)bst;
    // rord/cord (4 MB) alias su: written by hist, read by fill; su first written
    // by spmm_l2u (channel 0), which runs strictly after fill completes.
    int* rord = (int*)su;
    int* cord = rord + N_EDGES;
    // extra carves for the channel-fused path (+30.7 MB) — only used if they fit
    unsigned short* utr1 = (unsigned short*)carve(2ll * N_USERS * DIM);
    unsigned short* utr2 = (unsigned short*)carve(2ll * N_USERS * DIM);
    unsigned short* p1b1 = (unsigned short*)carve(2ll * N_POIS * DIM);
    unsigned short* p1b2 = (unsigned short*)carve(2ll * N_POIS * DIM);
    bool fused = (off <= ws_size);

    zero_kernel<<<(N_USERS + N_POIS + 255) / 256, 256, 0, stream>>>(
        (unsigned int*)cnts, N_USERS + N_POIS);
    cast_f16_kernel<<<(N_POIS * DIM / 2 + 255) / 256, 256, 0, stream>>>(pid, pid_h, N_POIS * DIM / 2);
    hist_kernel<<<(N_EDGES / 4 + 255) / 256, 256, 0, stream>>>(er, ec, rcnt, ccnt, rord, cord);
    dim3 sg2(RCH, 2);
    chunksum_kernel<<<sg2, 256, 0, stream>>>(rcnt, ccnt, rsum, csum);
    chunkscan_kernel<<<1, 128, 0, stream>>>(rsum, csum, rbase, cbase, rptr, cptr);
    scatterscan_kernel<<<sg2, 256, 0, stream>>>(rcnt, ccnt, rbase, cbase, rptr, cptr);
    fill_kernel<<<(N_EDGES / 4 + 255) / 256, 256, 0, stream>>>(
        er, ec, rptr, cptr, rord, cord, rpack, cpack, click, favor, consume);

    struct Ch { const float* Wu; const float* Wp; int wsel; int fsel; };
    // wn (softmax over w[1,3]):  favor=0, click=1, consume=2
    // fwn (softmax over fw[3,1]): favor=0, consume=1, click=2
    Ch chs[3] = { { Wuc,  Wpc,  1, 2 },     // ch0 = click
                  { Wufv, Wpfv, 0, 0 },     // ch1 = favor
                  { Wuco, Wpco, 2, 1 } };   // ch2 = consume

    const int UGB = N_USERS / 64;                 // 625
    const int PGB = (N_POIS + 63) / 64;           // 313
    const int PW = N_POIS * 64 / 256;
    const int UW = N_USERS * 64 / 256;

    auto launch_spmm_poi = [&](int c, const unsigned short* src, unsigned short* raw,
                               const float* base, float* acc) {
        if (c == 0)      spmm_kernel<0><<<PW, 256, 0, stream>>>(cptr, cpack, src, raw, base, acc, N_POIS);
        else if (c == 1) spmm_kernel<1><<<PW, 256, 0, stream>>>(cptr, cpack, src, raw, base, acc, N_POIS);
        else             spmm_kernel<2><<<PW, 256, 0, stream>>>(cptr, cpack, src, raw, base, acc, N_POIS);
    };
    auto launch_spmm_usr = [&](int c, const unsigned short* src, unsigned short* raw,
                               const float* base, float* acc) {
        if (c == 0)      spmm_kernel<0><<<UW, 256, 0, stream>>>(rptr, rpack, src, raw, base, acc, N_USERS);
        else if (c == 1) spmm_kernel<1><<<UW, 256, 0, stream>>>(rptr, rpack, src, raw, base, acc, N_USERS);
        else             spmm_kernel<2><<<UW, 256, 0, stream>>>(rptr, rpack, src, raw, base, acc, N_USERS);
    };
    auto launch_l2u = [&](int c, const unsigned short* src, unsigned short* u1raw) {
        if (c == 0)      spmm_l2u_kernel<0><<<UW, 256, 0, stream>>>(rptr, rpack, src, u1raw, uid, su, N_USERS);
        else if (c == 1) spmm_l2u_kernel<1><<<UW, 256, 0, stream>>>(rptr, rpack, src, u1raw, uid, su, N_USERS);
        else             spmm_l2u_kernel<2><<<UW, 256, 0, stream>>>(rptr, rpack, src, u1raw, uid, su, N_USERS);
    };
    auto launch_l2p = [&](int c, const unsigned short* src, const unsigned short* p1raw) {
        if (c == 0)      spmm_l2p_kernel<0><<<PW, 256, 0, stream>>>(cptr, cpack, src, p1raw, pid, sp, N_POIS);
        else if (c == 1) spmm_l2p_kernel<1><<<PW, 256, 0, stream>>>(cptr, cpack, src, p1raw, pid, sp, N_POIS);
        else             spmm_l2p_kernel<2><<<PW, 256, 0, stream>>>(cptr, cpack, src, p1raw, pid, sp, N_POIS);
    };

    if (fused) {
        // fused L1-user: one shared pid_h gather, 3 u1 outputs
        spmm3_kernel<<<UW, 256, 0, stream>>>(rptr, rpack, pid_h, utr0, utr1, utr2, N_USERS);
        // fused L1-poi: 3 distinct u1 srcs, 3 p1 raw outputs (sp deferred)
        spmm3p_kernel<<<PW, 256, 0, stream>>>(cptr, cpack, utr0, utr1, utr2,
                                              ptr_h, p1b1, p1b2, N_POIS);
        unsigned short* p1b[3] = { ptr_h, p1b1, p1b2 };
        unsigned short* utr[3] = { utr0, utr1, utr2 };
        for (int c = 0; c < 3; c++) {
            // ORDER MATTERS: l2p (reads cpack) MUST precede the user gemm on
            // c==2 because idf_h overwrites rpack + the head of cpack.
            launch_l2u(c, p1b[c], utr[c]);   // u2 = A p1_c ; su ; utr_c <- u2 raw
            launch_l2p(c, utr[c], p1b[c]);   // p2 = A^T u2 ; sp = pid + n(p1) + n(p2)
            gemm_mfma_kernel<<<UGB, 256, 0, stream>>>(
                su, chs[c].Wu, nullptr, idf, (c == 2) ? idf_h : nullptr,
                fw3, chs[c].fsel, (c == 0) ? 1 : 0, N_USERS);
            ufsel_kernel<<<BATCH, 128, 0, stream>>>(su, chs[c].Wu, uidx, ufs + (size_t)c * BATCH * DIM);
            gemm_mfma_kernel<<<PGB, 256, 0, stream>>>(
                sp, chs[c].Wp, pf, nullptr, nullptr, fw3, 0, 0, N_POIS);
            predict_kernel<<<BATCH * NPOS * 64 / 256, 256, 0, stream>>>(
                ufs + (size_t)c * BATCH * DIM, pf, pidx, w3, chs[c].wsel, (c == 0) ? 1 : 0, alt);
        }
    } else {
        // proven fallback: per-channel schedule, single utr0/ptr_h buffers
        for (int c = 0; c < 3; c++) {
            launch_spmm_usr(c, pid_h, utr0, uid, su);
            launch_spmm_poi(c, utr0, ptr_h, pid, sp);
            launch_spmm_usr(c, ptr_h, utr0, su, su);
            launch_spmm_poi(c, utr0, ptr_h, sp, sp);
            gemm_mfma_kernel<<<UGB, 256, 0, stream>>>(
                su, chs[c].Wu, nullptr, idf, (c == 2) ? idf_h : nullptr,
                fw3, chs[c].fsel, (c == 0) ? 1 : 0, N_USERS);
            ufsel_kernel<<<BATCH, 128, 0, stream>>>(su, chs[c].Wu, uidx, ufs + (size_t)c * BATCH * DIM);
            gemm_mfma_kernel<<<PGB, 256, 0, stream>>>(
                sp, chs[c].Wp, pf, nullptr, nullptr, fw3, 0, 0, N_POIS);
            predict_kernel<<<BATCH * NPOS * 64 / 256, 256, 0, stream>>>(
                ufs + (size_t)c * BATCH * DIM, pf, pidx, w3, chs[c].wsel, (c == 0) ? 1 : 0, alt);
        }
    }

    loss_part_kernel<<<LOSS_BLOCKS, 256, 0, stream>>>(alt, labels, losspart);
    loss_final_kernel<<<1, 64, 0, stream>>>(losspart, outp);
    bs_kernel<<<BATCH, 128, 0, stream>>>(idf, Wss, bias, uidx, bst_h);
    dim3 sg(NCHUNK, 4);
    score_topk_kernel<<<sg, 512, 0, stream>>>(idf_h, bst_h, cand_s, cand_i);
    topk_merge_kernel<<<BATCH, NCHUNK, 0, stream>>>(cand_s, cand_i, guf, outp);
}

// Round 12
// 626.272 us; speedup vs baseline: 1.1013x; 1.0337x over previous
//
#include <hip/hip_runtime.h>

#define N_USERS 40000
#define N_POIS  20000
#define DIM     128
#define N_EDGES 500000
#define BATCH   256
#define NPOS    100
#define TOPK    20
#define NCHUNK  128
#define CPT     313   // ceil(40000/128)
#define SCHUNK  1024  // scan chunk (256 thr x 4)
#define RCH     40    // ceil(40000/1024)
#define CCH     20    // ceil(20000/1024)
#define LOSS_BLOCKS 25  // 25600/1024

typedef _Float16 f16x8 __attribute__((ext_vector_type(8)));
typedef float f32x4 __attribute__((ext_vector_type(4)));

__device__ __forceinline__ int iclamp(int x, int lo, int hi) {
    return x < lo ? lo : (x > hi ? hi : x);
}
__device__ __forceinline__ float2 h2f2(unsigned int u) {
    union { unsigned int u32; _Float16 h[2]; } v; v.u32 = u;
    return make_float2((float)v.h[0], (float)v.h[1]);
}
__device__ __forceinline__ unsigned int f2h2(float x, float y) {
    union { unsigned int u32; _Float16 h[2]; } v;
    v.h[0] = (_Float16)x; v.h[1] = (_Float16)y; return v.u32;
}
__device__ __forceinline__ float softmax3(const float* p, int sel) {
    float a0 = p[0], a1 = p[1], a2 = p[2];
    float m = fmaxf(a0, fmaxf(a1, a2));
    float e0 = expf(a0 - m), e1 = expf(a1 - m), e2 = expf(a2 - m);
    float den = e0 + e1 + e2;
    float e = (sel == 0) ? e0 : ((sel == 1) ? e1 : e2);
    return e / den;
}
// compile-time channel pick from packed edge {idx, v0, v1, v2}
template<int CH>
__device__ __forceinline__ float pickvT(int4 q) {
    return __int_as_float(CH == 0 ? q.y : (CH == 1 ? q.z : q.w));
}
// build fp16x8 fragment from 8 contiguous fp32
__device__ __forceinline__ f16x8 frag8(const float* p) {
    float4 x = *(const float4*)(p);
    float4 y = *(const float4*)(p + 4);
    f16x8 f;
    f[0] = (_Float16)x.x; f[1] = (_Float16)x.y; f[2] = (_Float16)x.z; f[3] = (_Float16)x.w;
    f[4] = (_Float16)y.x; f[5] = (_Float16)y.y; f[6] = (_Float16)y.z; f[7] = (_Float16)y.w;
    return f;
}

// ---------------- zero init ----------------
__global__ void zero_kernel(unsigned int* __restrict__ p, int nwords) {
    int i = blockIdx.x * blockDim.x + threadIdx.x;
    if (i < nwords) p[i] = 0u;
}

// ---------------- fp32 -> fp16 cast ----------------
__global__ void cast_f16_kernel(const float* __restrict__ src, unsigned short* __restrict__ dst,
                                int n2) {
    int i = blockIdx.x * blockDim.x + threadIdx.x;
    if (i < n2) {
        float2 v = *(const float2*)(src + 2 * (size_t)i);
        *(unsigned int*)(dst + 2 * (size_t)i) = f2h2(v.x, v.y);
    }
}

// ---------------- CSR hist: counts + per-edge within-row/col ordinals ----------------
__global__ void hist_kernel(const int* __restrict__ er, const int* __restrict__ ec,
                            int* __restrict__ rcnt, int* __restrict__ ccnt,
                            int* __restrict__ rord, int* __restrict__ cord) {
    int e0 = 4 * (blockIdx.x * blockDim.x + threadIdx.x);
    if (e0 + 4 <= N_EDGES) {
        int4 r4 = *(const int4*)(er + e0);
        int4 c4 = *(const int4*)(ec + e0);
        int rr[4] = { r4.x, r4.y, r4.z, r4.w };
        int cc[4] = { c4.x, c4.y, c4.z, c4.w };
        int ro[4], co[4];
        #pragma unroll
        for (int j = 0; j < 4; j++) {
            ro[j] = atomicAdd(&rcnt[iclamp(rr[j], 0, N_USERS - 1)], 1);
            co[j] = atomicAdd(&ccnt[iclamp(cc[j], 0, N_POIS - 1)], 1);
        }
        *(int4*)(rord + e0) = make_int4(ro[0], ro[1], ro[2], ro[3]);
        *(int4*)(cord + e0) = make_int4(co[0], co[1], co[2], co[3]);
    } else {
        for (int e = e0; e < N_EDGES; e++) {
            rord[e] = atomicAdd(&rcnt[iclamp(er[e], 0, N_USERS - 1)], 1);
            cord[e] = atomicAdd(&ccnt[iclamp(ec[e], 0, N_POIS - 1)], 1);
        }
    }
}

// ---------------- parallel prefix sum, stage 1: per-1024-chunk sums ----------------
__global__ void chunksum_kernel(const int* __restrict__ rcnt, const int* __restrict__ ccnt,
                                int* __restrict__ rsum, int* __restrict__ csum) {
    int side = blockIdx.y;
    const int* cnt = side ? ccnt : rcnt;
    int n = side ? N_POIS : N_USERS;
    int nch = side ? CCH : RCH;
    int b = blockIdx.x;
    if (b >= nch) return;
    int t = threadIdx.x;
    int i = b * SCHUNK + t * 4;
    int s = 0;
    if (i + 4 <= n) {
        int4 v = *(const int4*)(cnt + i);
        s = v.x + v.y + v.z + v.w;
    } else {
        for (int j = i; j < n; j++) s += cnt[j];
    }
    __shared__ int red[256];
    red[t] = s;
    __syncthreads();
    for (int o = 128; o > 0; o >>= 1) {
        if (t < o) red[t] += red[t + o];
        __syncthreads();
    }
    if (t == 0) (side ? csum : rsum)[b] = red[0];
}

// ---------------- stage 2: scan chunk sums (wave shfl), write totals ----------------
__global__ void chunkscan_kernel(const int* __restrict__ rsum, const int* __restrict__ csum,
                                 int* __restrict__ rbase, int* __restrict__ cbase,
                                 int* __restrict__ rptr, int* __restrict__ cptr) {
    int w = threadIdx.x >> 6, l = threadIdx.x & 63;  // block 128: wave0=users, wave1=pois
    const int* src = w ? csum : rsum;
    int* dst = w ? cbase : rbase;
    int nch = w ? CCH : RCH;
    int orig = (l < nch) ? src[l] : 0;
    int v = orig;
    #pragma unroll
    for (int o = 1; o < 64; o <<= 1) {
        int u = __shfl_up(v, o, 64);
        if (l >= o) v += u;
    }
    if (l < nch) dst[l] = v - orig;                 // exclusive base
    if (l == nch - 1) {
        if (w) cptr[N_POIS] = v; else rptr[N_USERS] = v;
    }
}

// ---------------- stage 3: block scan within chunk + chunk base ----------------
__global__ void scatterscan_kernel(const int* __restrict__ rcnt, const int* __restrict__ ccnt,
                                   const int* __restrict__ rbase, const int* __restrict__ cbase,
                                   int* __restrict__ rptr, int* __restrict__ cptr) {
    int side = blockIdx.y;
    const int* cnt = side ? ccnt : rcnt;
    const int* basea = side ? cbase : rbase;
    int* ptr = side ? cptr : rptr;
    int n = side ? N_POIS : N_USERS;
    int nch = side ? CCH : RCH;
    int b = blockIdx.x;
    if (b >= nch) return;
    int t = threadIdx.x;
    int i = b * SCHUNK + t * 4;
    int c0 = 0, c1 = 0, c2 = 0, c3 = 0;
    if (i + 4 <= n) {
        int4 v = *(const int4*)(cnt + i);
        c0 = v.x; c1 = v.y; c2 = v.z; c3 = v.w;
    } else {
        if (i + 0 < n) c0 = cnt[i + 0];
        if (i + 1 < n) c1 = cnt[i + 1];
        if (i + 2 < n) c2 = cnt[i + 2];
    }
    int tsum = c0 + c1 + c2 + c3;
    int l = t & 63, w = t >> 6;
    int v = tsum;
    #pragma unroll
    for (int o = 1; o < 64; o <<= 1) {
        int u = __shfl_up(v, o, 64);
        if (l >= o) v += u;
    }
    __shared__ int wsum[4];
    if (l == 63) wsum[w] = v;
    __syncthreads();
    int wbase = 0;
    for (int k = 0; k < w; k++) wbase += wsum[k];
    int ex = v - tsum + wbase + basea[b];
    if (i + 4 <= n) {
        *(int4*)(ptr + i) = make_int4(ex, ex + c0, ex + c0 + c1, ex + c0 + c1 + c2);
    } else {
        if (i + 0 < n) ptr[i + 0] = ex;
        if (i + 1 < n) ptr[i + 1] = ex + c0;
        if (i + 2 < n) ptr[i + 2] = ex + c0 + c1;
    }
}

// ---------------- AoS CSR fill: NO atomics (slots precomputed in hist) ----------------
__global__ void fill_kernel(const int* __restrict__ er, const int* __restrict__ ec,
                            const int* __restrict__ rptr, const int* __restrict__ cptr,
                            const int* __restrict__ rord, const int* __restrict__ cord,
                            int4* __restrict__ rpack, int4* __restrict__ cpack,
                            const float* __restrict__ ck, const float* __restrict__ fv,
                            const float* __restrict__ cs) {
    int e0 = 4 * (blockIdx.x * blockDim.x + threadIdx.x);
    if (e0 + 4 <= N_EDGES) {
        int4 r4 = *(const int4*)(er + e0);
        int4 c4 = *(const int4*)(ec + e0);
        int4 ro4 = *(const int4*)(rord + e0);
        int4 co4 = *(const int4*)(cord + e0);
        float4 k4 = *(const float4*)(ck + e0);
        float4 f4 = *(const float4*)(fv + e0);
        float4 s4 = *(const float4*)(cs + e0);
        int rr[4] = { r4.x, r4.y, r4.z, r4.w };
        int cc[4] = { c4.x, c4.y, c4.z, c4.w };
        int ro[4] = { ro4.x, ro4.y, ro4.z, ro4.w };
        int co[4] = { co4.x, co4.y, co4.z, co4.w };
        float kk[4] = { k4.x, k4.y, k4.z, k4.w };
        float ff[4] = { f4.x, f4.y, f4.z, f4.w };
        float ss[4] = { s4.x, s4.y, s4.z, s4.w };
        #pragma unroll
        for (int j = 0; j < 4; j++) {
            int r = iclamp(rr[j], 0, N_USERS - 1), c = iclamp(cc[j], 0, N_POIS - 1);
            int v0 = __float_as_int(kk[j]);
            int v1 = __float_as_int(ff[j]);
            int v2 = __float_as_int(ss[j]);
            int pr = iclamp(rptr[r] + ro[j], 0, N_EDGES - 1);
            rpack[pr] = make_int4(c, v0, v1, v2);
            int pc = iclamp(cptr[c] + co[j], 0, N_EDGES - 1);
            cpack[pc] = make_int4(r, v0, v1, v2);
        }
    } else {
        for (int e = e0; e < N_EDGES; e++) {
            int r = iclamp(er[e], 0, N_USERS - 1), c = iclamp(ec[e], 0, N_POIS - 1);
            int v0 = __float_as_int(ck[e]);
            int v1 = __float_as_int(fv[e]);
            int v2 = __float_as_int(cs[e]);
            int pr = iclamp(rptr[r] + rord[e], 0, N_EDGES - 1);
            rpack[pr] = make_int4(c, v0, v1, v2);
            int pc = iclamp(cptr[c] + cord[e], 0, N_EDGES - 1);
            cpack[pc] = make_int4(r, v0, v1, v2);
        }
    }
}

// ---------------- SpMM: one wave per row; packed edges; fp16 src gather ----------------
// raw_h (fp16) = A*src ; acc (fp32) = base + raw/||raw||
template<int CH>
__global__ __launch_bounds__(256) void spmm_kernel(
        const int* __restrict__ ptr, const int4* __restrict__ pack,
        const unsigned short* __restrict__ src,         // fp16 [*,128]
        unsigned short* __restrict__ raw_h,             // fp16 out
        const float* __restrict__ base,                 // fp32 (may alias acc)
        float* __restrict__ acc, int nrows) {
    int wid = (blockIdx.x * blockDim.x + threadIdx.x) >> 6;
    int lane = threadIdx.x & 63;
    if (wid >= nrows) return;
    int beg = __builtin_amdgcn_readfirstlane(iclamp(ptr[wid], 0, N_EDGES));
    int end = __builtin_amdgcn_readfirstlane(iclamp(ptr[wid + 1], 0, N_EDGES));
    if (end < beg) end = beg;
    float ax = 0.f, ay = 0.f;
    int e = beg;
    int lo2 = lane * 2;
    for (; e + 8 <= end; e += 8) {
        int4 q0 = pack[e + 0], q1 = pack[e + 1], q2 = pack[e + 2], q3 = pack[e + 3];
        int4 q4 = pack[e + 4], q5 = pack[e + 5], q6 = pack[e + 6], q7 = pack[e + 7];
        float v0 = pickvT<CH>(q0), v1 = pickvT<CH>(q1), v2 = pickvT<CH>(q2), v3 = pickvT<CH>(q3);
        float v4 = pickvT<CH>(q4), v5 = pickvT<CH>(q5), v6 = pickvT<CH>(q6), v7 = pickvT<CH>(q7);
        float2 p0 = h2f2(*(const unsigned int*)(src + (size_t)q0.x * DIM + lo2));
        float2 p1 = h2f2(*(const unsigned int*)(src + (size_t)q1.x * DIM + lo2));
        float2 p2 = h2f2(*(const unsigned int*)(src + (size_t)q2.x * DIM + lo2));
        float2 p3 = h2f2(*(const unsigned int*)(src + (size_t)q3.x * DIM + lo2));
        float2 p4 = h2f2(*(const unsigned int*)(src + (size_t)q4.x * DIM + lo2));
        float2 p5 = h2f2(*(const unsigned int*)(src + (size_t)q5.x * DIM + lo2));
        float2 p6 = h2f2(*(const unsigned int*)(src + (size_t)q6.x * DIM + lo2));
        float2 p7 = h2f2(*(const unsigned int*)(src + (size_t)q7.x * DIM + lo2));
        ax = fmaf(v0, p0.x, fmaf(v1, p1.x, fmaf(v2, p2.x, fmaf(v3, p3.x, ax))));
        ax = fmaf(v4, p4.x, fmaf(v5, p5.x, fmaf(v6, p6.x, fmaf(v7, p7.x, ax))));
        ay = fmaf(v0, p0.y, fmaf(v1, p1.y, fmaf(v2, p2.y, fmaf(v3, p3.y, ay))));
        ay = fmaf(v4, p4.y, fmaf(v5, p5.y, fmaf(v6, p6.y, fmaf(v7, p7.y, ay))));
    }
    if (e < end) {
        int last = end - 1;
        int e1 = e + 1 <= last ? e + 1 : last;
        int e2 = e + 2 <= last ? e + 2 : last;
        int e3 = e + 3 <= last ? e + 3 : last;
        int e4 = e + 4 <= last ? e + 4 : last;
        int e5 = e + 5 <= last ? e + 5 : last;
        int e6 = e + 6 <= last ? e + 6 : last;
        int e7 = e + 7 <= last ? e + 7 : last;
        int4 q0 = pack[e], q1 = pack[e1], q2 = pack[e2], q3 = pack[e3];
        int4 q4 = pack[e4], q5 = pack[e5], q6 = pack[e6], q7 = pack[e7];
        float v0 = pickvT<CH>(q0);
        float v1 = (e + 1 < end) ? pickvT<CH>(q1) : 0.f;
        float v2 = (e + 2 < end) ? pickvT<CH>(q2) : 0.f;
        float v3 = (e + 3 < end) ? pickvT<CH>(q3) : 0.f;
        float v4 = (e + 4 < end) ? pickvT<CH>(q4) : 0.f;
        float v5 = (e + 5 < end) ? pickvT<CH>(q5) : 0.f;
        float v6 = (e + 6 < end) ? pickvT<CH>(q6) : 0.f;
        float v7 = (e + 7 < end) ? pickvT<CH>(q7) : 0.f;
        float2 p0 = h2f2(*(const unsigned int*)(src + (size_t)q0.x * DIM + lo2));
        float2 p1 = h2f2(*(const unsigned int*)(src + (size_t)q1.x * DIM + lo2));
        float2 p2 = h2f2(*(const unsigned int*)(src + (size_t)q2.x * DIM + lo2));
        float2 p3 = h2f2(*(const unsigned int*)(src + (size_t)q3.x * DIM + lo2));
        float2 p4 = h2f2(*(const unsigned int*)(src + (size_t)q4.x * DIM + lo2));
        float2 p5 = h2f2(*(const unsigned int*)(src + (size_t)q5.x * DIM + lo2));
        float2 p6 = h2f2(*(const unsigned int*)(src + (size_t)q6.x * DIM + lo2));
        float2 p7 = h2f2(*(const unsigned int*)(src + (size_t)q7.x * DIM + lo2));
        ax = fmaf(v0, p0.x, fmaf(v1, p1.x, fmaf(v2, p2.x, fmaf(v3, p3.x, ax))));
        ax = fmaf(v4, p4.x, fmaf(v5, p5.x, fmaf(v6, p6.x, fmaf(v7, p7.x, ax))));
        ay = fmaf(v0, p0.y, fmaf(v1, p1.y, fmaf(v2, p2.y, fmaf(v3, p3.y, ay))));
        ay = fmaf(v4, p4.y, fmaf(v5, p5.y, fmaf(v6, p6.y, fmaf(v7, p7.y, ay))));
    }
    float n2 = ax * ax + ay * ay;
    #pragma unroll
    for (int o = 32; o > 0; o >>= 1) n2 += __shfl_xor(n2, o, 64);
    float inv = rsqrtf(fmaxf(n2, 1e-30f));
    *(unsigned int*)(raw_h + (size_t)wid * DIM + lo2) = f2h2(ax, ay);
    float2 bv = *(const float2*)(base + (size_t)wid * DIM + lo2);
    *(float2*)(acc + (size_t)wid * DIM + lo2) =
        make_float2(bv.x + ax * inv, bv.y + ay * inv);
}

// ---------------- fused 3-channel L1-user SpMM: shared src gather, 3 raw outputs ----------------
__global__ __launch_bounds__(256) void spmm3_kernel(
        const int* __restrict__ ptr, const int4* __restrict__ pack,
        const unsigned short* __restrict__ src,     // pid_h (shared across channels)
        unsigned short* __restrict__ r0, unsigned short* __restrict__ r1,
        unsigned short* __restrict__ r2, int nrows) {
    int wid = (blockIdx.x * blockDim.x + threadIdx.x) >> 6;
    int lane = threadIdx.x & 63;
    if (wid >= nrows) return;
    int beg = __builtin_amdgcn_readfirstlane(iclamp(ptr[wid], 0, N_EDGES));
    int end = __builtin_amdgcn_readfirstlane(iclamp(ptr[wid + 1], 0, N_EDGES));
    if (end < beg) end = beg;
    float a0x = 0.f, a0y = 0.f, a1x = 0.f, a1y = 0.f, a2x = 0.f, a2y = 0.f;
    int e = beg;
    int lo2 = lane * 2;
    for (; e + 4 <= end; e += 4) {
        int4 q0 = pack[e + 0], q1 = pack[e + 1], q2 = pack[e + 2], q3 = pack[e + 3];
        float2 p0 = h2f2(*(const unsigned int*)(src + (size_t)q0.x * DIM + lo2));
        float2 p1 = h2f2(*(const unsigned int*)(src + (size_t)q1.x * DIM + lo2));
        float2 p2 = h2f2(*(const unsigned int*)(src + (size_t)q2.x * DIM + lo2));
        float2 p3 = h2f2(*(const unsigned int*)(src + (size_t)q3.x * DIM + lo2));
        a0x = fmaf(__int_as_float(q0.y), p0.x, fmaf(__int_as_float(q1.y), p1.x,
              fmaf(__int_as_float(q2.y), p2.x, fmaf(__int_as_float(q3.y), p3.x, a0x))));
        a0y = fmaf(__int_as_float(q0.y), p0.y, fmaf(__int_as_float(q1.y), p1.y,
              fmaf(__int_as_float(q2.y), p2.y, fmaf(__int_as_float(q3.y), p3.y, a0y))));
        a1x = fmaf(__int_as_float(q0.z), p0.x, fmaf(__int_as_float(q1.z), p1.x,
              fmaf(__int_as_float(q2.z), p2.x, fmaf(__int_as_float(q3.z), p3.x, a1x))));
        a1y = fmaf(__int_as_float(q0.z), p0.y, fmaf(__int_as_float(q1.z), p1.y,
              fmaf(__int_as_float(q2.z), p2.y, fmaf(__int_as_float(q3.z), p3.y, a1y))));
        a2x = fmaf(__int_as_float(q0.w), p0.x, fmaf(__int_as_float(q1.w), p1.x,
              fmaf(__int_as_float(q2.w), p2.x, fmaf(__int_as_float(q3.w), p3.x, a2x))));
        a2y = fmaf(__int_as_float(q0.w), p0.y, fmaf(__int_as_float(q1.w), p1.y,
              fmaf(__int_as_float(q2.w), p2.y, fmaf(__int_as_float(q3.w), p3.y, a2y))));
    }
    for (; e < end; e++) {
        int4 q = pack[e];
        float2 p = h2f2(*(const unsigned int*)(src + (size_t)q.x * DIM + lo2));
        a0x = fmaf(__int_as_float(q.y), p.x, a0x);
        a0y = fmaf(__int_as_float(q.y), p.y, a0y);
        a1x = fmaf(__int_as_float(q.z), p.x, a1x);
        a1y = fmaf(__int_as_float(q.z), p.y, a1y);
        a2x = fmaf(__int_as_float(q.w), p.x, a2x);
        a2y = fmaf(__int_as_float(q.w), p.y, a2y);
    }
    size_t o = (size_t)wid * DIM + lo2;
    *(unsigned int*)(r0 + o) = f2h2(a0x, a0y);
    *(unsigned int*)(r1 + o) = f2h2(a1x, a1y);
    *(unsigned int*)(r2 + o) = f2h2(a2x, a2y);
}

// ---------------- fused 3-channel L1-poi SpMM: 3 distinct srcs (u1 per channel) ----------------
__global__ __launch_bounds__(256) void spmm3p_kernel(
        const int* __restrict__ ptr, const int4* __restrict__ pack,
        const unsigned short* __restrict__ s0, const unsigned short* __restrict__ s1,
        const unsigned short* __restrict__ s2,
        unsigned short* __restrict__ r0, unsigned short* __restrict__ r1,
        unsigned short* __restrict__ r2, int nrows) {
    int wid = (blockIdx.x * blockDim.x + threadIdx.x) >> 6;
    int lane = threadIdx.x & 63;
    if (wid >= nrows) return;
    int beg = __builtin_amdgcn_readfirstlane(iclamp(ptr[wid], 0, N_EDGES));
    int end = __builtin_amdgcn_readfirstlane(iclamp(ptr[wid + 1], 0, N_EDGES));
    if (end < beg) end = beg;
    float a0x = 0.f, a0y = 0.f, a1x = 0.f, a1y = 0.f, a2x = 0.f, a2y = 0.f;
    int e = beg;
    int lo2 = lane * 2;
    for (; e + 4 <= end; e += 4) {
        int4 q0 = pack[e + 0], q1 = pack[e + 1], q2 = pack[e + 2], q3 = pack[e + 3];
        size_t o0 = (size_t)q0.x * DIM + lo2, o1 = (size_t)q1.x * DIM + lo2;
        size_t o2 = (size_t)q2.x * DIM + lo2, o3 = (size_t)q3.x * DIM + lo2;
        float2 u00 = h2f2(*(const unsigned int*)(s0 + o0));
        float2 u01 = h2f2(*(const unsigned int*)(s0 + o1));
        float2 u02 = h2f2(*(const unsigned int*)(s0 + o2));
        float2 u03 = h2f2(*(const unsigned int*)(s0 + o3));
        float2 u10 = h2f2(*(const unsigned int*)(s1 + o0));
        float2 u11 = h2f2(*(const unsigned int*)(s1 + o1));
        float2 u12 = h2f2(*(const unsigned int*)(s1 + o2));
        float2 u13 = h2f2(*(const unsigned int*)(s1 + o3));
        float2 u20 = h2f2(*(const unsigned int*)(s2 + o0));
        float2 u21 = h2f2(*(const unsigned int*)(s2 + o1));
        float2 u22 = h2f2(*(const unsigned int*)(s2 + o2));
        float2 u23 = h2f2(*(const unsigned int*)(s2 + o3));
        a0x = fmaf(__int_as_float(q0.y), u00.x, fmaf(__int_as_float(q1.y), u01.x,
              fmaf(__int_as_float(q2.y), u02.x, fmaf(__int_as_float(q3.y), u03.x, a0x))));
        a0y = fmaf(__int_as_float(q0.y), u00.y, fmaf(__int_as_float(q1.y), u01.y,
              fmaf(__int_as_float(q2.y), u02.y, fmaf(__int_as_float(q3.y), u03.y, a0y))));
        a1x = fmaf(__int_as_float(q0.z), u10.x, fmaf(__int_as_float(q1.z), u11.x,
              fmaf(__int_as_float(q2.z), u12.x, fmaf(__int_as_float(q3.z), u13.x, a1x))));
        a1y = fmaf(__int_as_float(q0.z), u10.y, fmaf(__int_as_float(q1.z), u11.y,
              fmaf(__int_as_float(q2.z), u12.y, fmaf(__int_as_float(q3.z), u13.y, a1y))));
        a2x = fmaf(__int_as_float(q0.w), u20.x, fmaf(__int_as_float(q1.w), u21.x,
              fmaf(__int_as_float(q2.w), u22.x, fmaf(__int_as_float(q3.w), u23.x, a2x))));
        a2y = fmaf(__int_as_float(q0.w), u20.y, fmaf(__int_as_float(q1.w), u21.y,
              fmaf(__int_as_float(q2.w), u22.y, fmaf(__int_as_float(q3.w), u23.y, a2y))));
    }
    for (; e < end; e++) {
        int4 q = pack[e];
        size_t o = (size_t)q.x * DIM + lo2;
        float2 p0 = h2f2(*(const unsigned int*)(s0 + o));
        float2 p1 = h2f2(*(const unsigned int*)(s1 + o));
        float2 p2 = h2f2(*(const unsigned int*)(s2 + o));
        a0x = fmaf(__int_as_float(q.y), p0.x, a0x);
        a0y = fmaf(__int_as_float(q.y), p0.y, a0y);
        a1x = fmaf(__int_as_float(q.z), p1.x, a1x);
        a1y = fmaf(__int_as_float(q.z), p1.y, a1y);
        a2x = fmaf(__int_as_float(q.w), p2.x, a2x);
        a2y = fmaf(__int_as_float(q.w), p2.y, a2y);
    }
    size_t o = (size_t)wid * DIM + lo2;
    *(unsigned int*)(r0 + o) = f2h2(a0x, a0y);
    *(unsigned int*)(r1 + o) = f2h2(a1x, a1y);
    *(unsigned int*)(r2 + o) = f2h2(a2x, a2y);
}

// ---------------- fused 3-channel L2-user: 3 p1 srcs; su_c = uid + n(u1_c) + n(u2_c) ----------------
__global__ __launch_bounds__(256) void spmm_l2u3_kernel(
        const int* __restrict__ ptr, const int4* __restrict__ pack,
        const unsigned short* __restrict__ s0, const unsigned short* __restrict__ s1,
        const unsigned short* __restrict__ s2,          // p1raw per channel
        unsigned short* __restrict__ u0, unsigned short* __restrict__ u1r,
        unsigned short* __restrict__ u2r,               // in: u1 raw; out: u2 raw
        const float* __restrict__ uid,
        float* __restrict__ su0, float* __restrict__ su1, float* __restrict__ su2,
        int nrows) {
    int wid = (blockIdx.x * blockDim.x + threadIdx.x) >> 6;
    int lane = threadIdx.x & 63;
    if (wid >= nrows) return;
    int beg = __builtin_amdgcn_readfirstlane(iclamp(ptr[wid], 0, N_EDGES));
    int end = __builtin_amdgcn_readfirstlane(iclamp(ptr[wid + 1], 0, N_EDGES));
    if (end < beg) end = beg;
    float a0x = 0.f, a0y = 0.f, a1x = 0.f, a1y = 0.f, a2x = 0.f, a2y = 0.f;
    int e = beg;
    int lo2 = lane * 2;
    for (; e + 4 <= end; e += 4) {
        int4 q0 = pack[e + 0], q1 = pack[e + 1], q2 = pack[e + 2], q3 = pack[e + 3];
        size_t o0 = (size_t)q0.x * DIM + lo2, o1 = (size_t)q1.x * DIM + lo2;
        size_t o2 = (size_t)q2.x * DIM + lo2, o3 = (size_t)q3.x * DIM + lo2;
        float2 u00 = h2f2(*(const unsigned int*)(s0 + o0));
        float2 u01 = h2f2(*(const unsigned int*)(s0 + o1));
        float2 u02 = h2f2(*(const unsigned int*)(s0 + o2));
        float2 u03 = h2f2(*(const unsigned int*)(s0 + o3));
        float2 u10 = h2f2(*(const unsigned int*)(s1 + o0));
        float2 u11 = h2f2(*(const unsigned int*)(s1 + o1));
        float2 u12 = h2f2(*(const unsigned int*)(s1 + o2));
        float2 u13 = h2f2(*(const unsigned int*)(s1 + o3));
        float2 u20 = h2f2(*(const unsigned int*)(s2 + o0));
        float2 u21 = h2f2(*(const unsigned int*)(s2 + o1));
        float2 u22 = h2f2(*(const unsigned int*)(s2 + o2));
        float2 u23 = h2f2(*(const unsigned int*)(s2 + o3));
        a0x = fmaf(__int_as_float(q0.y), u00.x, fmaf(__int_as_float(q1.y), u01.x,
              fmaf(__int_as_float(q2.y), u02.x, fmaf(__int_as_float(q3.y), u03.x, a0x))));
        a0y = fmaf(__int_as_float(q0.y), u00.y, fmaf(__int_as_float(q1.y), u01.y,
              fmaf(__int_as_float(q2.y), u02.y, fmaf(__int_as_float(q3.y), u03.y, a0y))));
        a1x = fmaf(__int_as_float(q0.z), u10.x, fmaf(__int_as_float(q1.z), u11.x,
              fmaf(__int_as_float(q2.z), u12.x, fmaf(__int_as_float(q3.z), u13.x, a1x))));
        a1y = fmaf(__int_as_float(q0.z), u10.y, fmaf(__int_as_float(q1.z), u11.y,
              fmaf(__int_as_float(q2.z), u12.y, fmaf(__int_as_float(q3.z), u13.y, a1y))));
        a2x = fmaf(__int_as_float(q0.w), u20.x, fmaf(__int_as_float(q1.w), u21.x,
              fmaf(__int_as_float(q2.w), u22.x, fmaf(__int_as_float(q3.w), u23.x, a2x))));
        a2y = fmaf(__int_as_float(q0.w), u20.y, fmaf(__int_as_float(q1.w), u21.y,
              fmaf(__int_as_float(q2.w), u22.y, fmaf(__int_as_float(q3.w), u23.y, a2y))));
    }
    for (; e < end; e++) {
        int4 q = pack[e];
        size_t o = (size_t)q.x * DIM + lo2;
        float2 p0 = h2f2(*(const unsigned int*)(s0 + o));
        float2 p1 = h2f2(*(const unsigned int*)(s1 + o));
        float2 p2 = h2f2(*(const unsigned int*)(s2 + o));
        a0x = fmaf(__int_as_float(q.y), p0.x, a0x);
        a0y = fmaf(__int_as_float(q.y), p0.y, a0y);
        a1x = fmaf(__int_as_float(q.z), p1.x, a1x);
        a1y = fmaf(__int_as_float(q.z), p1.y, a1y);
        a2x = fmaf(__int_as_float(q.w), p2.x, a2x);
        a2y = fmaf(__int_as_float(q.w), p2.y, a2y);
    }
    size_t o = (size_t)wid * DIM + lo2;
    float2 x0 = h2f2(*(const unsigned int*)(u0 + o));
    float2 x1 = h2f2(*(const unsigned int*)(u1r + o));
    float2 x2 = h2f2(*(const unsigned int*)(u2r + o));
    float m0 = a0x * a0x + a0y * a0y;   // u2 ch0
    float m1 = a1x * a1x + a1y * a1y;
    float m2 = a2x * a2x + a2y * a2y;
    float k0 = x0.x * x0.x + x0.y * x0.y; // u1 ch0
    float k1 = x1.x * x1.x + x1.y * x1.y;
    float k2 = x2.x * x2.x + x2.y * x2.y;
    #pragma unroll
    for (int oo = 32; oo > 0; oo >>= 1) {
        m0 += __shfl_xor(m0, oo, 64); m1 += __shfl_xor(m1, oo, 64); m2 += __shfl_xor(m2, oo, 64);
        k0 += __shfl_xor(k0, oo, 64); k1 += __shfl_xor(k1, oo, 64); k2 += __shfl_xor(k2, oo, 64);
    }
    float im0 = rsqrtf(fmaxf(m0, 1e-30f)), ik0 = rsqrtf(fmaxf(k0, 1e-30f));
    float im1 = rsqrtf(fmaxf(m1, 1e-30f)), ik1 = rsqrtf(fmaxf(k1, 1e-30f));
    float im2 = rsqrtf(fmaxf(m2, 1e-30f)), ik2 = rsqrtf(fmaxf(k2, 1e-30f));
    *(unsigned int*)(u0 + o)  = f2h2(a0x, a0y);
    *(unsigned int*)(u1r + o) = f2h2(a1x, a1y);
    *(unsigned int*)(u2r + o) = f2h2(a2x, a2y);
    float2 bv = *(const float2*)(uid + o);
    *(float2*)(su0 + o) = make_float2(bv.x + x0.x * ik0 + a0x * im0, bv.y + x0.y * ik0 + a0y * im0);
    *(float2*)(su1 + o) = make_float2(bv.x + x1.x * ik1 + a1x * im1, bv.y + x1.y * ik1 + a1y * im1);
    *(float2*)(su2 + o) = make_float2(bv.x + x2.x * ik2 + a2x * im2, bv.y + x2.y * ik2 + a2y * im2);
}

// ---------------- fused 3-channel L2-poi: 3 u2 srcs; sp_c = pid + n(p1_c) + n(p2_c) ----------------
__global__ __launch_bounds__(256) void spmm_l2p3_kernel(
        const int* __restrict__ ptr, const int4* __restrict__ pack,
        const unsigned short* __restrict__ s0, const unsigned short* __restrict__ s1,
        const unsigned short* __restrict__ s2,          // u2raw per channel
        const unsigned short* __restrict__ p0r, const unsigned short* __restrict__ p1r,
        const unsigned short* __restrict__ p2r,         // p1raw per channel (read-only)
        const float* __restrict__ pid,
        float* __restrict__ sp0, float* __restrict__ sp1, float* __restrict__ sp2,
        int nrows) {
    int wid = (blockIdx.x * blockDim.x + threadIdx.x) >> 6;
    int lane = threadIdx.x & 63;
    if (wid >= nrows) return;
    int beg = __builtin_amdgcn_readfirstlane(iclamp(ptr[wid], 0, N_EDGES));
    int end = __builtin_amdgcn_readfirstlane(iclamp(ptr[wid + 1], 0, N_EDGES));
    if (end < beg) end = beg;
    float a0x = 0.f, a0y = 0.f, a1x = 0.f, a1y = 0.f, a2x = 0.f, a2y = 0.f;
    int e = beg;
    int lo2 = lane * 2;
    for (; e + 4 <= end; e += 4) {
        int4 q0 = pack[e + 0], q1 = pack[e + 1], q2 = pack[e + 2], q3 = pack[e + 3];
        size_t o0 = (size_t)q0.x * DIM + lo2, o1 = (size_t)q1.x * DIM + lo2;
        size_t o2 = (size_t)q2.x * DIM + lo2, o3 = (size_t)q3.x * DIM + lo2;
        float2 u00 = h2f2(*(const unsigned int*)(s0 + o0));
        float2 u01 = h2f2(*(const unsigned int*)(s0 + o1));
        float2 u02 = h2f2(*(const unsigned int*)(s0 + o2));
        float2 u03 = h2f2(*(const unsigned int*)(s0 + o3));
        float2 u10 = h2f2(*(const unsigned int*)(s1 + o0));
        float2 u11 = h2f2(*(const unsigned int*)(s1 + o1));
        float2 u12 = h2f2(*(const unsigned int*)(s1 + o2));
        float2 u13 = h2f2(*(const unsigned int*)(s1 + o3));
        float2 u20 = h2f2(*(const unsigned int*)(s2 + o0));
        float2 u21 = h2f2(*(const unsigned int*)(s2 + o1));
        float2 u22 = h2f2(*(const unsigned int*)(s2 + o2));
        float2 u23 = h2f2(*(const unsigned int*)(s2 + o3));
        a0x = fmaf(__int_as_float(q0.y), u00.x, fmaf(__int_as_float(q1.y), u01.x,
              fmaf(__int_as_float(q2.y), u02.x, fmaf(__int_as_float(q3.y), u03.x, a0x))));
        a0y = fmaf(__int_as_float(q0.y), u00.y, fmaf(__int_as_float(q1.y), u01.y,
              fmaf(__int_as_float(q2.y), u02.y, fmaf(__int_as_float(q3.y), u03.y, a0y))));
        a1x = fmaf(__int_as_float(q0.z), u10.x, fmaf(__int_as_float(q1.z), u11.x,
              fmaf(__int_as_float(q2.z), u12.x, fmaf(__int_as_float(q3.z), u13.x, a1x))));
        a1y = fmaf(__int_as_float(q0.z), u10.y, fmaf(__int_as_float(q1.z), u11.y,
              fmaf(__int_as_float(q2.z), u12.y, fmaf(__int_as_float(q3.z), u13.y, a1y))));
        a2x = fmaf(__int_as_float(q0.w), u20.x, fmaf(__int_as_float(q1.w), u21.x,
              fmaf(__int_as_float(q2.w), u22.x, fmaf(__int_as_float(q3.w), u23.x, a2x))));
        a2y = fmaf(__int_as_float(q0.w), u20.y, fmaf(__int_as_float(q1.w), u21.y,
              fmaf(__int_as_float(q2.w), u22.y, fmaf(__int_as_float(q3.w), u23.y, a2y))));
    }
    for (; e < end; e++) {
        int4 q = pack[e];
        size_t o = (size_t)q.x * DIM + lo2;
        float2 p0 = h2f2(*(const unsigned int*)(s0 + o));
        float2 p1 = h2f2(*(const unsigned int*)(s1 + o));
        float2 p2 = h2f2(*(const unsigned int*)(s2 + o));
        a0x = fmaf(__int_as_float(q.y), p0.x, a0x);
        a0y = fmaf(__int_as_float(q.y), p0.y, a0y);
        a1x = fmaf(__int_as_float(q.z), p1.x, a1x);
        a1y = fmaf(__int_as_float(q.z), p1.y, a1y);
        a2x = fmaf(__int_as_float(q.w), p2.x, a2x);
        a2y = fmaf(__int_as_float(q.w), p2.y, a2y);
    }
    size_t o = (size_t)wid * DIM + lo2;
    float2 x0 = h2f2(*(const unsigned int*)(p0r + o));
    float2 x1 = h2f2(*(const unsigned int*)(p1r + o));
    float2 x2 = h2f2(*(const unsigned int*)(p2r + o));
    float m0 = a0x * a0x + a0y * a0y;
    float m1 = a1x * a1x + a1y * a1y;
    float m2 = a2x * a2x + a2y * a2y;
    float k0 = x0.x * x0.x + x0.y * x0.y;
    float k1 = x1.x * x1.x + x1.y * x1.y;
    float k2 = x2.x * x2.x + x2.y * x2.y;
    #pragma unroll
    for (int oo = 32; oo > 0; oo >>= 1) {
        m0 += __shfl_xor(m0, oo, 64); m1 += __shfl_xor(m1, oo, 64); m2 += __shfl_xor(m2, oo, 64);
        k0 += __shfl_xor(k0, oo, 64); k1 += __shfl_xor(k1, oo, 64); k2 += __shfl_xor(k2, oo, 64);
    }
    float im0 = rsqrtf(fmaxf(m0, 1e-30f)), ik0 = rsqrtf(fmaxf(k0, 1e-30f));
    float im1 = rsqrtf(fmaxf(m1, 1e-30f)), ik1 = rsqrtf(fmaxf(k1, 1e-30f));
    float im2 = rsqrtf(fmaxf(m2, 1e-30f)), ik2 = rsqrtf(fmaxf(k2, 1e-30f));
    float2 bv = *(const float2*)(pid + o);
    *(float2*)(sp0 + o) = make_float2(bv.x + x0.x * ik0 + a0x * im0, bv.y + x0.y * ik0 + a0y * im0);
    *(float2*)(sp1 + o) = make_float2(bv.x + x1.x * ik1 + a1x * im1, bv.y + x1.y * ik1 + a1y * im1);
    *(float2*)(sp2 + o) = make_float2(bv.x + x2.x * ik2 + a2x * im2, bv.y + x2.y * ik2 + a2y * im2);
}

// ---------------- L2-user SpMM (single channel, tier-1 path) ----------------
template<int CH>
__global__ __launch_bounds__(256) void spmm_l2u_kernel(
        const int* __restrict__ ptr, const int4* __restrict__ pack,
        const unsigned short* __restrict__ src,
        unsigned short* __restrict__ u1raw,
        const float* __restrict__ uid,
        float* __restrict__ su, int nrows) {
    int wid = (blockIdx.x * blockDim.x + threadIdx.x) >> 6;
    int lane = threadIdx.x & 63;
    if (wid >= nrows) return;
    int beg = __builtin_amdgcn_readfirstlane(iclamp(ptr[wid], 0, N_EDGES));
    int end = __builtin_amdgcn_readfirstlane(iclamp(ptr[wid + 1], 0, N_EDGES));
    if (end < beg) end = beg;
    float ax = 0.f, ay = 0.f;
    int e = beg;
    int lo2 = lane * 2;
    for (; e + 8 <= end; e += 8) {
        int4 q0 = pack[e + 0], q1 = pack[e + 1], q2 = pack[e + 2], q3 = pack[e + 3];
        int4 q4 = pack[e + 4], q5 = pack[e + 5], q6 = pack[e + 6], q7 = pack[e + 7];
        float v0 = pickvT<CH>(q0), v1 = pickvT<CH>(q1), v2 = pickvT<CH>(q2), v3 = pickvT<CH>(q3);
        float v4 = pickvT<CH>(q4), v5 = pickvT<CH>(q5), v6 = pickvT<CH>(q6), v7 = pickvT<CH>(q7);
        float2 p0 = h2f2(*(const unsigned int*)(src + (size_t)q0.x * DIM + lo2));
        float2 p1 = h2f2(*(const unsigned int*)(src + (size_t)q1.x * DIM + lo2));
        float2 p2 = h2f2(*(const unsigned int*)(src + (size_t)q2.x * DIM + lo2));
        float2 p3 = h2f2(*(const unsigned int*)(src + (size_t)q3.x * DIM + lo2));
        float2 p4 = h2f2(*(const unsigned int*)(src + (size_t)q4.x * DIM + lo2));
        float2 p5 = h2f2(*(const unsigned int*)(src + (size_t)q5.x * DIM + lo2));
        float2 p6 = h2f2(*(const unsigned int*)(src + (size_t)q6.x * DIM + lo2));
        float2 p7 = h2f2(*(const unsigned int*)(src + (size_t)q7.x * DIM + lo2));
        ax = fmaf(v0, p0.x, fmaf(v1, p1.x, fmaf(v2, p2.x, fmaf(v3, p3.x, ax))));
        ax = fmaf(v4, p4.x, fmaf(v5, p5.x, fmaf(v6, p6.x, fmaf(v7, p7.x, ax))));
        ay = fmaf(v0, p0.y, fmaf(v1, p1.y, fmaf(v2, p2.y, fmaf(v3, p3.y, ay))));
        ay = fmaf(v4, p4.y, fmaf(v5, p5.y, fmaf(v6, p6.y, fmaf(v7, p7.y, ay))));
    }
    if (e < end) {
        int last = end - 1;
        int e1 = e + 1 <= last ? e + 1 : last;
        int e2 = e + 2 <= last ? e + 2 : last;
        int e3 = e + 3 <= last ? e + 3 : last;
        int e4 = e + 4 <= last ? e + 4 : last;
        int e5 = e + 5 <= last ? e + 5 : last;
        int e6 = e + 6 <= last ? e + 6 : last;
        int e7 = e + 7 <= last ? e + 7 : last;
        int4 q0 = pack[e], q1 = pack[e1], q2 = pack[e2], q3 = pack[e3];
        int4 q4 = pack[e4], q5 = pack[e5], q6 = pack[e6], q7 = pack[e7];
        float v0 = pickvT<CH>(q0);
        float v1 = (e + 1 < end) ? pickvT<CH>(q1) : 0.f;
        float v2 = (e + 2 < end) ? pickvT<CH>(q2) : 0.f;
        float v3 = (e + 3 < end) ? pickvT<CH>(q3) : 0.f;
        float v4 = (e + 4 < end) ? pickvT<CH>(q4) : 0.f;
        float v5 = (e + 5 < end) ? pickvT<CH>(q5) : 0.f;
        float v6 = (e + 6 < end) ? pickvT<CH>(q6) : 0.f;
        float v7 = (e + 7 < end) ? pickvT<CH>(q7) : 0.f;
        float2 p0 = h2f2(*(const unsigned int*)(src + (size_t)q0.x * DIM + lo2));
        float2 p1 = h2f2(*(const unsigned int*)(src + (size_t)q1.x * DIM + lo2));
        float2 p2 = h2f2(*(const unsigned int*)(src + (size_t)q2.x * DIM + lo2));
        float2 p3 = h2f2(*(const unsigned int*)(src + (size_t)q3.x * DIM + lo2));
        float2 p4 = h2f2(*(const unsigned int*)(src + (size_t)q4.x * DIM + lo2));
        float2 p5 = h2f2(*(const unsigned int*)(src + (size_t)q5.x * DIM + lo2));
        float2 p6 = h2f2(*(const unsigned int*)(src + (size_t)q6.x * DIM + lo2));
        float2 p7 = h2f2(*(const unsigned int*)(src + (size_t)q7.x * DIM + lo2));
        ax = fmaf(v0, p0.x, fmaf(v1, p1.x, fmaf(v2, p2.x, fmaf(v3, p3.x, ax))));
        ax = fmaf(v4, p4.x, fmaf(v5, p5.x, fmaf(v6, p6.x, fmaf(v7, p7.x, ax))));
        ay = fmaf(v0, p0.y, fmaf(v1, p1.y, fmaf(v2, p2.y, fmaf(v3, p3.y, ay))));
        ay = fmaf(v4, p4.y, fmaf(v5, p5.y, fmaf(v6, p6.y, fmaf(v7, p7.y, ay))));
    }
    size_t o = (size_t)wid * DIM + lo2;
    float2 u1 = h2f2(*(const unsigned int*)(u1raw + o));
    float n2a = ax * ax + ay * ay;
    float n2b = u1.x * u1.x + u1.y * u1.y;
    #pragma unroll
    for (int oo = 32; oo > 0; oo >>= 1) {
        n2a += __shfl_xor(n2a, oo, 64);
        n2b += __shfl_xor(n2b, oo, 64);
    }
    float i2 = rsqrtf(fmaxf(n2a, 1e-30f));
    float i1 = rsqrtf(fmaxf(n2b, 1e-30f));
    *(unsigned int*)(u1raw + o) = f2h2(ax, ay);
    float2 bv = *(const float2*)(uid + o);
    *(float2*)(su + o) = make_float2(bv.x + u1.x * i1 + ax * i2,
                                     bv.y + u1.y * i1 + ay * i2);
}

// ---------------- L2-poi SpMM (single channel, tier-1 path) ----------------
template<int CH>
__global__ __launch_bounds__(256) void spmm_l2p_kernel(
        const int* __restrict__ ptr, const int4* __restrict__ pack,
        const unsigned short* __restrict__ src,
        const unsigned short* __restrict__ p1raw,
        const float* __restrict__ pid,
        float* __restrict__ sp, int nrows) {
    int wid = (blockIdx.x * blockDim.x + threadIdx.x) >> 6;
    int lane = threadIdx.x & 63;
    if (wid >= nrows) return;
    int beg = __builtin_amdgcn_readfirstlane(iclamp(ptr[wid], 0, N_EDGES));
    int end = __builtin_amdgcn_readfirstlane(iclamp(ptr[wid + 1], 0, N_EDGES));
    if (end < beg) end = beg;
    float ax = 0.f, ay = 0.f;
    int e = beg;
    int lo2 = lane * 2;
    for (; e + 8 <= end; e += 8) {
        int4 q0 = pack[e + 0], q1 = pack[e + 1], q2 = pack[e + 2], q3 = pack[e + 3];
        int4 q4 = pack[e + 4], q5 = pack[e + 5], q6 = pack[e + 6], q7 = pack[e + 7];
        float v0 = pickvT<CH>(q0), v1 = pickvT<CH>(q1), v2 = pickvT<CH>(q2), v3 = pickvT<CH>(q3);
        float v4 = pickvT<CH>(q4), v5 = pickvT<CH>(q5), v6 = pickvT<CH>(q6), v7 = pickvT<CH>(q7);
        float2 p0 = h2f2(*(const unsigned int*)(src + (size_t)q0.x * DIM + lo2));
        float2 p1 = h2f2(*(const unsigned int*)(src + (size_t)q1.x * DIM + lo2));
        float2 p2 = h2f2(*(const unsigned int*)(src + (size_t)q2.x * DIM + lo2));
        float2 p3 = h2f2(*(const unsigned int*)(src + (size_t)q3.x * DIM + lo2));
        float2 p4 = h2f2(*(const unsigned int*)(src + (size_t)q4.x * DIM + lo2));
        float2 p5 = h2f2(*(const unsigned int*)(src + (size_t)q5.x * DIM + lo2));
        float2 p6 = h2f2(*(const unsigned int*)(src + (size_t)q6.x * DIM + lo2));
        float2 p7 = h2f2(*(const unsigned int*)(src + (size_t)q7.x * DIM + lo2));
        ax = fmaf(v0, p0.x, fmaf(v1, p1.x, fmaf(v2, p2.x, fmaf(v3, p3.x, ax))));
        ax = fmaf(v4, p4.x, fmaf(v5, p5.x, fmaf(v6, p6.x, fmaf(v7, p7.x, ax))));
        ay = fmaf(v0, p0.y, fmaf(v1, p1.y, fmaf(v2, p2.y, fmaf(v3, p3.y, ay))));
        ay = fmaf(v4, p4.y, fmaf(v5, p5.y, fmaf(v6, p6.y, fmaf(v7, p7.y, ay))));
    }
    if (e < end) {
        int last = end - 1;
        int e1 = e + 1 <= last ? e + 1 : last;
        int e2 = e + 2 <= last ? e + 2 : last;
        int e3 = e + 3 <= last ? e + 3 : last;
        int e4 = e + 4 <= last ? e + 4 : last;
        int e5 = e + 5 <= last ? e + 5 : last;
        int e6 = e + 6 <= last ? e + 6 : last;
        int e7 = e + 7 <= last ? e + 7 : last;
        int4 q0 = pack[e], q1 = pack[e1], q2 = pack[e2], q3 = pack[e3];
        int4 q4 = pack[e4], q5 = pack[e5], q6 = pack[e6], q7 = pack[e7];
        float v0 = pickvT<CH>(q0);
        float v1 = (e + 1 < end) ? pickvT<CH>(q1) : 0.f;
        float v2 = (e + 2 < end) ? pickvT<CH>(q2) : 0.f;
        float v3 = (e + 3 < end) ? pickvT<CH>(q3) : 0.f;
        float v4 = (e + 4 < end) ? pickvT<CH>(q4) : 0.f;
        float v5 = (e + 5 < end) ? pickvT<CH>(q5) : 0.f;
        float v6 = (e + 6 < end) ? pickvT<CH>(q6) : 0.f;
        float v7 = (e + 7 < end) ? pickvT<CH>(q7) : 0.f;
        float2 p0 = h2f2(*(const unsigned int*)(src + (size_t)q0.x * DIM + lo2));
        float2 p1 = h2f2(*(const unsigned int*)(src + (size_t)q1.x * DIM + lo2));
        float2 p2 = h2f2(*(const unsigned int*)(src + (size_t)q2.x * DIM + lo2));
        float2 p3 = h2f2(*(const unsigned int*)(src + (size_t)q3.x * DIM + lo2));
        float2 p4 = h2f2(*(const unsigned int*)(src + (size_t)q4.x * DIM + lo2));
        float2 p5 = h2f2(*(const unsigned int*)(src + (size_t)q5.x * DIM + lo2));
        float2 p6 = h2f2(*(const unsigned int*)(src + (size_t)q6.x * DIM + lo2));
        float2 p7 = h2f2(*(const unsigned int*)(src + (size_t)q7.x * DIM + lo2));
        ax = fmaf(v0, p0.x, fmaf(v1, p1.x, fmaf(v2, p2.x, fmaf(v3, p3.x, ax))));
        ax = fmaf(v4, p4.x, fmaf(v5, p5.x, fmaf(v6, p6.x, fmaf(v7, p7.x, ax))));
        ay = fmaf(v0, p0.y, fmaf(v1, p1.y, fmaf(v2, p2.y, fmaf(v3, p3.y, ay))));
        ay = fmaf(v4, p4.y, fmaf(v5, p5.y, fmaf(v6, p6.y, fmaf(v7, p7.y, ay))));
    }
    size_t o = (size_t)wid * DIM + lo2;
    float2 p1v = h2f2(*(const unsigned int*)(p1raw + o));
    float n2a = ax * ax + ay * ay;
    float n2b = p1v.x * p1v.x + p1v.y * p1v.y;
    #pragma unroll
    for (int oo = 32; oo > 0; oo >>= 1) {
        n2a += __shfl_xor(n2a, oo, 64);
        n2b += __shfl_xor(n2b, oo, 64);
    }
    float i2 = rsqrtf(fmaxf(n2a, 1e-30f));
    float i1 = rsqrtf(fmaxf(n2b, 1e-30f));
    float2 bv = *(const float2*)(pid + o);
    *(float2*)(sp + o) = make_float2(bv.x + p1v.x * i1 + ax * i2,
                                     bv.y + p1v.y * i1 + ay * i2);
}

// ---------------- MFMA: out[Mx128] = A[Mx128] @ W^T ; fp32 in, fp16 frags, fp32 accum ----------------
__global__ __launch_bounds__(256) void gemm_mfma_kernel(
        const float* __restrict__ A, const float* __restrict__ W,
        float* __restrict__ store, float* __restrict__ accum,
        _Float16* __restrict__ accum_h,
        const float* __restrict__ fw3, int fsel, int first, int M) {
    int w = threadIdx.x >> 6, l = threadIdx.x & 63;
    int lg = l >> 4, lc = l & 15;
    int j0 = w * 32;
    float coef = accum ? softmax3(fw3, fsel) : 0.f;
    f16x8 Bf[2][4];
    #pragma unroll
    for (int t = 0; t < 2; t++) {
        const float* wr = W + (size_t)(j0 + t * 16 + lc) * DIM + lg * 8;
        #pragma unroll
        for (int s = 0; s < 4; s++) Bf[t][s] = frag8(wr + s * 32);
    }
    int base = blockIdx.x * 64;
    #pragma unroll
    for (int rt = 0; rt < 4; rt++) {
        int u0 = base + rt * 16;
        int ar = u0 + lc; if (ar > M - 1) ar = M - 1;
        const float* arow = A + (size_t)ar * DIM + lg * 8;
        f16x8 Af[4];
        #pragma unroll
        for (int s = 0; s < 4; s++) Af[s] = frag8(arow + s * 32);
        f32x4 acc0 = {0.f, 0.f, 0.f, 0.f};
        f32x4 acc1 = {0.f, 0.f, 0.f, 0.f};
        #pragma unroll
        for (int s = 0; s < 4; s++) {
            acc0 = __builtin_amdgcn_mfma_f32_16x16x32_f16(Af[s], Bf[0][s], acc0, 0, 0, 0);
            acc1 = __builtin_amdgcn_mfma_f32_16x16x32_f16(Af[s], Bf[1][s], acc1, 0, 0, 0);
        }
        int rbase = u0 + lg * 4;
        #pragma unroll
        for (int r = 0; r < 4; r++) {
            int row = rbase + r;
            if (row >= M) continue;
            size_t o0 = (size_t)row * DIM + j0 + lc;
            size_t o1 = o0 + 16;
            if (store) { store[o0] = acc0[r]; store[o1] = acc1[r]; }
            if (accum) {
                float p0 = first ? 0.f : accum[o0];
                float p1 = first ? 0.f : accum[o1];
                float n0 = p0 + coef * acc0[r];
                float n1 = p1 + coef * acc1[r];
                accum[o0] = n0;
                accum[o1] = n1;
                if (accum_h) {
                    accum_h[o0] = (_Float16)n0;
                    accum_h[o1] = (_Float16)n1;
                }
            }
        }
    }
}

// ---------------- 256 selected rows of uf = su @ Wu^T ----------------
__global__ void ufsel_kernel(const float* __restrict__ su, const float* __restrict__ W,
                             const int* __restrict__ uidx, float* __restrict__ outsel) {
    int b = blockIdx.x, j = threadIdx.x;  // block 128
    __shared__ float ar[128];
    int u = iclamp(uidx[b], 0, N_USERS - 1);
    ar[j] = su[(size_t)u * DIM + j];
    __syncthreads();
    const float4* Wr = (const float4*)(W + (size_t)j * DIM);
    float acc = 0.f;
    #pragma unroll 8
    for (int q = 0; q < 32; q++) {
        float4 wq = Wr[q];
        acc = fmaf(ar[4 * q + 0], wq.x, acc);
        acc = fmaf(ar[4 * q + 1], wq.y, acc);
        acc = fmaf(ar[4 * q + 2], wq.z, acc);
        acc = fmaf(ar[4 * q + 3], wq.w, acc);
    }
    outsel[(size_t)b * DIM + j] = acc;
}

// ---------------- alt[b,j] (+)= wn_c * dot(uf_c[b], pf_c[poi]) ----------------
__global__ __launch_bounds__(256) void predict_kernel(
        const float* __restrict__ ufs, const float* __restrict__ pf,
        const int* __restrict__ pidx, const float* __restrict__ w3,
        int wsel, int first, float* __restrict__ alt) {
    int wid = (blockIdx.x * blockDim.x + threadIdx.x) >> 6;
    int lane = threadIdx.x & 63;
    if (wid >= BATCH * NPOS) return;
    int b = wid / NPOS;
    int poi = iclamp(pidx[wid], 0, N_POIS - 1);
    const float2 uv = *(const float2*)(ufs + (size_t)b * DIM + lane * 2);
    const float2 pv = *(const float2*)(pf + (size_t)poi * DIM + lane * 2);
    float s = uv.x * pv.x + uv.y * pv.y;
    #pragma unroll
    for (int o = 32; o > 0; o >>= 1) s += __shfl_xor(s, o, 64);
    if (lane == 0) {
        float coef = softmax3(w3, wsel);
        float prev = first ? 0.f : alt[wid];
        alt[wid] = prev + coef * s;
    }
}

// ---------------- BCE loss: stage 1 partials (25 blocks) ----------------
__global__ void loss_part_kernel(const float* __restrict__ alt, const float* __restrict__ labels,
                                 float* __restrict__ part) {
    int b = blockIdx.x, t = threadIdx.x;
    int i = b * 1024 + t * 4;
    float4 x4 = *(const float4*)(alt + i);
    float4 y4 = *(const float4*)(labels + i);
    float s = 0.f;
    s += fmaxf(x4.x, 0.f) - x4.x * y4.x + log1pf(expf(-fabsf(x4.x)));
    s += fmaxf(x4.y, 0.f) - x4.y * y4.y + log1pf(expf(-fabsf(x4.y)));
    s += fmaxf(x4.z, 0.f) - x4.z * y4.z + log1pf(expf(-fabsf(x4.z)));
    s += fmaxf(x4.w, 0.f) - x4.w * y4.w + log1pf(expf(-fabsf(x4.w)));
    __shared__ float red[256];
    red[t] = s;
    __syncthreads();
    for (int o = 128; o > 0; o >>= 1) {
        if (t < o) red[t] += red[t + o];
        __syncthreads();
    }
    if (t == 0) part[b] = red[0];
}

// ---------------- BCE loss: stage 2 final (deterministic) ----------------
__global__ void loss_final_kernel(const float* __restrict__ part, float* __restrict__ out) {
    if (threadIdx.x == 0) {
        float s = 0.f;
        #pragma unroll
        for (int b = 0; b < LOSS_BLOCKS; b++) s += part[b];
        out[0] = s / (float)(BATCH * NPOS);
    }
}

// ---------------- bst_h[b][j] = id_feat[cur[b]] @ Ws^T + bias (fp16, row-major) ----------------
__global__ void bs_kernel(const float* __restrict__ idf, const float* __restrict__ Ws,
                          const float* __restrict__ bias, const int* __restrict__ uidx,
                          _Float16* __restrict__ bst_h) {
    int b = blockIdx.x, j = threadIdx.x;  // block 128
    __shared__ float ar[128];
    int u = iclamp(uidx[b], 0, N_USERS - 1);
    ar[j] = idf[(size_t)u * DIM + j];
    __syncthreads();
    const float4* Wr = (const float4*)(Ws + (size_t)j * DIM);
    float acc = 0.f;
    #pragma unroll 8
    for (int q = 0; q < 32; q++) {
        float4 wq = Wr[q];
        acc = fmaf(ar[4 * q + 0], wq.x, acc);
        acc = fmaf(ar[4 * q + 1], wq.y, acc);
        acc = fmaf(ar[4 * q + 2], wq.z, acc);
        acc = fmaf(ar[4 * q + 3], wq.w, acc);
    }
    bst_h[(size_t)b * DIM + j] = (_Float16)(acc + bias[j]);
}

__device__ __forceinline__ void topk_insert(float s, int u, float* ts, int* ti) {
    if (s > ts[TOPK - 1]) {
        #pragma unroll
        for (int j = TOPK - 1; j > 0; --j) {
            bool above = s > ts[j - 1];
            bool here = (!above) && (s > ts[j]);
            float nv = above ? ts[j - 1] : (here ? s : ts[j]);
            int ni = above ? ti[j - 1] : (here ? u : ti[j]);
            ts[j] = nv; ti[j] = ni;
        }
        if (s > ts[0]) { ts[0] = s; ti[0] = u; }
    }
}

// ---------------- MFMA uu scores + per-block top-20: 512 thr, 8 waves ----------------
__global__ __launch_bounds__(512) void score_topk_kernel(
        const _Float16* __restrict__ idf_h, const _Float16* __restrict__ bst_h,
        float* __restrict__ cand_s, int* __restrict__ cand_i) {
    __shared__ __align__(16) unsigned char smraw[61440];
    float* ms = (float*)smraw;                              // [20][512] 40 KB
    unsigned short* mi = (unsigned short*)(smraw + 40960);  // [20][512] 20 KB
    int cid = blockIdx.x, bg = blockIdx.y;
    int tid = threadIdx.x;
    int w = tid >> 6, l = tid & 63;
    int half = w >> 2, wq = w & 3;
    int lg = l >> 4, lc = l & 15;
    const _Float16* bbase = bst_h + ((size_t)(bg * 64 + wq * 16 + lc)) * DIM + lg * 8;
    f16x8 B0 = *(const f16x8*)(bbase + 0);
    f16x8 B1 = *(const f16x8*)(bbase + 32);
    f16x8 B2 = *(const f16x8*)(bbase + 64);
    f16x8 B3 = *(const f16x8*)(bbase + 96);
    float ts[TOPK]; int ti[TOPK];
    #pragma unroll
    for (int k = 0; k < TOPK; k++) { ts[k] = -3.0e38f; ti[k] = 0; }
    int lo = cid * CPT;
    int hi = lo + CPT; if (hi > N_USERS) hi = N_USERS;
    int ntiles = (hi - lo + 15) >> 4;
    int t0 = half ? (ntiles >> 1) : 0;
    int t1 = half ? ntiles : (ntiles >> 1);
    #pragma unroll 2
    for (int t = t0; t < t1; t++) {
        int u0 = lo + t * 16;
        int ar = u0 + lc; if (ar > N_USERS - 1) ar = N_USERS - 1;
        const _Float16* abase = idf_h + (size_t)ar * DIM + lg * 8;
        f16x8 A0 = *(const f16x8*)(abase + 0);
        f16x8 A1 = *(const f16x8*)(abase + 32);
        f16x8 A2 = *(const f16x8*)(abase + 64);
        f16x8 A3 = *(const f16x8*)(abase + 96);
        f32x4 accA = {0.f, 0.f, 0.f, 0.f};
        f32x4 accB = {0.f, 0.f, 0.f, 0.f};
        accA = __builtin_amdgcn_mfma_f32_16x16x32_f16(A0, B0, accA, 0, 0, 0);
        accB = __builtin_amdgcn_mfma_f32_16x16x32_f16(A1, B1, accB, 0, 0, 0);
        accA = __builtin_amdgcn_mfma_f32_16x16x32_f16(A2, B2, accA, 0, 0, 0);
        accB = __builtin_amdgcn_mfma_f32_16x16x32_f16(A3, B3, accB, 0, 0, 0);
        int ub = u0 + lg * 4;
        #pragma unroll
        for (int r = 0; r < 4; r++) {
            float s = accA[r] + accB[r];
            int u = ub + r;
            if (u < hi) topk_insert(s, u, ts, ti);
        }
    }
    #pragma unroll
    for (int k = 0; k < TOPK; k++) {
        ms[k * 512 + tid] = ts[k];
        mi[k * 512 + tid] = (unsigned short)ti[k];
    }
    __syncthreads();
    if (tid < 64) {
        int wm = tid >> 4, cm = tid & 15;
        int s0 = 0 * 256 + wm * 64 + 0 * 16 + cm;
        int s1 = s0 + 16, s2 = s0 + 32, s3 = s0 + 48;
        int s4 = s0 + 256, s5 = s1 + 256, s6 = s2 + 256, s7 = s3 + 256;
        int p0 = 0, p1 = 0, p2 = 0, p3 = 0, p4 = 0, p5 = 0, p6 = 0, p7 = 0;
        size_t ob = ((size_t)cid * 256 + bg * 64 + wm * 16 + cm) * TOPK;
        for (int k = 0; k < TOPK; k++) {
            float h0 = ms[p0 * 512 + s0];
            float h1 = ms[p1 * 512 + s1];
            float h2 = ms[p2 * 512 + s2];
            float h3 = ms[p3 * 512 + s3];
            float h4 = ms[p4 * 512 + s4];
            float h5 = ms[p5 * 512 + s5];
            float h6 = ms[p6 * 512 + s6];
            float h7 = ms[p7 * 512 + s7];
            float best = h0; int which = 0;
            if (h1 > best) { best = h1; which = 1; }
            if (h2 > best) { best = h2; which = 2; }
            if (h3 > best) { best = h3; which = 3; }
            if (h4 > best) { best = h4; which = 4; }
            if (h5 > best) { best = h5; which = 5; }
            if (h6 > best) { best = h6; which = 6; }
            if (h7 > best) { best = h7; which = 7; }
            int idx;
            if (which == 0)      { idx = mi[p0 * 512 + s0]; p0++; }
            else if (which == 1) { idx = mi[p1 * 512 + s1]; p1++; }
            else if (which == 2) { idx = mi[p2 * 512 + s2]; p2++; }
            else if (which == 3) { idx = mi[p3 * 512 + s3]; p3++; }
            else if (which == 4) { idx = mi[p4 * 512 + s4]; p4++; }
            else if (which == 5) { idx = mi[p5 * 512 + s5]; p5++; }
            else if (which == 6) { idx = mi[p6 * 512 + s6]; p6++; }
            else                 { idx = mi[p7 * 512 + s7]; p7++; }
            cand_s[ob + k] = best;
            cand_i[ob + k] = idx;
        }
    }
}

// ---------------- global merge + softmax + weighted gather ----------------
__global__ void topk_merge_kernel(const float* __restrict__ cand_s, const int* __restrict__ cand_i,
                                  const float* __restrict__ guf,
                                  float* __restrict__ outp) {
    int b = blockIdx.x, t = threadIdx.x;  // block 128 (= NCHUNK)
    __shared__ float rs[NCHUNK]; __shared__ int ru[NCHUNK]; __shared__ int rt[NCHUNK];
    __shared__ float win_s[TOPK]; __shared__ int win_u[TOPK]; __shared__ float wk[TOPK];
    __shared__ int winner;
    int ptr = 0;
    size_t base = ((size_t)t * 256 + b) * TOPK;
    for (int k = 0; k < TOPK; k++) {
        rs[t] = (ptr < TOPK) ? cand_s[base + ptr] : -3.0e38f;
        ru[t] = (ptr < TOPK) ? cand_i[base + ptr] : 0;
        rt[t] = t;
        __syncthreads();
        for (int off = NCHUNK / 2; off > 0; off >>= 1) {
            if (t < off && rs[t + off] > rs[t]) {
                rs[t] = rs[t + off]; ru[t] = ru[t + off]; rt[t] = rt[t + off];
            }
            __syncthreads();
        }
        if (t == 0) { win_s[k] = rs[0]; win_u[k] = iclamp(ru[0], 0, N_USERS - 1); winner = rt[0]; }
        __syncthreads();
        if (t == winner) ptr++;
        __syncthreads();
    }
    if (t == 0) {
        float m = win_s[0], den = 0.f;
        for (int k = 0; k < TOPK; k++) { wk[k] = expf(win_s[k] - m); den += wk[k]; }
        float inv = 1.f / den;
        for (int k = 0; k < TOPK; k++) wk[k] *= inv;
    }
    __syncthreads();
    float acc = 0.f;
    #pragma unroll
    for (int k = 0; k < TOPK; k++)
        acc = fmaf(wk[k], guf[(size_t)win_u[k] * DIM + t], acc);
    outp[1 + (size_t)b * DIM + t] = acc;
}

extern "C" void kernel_launch(void* const* d_in, const int* in_sizes, int n_in,
                              void* d_out, int out_size, void* d_ws, size_t ws_size,
                              hipStream_t stream) {
    (void)in_sizes; (void)n_in; (void)out_size;
    const int*   er      = (const int*)d_in[0];
    const int*   ec      = (const int*)d_in[1];
    const float* click   = (const float*)d_in[2];
    const float* favor   = (const float*)d_in[3];
    const float* consume = (const float*)d_in[4];
    const float* uid     = (const float*)d_in[5];
    const float* pid     = (const float*)d_in[6];
    const int*   uidx    = (const int*)d_in[7];
    const int*   pidx    = (const int*)d_in[8];
    const float* labels  = (const float*)d_in[9];
    const float* guf     = (const float*)d_in[10];
    const float* w3      = (const float*)d_in[11];
    const float* fw3     = (const float*)d_in[12];
    const float* Wuc     = (const float*)d_in[13];
    const float* Wpc     = (const float*)d_in[14];
    const float* Wufv    = (const float*)d_in[15];
    const float* Wpfv    = (const float*)d_in[16];
    const float* Wuco    = (const float*)d_in[17];
    const float* Wpco    = (const float*)d_in[18];
    const float* Wss     = (const float*)d_in[19];
    const float* bias    = (const float*)d_in[20];
    float* outp = (float*)d_out;

    char* ws = (char*)d_ws;
    size_t off = 0;
    auto carve = [&](size_t bytes) -> void* {
        off = (off + 255) & ~(size_t)255;
        void* p = ws + off;
        off += bytes;
        return p;
    };
    // base layout (~89 MB, proven safe)
    float* ufs = (float*)carve(4ll * 3 * BATCH * DIM);
    float* alt = (float*)carve(4ll * BATCH * NPOS);
    float* bst = (float*)carve(4ll * DIM * BATCH);       // reused as fp16 bst_h
    int* rptr = (int*)carve(4 * (N_USERS + 1));
    int* cptr = (int*)carve(4 * (N_POIS + 1));
    int* cnts = (int*)carve(4 * (N_USERS + N_POIS));
    int* rcnt = cnts;
    int* ccnt = cnts + N_USERS;
    int* scanws = (int*)carve(4 * 2 * (RCH + CCH) + 4 * 64);  // rsum/csum/rbase/cbase
    int* rsum = scanws;
    int* csum = rsum + RCH;
    int* rbase = csum + CCH;
    int* cbase = rbase + RCH;
    float* losspart = (float*)carve(4 * (LOSS_BLOCKS + 7));
    int4* rpack = (int4*)carve(16ll * N_EDGES);   // {col, v0, v1, v2}
    int4* cpack = (int4*)carve(16ll * N_EDGES);   // {row, v0, v1, v2}
    unsigned short* pid_h = (unsigned short*)carve(2ll * N_POIS * DIM);
    unsigned short* utr0 = (unsigned short*)carve(2ll * N_USERS * DIM);  // 10.24 MB; pf alias
    unsigned short* ptr_h = (unsigned short*)carve(2ll * N_POIS * DIM);  // p1raw ch0
    float* su  = (float*)carve(4ll * N_USERS * DIM);   // cand alias; rord/cord alias
    float* sp  = (float*)carve(4ll * N_POIS * DIM);
    float* idf = (float*)carve(4ll * N_USERS * DIM);
    float* pf = (float*)utr0;             // utr0 dead before pf written
    float* cand_s = su;                   // su dead before score_topk
    int*   cand_i = (int*)(su + (size_t)NCHUNK * BATCH * TOPK);
    // idf_h = rpack base, 10.24 MB: covers ALL of rpack (8 MB) + first 2.24 MB
    // of cpack. INVARIANT: the last read of rpack AND the last read of cpack
    // must both precede the c==2 user gemm that writes idf_h.
    _Float16* idf_h = (_Float16*)rpack;
    _Float16* bst_h = (_Float16*)bst;
    // rord/cord (4 MB) alias su: written by hist, read by fill; su first written
    // after fill completes (l2u3 or l2u ch0).
    int* rord = (int*)su;
    int* cord = rord + N_EDGES;
    // tier-1 extra carves (+30.7 MB)
    unsigned short* utr1 = (unsigned short*)carve(2ll * N_USERS * DIM);
    unsigned short* utr2 = (unsigned short*)carve(2ll * N_USERS * DIM);
    unsigned short* p1b1 = (unsigned short*)carve(2ll * N_POIS * DIM);
    unsigned short* p1b2 = (unsigned short*)carve(2ll * N_POIS * DIM);
    bool fused = (off <= ws_size);
    // tier-2 extra carves (+61.4 MB): per-channel su/sp for fully fused L2
    float* su1 = (float*)carve(4ll * N_USERS * DIM);
    float* su2 = (float*)carve(4ll * N_USERS * DIM);
    float* sp1 = (float*)carve(4ll * N_POIS * DIM);
    float* sp2 = (float*)carve(4ll * N_POIS * DIM);
    bool fused2 = (off <= ws_size);

    zero_kernel<<<(N_USERS + N_POIS + 255) / 256, 256, 0, stream>>>(
        (unsigned int*)cnts, N_USERS + N_POIS);
    cast_f16_kernel<<<(N_POIS * DIM / 2 + 255) / 256, 256, 0, stream>>>(pid, pid_h, N_POIS * DIM / 2);
    hist_kernel<<<(N_EDGES / 4 + 255) / 256, 256, 0, stream>>>(er, ec, rcnt, ccnt, rord, cord);
    dim3 sg2(RCH, 2);
    chunksum_kernel<<<sg2, 256, 0, stream>>>(rcnt, ccnt, rsum, csum);
    chunkscan_kernel<<<1, 128, 0, stream>>>(rsum, csum, rbase, cbase, rptr, cptr);
    scatterscan_kernel<<<sg2, 256, 0, stream>>>(rcnt, ccnt, rbase, cbase, rptr, cptr);
    fill_kernel<<<(N_EDGES / 4 + 255) / 256, 256, 0, stream>>>(
        er, ec, rptr, cptr, rord, cord, rpack, cpack, click, favor, consume);

    struct Ch { const float* Wu; const float* Wp; int wsel; int fsel; };
    // wn (softmax over w[1,3]):  favor=0, click=1, consume=2
    // fwn (softmax over fw[3,1]): favor=0, consume=1, click=2
    Ch chs[3] = { { Wuc,  Wpc,  1, 2 },     // ch0 = click
                  { Wufv, Wpfv, 0, 0 },     // ch1 = favor
                  { Wuco, Wpco, 2, 1 } };   // ch2 = consume

    const int UGB = N_USERS / 64;                 // 625
    const int PGB = (N_POIS + 63) / 64;           // 313
    const int PW = N_POIS * 64 / 256;
    const int UW = N_USERS * 64 / 256;

    auto launch_spmm_poi = [&](int c, const unsigned short* src, unsigned short* raw,
                               const float* base, float* acc) {
        if (c == 0)      spmm_kernel<0><<<PW, 256, 0, stream>>>(cptr, cpack, src, raw, base, acc, N_POIS);
        else if (c == 1) spmm_kernel<1><<<PW, 256, 0, stream>>>(cptr, cpack, src, raw, base, acc, N_POIS);
        else             spmm_kernel<2><<<PW, 256, 0, stream>>>(cptr, cpack, src, raw, base, acc, N_POIS);
    };
    auto launch_spmm_usr = [&](int c, const unsigned short* src, unsigned short* raw,
                               const float* base, float* acc) {
        if (c == 0)      spmm_kernel<0><<<UW, 256, 0, stream>>>(rptr, rpack, src, raw, base, acc, N_USERS);
        else if (c == 1) spmm_kernel<1><<<UW, 256, 0, stream>>>(rptr, rpack, src, raw, base, acc, N_USERS);
        else             spmm_kernel<2><<<UW, 256, 0, stream>>>(rptr, rpack, src, raw, base, acc, N_USERS);
    };
    auto launch_l2u = [&](int c, const unsigned short* src, unsigned short* u1raw) {
        if (c == 0)      spmm_l2u_kernel<0><<<UW, 256, 0, stream>>>(rptr, rpack, src, u1raw, uid, su, N_USERS);
        else if (c == 1) spmm_l2u_kernel<1><<<UW, 256, 0, stream>>>(rptr, rpack, src, u1raw, uid, su, N_USERS);
        else             spmm_l2u_kernel<2><<<UW, 256, 0, stream>>>(rptr, rpack, src, u1raw, uid, su, N_USERS);
    };
    auto launch_l2p = [&](int c, const unsigned short* src, const unsigned short* p1raw) {
        if (c == 0)      spmm_l2p_kernel<0><<<PW, 256, 0, stream>>>(cptr, cpack, src, p1raw, pid, sp, N_POIS);
        else if (c == 1) spmm_l2p_kernel<1><<<PW, 256, 0, stream>>>(cptr, cpack, src, p1raw, pid, sp, N_POIS);
        else             spmm_l2p_kernel<2><<<PW, 256, 0, stream>>>(cptr, cpack, src, p1raw, pid, sp, N_POIS);
    };

    if (fused2) {
        // tier-2: fully fused 3-channel pipeline, 4 spmm-class dispatches total
        spmm3_kernel<<<UW, 256, 0, stream>>>(rptr, rpack, pid_h, utr0, utr1, utr2, N_USERS);
        spmm3p_kernel<<<PW, 256, 0, stream>>>(cptr, cpack, utr0, utr1, utr2,
                                              ptr_h, p1b1, p1b2, N_POIS);
        // L2-user fused: last rpack read
        spmm_l2u3_kernel<<<UW, 256, 0, stream>>>(rptr, rpack, ptr_h, p1b1, p1b2,
                                                 utr0, utr1, utr2, uid, su, su1, su2, N_USERS);
        // L2-poi fused: last cpack read (precedes idf_h write below)
        spmm_l2p3_kernel<<<PW, 256, 0, stream>>>(cptr, cpack, utr0, utr1, utr2,
                                                 ptr_h, p1b1, p1b2, pid, sp, sp1, sp2, N_POIS);
        float* sus[3] = { su, su1, su2 };
        float* sps[3] = { sp, sp1, sp2 };
        for (int c = 0; c < 3; c++) {
            gemm_mfma_kernel<<<UGB, 256, 0, stream>>>(
                sus[c], chs[c].Wu, nullptr, idf, (c == 2) ? idf_h : nullptr,
                fw3, chs[c].fsel, (c == 0) ? 1 : 0, N_USERS);
            ufsel_kernel<<<BATCH, 128, 0, stream>>>(sus[c], chs[c].Wu, uidx, ufs + (size_t)c * BATCH * DIM);
            gemm_mfma_kernel<<<PGB, 256, 0, stream>>>(
                sps[c], chs[c].Wp, pf, nullptr, nullptr, fw3, 0, 0, N_POIS);
            predict_kernel<<<BATCH * NPOS * 64 / 256, 256, 0, stream>>>(
                ufs + (size_t)c * BATCH * DIM, pf, pidx, w3, chs[c].wsel, (c == 0) ? 1 : 0, alt);
        }
    } else if (fused) {
        // tier-1: round-11 proven schedule
        spmm3_kernel<<<UW, 256, 0, stream>>>(rptr, rpack, pid_h, utr0, utr1, utr2, N_USERS);
        spmm3p_kernel<<<PW, 256, 0, stream>>>(cptr, cpack, utr0, utr1, utr2,
                                              ptr_h, p1b1, p1b2, N_POIS);
        unsigned short* p1b[3] = { ptr_h, p1b1, p1b2 };
        unsigned short* utr[3] = { utr0, utr1, utr2 };
        for (int c = 0; c < 3; c++) {
            launch_l2u(c, p1b[c], utr[c]);
            launch_l2p(c, utr[c], p1b[c]);
            gemm_mfma_kernel<<<UGB, 256, 0, stream>>>(
                su, chs[c].Wu, nullptr, idf, (c == 2) ? idf_h : nullptr,
                fw3, chs[c].fsel, (c == 0) ? 1 : 0, N_USERS);
            ufsel_kernel<<<BATCH, 128, 0, stream>>>(su, chs[c].Wu, uidx, ufs + (size_t)c * BATCH * DIM);
            gemm_mfma_kernel<<<PGB, 256, 0, stream>>>(
                sp, chs[c].Wp, pf, nullptr, nullptr, fw3, 0, 0, N_POIS);
            predict_kernel<<<BATCH * NPOS * 64 / 256, 256, 0, stream>>>(
                ufs + (size_t)c * BATCH * DIM, pf, pidx, w3, chs[c].wsel, (c == 0) ? 1 : 0, alt);
        }
    } else {
        // fallback: per-channel schedule, single utr0/ptr_h buffers
        for (int c = 0; c < 3; c++) {
            launch_spmm_usr(c, pid_h, utr0, uid, su);
            launch_spmm_poi(c, utr0, ptr_h, pid, sp);
            launch_spmm_usr(c, ptr_h, utr0, su, su);
            launch_spmm_poi(c, utr0, ptr_h, sp, sp);
            gemm_mfma_kernel<<<UGB, 256, 0, stream>>>(
                su, chs[c].Wu, nullptr, idf, (c == 2) ? idf_h : nullptr,
                fw3, chs[c].fsel, (c == 0) ? 1 : 0, N_USERS);
            ufsel_kernel<<<BATCH, 128, 0, stream>>>(su, chs[c].Wu, uidx, ufs + (size_t)c * BATCH * DIM);
            gemm_mfma_kernel<<<PGB, 256, 0, stream>>>(
                sp, chs[c].Wp, pf, nullptr, nullptr, fw3, 0, 0, N_POIS);
            predict_kernel<<<BATCH * NPOS * 64 / 256, 256, 0, stream>>>(
                ufs + (size_t)c * BATCH * DIM, pf, pidx, w3, chs[c].wsel, (c == 0) ? 1 : 0, alt);
        }
    }

    loss_part_kernel<<<LOSS_BLOCKS, 256, 0, stream>>>(alt, labels, losspart);
    loss_final_kernel<<<1, 64, 0, stream>>>(losspart, outp);
    bs_kernel<<<BATCH, 128, 0, stream>>>(idf, Wss, bias, uidx, bst_h);
    dim3 sg(NCHUNK, 4);
    score_topk_kernel<<<sg, 512, 0, stream>>>(idf_h, bst_h, cand_s, cand_i);
    topk_merge_kernel<<<BATCH, NCHUNK, 0, stream>>>(cand_s, cand_i, guf, outp);
}

// Round 13
// 569.674 us; speedup vs baseline: 1.2107x; 1.0994x over previous
//
#include <hip/hip_runtime.h>

#define N_USERS 40000
#define N_POIS  20000
#define DIM     128
#define N_EDGES 500000
#define BATCH   256
#define NPOS    100
#define TOPK    20
#define NCHUNK  128
#define CPT     313   // ceil(40000/128)
#define SCHUNK  1024  // scan chunk (256 thr x 4)
#define RCH     40    // ceil(40000/1024)
#define CCH     20    // ceil(20000/1024)
#define LOSS_BLOCKS 25  // 25600/1024

typedef _Float16 f16x8 __attribute__((ext_vector_type(8)));
typedef float f32x4 __attribute__((ext_vector_type(4)));

__device__ __forceinline__ int iclamp(int x, int lo, int hi) {
    return x < lo ? lo : (x > hi ? hi : x);
}
__device__ __forceinline__ float2 h2f2(unsigned int u) {
    union { unsigned int u32; _Float16 h[2]; } v; v.u32 = u;
    return make_float2((float)v.h[0], (float)v.h[1]);
}
__device__ __forceinline__ unsigned int f2h2(float x, float y) {
    union { unsigned int u32; _Float16 h[2]; } v;
    v.h[0] = (_Float16)x; v.h[1] = (_Float16)y; return v.u32;
}
__device__ __forceinline__ float softmax3(const float* p, int sel) {
    float a0 = p[0], a1 = p[1], a2 = p[2];
    float m = fmaxf(a0, fmaxf(a1, a2));
    float e0 = expf(a0 - m), e1 = expf(a1 - m), e2 = expf(a2 - m);
    float den = e0 + e1 + e2;
    float e = (sel == 0) ? e0 : ((sel == 1) ? e1 : e2);
    return e / den;
}
// compile-time channel pick from packed edge {idx, v0, v1, v2}
template<int CH>
__device__ __forceinline__ float pickvT(int4 q) {
    return __int_as_float(CH == 0 ? q.y : (CH == 1 ? q.z : q.w));
}
// build fp16x8 fragment from 8 contiguous fp32
__device__ __forceinline__ f16x8 frag8(const float* p) {
    float4 x = *(const float4*)(p);
    float4 y = *(const float4*)(p + 4);
    f16x8 f;
    f[0] = (_Float16)x.x; f[1] = (_Float16)x.y; f[2] = (_Float16)x.z; f[3] = (_Float16)x.w;
    f[4] = (_Float16)y.x; f[5] = (_Float16)y.y; f[6] = (_Float16)y.z; f[7] = (_Float16)y.w;
    return f;
}

// ---------------- zero init ----------------
__global__ void zero_kernel(unsigned int* __restrict__ p, int nwords) {
    int i = blockIdx.x * blockDim.x + threadIdx.x;
    if (i < nwords) p[i] = 0u;
}

// ---------------- fp32 -> fp16 cast ----------------
__global__ void cast_f16_kernel(const float* __restrict__ src, unsigned short* __restrict__ dst,
                                int n2) {
    int i = blockIdx.x * blockDim.x + threadIdx.x;
    if (i < n2) {
        float2 v = *(const float2*)(src + 2 * (size_t)i);
        *(unsigned int*)(dst + 2 * (size_t)i) = f2h2(v.x, v.y);
    }
}

// ---------------- CSR hist: counts + per-edge within-row/col ordinals ----------------
__global__ void hist_kernel(const int* __restrict__ er, const int* __restrict__ ec,
                            int* __restrict__ rcnt, int* __restrict__ ccnt,
                            int* __restrict__ rord, int* __restrict__ cord) {
    int e0 = 4 * (blockIdx.x * blockDim.x + threadIdx.x);
    if (e0 + 4 <= N_EDGES) {
        int4 r4 = *(const int4*)(er + e0);
        int4 c4 = *(const int4*)(ec + e0);
        int rr[4] = { r4.x, r4.y, r4.z, r4.w };
        int cc[4] = { c4.x, c4.y, c4.z, c4.w };
        int ro[4], co[4];
        #pragma unroll
        for (int j = 0; j < 4; j++) {
            ro[j] = atomicAdd(&rcnt[iclamp(rr[j], 0, N_USERS - 1)], 1);
            co[j] = atomicAdd(&ccnt[iclamp(cc[j], 0, N_POIS - 1)], 1);
        }
        *(int4*)(rord + e0) = make_int4(ro[0], ro[1], ro[2], ro[3]);
        *(int4*)(cord + e0) = make_int4(co[0], co[1], co[2], co[3]);
    } else {
        for (int e = e0; e < N_EDGES; e++) {
            rord[e] = atomicAdd(&rcnt[iclamp(er[e], 0, N_USERS - 1)], 1);
            cord[e] = atomicAdd(&ccnt[iclamp(ec[e], 0, N_POIS - 1)], 1);
        }
    }
}

// ---------------- parallel prefix sum, stage 1 ----------------
__global__ void chunksum_kernel(const int* __restrict__ rcnt, const int* __restrict__ ccnt,
                                int* __restrict__ rsum, int* __restrict__ csum) {
    int side = blockIdx.y;
    const int* cnt = side ? ccnt : rcnt;
    int n = side ? N_POIS : N_USERS;
    int nch = side ? CCH : RCH;
    int b = blockIdx.x;
    if (b >= nch) return;
    int t = threadIdx.x;
    int i = b * SCHUNK + t * 4;
    int s = 0;
    if (i + 4 <= n) {
        int4 v = *(const int4*)(cnt + i);
        s = v.x + v.y + v.z + v.w;
    } else {
        for (int j = i; j < n; j++) s += cnt[j];
    }
    __shared__ int red[256];
    red[t] = s;
    __syncthreads();
    for (int o = 128; o > 0; o >>= 1) {
        if (t < o) red[t] += red[t + o];
        __syncthreads();
    }
    if (t == 0) (side ? csum : rsum)[b] = red[0];
}

// ---------------- stage 2 ----------------
__global__ void chunkscan_kernel(const int* __restrict__ rsum, const int* __restrict__ csum,
                                 int* __restrict__ rbase, int* __restrict__ cbase,
                                 int* __restrict__ rptr, int* __restrict__ cptr) {
    int w = threadIdx.x >> 6, l = threadIdx.x & 63;
    const int* src = w ? csum : rsum;
    int* dst = w ? cbase : rbase;
    int nch = w ? CCH : RCH;
    int orig = (l < nch) ? src[l] : 0;
    int v = orig;
    #pragma unroll
    for (int o = 1; o < 64; o <<= 1) {
        int u = __shfl_up(v, o, 64);
        if (l >= o) v += u;
    }
    if (l < nch) dst[l] = v - orig;
    if (l == nch - 1) {
        if (w) cptr[N_POIS] = v; else rptr[N_USERS] = v;
    }
}

// ---------------- stage 3 ----------------
__global__ void scatterscan_kernel(const int* __restrict__ rcnt, const int* __restrict__ ccnt,
                                   const int* __restrict__ rbase, const int* __restrict__ cbase,
                                   int* __restrict__ rptr, int* __restrict__ cptr) {
    int side = blockIdx.y;
    const int* cnt = side ? ccnt : rcnt;
    const int* basea = side ? cbase : rbase;
    int* ptr = side ? cptr : rptr;
    int n = side ? N_POIS : N_USERS;
    int nch = side ? CCH : RCH;
    int b = blockIdx.x;
    if (b >= nch) return;
    int t = threadIdx.x;
    int i = b * SCHUNK + t * 4;
    int c0 = 0, c1 = 0, c2 = 0, c3 = 0;
    if (i + 4 <= n) {
        int4 v = *(const int4*)(cnt + i);
        c0 = v.x; c1 = v.y; c2 = v.z; c3 = v.w;
    } else {
        if (i + 0 < n) c0 = cnt[i + 0];
        if (i + 1 < n) c1 = cnt[i + 1];
        if (i + 2 < n) c2 = cnt[i + 2];
    }
    int tsum = c0 + c1 + c2 + c3;
    int l = t & 63, w = t >> 6;
    int v = tsum;
    #pragma unroll
    for (int o = 1; o < 64; o <<= 1) {
        int u = __shfl_up(v, o, 64);
        if (l >= o) v += u;
    }
    __shared__ int wsum[4];
    if (l == 63) wsum[w] = v;
    __syncthreads();
    int wbase = 0;
    for (int k = 0; k < w; k++) wbase += wsum[k];
    int ex = v - tsum + wbase + basea[b];
    if (i + 4 <= n) {
        *(int4*)(ptr + i) = make_int4(ex, ex + c0, ex + c0 + c1, ex + c0 + c1 + c2);
    } else {
        if (i + 0 < n) ptr[i + 0] = ex;
        if (i + 1 < n) ptr[i + 1] = ex + c0;
        if (i + 2 < n) ptr[i + 2] = ex + c0 + c1;
    }
}

// ---------------- AoS CSR fill: NO atomics ----------------
__global__ void fill_kernel(const int* __restrict__ er, const int* __restrict__ ec,
                            const int* __restrict__ rptr, const int* __restrict__ cptr,
                            const int* __restrict__ rord, const int* __restrict__ cord,
                            int4* __restrict__ rpack, int4* __restrict__ cpack,
                            const float* __restrict__ ck, const float* __restrict__ fv,
                            const float* __restrict__ cs) {
    int e0 = 4 * (blockIdx.x * blockDim.x + threadIdx.x);
    if (e0 + 4 <= N_EDGES) {
        int4 r4 = *(const int4*)(er + e0);
        int4 c4 = *(const int4*)(ec + e0);
        int4 ro4 = *(const int4*)(rord + e0);
        int4 co4 = *(const int4*)(cord + e0);
        float4 k4 = *(const float4*)(ck + e0);
        float4 f4 = *(const float4*)(fv + e0);
        float4 s4 = *(const float4*)(cs + e0);
        int rr[4] = { r4.x, r4.y, r4.z, r4.w };
        int cc[4] = { c4.x, c4.y, c4.z, c4.w };
        int ro[4] = { ro4.x, ro4.y, ro4.z, ro4.w };
        int co[4] = { co4.x, co4.y, co4.z, co4.w };
        float kk[4] = { k4.x, k4.y, k4.z, k4.w };
        float ff[4] = { f4.x, f4.y, f4.z, f4.w };
        float ss[4] = { s4.x, s4.y, s4.z, s4.w };
        #pragma unroll
        for (int j = 0; j < 4; j++) {
            int r = iclamp(rr[j], 0, N_USERS - 1), c = iclamp(cc[j], 0, N_POIS - 1);
            int v0 = __float_as_int(kk[j]);
            int v1 = __float_as_int(ff[j]);
            int v2 = __float_as_int(ss[j]);
            int pr = iclamp(rptr[r] + ro[j], 0, N_EDGES - 1);
            rpack[pr] = make_int4(c, v0, v1, v2);
            int pc = iclamp(cptr[c] + co[j], 0, N_EDGES - 1);
            cpack[pc] = make_int4(r, v0, v1, v2);
        }
    } else {
        for (int e = e0; e < N_EDGES; e++) {
            int r = iclamp(er[e], 0, N_USERS - 1), c = iclamp(ec[e], 0, N_POIS - 1);
            int v0 = __float_as_int(ck[e]);
            int v1 = __float_as_int(fv[e]);
            int v2 = __float_as_int(cs[e]);
            int pr = iclamp(rptr[r] + rord[e], 0, N_EDGES - 1);
            rpack[pr] = make_int4(c, v0, v1, v2);
            int pc = iclamp(cptr[c] + cord[e], 0, N_EDGES - 1);
            cpack[pc] = make_int4(r, v0, v1, v2);
        }
    }
}

// ---------------- SpMM single-channel (fallback) ----------------
template<int CH>
__global__ __launch_bounds__(256) void spmm_kernel(
        const int* __restrict__ ptr, const int4* __restrict__ pack,
        const unsigned short* __restrict__ src,
        unsigned short* __restrict__ raw_h,
        const float* __restrict__ base,
        float* __restrict__ acc, int nrows) {
    int wid = (blockIdx.x * blockDim.x + threadIdx.x) >> 6;
    int lane = threadIdx.x & 63;
    if (wid >= nrows) return;
    int beg = __builtin_amdgcn_readfirstlane(iclamp(ptr[wid], 0, N_EDGES));
    int end = __builtin_amdgcn_readfirstlane(iclamp(ptr[wid + 1], 0, N_EDGES));
    if (end < beg) end = beg;
    float ax = 0.f, ay = 0.f;
    int e = beg;
    int lo2 = lane * 2;
    for (; e + 8 <= end; e += 8) {
        int4 q0 = pack[e + 0], q1 = pack[e + 1], q2 = pack[e + 2], q3 = pack[e + 3];
        int4 q4 = pack[e + 4], q5 = pack[e + 5], q6 = pack[e + 6], q7 = pack[e + 7];
        float v0 = pickvT<CH>(q0), v1 = pickvT<CH>(q1), v2 = pickvT<CH>(q2), v3 = pickvT<CH>(q3);
        float v4 = pickvT<CH>(q4), v5 = pickvT<CH>(q5), v6 = pickvT<CH>(q6), v7 = pickvT<CH>(q7);
        float2 p0 = h2f2(*(const unsigned int*)(src + (size_t)q0.x * DIM + lo2));
        float2 p1 = h2f2(*(const unsigned int*)(src + (size_t)q1.x * DIM + lo2));
        float2 p2 = h2f2(*(const unsigned int*)(src + (size_t)q2.x * DIM + lo2));
        float2 p3 = h2f2(*(const unsigned int*)(src + (size_t)q3.x * DIM + lo2));
        float2 p4 = h2f2(*(const unsigned int*)(src + (size_t)q4.x * DIM + lo2));
        float2 p5 = h2f2(*(const unsigned int*)(src + (size_t)q5.x * DIM + lo2));
        float2 p6 = h2f2(*(const unsigned int*)(src + (size_t)q6.x * DIM + lo2));
        float2 p7 = h2f2(*(const unsigned int*)(src + (size_t)q7.x * DIM + lo2));
        ax = fmaf(v0, p0.x, fmaf(v1, p1.x, fmaf(v2, p2.x, fmaf(v3, p3.x, ax))));
        ax = fmaf(v4, p4.x, fmaf(v5, p5.x, fmaf(v6, p6.x, fmaf(v7, p7.x, ax))));
        ay = fmaf(v0, p0.y, fmaf(v1, p1.y, fmaf(v2, p2.y, fmaf(v3, p3.y, ay))));
        ay = fmaf(v4, p4.y, fmaf(v5, p5.y, fmaf(v6, p6.y, fmaf(v7, p7.y, ay))));
    }
    for (; e < end; e++) {
        int4 q = pack[e];
        float v = pickvT<CH>(q);
        float2 p = h2f2(*(const unsigned int*)(src + (size_t)q.x * DIM + lo2));
        ax = fmaf(v, p.x, ax);
        ay = fmaf(v, p.y, ay);
    }
    float n2 = ax * ax + ay * ay;
    #pragma unroll
    for (int o = 32; o > 0; o >>= 1) n2 += __shfl_xor(n2, o, 64);
    float inv = rsqrtf(fmaxf(n2, 1e-30f));
    *(unsigned int*)(raw_h + (size_t)wid * DIM + lo2) = f2h2(ax, ay);
    float2 bv = *(const float2*)(base + (size_t)wid * DIM + lo2);
    *(float2*)(acc + (size_t)wid * DIM + lo2) =
        make_float2(bv.x + ax * inv, bv.y + ay * inv);
}

// ---------------- fused 3-channel L1-user SpMM ----------------
__global__ __launch_bounds__(256) void spmm3_kernel(
        const int* __restrict__ ptr, const int4* __restrict__ pack,
        const unsigned short* __restrict__ src,
        unsigned short* __restrict__ r0, unsigned short* __restrict__ r1,
        unsigned short* __restrict__ r2, int nrows) {
    int wid = (blockIdx.x * blockDim.x + threadIdx.x) >> 6;
    int lane = threadIdx.x & 63;
    if (wid >= nrows) return;
    int beg = __builtin_amdgcn_readfirstlane(iclamp(ptr[wid], 0, N_EDGES));
    int end = __builtin_amdgcn_readfirstlane(iclamp(ptr[wid + 1], 0, N_EDGES));
    if (end < beg) end = beg;
    float a0x = 0.f, a0y = 0.f, a1x = 0.f, a1y = 0.f, a2x = 0.f, a2y = 0.f;
    int e = beg;
    int lo2 = lane * 2;
    for (; e + 4 <= end; e += 4) {
        int4 q0 = pack[e + 0], q1 = pack[e + 1], q2 = pack[e + 2], q3 = pack[e + 3];
        float2 p0 = h2f2(*(const unsigned int*)(src + (size_t)q0.x * DIM + lo2));
        float2 p1 = h2f2(*(const unsigned int*)(src + (size_t)q1.x * DIM + lo2));
        float2 p2 = h2f2(*(const unsigned int*)(src + (size_t)q2.x * DIM + lo2));
        float2 p3 = h2f2(*(const unsigned int*)(src + (size_t)q3.x * DIM + lo2));
        a0x = fmaf(__int_as_float(q0.y), p0.x, fmaf(__int_as_float(q1.y), p1.x,
              fmaf(__int_as_float(q2.y), p2.x, fmaf(__int_as_float(q3.y), p3.x, a0x))));
        a0y = fmaf(__int_as_float(q0.y), p0.y, fmaf(__int_as_float(q1.y), p1.y,
              fmaf(__int_as_float(q2.y), p2.y, fmaf(__int_as_float(q3.y), p3.y, a0y))));
        a1x = fmaf(__int_as_float(q0.z), p0.x, fmaf(__int_as_float(q1.z), p1.x,
              fmaf(__int_as_float(q2.z), p2.x, fmaf(__int_as_float(q3.z), p3.x, a1x))));
        a1y = fmaf(__int_as_float(q0.z), p0.y, fmaf(__int_as_float(q1.z), p1.y,
              fmaf(__int_as_float(q2.z), p2.y, fmaf(__int_as_float(q3.z), p3.y, a1y))));
        a2x = fmaf(__int_as_float(q0.w), p0.x, fmaf(__int_as_float(q1.w), p1.x,
              fmaf(__int_as_float(q2.w), p2.x, fmaf(__int_as_float(q3.w), p3.x, a2x))));
        a2y = fmaf(__int_as_float(q0.w), p0.y, fmaf(__int_as_float(q1.w), p1.y,
              fmaf(__int_as_float(q2.w), p2.y, fmaf(__int_as_float(q3.w), p3.y, a2y))));
    }
    for (; e < end; e++) {
        int4 q = pack[e];
        float2 p = h2f2(*(const unsigned int*)(src + (size_t)q.x * DIM + lo2));
        a0x = fmaf(__int_as_float(q.y), p.x, a0x);
        a0y = fmaf(__int_as_float(q.y), p.y, a0y);
        a1x = fmaf(__int_as_float(q.z), p.x, a1x);
        a1y = fmaf(__int_as_float(q.z), p.y, a1y);
        a2x = fmaf(__int_as_float(q.w), p.x, a2x);
        a2y = fmaf(__int_as_float(q.w), p.y, a2y);
    }
    size_t o = (size_t)wid * DIM + lo2;
    *(unsigned int*)(r0 + o) = f2h2(a0x, a0y);
    *(unsigned int*)(r1 + o) = f2h2(a1x, a1y);
    *(unsigned int*)(r2 + o) = f2h2(a2x, a2y);
}

// ---------------- fused 3-channel L1-poi SpMM ----------------
__global__ __launch_bounds__(256) void spmm3p_kernel(
        const int* __restrict__ ptr, const int4* __restrict__ pack,
        const unsigned short* __restrict__ s0, const unsigned short* __restrict__ s1,
        const unsigned short* __restrict__ s2,
        unsigned short* __restrict__ r0, unsigned short* __restrict__ r1,
        unsigned short* __restrict__ r2, int nrows) {
    int wid = (blockIdx.x * blockDim.x + threadIdx.x) >> 6;
    int lane = threadIdx.x & 63;
    if (wid >= nrows) return;
    int beg = __builtin_amdgcn_readfirstlane(iclamp(ptr[wid], 0, N_EDGES));
    int end = __builtin_amdgcn_readfirstlane(iclamp(ptr[wid + 1], 0, N_EDGES));
    if (end < beg) end = beg;
    float a0x = 0.f, a0y = 0.f, a1x = 0.f, a1y = 0.f, a2x = 0.f, a2y = 0.f;
    int e = beg;
    int lo2 = lane * 2;
    for (; e + 4 <= end; e += 4) {
        int4 q0 = pack[e + 0], q1 = pack[e + 1], q2 = pack[e + 2], q3 = pack[e + 3];
        size_t o0 = (size_t)q0.x * DIM + lo2, o1 = (size_t)q1.x * DIM + lo2;
        size_t o2 = (size_t)q2.x * DIM + lo2, o3 = (size_t)q3.x * DIM + lo2;
        float2 u00 = h2f2(*(const unsigned int*)(s0 + o0));
        float2 u01 = h2f2(*(const unsigned int*)(s0 + o1));
        float2 u02 = h2f2(*(const unsigned int*)(s0 + o2));
        float2 u03 = h2f2(*(const unsigned int*)(s0 + o3));
        float2 u10 = h2f2(*(const unsigned int*)(s1 + o0));
        float2 u11 = h2f2(*(const unsigned int*)(s1 + o1));
        float2 u12 = h2f2(*(const unsigned int*)(s1 + o2));
        float2 u13 = h2f2(*(const unsigned int*)(s1 + o3));
        float2 u20 = h2f2(*(const unsigned int*)(s2 + o0));
        float2 u21 = h2f2(*(const unsigned int*)(s2 + o1));
        float2 u22 = h2f2(*(const unsigned int*)(s2 + o2));
        float2 u23 = h2f2(*(const unsigned int*)(s2 + o3));
        a0x = fmaf(__int_as_float(q0.y), u00.x, fmaf(__int_as_float(q1.y), u01.x,
              fmaf(__int_as_float(q2.y), u02.x, fmaf(__int_as_float(q3.y), u03.x, a0x))));
        a0y = fmaf(__int_as_float(q0.y), u00.y, fmaf(__int_as_float(q1.y), u01.y,
              fmaf(__int_as_float(q2.y), u02.y, fmaf(__int_as_float(q3.y), u03.y, a0y))));
        a1x = fmaf(__int_as_float(q0.z), u10.x, fmaf(__int_as_float(q1.z), u11.x,
              fmaf(__int_as_float(q2.z), u12.x, fmaf(__int_as_float(q3.z), u13.x, a1x))));
        a1y = fmaf(__int_as_float(q0.z), u10.y, fmaf(__int_as_float(q1.z), u11.y,
              fmaf(__int_as_float(q2.z), u12.y, fmaf(__int_as_float(q3.z), u13.y, a1y))));
        a2x = fmaf(__int_as_float(q0.w), u20.x, fmaf(__int_as_float(q1.w), u21.x,
              fmaf(__int_as_float(q2.w), u22.x, fmaf(__int_as_float(q3.w), u23.x, a2x))));
        a2y = fmaf(__int_as_float(q0.w), u20.y, fmaf(__int_as_float(q1.w), u21.y,
              fmaf(__int_as_float(q2.w), u22.y, fmaf(__int_as_float(q3.w), u23.y, a2y))));
    }
    for (; e < end; e++) {
        int4 q = pack[e];
        size_t o = (size_t)q.x * DIM + lo2;
        float2 p0 = h2f2(*(const unsigned int*)(s0 + o));
        float2 p1 = h2f2(*(const unsigned int*)(s1 + o));
        float2 p2 = h2f2(*(const unsigned int*)(s2 + o));
        a0x = fmaf(__int_as_float(q.y), p0.x, a0x);
        a0y = fmaf(__int_as_float(q.y), p0.y, a0y);
        a1x = fmaf(__int_as_float(q.z), p1.x, a1x);
        a1y = fmaf(__int_as_float(q.z), p1.y, a1y);
        a2x = fmaf(__int_as_float(q.w), p2.x, a2x);
        a2y = fmaf(__int_as_float(q.w), p2.y, a2y);
    }
    size_t o = (size_t)wid * DIM + lo2;
    *(unsigned int*)(r0 + o) = f2h2(a0x, a0y);
    *(unsigned int*)(r1 + o) = f2h2(a1x, a1y);
    *(unsigned int*)(r2 + o) = f2h2(a2x, a2y);
}

// ---------------- fused 3-channel L2-user ----------------
__global__ __launch_bounds__(256) void spmm_l2u3_kernel(
        const int* __restrict__ ptr, const int4* __restrict__ pack,
        const unsigned short* __restrict__ s0, const unsigned short* __restrict__ s1,
        const unsigned short* __restrict__ s2,
        unsigned short* __restrict__ u0, unsigned short* __restrict__ u1r,
        unsigned short* __restrict__ u2r,
        const float* __restrict__ uid,
        float* __restrict__ su0, float* __restrict__ su1, float* __restrict__ su2,
        int nrows) {
    int wid = (blockIdx.x * blockDim.x + threadIdx.x) >> 6;
    int lane = threadIdx.x & 63;
    if (wid >= nrows) return;
    int beg = __builtin_amdgcn_readfirstlane(iclamp(ptr[wid], 0, N_EDGES));
    int end = __builtin_amdgcn_readfirstlane(iclamp(ptr[wid + 1], 0, N_EDGES));
    if (end < beg) end = beg;
    float a0x = 0.f, a0y = 0.f, a1x = 0.f, a1y = 0.f, a2x = 0.f, a2y = 0.f;
    int e = beg;
    int lo2 = lane * 2;
    for (; e + 4 <= end; e += 4) {
        int4 q0 = pack[e + 0], q1 = pack[e + 1], q2 = pack[e + 2], q3 = pack[e + 3];
        size_t o0 = (size_t)q0.x * DIM + lo2, o1 = (size_t)q1.x * DIM + lo2;
        size_t o2 = (size_t)q2.x * DIM + lo2, o3 = (size_t)q3.x * DIM + lo2;
        float2 u00 = h2f2(*(const unsigned int*)(s0 + o0));
        float2 u01 = h2f2(*(const unsigned int*)(s0 + o1));
        float2 u02 = h2f2(*(const unsigned int*)(s0 + o2));
        float2 u03 = h2f2(*(const unsigned int*)(s0 + o3));
        float2 u10 = h2f2(*(const unsigned int*)(s1 + o0));
        float2 u11 = h2f2(*(const unsigned int*)(s1 + o1));
        float2 u12 = h2f2(*(const unsigned int*)(s1 + o2));
        float2 u13 = h2f2(*(const unsigned int*)(s1 + o3));
        float2 u20 = h2f2(*(const unsigned int*)(s2 + o0));
        float2 u21 = h2f2(*(const unsigned int*)(s2 + o1));
        float2 u22 = h2f2(*(const unsigned int*)(s2 + o2));
        float2 u23 = h2f2(*(const unsigned int*)(s2 + o3));
        a0x = fmaf(__int_as_float(q0.y), u00.x, fmaf(__int_as_float(q1.y), u01.x,
              fmaf(__int_as_float(q2.y), u02.x, fmaf(__int_as_float(q3.y), u03.x, a0x))));
        a0y = fmaf(__int_as_float(q0.y), u00.y, fmaf(__int_as_float(q1.y), u01.y,
              fmaf(__int_as_float(q2.y), u02.y, fmaf(__int_as_float(q3.y), u03.y, a0y))));
        a1x = fmaf(__int_as_float(q0.z), u10.x, fmaf(__int_as_float(q1.z), u11.x,
              fmaf(__int_as_float(q2.z), u12.x, fmaf(__int_as_float(q3.z), u13.x, a1x))));
        a1y = fmaf(__int_as_float(q0.z), u10.y, fmaf(__int_as_float(q1.z), u11.y,
              fmaf(__int_as_float(q2.z), u12.y, fmaf(__int_as_float(q3.z), u13.y, a1y))));
        a2x = fmaf(__int_as_float(q0.w), u20.x, fmaf(__int_as_float(q1.w), u21.x,
              fmaf(__int_as_float(q2.w), u22.x, fmaf(__int_as_float(q3.w), u23.x, a2x))));
        a2y = fmaf(__int_as_float(q0.w), u20.y, fmaf(__int_as_float(q1.w), u21.y,
              fmaf(__int_as_float(q2.w), u22.y, fmaf(__int_as_float(q3.w), u23.y, a2y))));
    }
    for (; e < end; e++) {
        int4 q = pack[e];
        size_t o = (size_t)q.x * DIM + lo2;
        float2 p0 = h2f2(*(const unsigned int*)(s0 + o));
        float2 p1 = h2f2(*(const unsigned int*)(s1 + o));
        float2 p2 = h2f2(*(const unsigned int*)(s2 + o));
        a0x = fmaf(__int_as_float(q.y), p0.x, a0x);
        a0y = fmaf(__int_as_float(q.y), p0.y, a0y);
        a1x = fmaf(__int_as_float(q.z), p1.x, a1x);
        a1y = fmaf(__int_as_float(q.z), p1.y, a1y);
        a2x = fmaf(__int_as_float(q.w), p2.x, a2x);
        a2y = fmaf(__int_as_float(q.w), p2.y, a2y);
    }
    size_t o = (size_t)wid * DIM + lo2;
    float2 x0 = h2f2(*(const unsigned int*)(u0 + o));
    float2 x1 = h2f2(*(const unsigned int*)(u1r + o));
    float2 x2 = h2f2(*(const unsigned int*)(u2r + o));
    float m0 = a0x * a0x + a0y * a0y;
    float m1 = a1x * a1x + a1y * a1y;
    float m2 = a2x * a2x + a2y * a2y;
    float k0 = x0.x * x0.x + x0.y * x0.y;
    float k1 = x1.x * x1.x + x1.y * x1.y;
    float k2 = x2.x * x2.x + x2.y * x2.y;
    #pragma unroll
    for (int oo = 32; oo > 0; oo >>= 1) {
        m0 += __shfl_xor(m0, oo, 64); m1 += __shfl_xor(m1, oo, 64); m2 += __shfl_xor(m2, oo, 64);
        k0 += __shfl_xor(k0, oo, 64); k1 += __shfl_xor(k1, oo, 64); k2 += __shfl_xor(k2, oo, 64);
    }
    float im0 = rsqrtf(fmaxf(m0, 1e-30f)), ik0 = rsqrtf(fmaxf(k0, 1e-30f));
    float im1 = rsqrtf(fmaxf(m1, 1e-30f)), ik1 = rsqrtf(fmaxf(k1, 1e-30f));
    float im2 = rsqrtf(fmaxf(m2, 1e-30f)), ik2 = rsqrtf(fmaxf(k2, 1e-30f));
    *(unsigned int*)(u0 + o)  = f2h2(a0x, a0y);
    *(unsigned int*)(u1r + o) = f2h2(a1x, a1y);
    *(unsigned int*)(u2r + o) = f2h2(a2x, a2y);
    float2 bv = *(const float2*)(uid + o);
    *(float2*)(su0 + o) = make_float2(bv.x + x0.x * ik0 + a0x * im0, bv.y + x0.y * ik0 + a0y * im0);
    *(float2*)(su1 + o) = make_float2(bv.x + x1.x * ik1 + a1x * im1, bv.y + x1.y * ik1 + a1y * im1);
    *(float2*)(su2 + o) = make_float2(bv.x + x2.x * ik2 + a2x * im2, bv.y + x2.y * ik2 + a2y * im2);
}

// ---------------- fused 3-channel L2-poi ----------------
__global__ __launch_bounds__(256) void spmm_l2p3_kernel(
        const int* __restrict__ ptr, const int4* __restrict__ pack,
        const unsigned short* __restrict__ s0, const unsigned short* __restrict__ s1,
        const unsigned short* __restrict__ s2,
        const unsigned short* __restrict__ p0r, const unsigned short* __restrict__ p1r,
        const unsigned short* __restrict__ p2r,
        const float* __restrict__ pid,
        float* __restrict__ sp0, float* __restrict__ sp1, float* __restrict__ sp2,
        int nrows) {
    int wid = (blockIdx.x * blockDim.x + threadIdx.x) >> 6;
    int lane = threadIdx.x & 63;
    if (wid >= nrows) return;
    int beg = __builtin_amdgcn_readfirstlane(iclamp(ptr[wid], 0, N_EDGES));
    int end = __builtin_amdgcn_readfirstlane(iclamp(ptr[wid + 1], 0, N_EDGES));
    if (end < beg) end = beg;
    float a0x = 0.f, a0y = 0.f, a1x = 0.f, a1y = 0.f, a2x = 0.f, a2y = 0.f;
    int e = beg;
    int lo2 = lane * 2;
    for (; e + 4 <= end; e += 4) {
        int4 q0 = pack[e + 0], q1 = pack[e + 1], q2 = pack[e + 2], q3 = pack[e + 3];
        size_t o0 = (size_t)q0.x * DIM + lo2, o1 = (size_t)q1.x * DIM + lo2;
        size_t o2 = (size_t)q2.x * DIM + lo2, o3 = (size_t)q3.x * DIM + lo2;
        float2 u00 = h2f2(*(const unsigned int*)(s0 + o0));
        float2 u01 = h2f2(*(const unsigned int*)(s0 + o1));
        float2 u02 = h2f2(*(const unsigned int*)(s0 + o2));
        float2 u03 = h2f2(*(const unsigned int*)(s0 + o3));
        float2 u10 = h2f2(*(const unsigned int*)(s1 + o0));
        float2 u11 = h2f2(*(const unsigned int*)(s1 + o1));
        float2 u12 = h2f2(*(const unsigned int*)(s1 + o2));
        float2 u13 = h2f2(*(const unsigned int*)(s1 + o3));
        float2 u20 = h2f2(*(const unsigned int*)(s2 + o0));
        float2 u21 = h2f2(*(const unsigned int*)(s2 + o1));
        float2 u22 = h2f2(*(const unsigned int*)(s2 + o2));
        float2 u23 = h2f2(*(const unsigned int*)(s2 + o3));
        a0x = fmaf(__int_as_float(q0.y), u00.x, fmaf(__int_as_float(q1.y), u01.x,
              fmaf(__int_as_float(q2.y), u02.x, fmaf(__int_as_float(q3.y), u03.x, a0x))));
        a0y = fmaf(__int_as_float(q0.y), u00.y, fmaf(__int_as_float(q1.y), u01.y,
              fmaf(__int_as_float(q2.y), u02.y, fmaf(__int_as_float(q3.y), u03.y, a0y))));
        a1x = fmaf(__int_as_float(q0.z), u10.x, fmaf(__int_as_float(q1.z), u11.x,
              fmaf(__int_as_float(q2.z), u12.x, fmaf(__int_as_float(q3.z), u13.x, a1x))));
        a1y = fmaf(__int_as_float(q0.z), u10.y, fmaf(__int_as_float(q1.z), u11.y,
              fmaf(__int_as_float(q2.z), u12.y, fmaf(__int_as_float(q3.z), u13.y, a1y))));
        a2x = fmaf(__int_as_float(q0.w), u20.x, fmaf(__int_as_float(q1.w), u21.x,
              fmaf(__int_as_float(q2.w), u22.x, fmaf(__int_as_float(q3.w), u23.x, a2x))));
        a2y = fmaf(__int_as_float(q0.w), u20.y, fmaf(__int_as_float(q1.w), u21.y,
              fmaf(__int_as_float(q2.w), u22.y, fmaf(__int_as_float(q3.w), u23.y, a2y))));
    }
    for (; e < end; e++) {
        int4 q = pack[e];
        size_t o = (size_t)q.x * DIM + lo2;
        float2 p0 = h2f2(*(const unsigned int*)(s0 + o));
        float2 p1 = h2f2(*(const unsigned int*)(s1 + o));
        float2 p2 = h2f2(*(const unsigned int*)(s2 + o));
        a0x = fmaf(__int_as_float(q.y), p0.x, a0x);
        a0y = fmaf(__int_as_float(q.y), p0.y, a0y);
        a1x = fmaf(__int_as_float(q.z), p1.x, a1x);
        a1y = fmaf(__int_as_float(q.z), p1.y, a1y);
        a2x = fmaf(__int_as_float(q.w), p2.x, a2x);
        a2y = fmaf(__int_as_float(q.w), p2.y, a2y);
    }
    size_t o = (size_t)wid * DIM + lo2;
    float2 x0 = h2f2(*(const unsigned int*)(p0r + o));
    float2 x1 = h2f2(*(const unsigned int*)(p1r + o));
    float2 x2 = h2f2(*(const unsigned int*)(p2r + o));
    float m0 = a0x * a0x + a0y * a0y;
    float m1 = a1x * a1x + a1y * a1y;
    float m2 = a2x * a2x + a2y * a2y;
    float k0 = x0.x * x0.x + x0.y * x0.y;
    float k1 = x1.x * x1.x + x1.y * x1.y;
    float k2 = x2.x * x2.x + x2.y * x2.y;
    #pragma unroll
    for (int oo = 32; oo > 0; oo >>= 1) {
        m0 += __shfl_xor(m0, oo, 64); m1 += __shfl_xor(m1, oo, 64); m2 += __shfl_xor(m2, oo, 64);
        k0 += __shfl_xor(k0, oo, 64); k1 += __shfl_xor(k1, oo, 64); k2 += __shfl_xor(k2, oo, 64);
    }
    float im0 = rsqrtf(fmaxf(m0, 1e-30f)), ik0 = rsqrtf(fmaxf(k0, 1e-30f));
    float im1 = rsqrtf(fmaxf(m1, 1e-30f)), ik1 = rsqrtf(fmaxf(k1, 1e-30f));
    float im2 = rsqrtf(fmaxf(m2, 1e-30f)), ik2 = rsqrtf(fmaxf(k2, 1e-30f));
    float2 bv = *(const float2*)(pid + o);
    *(float2*)(sp0 + o) = make_float2(bv.x + x0.x * ik0 + a0x * im0, bv.y + x0.y * ik0 + a0y * im0);
    *(float2*)(sp1 + o) = make_float2(bv.x + x1.x * ik1 + a1x * im1, bv.y + x1.y * ik1 + a1y * im1);
    *(float2*)(sp2 + o) = make_float2(bv.x + x2.x * ik2 + a2x * im2, bv.y + x2.y * ik2 + a2y * im2);
}

// ---------------- single-channel L2 kernels (tier-1 path) ----------------
template<int CH>
__global__ __launch_bounds__(256) void spmm_l2u_kernel(
        const int* __restrict__ ptr, const int4* __restrict__ pack,
        const unsigned short* __restrict__ src,
        unsigned short* __restrict__ u1raw,
        const float* __restrict__ uid,
        float* __restrict__ su, int nrows) {
    int wid = (blockIdx.x * blockDim.x + threadIdx.x) >> 6;
    int lane = threadIdx.x & 63;
    if (wid >= nrows) return;
    int beg = __builtin_amdgcn_readfirstlane(iclamp(ptr[wid], 0, N_EDGES));
    int end = __builtin_amdgcn_readfirstlane(iclamp(ptr[wid + 1], 0, N_EDGES));
    if (end < beg) end = beg;
    float ax = 0.f, ay = 0.f;
    int e = beg;
    int lo2 = lane * 2;
    for (; e < end; e++) {
        int4 q = pack[e];
        float v = pickvT<CH>(q);
        float2 p = h2f2(*(const unsigned int*)(src + (size_t)q.x * DIM + lo2));
        ax = fmaf(v, p.x, ax);
        ay = fmaf(v, p.y, ay);
    }
    size_t o = (size_t)wid * DIM + lo2;
    float2 u1 = h2f2(*(const unsigned int*)(u1raw + o));
    float n2a = ax * ax + ay * ay;
    float n2b = u1.x * u1.x + u1.y * u1.y;
    #pragma unroll
    for (int oo = 32; oo > 0; oo >>= 1) {
        n2a += __shfl_xor(n2a, oo, 64);
        n2b += __shfl_xor(n2b, oo, 64);
    }
    float i2 = rsqrtf(fmaxf(n2a, 1e-30f));
    float i1 = rsqrtf(fmaxf(n2b, 1e-30f));
    *(unsigned int*)(u1raw + o) = f2h2(ax, ay);
    float2 bv = *(const float2*)(uid + o);
    *(float2*)(su + o) = make_float2(bv.x + u1.x * i1 + ax * i2,
                                     bv.y + u1.y * i1 + ay * i2);
}

template<int CH>
__global__ __launch_bounds__(256) void spmm_l2p_kernel(
        const int* __restrict__ ptr, const int4* __restrict__ pack,
        const unsigned short* __restrict__ src,
        const unsigned short* __restrict__ p1raw,
        const float* __restrict__ pid,
        float* __restrict__ sp, int nrows) {
    int wid = (blockIdx.x * blockDim.x + threadIdx.x) >> 6;
    int lane = threadIdx.x & 63;
    if (wid >= nrows) return;
    int beg = __builtin_amdgcn_readfirstlane(iclamp(ptr[wid], 0, N_EDGES));
    int end = __builtin_amdgcn_readfirstlane(iclamp(ptr[wid + 1], 0, N_EDGES));
    if (end < beg) end = beg;
    float ax = 0.f, ay = 0.f;
    int e = beg;
    int lo2 = lane * 2;
    for (; e < end; e++) {
        int4 q = pack[e];
        float v = pickvT<CH>(q);
        float2 p = h2f2(*(const unsigned int*)(src + (size_t)q.x * DIM + lo2));
        ax = fmaf(v, p.x, ax);
        ay = fmaf(v, p.y, ay);
    }
    size_t o = (size_t)wid * DIM + lo2;
    float2 p1v = h2f2(*(const unsigned int*)(p1raw + o));
    float n2a = ax * ax + ay * ay;
    float n2b = p1v.x * p1v.x + p1v.y * p1v.y;
    #pragma unroll
    for (int oo = 32; oo > 0; oo >>= 1) {
        n2a += __shfl_xor(n2a, oo, 64);
        n2b += __shfl_xor(n2b, oo, 64);
    }
    float i2 = rsqrtf(fmaxf(n2a, 1e-30f));
    float i1 = rsqrtf(fmaxf(n2b, 1e-30f));
    float2 bv = *(const float2*)(pid + o);
    *(float2*)(sp + o) = make_float2(bv.x + p1v.x * i1 + ax * i2,
                                     bv.y + p1v.y * i1 + ay * i2);
}

// ---------------- MFMA single GEMM (tier-1/fallback) ----------------
__global__ __launch_bounds__(256) void gemm_mfma_kernel(
        const float* __restrict__ A, const float* __restrict__ W,
        float* __restrict__ store, float* __restrict__ accum,
        _Float16* __restrict__ accum_h,
        const float* __restrict__ fw3, int fsel, int first, int M) {
    int w = threadIdx.x >> 6, l = threadIdx.x & 63;
    int lg = l >> 4, lc = l & 15;
    int j0 = w * 32;
    float coef = accum ? softmax3(fw3, fsel) : 0.f;
    f16x8 Bf[2][4];
    #pragma unroll
    for (int t = 0; t < 2; t++) {
        const float* wr = W + (size_t)(j0 + t * 16 + lc) * DIM + lg * 8;
        #pragma unroll
        for (int s = 0; s < 4; s++) Bf[t][s] = frag8(wr + s * 32);
    }
    int base = blockIdx.x * 64;
    #pragma unroll
    for (int rt = 0; rt < 4; rt++) {
        int u0 = base + rt * 16;
        int ar = u0 + lc; if (ar > M - 1) ar = M - 1;
        const float* arow = A + (size_t)ar * DIM + lg * 8;
        f16x8 Af[4];
        #pragma unroll
        for (int s = 0; s < 4; s++) Af[s] = frag8(arow + s * 32);
        f32x4 acc0 = {0.f, 0.f, 0.f, 0.f};
        f32x4 acc1 = {0.f, 0.f, 0.f, 0.f};
        #pragma unroll
        for (int s = 0; s < 4; s++) {
            acc0 = __builtin_amdgcn_mfma_f32_16x16x32_f16(Af[s], Bf[0][s], acc0, 0, 0, 0);
            acc1 = __builtin_amdgcn_mfma_f32_16x16x32_f16(Af[s], Bf[1][s], acc1, 0, 0, 0);
        }
        int rbase = u0 + lg * 4;
        #pragma unroll
        for (int r = 0; r < 4; r++) {
            int row = rbase + r;
            if (row >= M) continue;
            size_t o0 = (size_t)row * DIM + j0 + lc;
            size_t o1 = o0 + 16;
            if (store) { store[o0] = acc0[r]; store[o1] = acc1[r]; }
            if (accum) {
                float p0 = first ? 0.f : accum[o0];
                float p1 = first ? 0.f : accum[o1];
                float n0 = p0 + coef * acc0[r];
                float n1 = p1 + coef * acc1[r];
                accum[o0] = n0;
                accum[o1] = n1;
                if (accum_h) {
                    accum_h[o0] = (_Float16)n0;
                    accum_h[o1] = (_Float16)n1;
                }
            }
        }
    }
}

// ---------------- fused 3-channel user GEMM: idf = sum_c coef_c * su_c @ Wu_c^T ----------------
__global__ __launch_bounds__(256) void gemm_mfma3u_kernel(
        const float* __restrict__ A0, const float* __restrict__ A1, const float* __restrict__ A2,
        const float* __restrict__ W0, const float* __restrict__ W1, const float* __restrict__ W2,
        float* __restrict__ idf, _Float16* __restrict__ idf_h,
        const float* __restrict__ fw3, int M) {
    int w = threadIdx.x >> 6, l = threadIdx.x & 63;
    int lg = l >> 4, lc = l & 15;
    int j0 = w * 32;
    // fwn coefs: ch0=click->fsel2, ch1=favor->fsel0, ch2=consume->fsel1
    float cf0 = softmax3(fw3, 2);
    float cf1 = softmax3(fw3, 0);
    float cf2 = softmax3(fw3, 1);
    f16x8 B0[2][4], B1[2][4], B2[2][4];
    #pragma unroll
    for (int t = 0; t < 2; t++) {
        size_t ro = (size_t)(j0 + t * 16 + lc) * DIM + lg * 8;
        const float* wr0 = W0 + ro;
        const float* wr1 = W1 + ro;
        const float* wr2 = W2 + ro;
        #pragma unroll
        for (int s = 0; s < 4; s++) {
            B0[t][s] = frag8(wr0 + s * 32);
            B1[t][s] = frag8(wr1 + s * 32);
            B2[t][s] = frag8(wr2 + s * 32);
        }
    }
    int base = blockIdx.x * 64;
    #pragma unroll
    for (int rt = 0; rt < 4; rt++) {
        int u0 = base + rt * 16;
        int ar = u0 + lc; if (ar > M - 1) ar = M - 1;
        size_t aro = (size_t)ar * DIM + lg * 8;
        f32x4 f0 = {0.f, 0.f, 0.f, 0.f};
        f32x4 f1 = {0.f, 0.f, 0.f, 0.f};
        {   // channel 0 (click)
            const float* arow = A0 + aro;
            f16x8 Af[4];
            #pragma unroll
            for (int s = 0; s < 4; s++) Af[s] = frag8(arow + s * 32);
            f32x4 a0 = {0.f, 0.f, 0.f, 0.f};
            f32x4 a1 = {0.f, 0.f, 0.f, 0.f};
            #pragma unroll
            for (int s = 0; s < 4; s++) {
                a0 = __builtin_amdgcn_mfma_f32_16x16x32_f16(Af[s], B0[0][s], a0, 0, 0, 0);
                a1 = __builtin_amdgcn_mfma_f32_16x16x32_f16(Af[s], B0[1][s], a1, 0, 0, 0);
            }
            f0 += a0 * cf0; f1 += a1 * cf0;
        }
        {   // channel 1 (favor)
            const float* arow = A1 + aro;
            f16x8 Af[4];
            #pragma unroll
            for (int s = 0; s < 4; s++) Af[s] = frag8(arow + s * 32);
            f32x4 a0 = {0.f, 0.f, 0.f, 0.f};
            f32x4 a1 = {0.f, 0.f, 0.f, 0.f};
            #pragma unroll
            for (int s = 0; s < 4; s++) {
                a0 = __builtin_amdgcn_mfma_f32_16x16x32_f16(Af[s], B1[0][s], a0, 0, 0, 0);
                a1 = __builtin_amdgcn_mfma_f32_16x16x32_f16(Af[s], B1[1][s], a1, 0, 0, 0);
            }
            f0 += a0 * cf1; f1 += a1 * cf1;
        }
        {   // channel 2 (consume)
            const float* arow = A2 + aro;
            f16x8 Af[4];
            #pragma unroll
            for (int s = 0; s < 4; s++) Af[s] = frag8(arow + s * 32);
            f32x4 a0 = {0.f, 0.f, 0.f, 0.f};
            f32x4 a1 = {0.f, 0.f, 0.f, 0.f};
            #pragma unroll
            for (int s = 0; s < 4; s++) {
                a0 = __builtin_amdgcn_mfma_f32_16x16x32_f16(Af[s], B2[0][s], a0, 0, 0, 0);
                a1 = __builtin_amdgcn_mfma_f32_16x16x32_f16(Af[s], B2[1][s], a1, 0, 0, 0);
            }
            f0 += a0 * cf2; f1 += a1 * cf2;
        }
        int rbase = u0 + lg * 4;
        #pragma unroll
        for (int r = 0; r < 4; r++) {
            int row = rbase + r;
            if (row >= M) continue;
            size_t o0 = (size_t)row * DIM + j0 + lc;
            size_t o1 = o0 + 16;
            idf[o0] = f0[r];
            idf[o1] = f1[r];
            idf_h[o0] = (_Float16)f0[r];
            idf_h[o1] = (_Float16)f1[r];
        }
    }
}

// ---------------- fused 3-channel poi GEMM: pf_c = sp_c @ Wp_c^T (grid.y = channel) ----------------
__global__ __launch_bounds__(256) void gemm_poi3_kernel(
        const float* __restrict__ S0, const float* __restrict__ S1, const float* __restrict__ S2,
        const float* __restrict__ Wp0, const float* __restrict__ Wp1, const float* __restrict__ Wp2,
        float* __restrict__ P0, float* __restrict__ P1, float* __restrict__ P2, int M) {
    int c = blockIdx.y;
    const float* A = (c == 0) ? S0 : ((c == 1) ? S1 : S2);
    const float* W = (c == 0) ? Wp0 : ((c == 1) ? Wp1 : Wp2);
    float* P = (c == 0) ? P0 : ((c == 1) ? P1 : P2);
    int w = threadIdx.x >> 6, l = threadIdx.x & 63;
    int lg = l >> 4, lc = l & 15;
    int j0 = w * 32;
    f16x8 Bf[2][4];
    #pragma unroll
    for (int t = 0; t < 2; t++) {
        const float* wr = W + (size_t)(j0 + t * 16 + lc) * DIM + lg * 8;
        #pragma unroll
        for (int s = 0; s < 4; s++) Bf[t][s] = frag8(wr + s * 32);
    }
    int base = blockIdx.x * 64;
    #pragma unroll
    for (int rt = 0; rt < 4; rt++) {
        int u0 = base + rt * 16;
        int ar = u0 + lc; if (ar > M - 1) ar = M - 1;
        const float* arow = A + (size_t)ar * DIM + lg * 8;
        f16x8 Af[4];
        #pragma unroll
        for (int s = 0; s < 4; s++) Af[s] = frag8(arow + s * 32);
        f32x4 acc0 = {0.f, 0.f, 0.f, 0.f};
        f32x4 acc1 = {0.f, 0.f, 0.f, 0.f};
        #pragma unroll
        for (int s = 0; s < 4; s++) {
            acc0 = __builtin_amdgcn_mfma_f32_16x16x32_f16(Af[s], Bf[0][s], acc0, 0, 0, 0);
            acc1 = __builtin_amdgcn_mfma_f32_16x16x32_f16(Af[s], Bf[1][s], acc1, 0, 0, 0);
        }
        int rbase = u0 + lg * 4;
        #pragma unroll
        for (int r = 0; r < 4; r++) {
            int row = rbase + r;
            if (row >= M) continue;
            size_t o0 = (size_t)row * DIM + j0 + lc;
            size_t o1 = o0 + 16;
            P[o0] = acc0[r];
            P[o1] = acc1[r];
        }
    }
}

// ---------------- ufsel: grid.y = channel (fused) ----------------
__global__ void ufsel3_kernel(const float* __restrict__ S0, const float* __restrict__ S1,
                              const float* __restrict__ S2,
                              const float* __restrict__ Wu0, const float* __restrict__ Wu1,
                              const float* __restrict__ Wu2,
                              const int* __restrict__ uidx, float* __restrict__ ufs) {
    int b = blockIdx.x, j = threadIdx.x;  // block 128
    int c = blockIdx.y;
    const float* su_c = (c == 0) ? S0 : ((c == 1) ? S1 : S2);
    const float* W = (c == 0) ? Wu0 : ((c == 1) ? Wu1 : Wu2);
    __shared__ float ar[128];
    int u = iclamp(uidx[b], 0, N_USERS - 1);
    ar[j] = su_c[(size_t)u * DIM + j];
    __syncthreads();
    const float4* Wr = (const float4*)(W + (size_t)j * DIM);
    float acc = 0.f;
    #pragma unroll 8
    for (int q = 0; q < 32; q++) {
        float4 wq = Wr[q];
        acc = fmaf(ar[4 * q + 0], wq.x, acc);
        acc = fmaf(ar[4 * q + 1], wq.y, acc);
        acc = fmaf(ar[4 * q + 2], wq.z, acc);
        acc = fmaf(ar[4 * q + 3], wq.w, acc);
    }
    ufs[(size_t)c * BATCH * DIM + (size_t)b * DIM + j] = acc;
}

// ---------------- ufsel single (tier-1/fallback) ----------------
__global__ void ufsel_kernel(const float* __restrict__ su, const float* __restrict__ W,
                             const int* __restrict__ uidx, float* __restrict__ outsel) {
    int b = blockIdx.x, j = threadIdx.x;
    __shared__ float ar[128];
    int u = iclamp(uidx[b], 0, N_USERS - 1);
    ar[j] = su[(size_t)u * DIM + j];
    __syncthreads();
    const float4* Wr = (const float4*)(W + (size_t)j * DIM);
    float acc = 0.f;
    #pragma unroll 8
    for (int q = 0; q < 32; q++) {
        float4 wq = Wr[q];
        acc = fmaf(ar[4 * q + 0], wq.x, acc);
        acc = fmaf(ar[4 * q + 1], wq.y, acc);
        acc = fmaf(ar[4 * q + 2], wq.z, acc);
        acc = fmaf(ar[4 * q + 3], wq.w, acc);
    }
    outsel[(size_t)b * DIM + j] = acc;
}

// ---------------- fused predict: alt = sum_c wn_c * dot(uf_c, pf_c) ----------------
__global__ __launch_bounds__(256) void predict3_kernel(
        const float* __restrict__ ufs,
        const float* __restrict__ pf0, const float* __restrict__ pf1, const float* __restrict__ pf2,
        const int* __restrict__ pidx, const float* __restrict__ w3,
        float* __restrict__ alt) {
    int wid = (blockIdx.x * blockDim.x + threadIdx.x) >> 6;
    int lane = threadIdx.x & 63;
    if (wid >= BATCH * NPOS) return;
    int b = wid / NPOS;
    int poi = iclamp(pidx[wid], 0, N_POIS - 1);
    // wn coefs: ch0=click->wsel1, ch1=favor->wsel0, ch2=consume->wsel2
    float cc0 = softmax3(w3, 1);
    float cc1 = softmax3(w3, 0);
    float cc2 = softmax3(w3, 2);
    size_t ub = (size_t)b * DIM + lane * 2;
    size_t pb = (size_t)poi * DIM + lane * 2;
    float2 u0 = *(const float2*)(ufs + 0 * BATCH * DIM + ub);
    float2 u1 = *(const float2*)(ufs + 1 * BATCH * DIM + ub);
    float2 u2 = *(const float2*)(ufs + 2 * BATCH * DIM + ub);
    float2 p0 = *(const float2*)(pf0 + pb);
    float2 p1 = *(const float2*)(pf1 + pb);
    float2 p2 = *(const float2*)(pf2 + pb);
    float s = cc0 * (u0.x * p0.x + u0.y * p0.y)
            + cc1 * (u1.x * p1.x + u1.y * p1.y)
            + cc2 * (u2.x * p2.x + u2.y * p2.y);
    #pragma unroll
    for (int o = 32; o > 0; o >>= 1) s += __shfl_xor(s, o, 64);
    if (lane == 0) alt[wid] = s;
}

// ---------------- predict single (tier-1/fallback) ----------------
__global__ __launch_bounds__(256) void predict_kernel(
        const float* __restrict__ ufs, const float* __restrict__ pf,
        const int* __restrict__ pidx, const float* __restrict__ w3,
        int wsel, int first, float* __restrict__ alt) {
    int wid = (blockIdx.x * blockDim.x + threadIdx.x) >> 6;
    int lane = threadIdx.x & 63;
    if (wid >= BATCH * NPOS) return;
    int b = wid / NPOS;
    int poi = iclamp(pidx[wid], 0, N_POIS - 1);
    const float2 uv = *(const float2*)(ufs + (size_t)b * DIM + lane * 2);
    const float2 pv = *(const float2*)(pf + (size_t)poi * DIM + lane * 2);
    float s = uv.x * pv.x + uv.y * pv.y;
    #pragma unroll
    for (int o = 32; o > 0; o >>= 1) s += __shfl_xor(s, o, 64);
    if (lane == 0) {
        float coef = softmax3(w3, wsel);
        float prev = first ? 0.f : alt[wid];
        alt[wid] = prev + coef * s;
    }
}

// ---------------- BCE loss ----------------
__global__ void loss_part_kernel(const float* __restrict__ alt, const float* __restrict__ labels,
                                 float* __restrict__ part) {
    int b = blockIdx.x, t = threadIdx.x;
    int i = b * 1024 + t * 4;
    float4 x4 = *(const float4*)(alt + i);
    float4 y4 = *(const float4*)(labels + i);
    float s = 0.f;
    s += fmaxf(x4.x, 0.f) - x4.x * y4.x + log1pf(expf(-fabsf(x4.x)));
    s += fmaxf(x4.y, 0.f) - x4.y * y4.y + log1pf(expf(-fabsf(x4.y)));
    s += fmaxf(x4.z, 0.f) - x4.z * y4.z + log1pf(expf(-fabsf(x4.z)));
    s += fmaxf(x4.w, 0.f) - x4.w * y4.w + log1pf(expf(-fabsf(x4.w)));
    __shared__ float red[256];
    red[t] = s;
    __syncthreads();
    for (int o = 128; o > 0; o >>= 1) {
        if (t < o) red[t] += red[t + o];
        __syncthreads();
    }
    if (t == 0) part[b] = red[0];
}

__global__ void loss_final_kernel(const float* __restrict__ part, float* __restrict__ out) {
    if (threadIdx.x == 0) {
        float s = 0.f;
        #pragma unroll
        for (int b = 0; b < LOSS_BLOCKS; b++) s += part[b];
        out[0] = s / (float)(BATCH * NPOS);
    }
}

// ---------------- bst_h ----------------
__global__ void bs_kernel(const float* __restrict__ idf, const float* __restrict__ Ws,
                          const float* __restrict__ bias, const int* __restrict__ uidx,
                          _Float16* __restrict__ bst_h) {
    int b = blockIdx.x, j = threadIdx.x;
    __shared__ float ar[128];
    int u = iclamp(uidx[b], 0, N_USERS - 1);
    ar[j] = idf[(size_t)u * DIM + j];
    __syncthreads();
    const float4* Wr = (const float4*)(Ws + (size_t)j * DIM);
    float acc = 0.f;
    #pragma unroll 8
    for (int q = 0; q < 32; q++) {
        float4 wq = Wr[q];
        acc = fmaf(ar[4 * q + 0], wq.x, acc);
        acc = fmaf(ar[4 * q + 1], wq.y, acc);
        acc = fmaf(ar[4 * q + 2], wq.z, acc);
        acc = fmaf(ar[4 * q + 3], wq.w, acc);
    }
    bst_h[(size_t)b * DIM + j] = (_Float16)(acc + bias[j]);
}

__device__ __forceinline__ void topk_insert(float s, int u, float* ts, int* ti) {
    if (s > ts[TOPK - 1]) {
        #pragma unroll
        for (int j = TOPK - 1; j > 0; --j) {
            bool above = s > ts[j - 1];
            bool here = (!above) && (s > ts[j]);
            float nv = above ? ts[j - 1] : (here ? s : ts[j]);
            int ni = above ? ti[j - 1] : (here ? u : ti[j]);
            ts[j] = nv; ti[j] = ni;
        }
        if (s > ts[0]) { ts[0] = s; ti[0] = u; }
    }
}

// ---------------- MFMA uu scores + per-block top-20: 512 thr ----------------
__global__ __launch_bounds__(512) void score_topk_kernel(
        const _Float16* __restrict__ idf_h, const _Float16* __restrict__ bst_h,
        float* __restrict__ cand_s, int* __restrict__ cand_i) {
    __shared__ __align__(16) unsigned char smraw[61440];
    float* ms = (float*)smraw;
    unsigned short* mi = (unsigned short*)(smraw + 40960);
    int cid = blockIdx.x, bg = blockIdx.y;
    int tid = threadIdx.x;
    int w = tid >> 6, l = tid & 63;
    int half = w >> 2, wq = w & 3;
    int lg = l >> 4, lc = l & 15;
    const _Float16* bbase = bst_h + ((size_t)(bg * 64 + wq * 16 + lc)) * DIM + lg * 8;
    f16x8 B0 = *(const f16x8*)(bbase + 0);
    f16x8 B1 = *(const f16x8*)(bbase + 32);
    f16x8 B2 = *(const f16x8*)(bbase + 64);
    f16x8 B3 = *(const f16x8*)(bbase + 96);
    float ts[TOPK]; int ti[TOPK];
    #pragma unroll
    for (int k = 0; k < TOPK; k++) { ts[k] = -3.0e38f; ti[k] = 0; }
    int lo = cid * CPT;
    int hi = lo + CPT; if (hi > N_USERS) hi = N_USERS;
    int ntiles = (hi - lo + 15) >> 4;
    int t0 = half ? (ntiles >> 1) : 0;
    int t1 = half ? ntiles : (ntiles >> 1);
    #pragma unroll 2
    for (int t = t0; t < t1; t++) {
        int u0 = lo + t * 16;
        int ar = u0 + lc; if (ar > N_USERS - 1) ar = N_USERS - 1;
        const _Float16* abase = idf_h + (size_t)ar * DIM + lg * 8;
        f16x8 A0 = *(const f16x8*)(abase + 0);
        f16x8 A1 = *(const f16x8*)(abase + 32);
        f16x8 A2 = *(const f16x8*)(abase + 64);
        f16x8 A3 = *(const f16x8*)(abase + 96);
        f32x4 accA = {0.f, 0.f, 0.f, 0.f};
        f32x4 accB = {0.f, 0.f, 0.f, 0.f};
        accA = __builtin_amdgcn_mfma_f32_16x16x32_f16(A0, B0, accA, 0, 0, 0);
        accB = __builtin_amdgcn_mfma_f32_16x16x32_f16(A1, B1, accB, 0, 0, 0);
        accA = __builtin_amdgcn_mfma_f32_16x16x32_f16(A2, B2, accA, 0, 0, 0);
        accB = __builtin_amdgcn_mfma_f32_16x16x32_f16(A3, B3, accB, 0, 0, 0);
        int ub = u0 + lg * 4;
        #pragma unroll
        for (int r = 0; r < 4; r++) {
            float s = accA[r] + accB[r];
            int u = ub + r;
            if (u < hi) topk_insert(s, u, ts, ti);
        }
    }
    #pragma unroll
    for (int k = 0; k < TOPK; k++) {
        ms[k * 512 + tid] = ts[k];
        mi[k * 512 + tid] = (unsigned short)ti[k];
    }
    __syncthreads();
    if (tid < 64) {
        int wm = tid >> 4, cm = tid & 15;
        int s0 = 0 * 256 + wm * 64 + 0 * 16 + cm;
        int s1 = s0 + 16, s2 = s0 + 32, s3 = s0 + 48;
        int s4 = s0 + 256, s5 = s1 + 256, s6 = s2 + 256, s7 = s3 + 256;
        int p0 = 0, p1 = 0, p2 = 0, p3 = 0, p4 = 0, p5 = 0, p6 = 0, p7 = 0;
        size_t ob = ((size_t)cid * 256 + bg * 64 + wm * 16 + cm) * TOPK;
        for (int k = 0; k < TOPK; k++) {
            float h0 = ms[p0 * 512 + s0];
            float h1 = ms[p1 * 512 + s1];
            float h2 = ms[p2 * 512 + s2];
            float h3 = ms[p3 * 512 + s3];
            float h4 = ms[p4 * 512 + s4];
            float h5 = ms[p5 * 512 + s5];
            float h6 = ms[p6 * 512 + s6];
            float h7 = ms[p7 * 512 + s7];
            float best = h0; int which = 0;
            if (h1 > best) { best = h1; which = 1; }
            if (h2 > best) { best = h2; which = 2; }
            if (h3 > best) { best = h3; which = 3; }
            if (h4 > best) { best = h4; which = 4; }
            if (h5 > best) { best = h5; which = 5; }
            if (h6 > best) { best = h6; which = 6; }
            if (h7 > best) { best = h7; which = 7; }
            int idx;
            if (which == 0)      { idx = mi[p0 * 512 + s0]; p0++; }
            else if (which == 1) { idx = mi[p1 * 512 + s1]; p1++; }
            else if (which == 2) { idx = mi[p2 * 512 + s2]; p2++; }
            else if (which == 3) { idx = mi[p3 * 512 + s3]; p3++; }
            else if (which == 4) { idx = mi[p4 * 512 + s4]; p4++; }
            else if (which == 5) { idx = mi[p5 * 512 + s5]; p5++; }
            else if (which == 6) { idx = mi[p6 * 512 + s6]; p6++; }
            else                 { idx = mi[p7 * 512 + s7]; p7++; }
            cand_s[ob + k] = best;
            cand_i[ob + k] = idx;
        }
    }
}

// ---------------- global merge + softmax + weighted gather ----------------
__global__ void topk_merge_kernel(const float* __restrict__ cand_s, const int* __restrict__ cand_i,
                                  const float* __restrict__ guf,
                                  float* __restrict__ outp) {
    int b = blockIdx.x, t = threadIdx.x;
    __shared__ float rs[NCHUNK]; __shared__ int ru[NCHUNK]; __shared__ int rt[NCHUNK];
    __shared__ float win_s[TOPK]; __shared__ int win_u[TOPK]; __shared__ float wk[TOPK];
    __shared__ int winner;
    int ptr = 0;
    size_t base = ((size_t)t * 256 + b) * TOPK;
    for (int k = 0; k < TOPK; k++) {
        rs[t] = (ptr < TOPK) ? cand_s[base + ptr] : -3.0e38f;
        ru[t] = (ptr < TOPK) ? cand_i[base + ptr] : 0;
        rt[t] = t;
        __syncthreads();
        for (int off = NCHUNK / 2; off > 0; off >>= 1) {
            if (t < off && rs[t + off] > rs[t]) {
                rs[t] = rs[t + off]; ru[t] = ru[t + off]; rt[t] = rt[t + off];
            }
            __syncthreads();
        }
        if (t == 0) { win_s[k] = rs[0]; win_u[k] = iclamp(ru[0], 0, N_USERS - 1); winner = rt[0]; }
        __syncthreads();
        if (t == winner) ptr++;
        __syncthreads();
    }
    if (t == 0) {
        float m = win_s[0], den = 0.f;
        for (int k = 0; k < TOPK; k++) { wk[k] = expf(win_s[k] - m); den += wk[k]; }
        float inv = 1.f / den;
        for (int k = 0; k < TOPK; k++) wk[k] *= inv;
    }
    __syncthreads();
    float acc = 0.f;
    #pragma unroll
    for (int k = 0; k < TOPK; k++)
        acc = fmaf(wk[k], guf[(size_t)win_u[k] * DIM + t], acc);
    outp[1 + (size_t)b * DIM + t] = acc;
}

extern "C" void kernel_launch(void* const* d_in, const int* in_sizes, int n_in,
                              void* d_out, int out_size, void* d_ws, size_t ws_size,
                              hipStream_t stream) {
    (void)in_sizes; (void)n_in; (void)out_size;
    const int*   er      = (const int*)d_in[0];
    const int*   ec      = (const int*)d_in[1];
    const float* click   = (const float*)d_in[2];
    const float* favor   = (const float*)d_in[3];
    const float* consume = (const float*)d_in[4];
    const float* uid     = (const float*)d_in[5];
    const float* pid     = (const float*)d_in[6];
    const int*   uidx    = (const int*)d_in[7];
    const int*   pidx    = (const int*)d_in[8];
    const float* labels  = (const float*)d_in[9];
    const float* guf     = (const float*)d_in[10];
    const float* w3      = (const float*)d_in[11];
    const float* fw3     = (const float*)d_in[12];
    const float* Wuc     = (const float*)d_in[13];
    const float* Wpc     = (const float*)d_in[14];
    const float* Wufv    = (const float*)d_in[15];
    const float* Wpfv    = (const float*)d_in[16];
    const float* Wuco    = (const float*)d_in[17];
    const float* Wpco    = (const float*)d_in[18];
    const float* Wss     = (const float*)d_in[19];
    const float* bias    = (const float*)d_in[20];
    float* outp = (float*)d_out;

    char* ws = (char*)d_ws;
    size_t off = 0;
    auto carve = [&](size_t bytes) -> void* {
        off = (off + 255) & ~(size_t)255;
        void* p = ws + off;
        off += bytes;
        return p;
    };
    float* ufs = (float*)carve(4ll * 3 * BATCH * DIM);
    float* alt = (float*)carve(4ll * BATCH * NPOS);
    float* bst = (float*)carve(4ll * DIM * BATCH);
    int* rptr = (int*)carve(4 * (N_USERS + 1));
    int* cptr = (int*)carve(4 * (N_POIS + 1));
    int* cnts = (int*)carve(4 * (N_USERS + N_POIS));
    int* rcnt = cnts;
    int* ccnt = cnts + N_USERS;
    int* scanws = (int*)carve(4 * 2 * (RCH + CCH) + 4 * 64);
    int* rsum = scanws;
    int* csum = rsum + RCH;
    int* rbase = csum + CCH;
    int* cbase = rbase + RCH;
    float* losspart = (float*)carve(4 * (LOSS_BLOCKS + 7));
    int4* rpack = (int4*)carve(16ll * N_EDGES);
    int4* cpack = (int4*)carve(16ll * N_EDGES);
    unsigned short* pid_h = (unsigned short*)carve(2ll * N_POIS * DIM);
    unsigned short* utr0 = (unsigned short*)carve(2ll * N_USERS * DIM);
    unsigned short* ptr_h = (unsigned short*)carve(2ll * N_POIS * DIM);
    float* su  = (float*)carve(4ll * N_USERS * DIM);
    float* sp  = (float*)carve(4ll * N_POIS * DIM);
    float* idf = (float*)carve(4ll * N_USERS * DIM);
    float* pf = (float*)utr0;
    float* cand_s = su;
    int*   cand_i = (int*)(su + (size_t)NCHUNK * BATCH * TOPK);
    // idf_h = rpack base, 10.24 MB: rpack (8 MB) + head of cpack (2.24 MB).
    // INVARIANT: last reads of rpack (l2u3) and cpack (l2p3) precede idf_h write.
    _Float16* idf_h = (_Float16*)rpack;
    _Float16* bst_h = (_Float16*)bst;
    int* rord = (int*)su;
    int* cord = rord + N_EDGES;
    // tier-1 carves
    unsigned short* utr1 = (unsigned short*)carve(2ll * N_USERS * DIM);
    unsigned short* utr2 = (unsigned short*)carve(2ll * N_USERS * DIM);
    unsigned short* p1b1 = (unsigned short*)carve(2ll * N_POIS * DIM);
    unsigned short* p1b2 = (unsigned short*)carve(2ll * N_POIS * DIM);
    bool fused = (off <= ws_size);
    // tier-2 carves: per-channel su/sp
    float* su1 = (float*)carve(4ll * N_USERS * DIM);
    float* su2 = (float*)carve(4ll * N_USERS * DIM);
    float* sp1 = (float*)carve(4ll * N_POIS * DIM);
    float* sp2 = (float*)carve(4ll * N_POIS * DIM);
    bool fused2 = (off <= ws_size);
    // tier-2 pf buffers: alias utr0/1/2 (each exactly 20000*128*4 B, dead after l2p3)
    float* pf0 = (float*)utr0;
    float* pf1 = (float*)utr1;
    float* pf2 = (float*)utr2;

    zero_kernel<<<(N_USERS + N_POIS + 255) / 256, 256, 0, stream>>>(
        (unsigned int*)cnts, N_USERS + N_POIS);
    cast_f16_kernel<<<(N_POIS * DIM / 2 + 255) / 256, 256, 0, stream>>>(pid, pid_h, N_POIS * DIM / 2);
    hist_kernel<<<(N_EDGES / 4 + 255) / 256, 256, 0, stream>>>(er, ec, rcnt, ccnt, rord, cord);
    dim3 sg2(RCH, 2);
    chunksum_kernel<<<sg2, 256, 0, stream>>>(rcnt, ccnt, rsum, csum);
    chunkscan_kernel<<<1, 128, 0, stream>>>(rsum, csum, rbase, cbase, rptr, cptr);
    scatterscan_kernel<<<sg2, 256, 0, stream>>>(rcnt, ccnt, rbase, cbase, rptr, cptr);
    fill_kernel<<<(N_EDGES / 4 + 255) / 256, 256, 0, stream>>>(
        er, ec, rptr, cptr, rord, cord, rpack, cpack, click, favor, consume);

    struct Ch { const float* Wu; const float* Wp; int wsel; int fsel; };
    Ch chs[3] = { { Wuc,  Wpc,  1, 2 },
                  { Wufv, Wpfv, 0, 0 },
                  { Wuco, Wpco, 2, 1 } };

    const int UGB = N_USERS / 64;                 // 625
    const int PGB = (N_POIS + 63) / 64;           // 313
    const int PW = N_POIS * 64 / 256;
    const int UW = N_USERS * 64 / 256;

    auto launch_spmm_poi = [&](int c, const unsigned short* src, unsigned short* raw,
                               const float* base, float* acc) {
        if (c == 0)      spmm_kernel<0><<<PW, 256, 0, stream>>>(cptr, cpack, src, raw, base, acc, N_POIS);
        else if (c == 1) spmm_kernel<1><<<PW, 256, 0, stream>>>(cptr, cpack, src, raw, base, acc, N_POIS);
        else             spmm_kernel<2><<<PW, 256, 0, stream>>>(cptr, cpack, src, raw, base, acc, N_POIS);
    };
    auto launch_spmm_usr = [&](int c, const unsigned short* src, unsigned short* raw,
                               const float* base, float* acc) {
        if (c == 0)      spmm_kernel<0><<<UW, 256, 0, stream>>>(rptr, rpack, src, raw, base, acc, N_USERS);
        else if (c == 1) spmm_kernel<1><<<UW, 256, 0, stream>>>(rptr, rpack, src, raw, base, acc, N_USERS);
        else             spmm_kernel<2><<<UW, 256, 0, stream>>>(rptr, rpack, src, raw, base, acc, N_USERS);
    };
    auto launch_l2u = [&](int c, const unsigned short* src, unsigned short* u1raw) {
        if (c == 0)      spmm_l2u_kernel<0><<<UW, 256, 0, stream>>>(rptr, rpack, src, u1raw, uid, su, N_USERS);
        else if (c == 1) spmm_l2u_kernel<1><<<UW, 256, 0, stream>>>(rptr, rpack, src, u1raw, uid, su, N_USERS);
        else             spmm_l2u_kernel<2><<<UW, 256, 0, stream>>>(rptr, rpack, src, u1raw, uid, su, N_USERS);
    };
    auto launch_l2p = [&](int c, const unsigned short* src, const unsigned short* p1raw) {
        if (c == 0)      spmm_l2p_kernel<0><<<PW, 256, 0, stream>>>(cptr, cpack, src, p1raw, pid, sp, N_POIS);
        else if (c == 1) spmm_l2p_kernel<1><<<PW, 256, 0, stream>>>(cptr, cpack, src, p1raw, pid, sp, N_POIS);
        else             spmm_l2p_kernel<2><<<PW, 256, 0, stream>>>(cptr, cpack, src, p1raw, pid, sp, N_POIS);
    };

    if (fused2) {
        // tier-2: fully fused pipeline
        spmm3_kernel<<<UW, 256, 0, stream>>>(rptr, rpack, pid_h, utr0, utr1, utr2, N_USERS);
        spmm3p_kernel<<<PW, 256, 0, stream>>>(cptr, cpack, utr0, utr1, utr2,
                                              ptr_h, p1b1, p1b2, N_POIS);
        spmm_l2u3_kernel<<<UW, 256, 0, stream>>>(rptr, rpack, ptr_h, p1b1, p1b2,
                                                 utr0, utr1, utr2, uid, su, su1, su2, N_USERS);
        spmm_l2p3_kernel<<<PW, 256, 0, stream>>>(cptr, cpack, utr0, utr1, utr2,
                                                 ptr_h, p1b1, p1b2, pid, sp, sp1, sp2, N_POIS);
        // fused user GEMM: writes idf + idf_h once (after last rpack/cpack reads)
        gemm_mfma3u_kernel<<<UGB, 256, 0, stream>>>(
            su, su1, su2, Wuc, Wufv, Wuco, idf, idf_h, fw3, N_USERS);
        dim3 ug(BATCH, 3);
        ufsel3_kernel<<<ug, 128, 0, stream>>>(su, su1, su2, Wuc, Wufv, Wuco, uidx, ufs);
        // fused poi GEMM: pf_c into utr_c (dead after l2p3)
        dim3 pg(PGB, 3);
        gemm_poi3_kernel<<<pg, 256, 0, stream>>>(sp, sp1, sp2, Wpc, Wpfv, Wpco,
                                                 pf0, pf1, pf2, N_POIS);
        predict3_kernel<<<BATCH * NPOS * 64 / 256, 256, 0, stream>>>(
            ufs, pf0, pf1, pf2, pidx, w3, alt);
    } else if (fused) {
        // tier-1: round-11 proven schedule
        spmm3_kernel<<<UW, 256, 0, stream>>>(rptr, rpack, pid_h, utr0, utr1, utr2, N_USERS);
        spmm3p_kernel<<<PW, 256, 0, stream>>>(cptr, cpack, utr0, utr1, utr2,
                                              ptr_h, p1b1, p1b2, N_POIS);
        unsigned short* p1b[3] = { ptr_h, p1b1, p1b2 };
        unsigned short* utr[3] = { utr0, utr1, utr2 };
        for (int c = 0; c < 3; c++) {
            launch_l2u(c, p1b[c], utr[c]);
            launch_l2p(c, utr[c], p1b[c]);
            gemm_mfma_kernel<<<UGB, 256, 0, stream>>>(
                su, chs[c].Wu, nullptr, idf, (c == 2) ? idf_h : nullptr,
                fw3, chs[c].fsel, (c == 0) ? 1 : 0, N_USERS);
            ufsel_kernel<<<BATCH, 128, 0, stream>>>(su, chs[c].Wu, uidx, ufs + (size_t)c * BATCH * DIM);
            gemm_mfma_kernel<<<PGB, 256, 0, stream>>>(
                sp, chs[c].Wp, pf, nullptr, nullptr, fw3, 0, 0, N_POIS);
            predict_kernel<<<BATCH * NPOS * 64 / 256, 256, 0, stream>>>(
                ufs + (size_t)c * BATCH * DIM, pf, pidx, w3, chs[c].wsel, (c == 0) ? 1 : 0, alt);
        }
    } else {
        // fallback: per-channel schedule
        for (int c = 0; c < 3; c++) {
            launch_spmm_usr(c, pid_h, utr0, uid, su);
            launch_spmm_poi(c, utr0, ptr_h, pid, sp);
            launch_spmm_usr(c, ptr_h, utr0, su, su);
            launch_spmm_poi(c, utr0, ptr_h, sp, sp);
            gemm_mfma_kernel<<<UGB, 256, 0, stream>>>(
                su, chs[c].Wu, nullptr, idf, (c == 2) ? idf_h : nullptr,
                fw3, chs[c].fsel, (c == 0) ? 1 : 0, N_USERS);
            ufsel_kernel<<<BATCH, 128, 0, stream>>>(su, chs[c].Wu, uidx, ufs + (size_t)c * BATCH * DIM);
            gemm_mfma_kernel<<<PGB, 256, 0, stream>>>(
                sp, chs[c].Wp, pf, nullptr, nullptr, fw3, 0, 0, N_POIS);
            predict_kernel<<<BATCH * NPOS * 64 / 256, 256, 0, stream>>>(
                ufs + (size_t)c * BATCH * DIM, pf, pidx, w3, chs[c].wsel, (c == 0) ? 1 : 0, alt);
        }
    }

    loss_part_kernel<<<LOSS_BLOCKS, 256, 0, stream>>>(alt, labels, losspart);
    loss_final_kernel<<<1, 64, 0, stream>>>(losspart, outp);
    bs_kernel<<<BATCH, 128, 0, stream>>>(idf, Wss, bias, uidx, bst_h);
    dim3 sg(NCHUNK, 4);
    score_topk_kernel<<<sg, 512, 0, stream>>>(idf_h, bst_h, cand_s, cand_i);
    topk_merge_kernel<<<BATCH, NCHUNK, 0, stream>>>(cand_s, cand_i, guf, outp);
}

// Round 14
// 542.568 us; speedup vs baseline: 1.2712x; 1.0500x over previous
//
#include <hip/hip_runtime.h>

#define N_USERS 40000
#define N_POIS  20000
#define DIM     128
#define N_EDGES 500000
#define BATCH   256
#define NPOS    100
#define TOPK    20
#define NCHUNK  128
#define CPT     313   // ceil(40000/128)
#define SCHUNK  1024  // scan chunk (256 thr x 4)
#define RCH     40    // ceil(40000/1024)
#define CCH     20    // ceil(20000/1024)
#define LOSS_BLOCKS 25  // 25600/1024

typedef _Float16 f16x8 __attribute__((ext_vector_type(8)));
typedef float f32x4 __attribute__((ext_vector_type(4)));

__device__ __forceinline__ int iclamp(int x, int lo, int hi) {
    return x < lo ? lo : (x > hi ? hi : x);
}
__device__ __forceinline__ float2 h2f2(unsigned int u) {
    union { unsigned int u32; _Float16 h[2]; } v; v.u32 = u;
    return make_float2((float)v.h[0], (float)v.h[1]);
}
__device__ __forceinline__ unsigned int f2h2(float x, float y) {
    union { unsigned int u32; _Float16 h[2]; } v;
    v.h[0] = (_Float16)x; v.h[1] = (_Float16)y; return v.u32;
}
__device__ __forceinline__ float softmax3(const float* p, int sel) {
    float a0 = p[0], a1 = p[1], a2 = p[2];
    float m = fmaxf(a0, fmaxf(a1, a2));
    float e0 = expf(a0 - m), e1 = expf(a1 - m), e2 = expf(a2 - m);
    float den = e0 + e1 + e2;
    float e = (sel == 0) ? e0 : ((sel == 1) ? e1 : e2);
    return e / den;
}
// compile-time channel pick from packed edge {idx, v0, v1, v2}
template<int CH>
__device__ __forceinline__ float pickvT(int4 q) {
    return __int_as_float(CH == 0 ? q.y : (CH == 1 ? q.z : q.w));
}
// build fp16x8 fragment from 8 contiguous fp32
__device__ __forceinline__ f16x8 frag8(const float* p) {
    float4 x = *(const float4*)(p);
    float4 y = *(const float4*)(p + 4);
    f16x8 f;
    f[0] = (_Float16)x.x; f[1] = (_Float16)x.y; f[2] = (_Float16)x.z; f[3] = (_Float16)x.w;
    f[4] = (_Float16)y.x; f[5] = (_Float16)y.y; f[6] = (_Float16)y.z; f[7] = (_Float16)y.w;
    return f;
}

// ---------------- zero init ----------------
__global__ void zero_kernel(unsigned int* __restrict__ p, int nwords) {
    int i = blockIdx.x * blockDim.x + threadIdx.x;
    if (i < nwords) p[i] = 0u;
}

// ---------------- fp32 -> fp16 cast ----------------
__global__ void cast_f16_kernel(const float* __restrict__ src, unsigned short* __restrict__ dst,
                                int n2) {
    int i = blockIdx.x * blockDim.x + threadIdx.x;
    if (i < n2) {
        float2 v = *(const float2*)(src + 2 * (size_t)i);
        *(unsigned int*)(dst + 2 * (size_t)i) = f2h2(v.x, v.y);
    }
}

// ---------------- CSR hist: counts + per-edge within-row/col ordinals ----------------
__global__ void hist_kernel(const int* __restrict__ er, const int* __restrict__ ec,
                            int* __restrict__ rcnt, int* __restrict__ ccnt,
                            int* __restrict__ rord, int* __restrict__ cord) {
    int e0 = 4 * (blockIdx.x * blockDim.x + threadIdx.x);
    if (e0 + 4 <= N_EDGES) {
        int4 r4 = *(const int4*)(er + e0);
        int4 c4 = *(const int4*)(ec + e0);
        int rr[4] = { r4.x, r4.y, r4.z, r4.w };
        int cc[4] = { c4.x, c4.y, c4.z, c4.w };
        int ro[4], co[4];
        #pragma unroll
        for (int j = 0; j < 4; j++) {
            ro[j] = atomicAdd(&rcnt[iclamp(rr[j], 0, N_USERS - 1)], 1);
            co[j] = atomicAdd(&ccnt[iclamp(cc[j], 0, N_POIS - 1)], 1);
        }
        *(int4*)(rord + e0) = make_int4(ro[0], ro[1], ro[2], ro[3]);
        *(int4*)(cord + e0) = make_int4(co[0], co[1], co[2], co[3]);
    } else {
        for (int e = e0; e < N_EDGES; e++) {
            rord[e] = atomicAdd(&rcnt[iclamp(er[e], 0, N_USERS - 1)], 1);
            cord[e] = atomicAdd(&ccnt[iclamp(ec[e], 0, N_POIS - 1)], 1);
        }
    }
}

// ---------------- parallel prefix sum, stage 1 ----------------
__global__ void chunksum_kernel(const int* __restrict__ rcnt, const int* __restrict__ ccnt,
                                int* __restrict__ rsum, int* __restrict__ csum) {
    int side = blockIdx.y;
    const int* cnt = side ? ccnt : rcnt;
    int n = side ? N_POIS : N_USERS;
    int nch = side ? CCH : RCH;
    int b = blockIdx.x;
    if (b >= nch) return;
    int t = threadIdx.x;
    int i = b * SCHUNK + t * 4;
    int s = 0;
    if (i + 4 <= n) {
        int4 v = *(const int4*)(cnt + i);
        s = v.x + v.y + v.z + v.w;
    } else {
        for (int j = i; j < n; j++) s += cnt[j];
    }
    __shared__ int red[256];
    red[t] = s;
    __syncthreads();
    for (int o = 128; o > 0; o >>= 1) {
        if (t < o) red[t] += red[t + o];
        __syncthreads();
    }
    if (t == 0) (side ? csum : rsum)[b] = red[0];
}

// ---------------- stage 2 ----------------
__global__ void chunkscan_kernel(const int* __restrict__ rsum, const int* __restrict__ csum,
                                 int* __restrict__ rbase, int* __restrict__ cbase,
                                 int* __restrict__ rptr, int* __restrict__ cptr) {
    int w = threadIdx.x >> 6, l = threadIdx.x & 63;
    const int* src = w ? csum : rsum;
    int* dst = w ? cbase : rbase;
    int nch = w ? CCH : RCH;
    int orig = (l < nch) ? src[l] : 0;
    int v = orig;
    #pragma unroll
    for (int o = 1; o < 64; o <<= 1) {
        int u = __shfl_up(v, o, 64);
        if (l >= o) v += u;
    }
    if (l < nch) dst[l] = v - orig;
    if (l == nch - 1) {
        if (w) cptr[N_POIS] = v; else rptr[N_USERS] = v;
    }
}

// ---------------- stage 3 ----------------
__global__ void scatterscan_kernel(const int* __restrict__ rcnt, const int* __restrict__ ccnt,
                                   const int* __restrict__ rbase, const int* __restrict__ cbase,
                                   int* __restrict__ rptr, int* __restrict__ cptr) {
    int side = blockIdx.y;
    const int* cnt = side ? ccnt : rcnt;
    const int* basea = side ? cbase : rbase;
    int* ptr = side ? cptr : rptr;
    int n = side ? N_POIS : N_USERS;
    int nch = side ? CCH : RCH;
    int b = blockIdx.x;
    if (b >= nch) return;
    int t = threadIdx.x;
    int i = b * SCHUNK + t * 4;
    int c0 = 0, c1 = 0, c2 = 0, c3 = 0;
    if (i + 4 <= n) {
        int4 v = *(const int4*)(cnt + i);
        c0 = v.x; c1 = v.y; c2 = v.z; c3 = v.w;
    } else {
        if (i + 0 < n) c0 = cnt[i + 0];
        if (i + 1 < n) c1 = cnt[i + 1];
        if (i + 2 < n) c2 = cnt[i + 2];
    }
    int tsum = c0 + c1 + c2 + c3;
    int l = t & 63, w = t >> 6;
    int v = tsum;
    #pragma unroll
    for (int o = 1; o < 64; o <<= 1) {
        int u = __shfl_up(v, o, 64);
        if (l >= o) v += u;
    }
    __shared__ int wsum[4];
    if (l == 63) wsum[w] = v;
    __syncthreads();
    int wbase = 0;
    for (int k = 0; k < w; k++) wbase += wsum[k];
    int ex = v - tsum + wbase + basea[b];
    if (i + 4 <= n) {
        *(int4*)(ptr + i) = make_int4(ex, ex + c0, ex + c0 + c1, ex + c0 + c1 + c2);
    } else {
        if (i + 0 < n) ptr[i + 0] = ex;
        if (i + 1 < n) ptr[i + 1] = ex + c0;
        if (i + 2 < n) ptr[i + 2] = ex + c0 + c1;
    }
}

// ---------------- AoS CSR fill: NO atomics ----------------
__global__ void fill_kernel(const int* __restrict__ er, const int* __restrict__ ec,
                            const int* __restrict__ rptr, const int* __restrict__ cptr,
                            const int* __restrict__ rord, const int* __restrict__ cord,
                            int4* __restrict__ rpack, int4* __restrict__ cpack,
                            const float* __restrict__ ck, const float* __restrict__ fv,
                            const float* __restrict__ cs) {
    int e0 = 4 * (blockIdx.x * blockDim.x + threadIdx.x);
    if (e0 + 4 <= N_EDGES) {
        int4 r4 = *(const int4*)(er + e0);
        int4 c4 = *(const int4*)(ec + e0);
        int4 ro4 = *(const int4*)(rord + e0);
        int4 co4 = *(const int4*)(cord + e0);
        float4 k4 = *(const float4*)(ck + e0);
        float4 f4 = *(const float4*)(fv + e0);
        float4 s4 = *(const float4*)(cs + e0);
        int rr[4] = { r4.x, r4.y, r4.z, r4.w };
        int cc[4] = { c4.x, c4.y, c4.z, c4.w };
        int ro[4] = { ro4.x, ro4.y, ro4.z, ro4.w };
        int co[4] = { co4.x, co4.y, co4.z, co4.w };
        float kk[4] = { k4.x, k4.y, k4.z, k4.w };
        float ff[4] = { f4.x, f4.y, f4.z, f4.w };
        float ss[4] = { s4.x, s4.y, s4.z, s4.w };
        #pragma unroll
        for (int j = 0; j < 4; j++) {
            int r = iclamp(rr[j], 0, N_USERS - 1), c = iclamp(cc[j], 0, N_POIS - 1);
            int v0 = __float_as_int(kk[j]);
            int v1 = __float_as_int(ff[j]);
            int v2 = __float_as_int(ss[j]);
            int pr = iclamp(rptr[r] + ro[j], 0, N_EDGES - 1);
            rpack[pr] = make_int4(c, v0, v1, v2);
            int pc = iclamp(cptr[c] + co[j], 0, N_EDGES - 1);
            cpack[pc] = make_int4(r, v0, v1, v2);
        }
    } else {
        for (int e = e0; e < N_EDGES; e++) {
            int r = iclamp(er[e], 0, N_USERS - 1), c = iclamp(ec[e], 0, N_POIS - 1);
            int v0 = __float_as_int(ck[e]);
            int v1 = __float_as_int(fv[e]);
            int v2 = __float_as_int(cs[e]);
            int pr = iclamp(rptr[r] + rord[e], 0, N_EDGES - 1);
            rpack[pr] = make_int4(c, v0, v1, v2);
            int pc = iclamp(cptr[c] + cord[e], 0, N_EDGES - 1);
            cpack[pc] = make_int4(r, v0, v1, v2);
        }
    }
}

// ---------------- SpMM single-channel (fallback) ----------------
template<int CH>
__global__ __launch_bounds__(256) void spmm_kernel(
        const int* __restrict__ ptr, const int4* __restrict__ pack,
        const unsigned short* __restrict__ src,
        unsigned short* __restrict__ raw_h,
        const float* __restrict__ base,
        float* __restrict__ acc, int nrows) {
    int wid = (blockIdx.x * blockDim.x + threadIdx.x) >> 6;
    int lane = threadIdx.x & 63;
    if (wid >= nrows) return;
    int beg = __builtin_amdgcn_readfirstlane(iclamp(ptr[wid], 0, N_EDGES));
    int end = __builtin_amdgcn_readfirstlane(iclamp(ptr[wid + 1], 0, N_EDGES));
    if (end < beg) end = beg;
    float ax = 0.f, ay = 0.f;
    int e = beg;
    int lo2 = lane * 2;
    for (; e + 8 <= end; e += 8) {
        int4 q0 = pack[e + 0], q1 = pack[e + 1], q2 = pack[e + 2], q3 = pack[e + 3];
        int4 q4 = pack[e + 4], q5 = pack[e + 5], q6 = pack[e + 6], q7 = pack[e + 7];
        float v0 = pickvT<CH>(q0), v1 = pickvT<CH>(q1), v2 = pickvT<CH>(q2), v3 = pickvT<CH>(q3);
        float v4 = pickvT<CH>(q4), v5 = pickvT<CH>(q5), v6 = pickvT<CH>(q6), v7 = pickvT<CH>(q7);
        float2 p0 = h2f2(*(const unsigned int*)(src + (size_t)q0.x * DIM + lo2));
        float2 p1 = h2f2(*(const unsigned int*)(src + (size_t)q1.x * DIM + lo2));
        float2 p2 = h2f2(*(const unsigned int*)(src + (size_t)q2.x * DIM + lo2));
        float2 p3 = h2f2(*(const unsigned int*)(src + (size_t)q3.x * DIM + lo2));
        float2 p4 = h2f2(*(const unsigned int*)(src + (size_t)q4.x * DIM + lo2));
        float2 p5 = h2f2(*(const unsigned int*)(src + (size_t)q5.x * DIM + lo2));
        float2 p6 = h2f2(*(const unsigned int*)(src + (size_t)q6.x * DIM + lo2));
        float2 p7 = h2f2(*(const unsigned int*)(src + (size_t)q7.x * DIM + lo2));
        ax = fmaf(v0, p0.x, fmaf(v1, p1.x, fmaf(v2, p2.x, fmaf(v3, p3.x, ax))));
        ax = fmaf(v4, p4.x, fmaf(v5, p5.x, fmaf(v6, p6.x, fmaf(v7, p7.x, ax))));
        ay = fmaf(v0, p0.y, fmaf(v1, p1.y, fmaf(v2, p2.y, fmaf(v3, p3.y, ay))));
        ay = fmaf(v4, p4.y, fmaf(v5, p5.y, fmaf(v6, p6.y, fmaf(v7, p7.y, ay))));
    }
    for (; e < end; e++) {
        int4 q = pack[e];
        float v = pickvT<CH>(q);
        float2 p = h2f2(*(const unsigned int*)(src + (size_t)q.x * DIM + lo2));
        ax = fmaf(v, p.x, ax);
        ay = fmaf(v, p.y, ay);
    }
    float n2 = ax * ax + ay * ay;
    #pragma unroll
    for (int o = 32; o > 0; o >>= 1) n2 += __shfl_xor(n2, o, 64);
    float inv = rsqrtf(fmaxf(n2, 1e-30f));
    *(unsigned int*)(raw_h + (size_t)wid * DIM + lo2) = f2h2(ax, ay);
    float2 bv = *(const float2*)(base + (size_t)wid * DIM + lo2);
    *(float2*)(acc + (size_t)wid * DIM + lo2) =
        make_float2(bv.x + ax * inv, bv.y + ay * inv);
}

// ---------------- fused 3-channel L1-user SpMM ----------------
__global__ __launch_bounds__(256) void spmm3_kernel(
        const int* __restrict__ ptr, const int4* __restrict__ pack,
        const unsigned short* __restrict__ src,
        unsigned short* __restrict__ r0, unsigned short* __restrict__ r1,
        unsigned short* __restrict__ r2, int nrows) {
    int wid = (blockIdx.x * blockDim.x + threadIdx.x) >> 6;
    int lane = threadIdx.x & 63;
    if (wid >= nrows) return;
    int beg = __builtin_amdgcn_readfirstlane(iclamp(ptr[wid], 0, N_EDGES));
    int end = __builtin_amdgcn_readfirstlane(iclamp(ptr[wid + 1], 0, N_EDGES));
    if (end < beg) end = beg;
    float a0x = 0.f, a0y = 0.f, a1x = 0.f, a1y = 0.f, a2x = 0.f, a2y = 0.f;
    int e = beg;
    int lo2 = lane * 2;
    for (; e + 4 <= end; e += 4) {
        int4 q0 = pack[e + 0], q1 = pack[e + 1], q2 = pack[e + 2], q3 = pack[e + 3];
        float2 p0 = h2f2(*(const unsigned int*)(src + (size_t)q0.x * DIM + lo2));
        float2 p1 = h2f2(*(const unsigned int*)(src + (size_t)q1.x * DIM + lo2));
        float2 p2 = h2f2(*(const unsigned int*)(src + (size_t)q2.x * DIM + lo2));
        float2 p3 = h2f2(*(const unsigned int*)(src + (size_t)q3.x * DIM + lo2));
        a0x = fmaf(__int_as_float(q0.y), p0.x, fmaf(__int_as_float(q1.y), p1.x,
              fmaf(__int_as_float(q2.y), p2.x, fmaf(__int_as_float(q3.y), p3.x, a0x))));
        a0y = fmaf(__int_as_float(q0.y), p0.y, fmaf(__int_as_float(q1.y), p1.y,
              fmaf(__int_as_float(q2.y), p2.y, fmaf(__int_as_float(q3.y), p3.y, a0y))));
        a1x = fmaf(__int_as_float(q0.z), p0.x, fmaf(__int_as_float(q1.z), p1.x,
              fmaf(__int_as_float(q2.z), p2.x, fmaf(__int_as_float(q3.z), p3.x, a1x))));
        a1y = fmaf(__int_as_float(q0.z), p0.y, fmaf(__int_as_float(q1.z), p1.y,
              fmaf(__int_as_float(q2.z), p2.y, fmaf(__int_as_float(q3.z), p3.y, a1y))));
        a2x = fmaf(__int_as_float(q0.w), p0.x, fmaf(__int_as_float(q1.w), p1.x,
              fmaf(__int_as_float(q2.w), p2.x, fmaf(__int_as_float(q3.w), p3.x, a2x))));
        a2y = fmaf(__int_as_float(q0.w), p0.y, fmaf(__int_as_float(q1.w), p1.y,
              fmaf(__int_as_float(q2.w), p2.y, fmaf(__int_as_float(q3.w), p3.y, a2y))));
    }
    for (; e < end; e++) {
        int4 q = pack[e];
        float2 p = h2f2(*(const unsigned int*)(src + (size_t)q.x * DIM + lo2));
        a0x = fmaf(__int_as_float(q.y), p.x, a0x);
        a0y = fmaf(__int_as_float(q.y), p.y, a0y);
        a1x = fmaf(__int_as_float(q.z), p.x, a1x);
        a1y = fmaf(__int_as_float(q.z), p.y, a1y);
        a2x = fmaf(__int_as_float(q.w), p.x, a2x);
        a2y = fmaf(__int_as_float(q.w), p.y, a2y);
    }
    size_t o = (size_t)wid * DIM + lo2;
    *(unsigned int*)(r0 + o) = f2h2(a0x, a0y);
    *(unsigned int*)(r1 + o) = f2h2(a1x, a1y);
    *(unsigned int*)(r2 + o) = f2h2(a2x, a2y);
}

// ---------------- fused 3-channel L1-poi SpMM ----------------
__global__ __launch_bounds__(256) void spmm3p_kernel(
        const int* __restrict__ ptr, const int4* __restrict__ pack,
        const unsigned short* __restrict__ s0, const unsigned short* __restrict__ s1,
        const unsigned short* __restrict__ s2,
        unsigned short* __restrict__ r0, unsigned short* __restrict__ r1,
        unsigned short* __restrict__ r2, int nrows) {
    int wid = (blockIdx.x * blockDim.x + threadIdx.x) >> 6;
    int lane = threadIdx.x & 63;
    if (wid >= nrows) return;
    int beg = __builtin_amdgcn_readfirstlane(iclamp(ptr[wid], 0, N_EDGES));
    int end = __builtin_amdgcn_readfirstlane(iclamp(ptr[wid + 1], 0, N_EDGES));
    if (end < beg) end = beg;
    float a0x = 0.f, a0y = 0.f, a1x = 0.f, a1y = 0.f, a2x = 0.f, a2y = 0.f;
    int e = beg;
    int lo2 = lane * 2;
    for (; e + 4 <= end; e += 4) {
        int4 q0 = pack[e + 0], q1 = pack[e + 1], q2 = pack[e + 2], q3 = pack[e + 3];
        size_t o0 = (size_t)q0.x * DIM + lo2, o1 = (size_t)q1.x * DIM + lo2;
        size_t o2 = (size_t)q2.x * DIM + lo2, o3 = (size_t)q3.x * DIM + lo2;
        float2 u00 = h2f2(*(const unsigned int*)(s0 + o0));
        float2 u01 = h2f2(*(const unsigned int*)(s0 + o1));
        float2 u02 = h2f2(*(const unsigned int*)(s0 + o2));
        float2 u03 = h2f2(*(const unsigned int*)(s0 + o3));
        float2 u10 = h2f2(*(const unsigned int*)(s1 + o0));
        float2 u11 = h2f2(*(const unsigned int*)(s1 + o1));
        float2 u12 = h2f2(*(const unsigned int*)(s1 + o2));
        float2 u13 = h2f2(*(const unsigned int*)(s1 + o3));
        float2 u20 = h2f2(*(const unsigned int*)(s2 + o0));
        float2 u21 = h2f2(*(const unsigned int*)(s2 + o1));
        float2 u22 = h2f2(*(const unsigned int*)(s2 + o2));
        float2 u23 = h2f2(*(const unsigned int*)(s2 + o3));
        a0x = fmaf(__int_as_float(q0.y), u00.x, fmaf(__int_as_float(q1.y), u01.x,
              fmaf(__int_as_float(q2.y), u02.x, fmaf(__int_as_float(q3.y), u03.x, a0x))));
        a0y = fmaf(__int_as_float(q0.y), u00.y, fmaf(__int_as_float(q1.y), u01.y,
              fmaf(__int_as_float(q2.y), u02.y, fmaf(__int_as_float(q3.y), u03.y, a0y))));
        a1x = fmaf(__int_as_float(q0.z), u10.x, fmaf(__int_as_float(q1.z), u11.x,
              fmaf(__int_as_float(q2.z), u12.x, fmaf(__int_as_float(q3.z), u13.x, a1x))));
        a1y = fmaf(__int_as_float(q0.z), u10.y, fmaf(__int_as_float(q1.z), u11.y,
              fmaf(__int_as_float(q2.z), u12.y, fmaf(__int_as_float(q3.z), u13.y, a1y))));
        a2x = fmaf(__int_as_float(q0.w), u20.x, fmaf(__int_as_float(q1.w), u21.x,
              fmaf(__int_as_float(q2.w), u22.x, fmaf(__int_as_float(q3.w), u23.x, a2x))));
        a2y = fmaf(__int_as_float(q0.w), u20.y, fmaf(__int_as_float(q1.w), u21.y,
              fmaf(__int_as_float(q2.w), u22.y, fmaf(__int_as_float(q3.w), u23.y, a2y))));
    }
    for (; e < end; e++) {
        int4 q = pack[e];
        size_t o = (size_t)q.x * DIM + lo2;
        float2 p0 = h2f2(*(const unsigned int*)(s0 + o));
        float2 p1 = h2f2(*(const unsigned int*)(s1 + o));
        float2 p2 = h2f2(*(const unsigned int*)(s2 + o));
        a0x = fmaf(__int_as_float(q.y), p0.x, a0x);
        a0y = fmaf(__int_as_float(q.y), p0.y, a0y);
        a1x = fmaf(__int_as_float(q.z), p1.x, a1x);
        a1y = fmaf(__int_as_float(q.z), p1.y, a1y);
        a2x = fmaf(__int_as_float(q.w), p2.x, a2x);
        a2y = fmaf(__int_as_float(q.w), p2.y, a2y);
    }
    size_t o = (size_t)wid * DIM + lo2;
    *(unsigned int*)(r0 + o) = f2h2(a0x, a0y);
    *(unsigned int*)(r1 + o) = f2h2(a1x, a1y);
    *(unsigned int*)(r2 + o) = f2h2(a2x, a2y);
}

// ---------------- fused 3-channel L2-user: su_c stored fp16 ----------------
__global__ __launch_bounds__(256) void spmm_l2u3_kernel(
        const int* __restrict__ ptr, const int4* __restrict__ pack,
        const unsigned short* __restrict__ s0, const unsigned short* __restrict__ s1,
        const unsigned short* __restrict__ s2,
        unsigned short* __restrict__ u0, unsigned short* __restrict__ u1r,
        unsigned short* __restrict__ u2r,
        const float* __restrict__ uid,
        _Float16* __restrict__ su0, _Float16* __restrict__ su1, _Float16* __restrict__ su2,
        int nrows) {
    int wid = (blockIdx.x * blockDim.x + threadIdx.x) >> 6;
    int lane = threadIdx.x & 63;
    if (wid >= nrows) return;
    int beg = __builtin_amdgcn_readfirstlane(iclamp(ptr[wid], 0, N_EDGES));
    int end = __builtin_amdgcn_readfirstlane(iclamp(ptr[wid + 1], 0, N_EDGES));
    if (end < beg) end = beg;
    float a0x = 0.f, a0y = 0.f, a1x = 0.f, a1y = 0.f, a2x = 0.f, a2y = 0.f;
    int e = beg;
    int lo2 = lane * 2;
    for (; e + 4 <= end; e += 4) {
        int4 q0 = pack[e + 0], q1 = pack[e + 1], q2 = pack[e + 2], q3 = pack[e + 3];
        size_t o0 = (size_t)q0.x * DIM + lo2, o1 = (size_t)q1.x * DIM + lo2;
        size_t o2 = (size_t)q2.x * DIM + lo2, o3 = (size_t)q3.x * DIM + lo2;
        float2 u00 = h2f2(*(const unsigned int*)(s0 + o0));
        float2 u01 = h2f2(*(const unsigned int*)(s0 + o1));
        float2 u02 = h2f2(*(const unsigned int*)(s0 + o2));
        float2 u03 = h2f2(*(const unsigned int*)(s0 + o3));
        float2 u10 = h2f2(*(const unsigned int*)(s1 + o0));
        float2 u11 = h2f2(*(const unsigned int*)(s1 + o1));
        float2 u12 = h2f2(*(const unsigned int*)(s1 + o2));
        float2 u13 = h2f2(*(const unsigned int*)(s1 + o3));
        float2 u20 = h2f2(*(const unsigned int*)(s2 + o0));
        float2 u21 = h2f2(*(const unsigned int*)(s2 + o1));
        float2 u22 = h2f2(*(const unsigned int*)(s2 + o2));
        float2 u23 = h2f2(*(const unsigned int*)(s2 + o3));
        a0x = fmaf(__int_as_float(q0.y), u00.x, fmaf(__int_as_float(q1.y), u01.x,
              fmaf(__int_as_float(q2.y), u02.x, fmaf(__int_as_float(q3.y), u03.x, a0x))));
        a0y = fmaf(__int_as_float(q0.y), u00.y, fmaf(__int_as_float(q1.y), u01.y,
              fmaf(__int_as_float(q2.y), u02.y, fmaf(__int_as_float(q3.y), u03.y, a0y))));
        a1x = fmaf(__int_as_float(q0.z), u10.x, fmaf(__int_as_float(q1.z), u11.x,
              fmaf(__int_as_float(q2.z), u12.x, fmaf(__int_as_float(q3.z), u13.x, a1x))));
        a1y = fmaf(__int_as_float(q0.z), u10.y, fmaf(__int_as_float(q1.z), u11.y,
              fmaf(__int_as_float(q2.z), u12.y, fmaf(__int_as_float(q3.z), u13.y, a1y))));
        a2x = fmaf(__int_as_float(q0.w), u20.x, fmaf(__int_as_float(q1.w), u21.x,
              fmaf(__int_as_float(q2.w), u22.x, fmaf(__int_as_float(q3.w), u23.x, a2x))));
        a2y = fmaf(__int_as_float(q0.w), u20.y, fmaf(__int_as_float(q1.w), u21.y,
              fmaf(__int_as_float(q2.w), u22.y, fmaf(__int_as_float(q3.w), u23.y, a2y))));
    }
    for (; e < end; e++) {
        int4 q = pack[e];
        size_t o = (size_t)q.x * DIM + lo2;
        float2 p0 = h2f2(*(const unsigned int*)(s0 + o));
        float2 p1 = h2f2(*(const unsigned int*)(s1 + o));
        float2 p2 = h2f2(*(const unsigned int*)(s2 + o));
        a0x = fmaf(__int_as_float(q.y), p0.x, a0x);
        a0y = fmaf(__int_as_float(q.y), p0.y, a0y);
        a1x = fmaf(__int_as_float(q.z), p1.x, a1x);
        a1y = fmaf(__int_as_float(q.z), p1.y, a1y);
        a2x = fmaf(__int_as_float(q.w), p2.x, a2x);
        a2y = fmaf(__int_as_float(q.w), p2.y, a2y);
    }
    size_t o = (size_t)wid * DIM + lo2;
    float2 x0 = h2f2(*(const unsigned int*)(u0 + o));
    float2 x1 = h2f2(*(const unsigned int*)(u1r + o));
    float2 x2 = h2f2(*(const unsigned int*)(u2r + o));
    float m0 = a0x * a0x + a0y * a0y;
    float m1 = a1x * a1x + a1y * a1y;
    float m2 = a2x * a2x + a2y * a2y;
    float k0 = x0.x * x0.x + x0.y * x0.y;
    float k1 = x1.x * x1.x + x1.y * x1.y;
    float k2 = x2.x * x2.x + x2.y * x2.y;
    #pragma unroll
    for (int oo = 32; oo > 0; oo >>= 1) {
        m0 += __shfl_xor(m0, oo, 64); m1 += __shfl_xor(m1, oo, 64); m2 += __shfl_xor(m2, oo, 64);
        k0 += __shfl_xor(k0, oo, 64); k1 += __shfl_xor(k1, oo, 64); k2 += __shfl_xor(k2, oo, 64);
    }
    float im0 = rsqrtf(fmaxf(m0, 1e-30f)), ik0 = rsqrtf(fmaxf(k0, 1e-30f));
    float im1 = rsqrtf(fmaxf(m1, 1e-30f)), ik1 = rsqrtf(fmaxf(k1, 1e-30f));
    float im2 = rsqrtf(fmaxf(m2, 1e-30f)), ik2 = rsqrtf(fmaxf(k2, 1e-30f));
    *(unsigned int*)(u0 + o)  = f2h2(a0x, a0y);
    *(unsigned int*)(u1r + o) = f2h2(a1x, a1y);
    *(unsigned int*)(u2r + o) = f2h2(a2x, a2y);
    float2 bv = *(const float2*)(uid + o);
    *(unsigned int*)(su0 + o) = f2h2(bv.x + x0.x * ik0 + a0x * im0, bv.y + x0.y * ik0 + a0y * im0);
    *(unsigned int*)(su1 + o) = f2h2(bv.x + x1.x * ik1 + a1x * im1, bv.y + x1.y * ik1 + a1y * im1);
    *(unsigned int*)(su2 + o) = f2h2(bv.x + x2.x * ik2 + a2x * im2, bv.y + x2.y * ik2 + a2y * im2);
}

// ---------------- fused 3-channel L2-poi: sp_c stored fp16 ----------------
__global__ __launch_bounds__(256) void spmm_l2p3_kernel(
        const int* __restrict__ ptr, const int4* __restrict__ pack,
        const unsigned short* __restrict__ s0, const unsigned short* __restrict__ s1,
        const unsigned short* __restrict__ s2,
        const unsigned short* __restrict__ p0r, const unsigned short* __restrict__ p1r,
        const unsigned short* __restrict__ p2r,
        const float* __restrict__ pid,
        _Float16* __restrict__ sp0, _Float16* __restrict__ sp1, _Float16* __restrict__ sp2,
        int nrows) {
    int wid = (blockIdx.x * blockDim.x + threadIdx.x) >> 6;
    int lane = threadIdx.x & 63;
    if (wid >= nrows) return;
    int beg = __builtin_amdgcn_readfirstlane(iclamp(ptr[wid], 0, N_EDGES));
    int end = __builtin_amdgcn_readfirstlane(iclamp(ptr[wid + 1], 0, N_EDGES));
    if (end < beg) end = beg;
    float a0x = 0.f, a0y = 0.f, a1x = 0.f, a1y = 0.f, a2x = 0.f, a2y = 0.f;
    int e = beg;
    int lo2 = lane * 2;
    for (; e + 4 <= end; e += 4) {
        int4 q0 = pack[e + 0], q1 = pack[e + 1], q2 = pack[e + 2], q3 = pack[e + 3];
        size_t o0 = (size_t)q0.x * DIM + lo2, o1 = (size_t)q1.x * DIM + lo2;
        size_t o2 = (size_t)q2.x * DIM + lo2, o3 = (size_t)q3.x * DIM + lo2;
        float2 u00 = h2f2(*(const unsigned int*)(s0 + o0));
        float2 u01 = h2f2(*(const unsigned int*)(s0 + o1));
        float2 u02 = h2f2(*(const unsigned int*)(s0 + o2));
        float2 u03 = h2f2(*(const unsigned int*)(s0 + o3));
        float2 u10 = h2f2(*(const unsigned int*)(s1 + o0));
        float2 u11 = h2f2(*(const unsigned int*)(s1 + o1));
        float2 u12 = h2f2(*(const unsigned int*)(s1 + o2));
        float2 u13 = h2f2(*(const unsigned int*)(s1 + o3));
        float2 u20 = h2f2(*(const unsigned int*)(s2 + o0));
        float2 u21 = h2f2(*(const unsigned int*)(s2 + o1));
        float2 u22 = h2f2(*(const unsigned int*)(s2 + o2));
        float2 u23 = h2f2(*(const unsigned int*)(s2 + o3));
        a0x = fmaf(__int_as_float(q0.y), u00.x, fmaf(__int_as_float(q1.y), u01.x,
              fmaf(__int_as_float(q2.y), u02.x, fmaf(__int_as_float(q3.y), u03.x, a0x))));
        a0y = fmaf(__int_as_float(q0.y), u00.y, fmaf(__int_as_float(q1.y), u01.y,
              fmaf(__int_as_float(q2.y), u02.y, fmaf(__int_as_float(q3.y), u03.y, a0y))));
        a1x = fmaf(__int_as_float(q0.z), u10.x, fmaf(__int_as_float(q1.z), u11.x,
              fmaf(__int_as_float(q2.z), u12.x, fmaf(__int_as_float(q3.z), u13.x, a1x))));
        a1y = fmaf(__int_as_float(q0.z), u10.y, fmaf(__int_as_float(q1.z), u11.y,
              fmaf(__int_as_float(q2.z), u12.y, fmaf(__int_as_float(q3.z), u13.y, a1y))));
        a2x = fmaf(__int_as_float(q0.w), u20.x, fmaf(__int_as_float(q1.w), u21.x,
              fmaf(__int_as_float(q2.w), u22.x, fmaf(__int_as_float(q3.w), u23.x, a2x))));
        a2y = fmaf(__int_as_float(q0.w), u20.y, fmaf(__int_as_float(q1.w), u21.y,
              fmaf(__int_as_float(q2.w), u22.y, fmaf(__int_as_float(q3.w), u23.y, a2y))));
    }
    for (; e < end; e++) {
        int4 q = pack[e];
        size_t o = (size_t)q.x * DIM + lo2;
        float2 p0 = h2f2(*(const unsigned int*)(s0 + o));
        float2 p1 = h2f2(*(const unsigned int*)(s1 + o));
        float2 p2 = h2f2(*(const unsigned int*)(s2 + o));
        a0x = fmaf(__int_as_float(q.y), p0.x, a0x);
        a0y = fmaf(__int_as_float(q.y), p0.y, a0y);
        a1x = fmaf(__int_as_float(q.z), p1.x, a1x);
        a1y = fmaf(__int_as_float(q.z), p1.y, a1y);
        a2x = fmaf(__int_as_float(q.w), p2.x, a2x);
        a2y = fmaf(__int_as_float(q.w), p2.y, a2y);
    }
    size_t o = (size_t)wid * DIM + lo2;
    float2 x0 = h2f2(*(const unsigned int*)(p0r + o));
    float2 x1 = h2f2(*(const unsigned int*)(p1r + o));
    float2 x2 = h2f2(*(const unsigned int*)(p2r + o));
    float m0 = a0x * a0x + a0y * a0y;
    float m1 = a1x * a1x + a1y * a1y;
    float m2 = a2x * a2x + a2y * a2y;
    float k0 = x0.x * x0.x + x0.y * x0.y;
    float k1 = x1.x * x1.x + x1.y * x1.y;
    float k2 = x2.x * x2.x + x2.y * x2.y;
    #pragma unroll
    for (int oo = 32; oo > 0; oo >>= 1) {
        m0 += __shfl_xor(m0, oo, 64); m1 += __shfl_xor(m1, oo, 64); m2 += __shfl_xor(m2, oo, 64);
        k0 += __shfl_xor(k0, oo, 64); k1 += __shfl_xor(k1, oo, 64); k2 += __shfl_xor(k2, oo, 64);
    }
    float im0 = rsqrtf(fmaxf(m0, 1e-30f)), ik0 = rsqrtf(fmaxf(k0, 1e-30f));
    float im1 = rsqrtf(fmaxf(m1, 1e-30f)), ik1 = rsqrtf(fmaxf(k1, 1e-30f));
    float im2 = rsqrtf(fmaxf(m2, 1e-30f)), ik2 = rsqrtf(fmaxf(k2, 1e-30f));
    float2 bv = *(const float2*)(pid + o);
    *(unsigned int*)(sp0 + o) = f2h2(bv.x + x0.x * ik0 + a0x * im0, bv.y + x0.y * ik0 + a0y * im0);
    *(unsigned int*)(sp1 + o) = f2h2(bv.x + x1.x * ik1 + a1x * im1, bv.y + x1.y * ik1 + a1y * im1);
    *(unsigned int*)(sp2 + o) = f2h2(bv.x + x2.x * ik2 + a2x * im2, bv.y + x2.y * ik2 + a2y * im2);
}

// ---------------- single-channel L2 kernels (tier-1 path) ----------------
template<int CH>
__global__ __launch_bounds__(256) void spmm_l2u_kernel(
        const int* __restrict__ ptr, const int4* __restrict__ pack,
        const unsigned short* __restrict__ src,
        unsigned short* __restrict__ u1raw,
        const float* __restrict__ uid,
        float* __restrict__ su, int nrows) {
    int wid = (blockIdx.x * blockDim.x + threadIdx.x) >> 6;
    int lane = threadIdx.x & 63;
    if (wid >= nrows) return;
    int beg = __builtin_amdgcn_readfirstlane(iclamp(ptr[wid], 0, N_EDGES));
    int end = __builtin_amdgcn_readfirstlane(iclamp(ptr[wid + 1], 0, N_EDGES));
    if (end < beg) end = beg;
    float ax = 0.f, ay = 0.f;
    int e = beg;
    int lo2 = lane * 2;
    for (; e < end; e++) {
        int4 q = pack[e];
        float v = pickvT<CH>(q);
        float2 p = h2f2(*(const unsigned int*)(src + (size_t)q.x * DIM + lo2));
        ax = fmaf(v, p.x, ax);
        ay = fmaf(v, p.y, ay);
    }
    size_t o = (size_t)wid * DIM + lo2;
    float2 u1 = h2f2(*(const unsigned int*)(u1raw + o));
    float n2a = ax * ax + ay * ay;
    float n2b = u1.x * u1.x + u1.y * u1.y;
    #pragma unroll
    for (int oo = 32; oo > 0; oo >>= 1) {
        n2a += __shfl_xor(n2a, oo, 64);
        n2b += __shfl_xor(n2b, oo, 64);
    }
    float i2 = rsqrtf(fmaxf(n2a, 1e-30f));
    float i1 = rsqrtf(fmaxf(n2b, 1e-30f));
    *(unsigned int*)(u1raw + o) = f2h2(ax, ay);
    float2 bv = *(const float2*)(uid + o);
    *(float2*)(su + o) = make_float2(bv.x + u1.x * i1 + ax * i2,
                                     bv.y + u1.y * i1 + ay * i2);
}

template<int CH>
__global__ __launch_bounds__(256) void spmm_l2p_kernel(
        const int* __restrict__ ptr, const int4* __restrict__ pack,
        const unsigned short* __restrict__ src,
        const unsigned short* __restrict__ p1raw,
        const float* __restrict__ pid,
        float* __restrict__ sp, int nrows) {
    int wid = (blockIdx.x * blockDim.x + threadIdx.x) >> 6;
    int lane = threadIdx.x & 63;
    if (wid >= nrows) return;
    int beg = __builtin_amdgcn_readfirstlane(iclamp(ptr[wid], 0, N_EDGES));
    int end = __builtin_amdgcn_readfirstlane(iclamp(ptr[wid + 1], 0, N_EDGES));
    if (end < beg) end = beg;
    float ax = 0.f, ay = 0.f;
    int e = beg;
    int lo2 = lane * 2;
    for (; e < end; e++) {
        int4 q = pack[e];
        float v = pickvT<CH>(q);
        float2 p = h2f2(*(const unsigned int*)(src + (size_t)q.x * DIM + lo2));
        ax = fmaf(v, p.x, ax);
        ay = fmaf(v, p.y, ay);
    }
    size_t o = (size_t)wid * DIM + lo2;
    float2 p1v = h2f2(*(const unsigned int*)(p1raw + o));
    float n2a = ax * ax + ay * ay;
    float n2b = p1v.x * p1v.x + p1v.y * p1v.y;
    #pragma unroll
    for (int oo = 32; oo > 0; oo >>= 1) {
        n2a += __shfl_xor(n2a, oo, 64);
        n2b += __shfl_xor(n2b, oo, 64);
    }
    float i2 = rsqrtf(fmaxf(n2a, 1e-30f));
    float i1 = rsqrtf(fmaxf(n2b, 1e-30f));
    float2 bv = *(const float2*)(pid + o);
    *(float2*)(sp + o) = make_float2(bv.x + p1v.x * i1 + ax * i2,
                                     bv.y + p1v.y * i1 + ay * i2);
}

// ---------------- MFMA single GEMM (tier-1/fallback) ----------------
__global__ __launch_bounds__(256) void gemm_mfma_kernel(
        const float* __restrict__ A, const float* __restrict__ W,
        float* __restrict__ store, float* __restrict__ accum,
        _Float16* __restrict__ accum_h,
        const float* __restrict__ fw3, int fsel, int first, int M) {
    int w = threadIdx.x >> 6, l = threadIdx.x & 63;
    int lg = l >> 4, lc = l & 15;
    int j0 = w * 32;
    float coef = accum ? softmax3(fw3, fsel) : 0.f;
    f16x8 Bf[2][4];
    #pragma unroll
    for (int t = 0; t < 2; t++) {
        const float* wr = W + (size_t)(j0 + t * 16 + lc) * DIM + lg * 8;
        #pragma unroll
        for (int s = 0; s < 4; s++) Bf[t][s] = frag8(wr + s * 32);
    }
    int base = blockIdx.x * 64;
    #pragma unroll
    for (int rt = 0; rt < 4; rt++) {
        int u0 = base + rt * 16;
        int ar = u0 + lc; if (ar > M - 1) ar = M - 1;
        const float* arow = A + (size_t)ar * DIM + lg * 8;
        f16x8 Af[4];
        #pragma unroll
        for (int s = 0; s < 4; s++) Af[s] = frag8(arow + s * 32);
        f32x4 acc0 = {0.f, 0.f, 0.f, 0.f};
        f32x4 acc1 = {0.f, 0.f, 0.f, 0.f};
        #pragma unroll
        for (int s = 0; s < 4; s++) {
            acc0 = __builtin_amdgcn_mfma_f32_16x16x32_f16(Af[s], Bf[0][s], acc0, 0, 0, 0);
            acc1 = __builtin_amdgcn_mfma_f32_16x16x32_f16(Af[s], Bf[1][s], acc1, 0, 0, 0);
        }
        int rbase = u0 + lg * 4;
        #pragma unroll
        for (int r = 0; r < 4; r++) {
            int row = rbase + r;
            if (row >= M) continue;
            size_t o0 = (size_t)row * DIM + j0 + lc;
            size_t o1 = o0 + 16;
            if (store) { store[o0] = acc0[r]; store[o1] = acc1[r]; }
            if (accum) {
                float p0 = first ? 0.f : accum[o0];
                float p1 = first ? 0.f : accum[o1];
                float n0 = p0 + coef * acc0[r];
                float n1 = p1 + coef * acc1[r];
                accum[o0] = n0;
                accum[o1] = n1;
                if (accum_h) {
                    accum_h[o0] = (_Float16)n0;
                    accum_h[o1] = (_Float16)n1;
                }
            }
        }
    }
}

// ---------------- fused 3-channel user GEMM: fp16 A inputs ----------------
__global__ __launch_bounds__(256) void gemm_mfma3u_kernel(
        const _Float16* __restrict__ A0, const _Float16* __restrict__ A1,
        const _Float16* __restrict__ A2,
        const float* __restrict__ W0, const float* __restrict__ W1, const float* __restrict__ W2,
        float* __restrict__ idf, _Float16* __restrict__ idf_h,
        const float* __restrict__ fw3, int M) {
    int w = threadIdx.x >> 6, l = threadIdx.x & 63;
    int lg = l >> 4, lc = l & 15;
    int j0 = w * 32;
    // fwn coefs: ch0=click->fsel2, ch1=favor->fsel0, ch2=consume->fsel1
    float cf0 = softmax3(fw3, 2);
    float cf1 = softmax3(fw3, 0);
    float cf2 = softmax3(fw3, 1);
    f16x8 B0[2][4], B1[2][4], B2[2][4];
    #pragma unroll
    for (int t = 0; t < 2; t++) {
        size_t ro = (size_t)(j0 + t * 16 + lc) * DIM + lg * 8;
        const float* wr0 = W0 + ro;
        const float* wr1 = W1 + ro;
        const float* wr2 = W2 + ro;
        #pragma unroll
        for (int s = 0; s < 4; s++) {
            B0[t][s] = frag8(wr0 + s * 32);
            B1[t][s] = frag8(wr1 + s * 32);
            B2[t][s] = frag8(wr2 + s * 32);
        }
    }
    int base = blockIdx.x * 64;
    #pragma unroll
    for (int rt = 0; rt < 4; rt++) {
        int u0 = base + rt * 16;
        int ar = u0 + lc; if (ar > M - 1) ar = M - 1;
        size_t aro = (size_t)ar * DIM + lg * 8;
        f32x4 f0 = {0.f, 0.f, 0.f, 0.f};
        f32x4 f1 = {0.f, 0.f, 0.f, 0.f};
        {   // channel 0 (click)
            f16x8 Af[4];
            #pragma unroll
            for (int s = 0; s < 4; s++) Af[s] = *(const f16x8*)(A0 + aro + s * 32);
            f32x4 a0 = {0.f, 0.f, 0.f, 0.f};
            f32x4 a1 = {0.f, 0.f, 0.f, 0.f};
            #pragma unroll
            for (int s = 0; s < 4; s++) {
                a0 = __builtin_amdgcn_mfma_f32_16x16x32_f16(Af[s], B0[0][s], a0, 0, 0, 0);
                a1 = __builtin_amdgcn_mfma_f32_16x16x32_f16(Af[s], B0[1][s], a1, 0, 0, 0);
            }
            f0 += a0 * cf0; f1 += a1 * cf0;
        }
        {   // channel 1 (favor)
            f16x8 Af[4];
            #pragma unroll
            for (int s = 0; s < 4; s++) Af[s] = *(const f16x8*)(A1 + aro + s * 32);
            f32x4 a0 = {0.f, 0.f, 0.f, 0.f};
            f32x4 a1 = {0.f, 0.f, 0.f, 0.f};
            #pragma unroll
            for (int s = 0; s < 4; s++) {
                a0 = __builtin_amdgcn_mfma_f32_16x16x32_f16(Af[s], B1[0][s], a0, 0, 0, 0);
                a1 = __builtin_amdgcn_mfma_f32_16x16x32_f16(Af[s], B1[1][s], a1, 0, 0, 0);
            }
            f0 += a0 * cf1; f1 += a1 * cf1;
        }
        {   // channel 2 (consume)
            f16x8 Af[4];
            #pragma unroll
            for (int s = 0; s < 4; s++) Af[s] = *(const f16x8*)(A2 + aro + s * 32);
            f32x4 a0 = {0.f, 0.f, 0.f, 0.f};
            f32x4 a1 = {0.f, 0.f, 0.f, 0.f};
            #pragma unroll
            for (int s = 0; s < 4; s++) {
                a0 = __builtin_amdgcn_mfma_f32_16x16x32_f16(Af[s], B2[0][s], a0, 0, 0, 0);
                a1 = __builtin_amdgcn_mfma_f32_16x16x32_f16(Af[s], B2[1][s], a1, 0, 0, 0);
            }
            f0 += a0 * cf2; f1 += a1 * cf2;
        }
        int rbase = u0 + lg * 4;
        #pragma unroll
        for (int r = 0; r < 4; r++) {
            int row = rbase + r;
            if (row >= M) continue;
            size_t o0 = (size_t)row * DIM + j0 + lc;
            size_t o1 = o0 + 16;
            idf[o0] = f0[r];
            idf[o1] = f1[r];
            idf_h[o0] = (_Float16)f0[r];
            idf_h[o1] = (_Float16)f1[r];
        }
    }
}

// ---------------- fused 3-channel poi GEMM: fp16 A inputs (grid.y = channel) ----------------
__global__ __launch_bounds__(256) void gemm_poi3_kernel(
        const _Float16* __restrict__ S0, const _Float16* __restrict__ S1,
        const _Float16* __restrict__ S2,
        const float* __restrict__ Wp0, const float* __restrict__ Wp1, const float* __restrict__ Wp2,
        float* __restrict__ P0, float* __restrict__ P1, float* __restrict__ P2, int M) {
    int c = blockIdx.y;
    const _Float16* A = (c == 0) ? S0 : ((c == 1) ? S1 : S2);
    const float* W = (c == 0) ? Wp0 : ((c == 1) ? Wp1 : Wp2);
    float* P = (c == 0) ? P0 : ((c == 1) ? P1 : P2);
    int w = threadIdx.x >> 6, l = threadIdx.x & 63;
    int lg = l >> 4, lc = l & 15;
    int j0 = w * 32;
    f16x8 Bf[2][4];
    #pragma unroll
    for (int t = 0; t < 2; t++) {
        const float* wr = W + (size_t)(j0 + t * 16 + lc) * DIM + lg * 8;
        #pragma unroll
        for (int s = 0; s < 4; s++) Bf[t][s] = frag8(wr + s * 32);
    }
    int base = blockIdx.x * 64;
    #pragma unroll
    for (int rt = 0; rt < 4; rt++) {
        int u0 = base + rt * 16;
        int ar = u0 + lc; if (ar > M - 1) ar = M - 1;
        const _Float16* arow = A + (size_t)ar * DIM + lg * 8;
        f16x8 Af[4];
        #pragma unroll
        for (int s = 0; s < 4; s++) Af[s] = *(const f16x8*)(arow + s * 32);
        f32x4 acc0 = {0.f, 0.f, 0.f, 0.f};
        f32x4 acc1 = {0.f, 0.f, 0.f, 0.f};
        #pragma unroll
        for (int s = 0; s < 4; s++) {
            acc0 = __builtin_amdgcn_mfma_f32_16x16x32_f16(Af[s], Bf[0][s], acc0, 0, 0, 0);
            acc1 = __builtin_amdgcn_mfma_f32_16x16x32_f16(Af[s], Bf[1][s], acc1, 0, 0, 0);
        }
        int rbase = u0 + lg * 4;
        #pragma unroll
        for (int r = 0; r < 4; r++) {
            int row = rbase + r;
            if (row >= M) continue;
            size_t o0 = (size_t)row * DIM + j0 + lc;
            size_t o1 = o0 + 16;
            P[o0] = acc0[r];
            P[o1] = acc1[r];
        }
    }
}

// ---------------- ufsel: grid.y = channel (fused, fp16 su) ----------------
__global__ void ufsel3_kernel(const _Float16* __restrict__ S0, const _Float16* __restrict__ S1,
                              const _Float16* __restrict__ S2,
                              const float* __restrict__ Wu0, const float* __restrict__ Wu1,
                              const float* __restrict__ Wu2,
                              const int* __restrict__ uidx, float* __restrict__ ufs) {
    int b = blockIdx.x, j = threadIdx.x;  // block 128
    int c = blockIdx.y;
    const _Float16* su_c = (c == 0) ? S0 : ((c == 1) ? S1 : S2);
    const float* W = (c == 0) ? Wu0 : ((c == 1) ? Wu1 : Wu2);
    __shared__ float ar[128];
    int u = iclamp(uidx[b], 0, N_USERS - 1);
    ar[j] = (float)su_c[(size_t)u * DIM + j];
    __syncthreads();
    const float4* Wr = (const float4*)(W + (size_t)j * DIM);
    float acc = 0.f;
    #pragma unroll 8
    for (int q = 0; q < 32; q++) {
        float4 wq = Wr[q];
        acc = fmaf(ar[4 * q + 0], wq.x, acc);
        acc = fmaf(ar[4 * q + 1], wq.y, acc);
        acc = fmaf(ar[4 * q + 2], wq.z, acc);
        acc = fmaf(ar[4 * q + 3], wq.w, acc);
    }
    ufs[(size_t)c * BATCH * DIM + (size_t)b * DIM + j] = acc;
}

// ---------------- ufsel single (tier-1/fallback) ----------------
__global__ void ufsel_kernel(const float* __restrict__ su, const float* __restrict__ W,
                             const int* __restrict__ uidx, float* __restrict__ outsel) {
    int b = blockIdx.x, j = threadIdx.x;
    __shared__ float ar[128];
    int u = iclamp(uidx[b], 0, N_USERS - 1);
    ar[j] = su[(size_t)u * DIM + j];
    __syncthreads();
    const float4* Wr = (const float4*)(W + (size_t)j * DIM);
    float acc = 0.f;
    #pragma unroll 8
    for (int q = 0; q < 32; q++) {
        float4 wq = Wr[q];
        acc = fmaf(ar[4 * q + 0], wq.x, acc);
        acc = fmaf(ar[4 * q + 1], wq.y, acc);
        acc = fmaf(ar[4 * q + 2], wq.z, acc);
        acc = fmaf(ar[4 * q + 3], wq.w, acc);
    }
    outsel[(size_t)b * DIM + j] = acc;
}

// ---------------- fused predict: alt = sum_c wn_c * dot(uf_c, pf_c) ----------------
__global__ __launch_bounds__(256) void predict3_kernel(
        const float* __restrict__ ufs,
        const float* __restrict__ pf0, const float* __restrict__ pf1, const float* __restrict__ pf2,
        const int* __restrict__ pidx, const float* __restrict__ w3,
        float* __restrict__ alt) {
    int wid = (blockIdx.x * blockDim.x + threadIdx.x) >> 6;
    int lane = threadIdx.x & 63;
    if (wid >= BATCH * NPOS) return;
    int b = wid / NPOS;
    int poi = iclamp(pidx[wid], 0, N_POIS - 1);
    float cc0 = softmax3(w3, 1);
    float cc1 = softmax3(w3, 0);
    float cc2 = softmax3(w3, 2);
    size_t ub = (size_t)b * DIM + lane * 2;
    size_t pb = (size_t)poi * DIM + lane * 2;
    float2 u0 = *(const float2*)(ufs + 0 * BATCH * DIM + ub);
    float2 u1 = *(const float2*)(ufs + 1 * BATCH * DIM + ub);
    float2 u2 = *(const float2*)(ufs + 2 * BATCH * DIM + ub);
    float2 p0 = *(const float2*)(pf0 + pb);
    float2 p1 = *(const float2*)(pf1 + pb);
    float2 p2 = *(const float2*)(pf2 + pb);
    float s = cc0 * (u0.x * p0.x + u0.y * p0.y)
            + cc1 * (u1.x * p1.x + u1.y * p1.y)
            + cc2 * (u2.x * p2.x + u2.y * p2.y);
    #pragma unroll
    for (int o = 32; o > 0; o >>= 1) s += __shfl_xor(s, o, 64);
    if (lane == 0) alt[wid] = s;
}

// ---------------- predict single (tier-1/fallback) ----------------
__global__ __launch_bounds__(256) void predict_kernel(
        const float* __restrict__ ufs, const float* __restrict__ pf,
        const int* __restrict__ pidx, const float* __restrict__ w3,
        int wsel, int first, float* __restrict__ alt) {
    int wid = (blockIdx.x * blockDim.x + threadIdx.x) >> 6;
    int lane = threadIdx.x & 63;
    if (wid >= BATCH * NPOS) return;
    int b = wid / NPOS;
    int poi = iclamp(pidx[wid], 0, N_POIS - 1);
    const float2 uv = *(const float2*)(ufs + (size_t)b * DIM + lane * 2);
    const float2 pv = *(const float2*)(pf + (size_t)poi * DIM + lane * 2);
    float s = uv.x * pv.x + uv.y * pv.y;
    #pragma unroll
    for (int o = 32; o > 0; o >>= 1) s += __shfl_xor(s, o, 64);
    if (lane == 0) {
        float coef = softmax3(w3, wsel);
        float prev = first ? 0.f : alt[wid];
        alt[wid] = prev + coef * s;
    }
}

// ---------------- BCE loss ----------------
__global__ void loss_part_kernel(const float* __restrict__ alt, const float* __restrict__ labels,
                                 float* __restrict__ part) {
    int b = blockIdx.x, t = threadIdx.x;
    int i = b * 1024 + t * 4;
    float4 x4 = *(const float4*)(alt + i);
    float4 y4 = *(const float4*)(labels + i);
    float s = 0.f;
    s += fmaxf(x4.x, 0.f) - x4.x * y4.x + log1pf(expf(-fabsf(x4.x)));
    s += fmaxf(x4.y, 0.f) - x4.y * y4.y + log1pf(expf(-fabsf(x4.y)));
    s += fmaxf(x4.z, 0.f) - x4.z * y4.z + log1pf(expf(-fabsf(x4.z)));
    s += fmaxf(x4.w, 0.f) - x4.w * y4.w + log1pf(expf(-fabsf(x4.w)));
    __shared__ float red[256];
    red[t] = s;
    __syncthreads();
    for (int o = 128; o > 0; o >>= 1) {
        if (t < o) red[t] += red[t + o];
        __syncthreads();
    }
    if (t == 0) part[b] = red[0];
}

__global__ void loss_final_kernel(const float* __restrict__ part, float* __restrict__ out) {
    if (threadIdx.x == 0) {
        float s = 0.f;
        #pragma unroll
        for (int b = 0; b < LOSS_BLOCKS; b++) s += part[b];
        out[0] = s / (float)(BATCH * NPOS);
    }
}

// ---------------- bst_h ----------------
__global__ void bs_kernel(const float* __restrict__ idf, const float* __restrict__ Ws,
                          const float* __restrict__ bias, const int* __restrict__ uidx,
                          _Float16* __restrict__ bst_h) {
    int b = blockIdx.x, j = threadIdx.x;
    __shared__ float ar[128];
    int u = iclamp(uidx[b], 0, N_USERS - 1);
    ar[j] = idf[(size_t)u * DIM + j];
    __syncthreads();
    const float4* Wr = (const float4*)(Ws + (size_t)j * DIM);
    float acc = 0.f;
    #pragma unroll 8
    for (int q = 0; q < 32; q++) {
        float4 wq = Wr[q];
        acc = fmaf(ar[4 * q + 0], wq.x, acc);
        acc = fmaf(ar[4 * q + 1], wq.y, acc);
        acc = fmaf(ar[4 * q + 2], wq.z, acc);
        acc = fmaf(ar[4 * q + 3], wq.w, acc);
    }
    bst_h[(size_t)b * DIM + j] = (_Float16)(acc + bias[j]);
}

__device__ __forceinline__ void topk_insert(float s, int u, float* ts, int* ti) {
    if (s > ts[TOPK - 1]) {
        #pragma unroll
        for (int j = TOPK - 1; j > 0; --j) {
            bool above = s > ts[j - 1];
            bool here = (!above) && (s > ts[j]);
            float nv = above ? ts[j - 1] : (here ? s : ts[j]);
            int ni = above ? ti[j - 1] : (here ? u : ti[j]);
            ts[j] = nv; ti[j] = ni;
        }
        if (s > ts[0]) { ts[0] = s; ti[0] = u; }
    }
}

// ---------------- MFMA uu scores + per-block top-20: 512 thr ----------------
__global__ __launch_bounds__(512) void score_topk_kernel(
        const _Float16* __restrict__ idf_h, const _Float16* __restrict__ bst_h,
        float* __restrict__ cand_s, int* __restrict__ cand_i) {
    __shared__ __align__(16) unsigned char smraw[61440];
    float* ms = (float*)smraw;
    unsigned short* mi = (unsigned short*)(smraw + 40960);
    int cid = blockIdx.x, bg = blockIdx.y;
    int tid = threadIdx.x;
    int w = tid >> 6, l = tid & 63;
    int half = w >> 2, wq = w & 3;
    int lg = l >> 4, lc = l & 15;
    const _Float16* bbase = bst_h + ((size_t)(bg * 64 + wq * 16 + lc)) * DIM + lg * 8;
    f16x8 B0 = *(const f16x8*)(bbase + 0);
    f16x8 B1 = *(const f16x8*)(bbase + 32);
    f16x8 B2 = *(const f16x8*)(bbase + 64);
    f16x8 B3 = *(const f16x8*)(bbase + 96);
    float ts[TOPK]; int ti[TOPK];
    #pragma unroll
    for (int k = 0; k < TOPK; k++) { ts[k] = -3.0e38f; ti[k] = 0; }
    int lo = cid * CPT;
    int hi = lo + CPT; if (hi > N_USERS) hi = N_USERS;
    int ntiles = (hi - lo + 15) >> 4;
    int t0 = half ? (ntiles >> 1) : 0;
    int t1 = half ? ntiles : (ntiles >> 1);
    #pragma unroll 2
    for (int t = t0; t < t1; t++) {
        int u0 = lo + t * 16;
        int ar = u0 + lc; if (ar > N_USERS - 1) ar = N_USERS - 1;
        const _Float16* abase = idf_h + (size_t)ar * DIM + lg * 8;
        f16x8 A0 = *(const f16x8*)(abase + 0);
        f16x8 A1 = *(const f16x8*)(abase + 32);
        f16x8 A2 = *(const f16x8*)(abase + 64);
        f16x8 A3 = *(const f16x8*)(abase + 96);
        f32x4 accA = {0.f, 0.f, 0.f, 0.f};
        f32x4 accB = {0.f, 0.f, 0.f, 0.f};
        accA = __builtin_amdgcn_mfma_f32_16x16x32_f16(A0, B0, accA, 0, 0, 0);
        accB = __builtin_amdgcn_mfma_f32_16x16x32_f16(A1, B1, accB, 0, 0, 0);
        accA = __builtin_amdgcn_mfma_f32_16x16x32_f16(A2, B2, accA, 0, 0, 0);
        accB = __builtin_amdgcn_mfma_f32_16x16x32_f16(A3, B3, accB, 0, 0, 0);
        int ub = u0 + lg * 4;
        #pragma unroll
        for (int r = 0; r < 4; r++) {
            float s = accA[r] + accB[r];
            int u = ub + r;
            if (u < hi) topk_insert(s, u, ts, ti);
        }
    }
    #pragma unroll
    for (int k = 0; k < TOPK; k++) {
        ms[k * 512 + tid] = ts[k];
        mi[k * 512 + tid] = (unsigned short)ti[k];
    }
    __syncthreads();
    if (tid < 64) {
        int wm = tid >> 4, cm = tid & 15;
        int s0 = 0 * 256 + wm * 64 + 0 * 16 + cm;
        int s1 = s0 + 16, s2 = s0 + 32, s3 = s0 + 48;
        int s4 = s0 + 256, s5 = s1 + 256, s6 = s2 + 256, s7 = s3 + 256;
        int p0 = 0, p1 = 0, p2 = 0, p3 = 0, p4 = 0, p5 = 0, p6 = 0, p7 = 0;
        size_t ob = ((size_t)cid * 256 + bg * 64 + wm * 16 + cm) * TOPK;
        for (int k = 0; k < TOPK; k++) {
            float h0 = ms[p0 * 512 + s0];
            float h1 = ms[p1 * 512 + s1];
            float h2 = ms[p2 * 512 + s2];
            float h3 = ms[p3 * 512 + s3];
            float h4 = ms[p4 * 512 + s4];
            float h5 = ms[p5 * 512 + s5];
            float h6 = ms[p6 * 512 + s6];
            float h7 = ms[p7 * 512 + s7];
            float best = h0; int which = 0;
            if (h1 > best) { best = h1; which = 1; }
            if (h2 > best) { best = h2; which = 2; }
            if (h3 > best) { best = h3; which = 3; }
            if (h4 > best) { best = h4; which = 4; }
            if (h5 > best) { best = h5; which = 5; }
            if (h6 > best) { best = h6; which = 6; }
            if (h7 > best) { best = h7; which = 7; }
            int idx;
            if (which == 0)      { idx = mi[p0 * 512 + s0]; p0++; }
            else if (which == 1) { idx = mi[p1 * 512 + s1]; p1++; }
            else if (which == 2) { idx = mi[p2 * 512 + s2]; p2++; }
            else if (which == 3) { idx = mi[p3 * 512 + s3]; p3++; }
            else if (which == 4) { idx = mi[p4 * 512 + s4]; p4++; }
            else if (which == 5) { idx = mi[p5 * 512 + s5]; p5++; }
            else if (which == 6) { idx = mi[p6 * 512 + s6]; p6++; }
            else                 { idx = mi[p7 * 512 + s7]; p7++; }
            cand_s[ob + k] = best;
            cand_i[ob + k] = idx;
        }
    }
}

// ---------------- global merge + softmax + weighted gather ----------------
__global__ void topk_merge_kernel(const float* __restrict__ cand_s, const int* __restrict__ cand_i,
                                  const float* __restrict__ guf,
                                  float* __restrict__ outp) {
    int b = blockIdx.x, t = threadIdx.x;
    __shared__ float rs[NCHUNK]; __shared__ int ru[NCHUNK]; __shared__ int rt[NCHUNK];
    __shared__ float win_s[TOPK]; __shared__ int win_u[TOPK]; __shared__ float wk[TOPK];
    __shared__ int winner;
    int ptr = 0;
    size_t base = ((size_t)t * 256 + b) * TOPK;
    for (int k = 0; k < TOPK; k++) {
        rs[t] = (ptr < TOPK) ? cand_s[base + ptr] : -3.0e38f;
        ru[t] = (ptr < TOPK) ? cand_i[base + ptr] : 0;
        rt[t] = t;
        __syncthreads();
        for (int off = NCHUNK / 2; off > 0; off >>= 1) {
            if (t < off && rs[t + off] > rs[t]) {
                rs[t] = rs[t + off]; ru[t] = ru[t + off]; rt[t] = rt[t + off];
            }
            __syncthreads();
        }
        if (t == 0) { win_s[k] = rs[0]; win_u[k] = iclamp(ru[0], 0, N_USERS - 1); winner = rt[0]; }
        __syncthreads();
        if (t == winner) ptr++;
        __syncthreads();
    }
    if (t == 0) {
        float m = win_s[0], den = 0.f;
        for (int k = 0; k < TOPK; k++) { wk[k] = expf(win_s[k] - m); den += wk[k]; }
        float inv = 1.f / den;
        for (int k = 0; k < TOPK; k++) wk[k] *= inv;
    }
    __syncthreads();
    float acc = 0.f;
    #pragma unroll
    for (int k = 0; k < TOPK; k++)
        acc = fmaf(wk[k], guf[(size_t)win_u[k] * DIM + t], acc);
    outp[1 + (size_t)b * DIM + t] = acc;
}

extern "C" void kernel_launch(void* const* d_in, const int* in_sizes, int n_in,
                              void* d_out, int out_size, void* d_ws, size_t ws_size,
                              hipStream_t stream) {
    (void)in_sizes; (void)n_in; (void)out_size;
    const int*   er      = (const int*)d_in[0];
    const int*   ec      = (const int*)d_in[1];
    const float* click   = (const float*)d_in[2];
    const float* favor   = (const float*)d_in[3];
    const float* consume = (const float*)d_in[4];
    const float* uid     = (const float*)d_in[5];
    const float* pid     = (const float*)d_in[6];
    const int*   uidx    = (const int*)d_in[7];
    const int*   pidx    = (const int*)d_in[8];
    const float* labels  = (const float*)d_in[9];
    const float* guf     = (const float*)d_in[10];
    const float* w3      = (const float*)d_in[11];
    const float* fw3     = (const float*)d_in[12];
    const float* Wuc     = (const float*)d_in[13];
    const float* Wpc     = (const float*)d_in[14];
    const float* Wufv    = (const float*)d_in[15];
    const float* Wpfv    = (const float*)d_in[16];
    const float* Wuco    = (const float*)d_in[17];
    const float* Wpco    = (const float*)d_in[18];
    const float* Wss     = (const float*)d_in[19];
    const float* bias    = (const float*)d_in[20];
    float* outp = (float*)d_out;

    char* ws = (char*)d_ws;
    size_t off = 0;
    auto carve = [&](size_t bytes) -> void* {
        off = (off + 255) & ~(size_t)255;
        void* p = ws + off;
        off += bytes;
        return p;
    };
    float* ufs = (float*)carve(4ll * 3 * BATCH * DIM);
    float* alt = (float*)carve(4ll * BATCH * NPOS);
    float* bst = (float*)carve(4ll * DIM * BATCH);
    int* rptr = (int*)carve(4 * (N_USERS + 1));
    int* cptr = (int*)carve(4 * (N_POIS + 1));
    int* cnts = (int*)carve(4 * (N_USERS + N_POIS));
    int* rcnt = cnts;
    int* ccnt = cnts + N_USERS;
    int* scanws = (int*)carve(4 * 2 * (RCH + CCH) + 4 * 64);
    int* rsum = scanws;
    int* csum = rsum + RCH;
    int* rbase = csum + CCH;
    int* cbase = rbase + RCH;
    float* losspart = (float*)carve(4 * (LOSS_BLOCKS + 7));
    int4* rpack = (int4*)carve(16ll * N_EDGES);
    int4* cpack = (int4*)carve(16ll * N_EDGES);
    unsigned short* pid_h = (unsigned short*)carve(2ll * N_POIS * DIM);
    unsigned short* utr0 = (unsigned short*)carve(2ll * N_USERS * DIM);
    unsigned short* ptr_h = (unsigned short*)carve(2ll * N_POIS * DIM);
    float* su  = (float*)carve(4ll * N_USERS * DIM);
    float* sp  = (float*)carve(4ll * N_POIS * DIM);
    float* idf = (float*)carve(4ll * N_USERS * DIM);
    float* pf = (float*)utr0;
    float* cand_s = su;
    int*   cand_i = (int*)(su + (size_t)NCHUNK * BATCH * TOPK);
    // idf_h = rpack base, 10.24 MB: rpack (8 MB) + head of cpack (2.24 MB).
    // INVARIANT: last reads of rpack (l2u3) and cpack (l2p3) precede idf_h write.
    _Float16* idf_h = (_Float16*)rpack;
    _Float16* bst_h = (_Float16*)bst;
    int* rord = (int*)su;
    int* cord = rord + N_EDGES;
    // tier-1 carves
    unsigned short* utr1 = (unsigned short*)carve(2ll * N_USERS * DIM);
    unsigned short* utr2 = (unsigned short*)carve(2ll * N_USERS * DIM);
    unsigned short* p1b1 = (unsigned short*)carve(2ll * N_POIS * DIM);
    unsigned short* p1b2 = (unsigned short*)carve(2ll * N_POIS * DIM);
    bool fused = (off <= ws_size);
    // tier-2 carves: per-channel su/sp (fp32-sized regions; tier-2 uses fp16 views)
    float* su1 = (float*)carve(4ll * N_USERS * DIM);
    float* su2 = (float*)carve(4ll * N_USERS * DIM);
    float* sp1 = (float*)carve(4ll * N_POIS * DIM);
    float* sp2 = (float*)carve(4ll * N_POIS * DIM);
    bool fused2 = (off <= ws_size);
    // tier-2 fp16 views of su/sp regions (each needs only half the carve)
    _Float16* su_h  = (_Float16*)su;
    _Float16* su1_h = (_Float16*)su1;
    _Float16* su2_h = (_Float16*)su2;
    _Float16* sp_h  = (_Float16*)sp;
    _Float16* sp1_h = (_Float16*)sp1;
    _Float16* sp2_h = (_Float16*)sp2;
    // tier-2 pf buffers: alias utr0/1/2 (dead after l2p3)
    float* pf0 = (float*)utr0;
    float* pf1 = (float*)utr1;
    float* pf2 = (float*)utr2;

    zero_kernel<<<(N_USERS + N_POIS + 255) / 256, 256, 0, stream>>>(
        (unsigned int*)cnts, N_USERS + N_POIS);
    cast_f16_kernel<<<(N_POIS * DIM / 2 + 255) / 256, 256, 0, stream>>>(pid, pid_h, N_POIS * DIM / 2);
    hist_kernel<<<(N_EDGES / 4 + 255) / 256, 256, 0, stream>>>(er, ec, rcnt, ccnt, rord, cord);
    dim3 sg2(RCH, 2);
    chunksum_kernel<<<sg2, 256, 0, stream>>>(rcnt, ccnt, rsum, csum);
    chunkscan_kernel<<<1, 128, 0, stream>>>(rsum, csum, rbase, cbase, rptr, cptr);
    scatterscan_kernel<<<sg2, 256, 0, stream>>>(rcnt, ccnt, rbase, cbase, rptr, cptr);
    fill_kernel<<<(N_EDGES / 4 + 255) / 256, 256, 0, stream>>>(
        er, ec, rptr, cptr, rord, cord, rpack, cpack, click, favor, consume);

    struct Ch { const float* Wu; const float* Wp; int wsel; int fsel; };
    Ch chs[3] = { { Wuc,  Wpc,  1, 2 },
                  { Wufv, Wpfv, 0, 0 },
                  { Wuco, Wpco, 2, 1 } };

    const int UGB = N_USERS / 64;                 // 625
    const int PGB = (N_POIS + 63) / 64;           // 313
    const int PW = N_POIS * 64 / 256;
    const int UW = N_USERS * 64 / 256;

    auto launch_spmm_poi = [&](int c, const unsigned short* src, unsigned short* raw,
                               const float* base, float* acc) {
        if (c == 0)      spmm_kernel<0><<<PW, 256, 0, stream>>>(cptr, cpack, src, raw, base, acc, N_POIS);
        else if (c == 1) spmm_kernel<1><<<PW, 256, 0, stream>>>(cptr, cpack, src, raw, base, acc, N_POIS);
        else             spmm_kernel<2><<<PW, 256, 0, stream>>>(cptr, cpack, src, raw, base, acc, N_POIS);
    };
    auto launch_spmm_usr = [&](int c, const unsigned short* src, unsigned short* raw,
                               const float* base, float* acc) {
        if (c == 0)      spmm_kernel<0><<<UW, 256, 0, stream>>>(rptr, rpack, src, raw, base, acc, N_USERS);
        else if (c == 1) spmm_kernel<1><<<UW, 256, 0, stream>>>(rptr, rpack, src, raw, base, acc, N_USERS);
        else             spmm_kernel<2><<<UW, 256, 0, stream>>>(rptr, rpack, src, raw, base, acc, N_USERS);
    };
    auto launch_l2u = [&](int c, const unsigned short* src, unsigned short* u1raw) {
        if (c == 0)      spmm_l2u_kernel<0><<<UW, 256, 0, stream>>>(rptr, rpack, src, u1raw, uid, su, N_USERS);
        else if (c == 1) spmm_l2u_kernel<1><<<UW, 256, 0, stream>>>(rptr, rpack, src, u1raw, uid, su, N_USERS);
        else             spmm_l2u_kernel<2><<<UW, 256, 0, stream>>>(rptr, rpack, src, u1raw, uid, su, N_USERS);
    };
    auto launch_l2p = [&](int c, const unsigned short* src, const unsigned short* p1raw) {
        if (c == 0)      spmm_l2p_kernel<0><<<PW, 256, 0, stream>>>(cptr, cpack, src, p1raw, pid, sp, N_POIS);
        else if (c == 1) spmm_l2p_kernel<1><<<PW, 256, 0, stream>>>(cptr, cpack, src, p1raw, pid, sp, N_POIS);
        else             spmm_l2p_kernel<2><<<PW, 256, 0, stream>>>(cptr, cpack, src, p1raw, pid, sp, N_POIS);
    };

    if (fused2) {
        // tier-2: fully fused pipeline, fp16 su/sp
        spmm3_kernel<<<UW, 256, 0, stream>>>(rptr, rpack, pid_h, utr0, utr1, utr2, N_USERS);
        spmm3p_kernel<<<PW, 256, 0, stream>>>(cptr, cpack, utr0, utr1, utr2,
                                              ptr_h, p1b1, p1b2, N_POIS);
        spmm_l2u3_kernel<<<UW, 256, 0, stream>>>(rptr, rpack, ptr_h, p1b1, p1b2,
                                                 utr0, utr1, utr2, uid,
                                                 su_h, su1_h, su2_h, N_USERS);
        spmm_l2p3_kernel<<<PW, 256, 0, stream>>>(cptr, cpack, utr0, utr1, utr2,
                                                 ptr_h, p1b1, p1b2, pid,
                                                 sp_h, sp1_h, sp2_h, N_POIS);
        gemm_mfma3u_kernel<<<UGB, 256, 0, stream>>>(
            su_h, su1_h, su2_h, Wuc, Wufv, Wuco, idf, idf_h, fw3, N_USERS);
        dim3 ug(BATCH, 3);
        ufsel3_kernel<<<ug, 128, 0, stream>>>(su_h, su1_h, su2_h, Wuc, Wufv, Wuco, uidx, ufs);
        dim3 pg(PGB, 3);
        gemm_poi3_kernel<<<pg, 256, 0, stream>>>(sp_h, sp1_h, sp2_h, Wpc, Wpfv, Wpco,
                                                 pf0, pf1, pf2, N_POIS);
        predict3_kernel<<<BATCH * NPOS * 64 / 256, 256, 0, stream>>>(
            ufs, pf0, pf1, pf2, pidx, w3, alt);
    } else if (fused) {
        // tier-1: round-11 proven schedule (fp32 su/sp)
        spmm3_kernel<<<UW, 256, 0, stream>>>(rptr, rpack, pid_h, utr0, utr1, utr2, N_USERS);
        spmm3p_kernel<<<PW, 256, 0, stream>>>(cptr, cpack, utr0, utr1, utr2,
                                              ptr_h, p1b1, p1b2, N_POIS);
        unsigned short* p1b[3] = { ptr_h, p1b1, p1b2 };
        unsigned short* utr[3] = { utr0, utr1, utr2 };
        for (int c = 0; c < 3; c++) {
            launch_l2u(c, p1b[c], utr[c]);
            launch_l2p(c, utr[c], p1b[c]);
            gemm_mfma_kernel<<<UGB, 256, 0, stream>>>(
                su, chs[c].Wu, nullptr, idf, (c == 2) ? idf_h : nullptr,
                fw3, chs[c].fsel, (c == 0) ? 1 : 0, N_USERS);
            ufsel_kernel<<<BATCH, 128, 0, stream>>>(su, chs[c].Wu, uidx, ufs + (size_t)c * BATCH * DIM);
            gemm_mfma_kernel<<<PGB, 256, 0, stream>>>(
                sp, chs[c].Wp, pf, nullptr, nullptr, fw3, 0, 0, N_POIS);
            predict_kernel<<<BATCH * NPOS * 64 / 256, 256, 0, stream>>>(
                ufs + (size_t)c * BATCH * DIM, pf, pidx, w3, chs[c].wsel, (c == 0) ? 1 : 0, alt);
        }
    } else {
        // fallback: per-channel schedule
        for (int c = 0; c < 3; c++) {
            launch_spmm_usr(c, pid_h, utr0, uid, su);
            launch_spmm_poi(c, utr0, ptr_h, pid, sp);
            launch_spmm_usr(c, ptr_h, utr0, su, su);
            launch_spmm_poi(c, utr0, ptr_h, sp, sp);
            gemm_mfma_kernel<<<UGB, 256, 0, stream>>>(
                su, chs[c].Wu, nullptr, idf, (c == 2) ? idf_h : nullptr,
                fw3, chs[c].fsel, (c == 0) ? 1 : 0, N_USERS);
            ufsel_kernel<<<BATCH, 128, 0, stream>>>(su, chs[c].Wu, uidx, ufs + (size_t)c * BATCH * DIM);
            gemm_mfma_kernel<<<PGB, 256, 0, stream>>>(
                sp, chs[c].Wp, pf, nullptr, nullptr, fw3, 0, 0, N_POIS);
            predict_kernel<<<BATCH * NPOS * 64 / 256, 256, 0, stream>>>(
                ufs + (size_t)c * BATCH * DIM, pf, pidx, w3, chs[c].wsel, (c == 0) ? 1 : 0, alt);
        }
    }

    loss_part_kernel<<<LOSS_BLOCKS, 256, 0, stream>>>(alt, labels, losspart);
    loss_final_kernel<<<1, 64, 0, stream>>>(losspart, outp);
    bs_kernel<<<BATCH, 128, 0, stream>>>(idf, Wss, bias, uidx, bst_h);
    dim3 sg(NCHUNK, 4);
    score_topk_kernel<<<sg, 512, 0, stream>>>(idf_h, bst_h, cand_s, cand_i);
    topk_merge_kernel<<<BATCH, NCHUNK, 0, stream>>>(cand_s, cand_i, guf, outp);
}